// Round 3
// baseline (4523.123 us; speedup 1.0000x reference)
//
#include <hip/hip_runtime.h>
#include <cfloat>
#include <math.h>

#define NPTS 2048
#define RTOT 4096   // B*N = 2*2048

// ---------------- prep: derived weight matrices ----------------
__global__ __launch_bounds__(256) void prep_weights(
    const float* __restrict__ conv1, const float* __restrict__ conv2,
    const float* __restrict__ a1w1, const float* __restrict__ a1w2,
    const float* __restrict__ a2w1, const float* __restrict__ a2w2,
    const float* __restrict__ gw2,
    float* __restrict__ dwA1, float* __restrict__ a1w2r,
    float* __restrict__ dwA2, float* __restrict__ a2w2r,
    float* __restrict__ gw2r, float* __restrict__ dwC1, float* __restrict__ dwC2)
{
  int i = blockIdx.x * 256 + threadIdx.x;
  if (i < 512*128) {
    int row = i >> 7, c = i & 127;
    float v1, v2;
    if (row < 128) {             // ctrW[o][c] = sum_t (w1[o,c,t] - w1[o,128+c,t])
      float s1 = 0.f, s2 = 0.f;
      for (int t = 0; t < 3; t++) {
        s1 += a1w1[(row*256 + c)*3 + t] - a1w1[(row*256 + 128 + c)*3 + t];
        s2 += a2w1[(row*256 + c)*3 + t] - a2w1[(row*256 + 128 + c)*3 + t];
      }
      v1 = s1; v2 = s2;
    } else {                     // row = 128 + t*128 + o : nbW_t[o][c] = w1[o,128+c,t]
      int t = (row - 128) >> 7, o = row & 127;
      v1 = a1w1[(o*256 + 128 + c)*3 + t];
      v2 = a2w1[(o*256 + 128 + c)*3 + t];
    }
    dwA1[i] = v1; dwA2[i] = v2;
    // dwC2 [512][128] from conv2 [256][256] (feats = x1o, C=128)
    dwC2[i] = (row < 256) ? (conv2[row*256 + c] - conv2[row*256 + 128 + c])
                          : conv2[(row-256)*256 + 128 + c];
  }
  if (i < 128*384) {             // w2r[o][w*128+c] = w2[o,c,w]
    int o = i / 384, rem = i % 384, w = rem >> 7, c = rem & 127;
    a1w2r[i] = a1w2[(o*128 + c)*3 + w];
    a2w2r[i] = a2w2[(o*128 + c)*3 + w];
    gw2r[i]  = gw2[(o*128 + c)*3 + w];
  }
  if (i < 256*128) {             // dwC1 [256][128] from conv1 [128][256]
    int row = i >> 7, c = i & 127;
    dwC1[i] = (row < 128) ? (conv1[row*256 + c] - conv1[row*256 + 128 + c])
                          : conv1[(row-128)*256 + 128 + c];
  }
}

// ---------------- transpose [b][I][J] -> [b][J][I] ----------------
__global__ void transpose_k(const float* __restrict__ in, float* __restrict__ out, int I, int J) {
  __shared__ float tile[32][33];
  int b = blockIdx.z;
  int i0 = blockIdx.y * 32, j0 = blockIdx.x * 32;
  int tx = threadIdx.x, ty = threadIdx.y;   // block (32,8)
  for (int s = 0; s < 32; s += 8)
    tile[ty + s][tx] = in[((size_t)b*I + (i0 + ty + s))*J + (j0 + tx)];
  __syncthreads();
  for (int s = 0; s < 32; s += 8)
    out[((size_t)b*J + (j0 + ty + s))*I + (i0 + tx)] = tile[tx][ty + s];
}

// ---------------- KNN: f32 distances EXACTLY as np computes them, (dist,idx)-lex order ----------------
__global__ __launch_bounds__(256) void knn_kernel(const float* __restrict__ P,
                                                  int* __restrict__ idx, float* __restrict__ cosv) {
  __shared__ float px[NPTS], py[NPTS], sq[NPTS];
  int tid = threadIdx.x;
  int gw = blockIdx.x * 4 + (tid >> 6);   // wave id = b*2048 + n
  int b = gw >> 11, n = gw & 2047;
  int lane = tid & 63;
  const float* Pb = P + (size_t)b * 2 * NPTS;
  for (int i = tid; i < NPTS; i += 256) {
    float x = Pb[i], y = Pb[NPTS + i];
    px[i] = x; py[i] = y;
    sq[i] = __fadd_rn(__fmul_rn(x, x), __fmul_rn(y, y));   // np: (pts**2).sum(-1), f32, no fma
  }
  __syncthreads();
  float xn = px[n], yn = py[n], sqn = sq[n];
  float d[10]; int id_[10];
#pragma unroll
  for (int j = 0; j < 10; j++) { d[j] = FLT_MAX; id_[j] = 0x7fffffff; }
  for (int m = lane; m < NPTS; m += 64) {
    // np: dist = sq[n] + sq[m] - 2.0*dot, all f32 ops, einsum dot = x*x' + y*y' (no fma)
    float dot  = __fadd_rn(__fmul_rn(xn, px[m]), __fmul_rn(yn, py[m]));
    float dist = __fsub_rn(__fadd_rn(sqn, sq[m]), __fmul_rn(2.0f, dot));
    dist = fmaxf(dist, 1e-12f);
    if (dist < d[9] || (dist == d[9] && m < id_[9])) {
      int p = 0;
#pragma unroll
      for (int j = 0; j < 10; j++) p += (d[j] < dist || (d[j] == dist && id_[j] < m)) ? 1 : 0;
#pragma unroll
      for (int j = 9; j >= 1; j--) if (j > p) { d[j] = d[j-1]; id_[j] = id_[j-1]; }
#pragma unroll
      for (int j = 0; j < 10; j++) if (j == p) { d[j] = dist; id_[j] = m; }
    }
  }
  int ptr = 0;
  for (int r = 0; r < 10; r++) {
    float bd = FLT_MAX; int bi = 0x7fffffff;
#pragma unroll
    for (int j = 0; j < 10; j++) if (j == ptr) { bd = d[j]; bi = id_[j]; }
    for (int off = 32; off >= 1; off >>= 1) {
      float od = __shfl_xor(bd, off);
      int   oi = __shfl_xor(bi, off);
      if (od < bd || (od == bd && oi < bi)) { bd = od; bi = oi; }
    }
    bool adv = false;
#pragma unroll
    for (int j = 0; j < 10; j++) if (j == ptr) adv = (d[j] == bd && id_[j] == bi);
    if (adv) ptr++;
    if (r > 0 && lane == 0) {
      size_t base = ((size_t)b*NPTS + n)*9 + (r - 1);
      idx[base] = bi;
      float dot = __fadd_rn(__fmul_rn(xn, px[bi]), __fmul_rn(yn, py[bi]));
      cosv[base] = __fdiv_rn(dot, __fmul_rn(__fsqrt_rn(sqn), __fsqrt_rn(sq[bi])));
    }
  }
}

// ---------------- generic f32 GEMM: Y[4096][O] = X[4096][Cin] * W[O][Cin]^T + bias ----------------
__global__ __launch_bounds__(256) void gemm_nc(const float* __restrict__ X, const float* __restrict__ W,
                                               const float* __restrict__ bias, float* __restrict__ Y,
                                               int Cin, int O) {
  __shared__ float Xs[64][36], Ws[64][36];
  int tid = threadIdx.x;
  int r0 = blockIdx.x * 64, c0 = blockIdx.y * 64;
  int tx = tid & 15, ty = tid >> 4;
  float acc[4][4] = {};
  for (int k0 = 0; k0 < Cin; k0 += 32) {
    int e = tid * 8, row = e >> 5, col = e & 31;
    {
      const float4* s = (const float4*)(X + (size_t)(r0 + row)*Cin + k0 + col);
      float4 v0 = s[0], v1 = s[1];
      Xs[row][col+0]=v0.x; Xs[row][col+1]=v0.y; Xs[row][col+2]=v0.z; Xs[row][col+3]=v0.w;
      Xs[row][col+4]=v1.x; Xs[row][col+5]=v1.y; Xs[row][col+6]=v1.z; Xs[row][col+7]=v1.w;
    }
    {
      const float4* s = (const float4*)(W + (size_t)(c0 + row)*Cin + k0 + col);
      float4 v0 = s[0], v1 = s[1];
      Ws[row][col+0]=v0.x; Ws[row][col+1]=v0.y; Ws[row][col+2]=v0.z; Ws[row][col+3]=v0.w;
      Ws[row][col+4]=v1.x; Ws[row][col+5]=v1.y; Ws[row][col+6]=v1.z; Ws[row][col+7]=v1.w;
    }
    __syncthreads();
#pragma unroll
    for (int kk = 0; kk < 32; kk++) {
      float av[4], bv[4];
#pragma unroll
      for (int i = 0; i < 4; i++) { av[i] = Xs[ty*4+i][kk]; bv[i] = Ws[tx*4+i][kk]; }
#pragma unroll
      for (int i = 0; i < 4; i++)
#pragma unroll
        for (int j = 0; j < 4; j++) acc[i][j] = fmaf(av[i], bv[j], acc[i][j]);
    }
    __syncthreads();
  }
#pragma unroll
  for (int i = 0; i < 4; i++) {
    int r = r0 + ty*4 + i;
#pragma unroll
    for (int j = 0; j < 4; j++) {
      int c = c0 + tx*4 + j;
      float v = acc[i][j] + (bias ? bias[c] : 0.f);
      Y[(size_t)r*O + c] = v;
    }
  }
}

// ---------------- annu conv1 combine: A[r][w*128+o] = G0 + sum_t Hnb + b1 ----------------
__global__ __launch_bounds__(384) void combine_annu(const float* __restrict__ GA, const int* __restrict__ idx,
                                                    const float* __restrict__ b1, float* __restrict__ A) {
  int r = blockIdx.x, t = threadIdx.x;
  int w = t >> 7, o = t & 127;
  int rb = r & ~2047;
  __shared__ int nb[9];
  if (t < 9) nb[t] = idx[(size_t)r*9 + t];
  __syncthreads();
  float acc = GA[(size_t)r*512 + o] + b1[o];
#pragma unroll
  for (int t3 = 0; t3 < 3; t3++) {
    int m = nb[w*3 + t3];
    acc += GA[(size_t)(rb + m)*512 + 128 + t3*128 + o];
  }
  A[(size_t)r*384 + w*128 + o] = acc;
}

// ---------------- instance-norm stats (two stage, f64 accumulation) ----------------
__global__ __launch_bounds__(256) void stats_partial(const float* __restrict__ X, double* __restrict__ part,
                                                     int J, int Cc) {
  int t = threadIdx.x;
  int o = t % Cc, sub = t / Cc, nsub = 256 / Cc;
  int r0 = blockIdx.x * 64;
  double s = 0.0, s2 = 0.0;
  for (int rr = sub; rr < 64; rr += nsub)
    for (int j = 0; j < J; j++) {
      double v = X[(((size_t)(r0 + rr))*J + j)*Cc + o];
      s += v; s2 += v*v;
    }
  __shared__ double ls[256], ls2[256];
  ls[t] = s; ls2[t] = s2;
  __syncthreads();
  if (sub == 0) {
    for (int u = 1; u < nsub; u++) { s += ls[u*Cc + o]; s2 += ls2[u*Cc + o]; }
    part[((size_t)blockIdx.x*Cc + o)*2] = s;
    part[((size_t)blockIdx.x*Cc + o)*2 + 1] = s2;
  }
}

__global__ void stats_final(const double* __restrict__ part, float* __restrict__ stats,
                            int Cc, int nblkPerB, int count) {
  int i = blockIdx.x * 256 + threadIdx.x;
  if (i >= 2*Cc) return;
  int b = i / Cc, o = i % Cc;
  double S = 0.0, S2 = 0.0;
  for (int u = 0; u < nblkPerB; u++) {
    int blk = b*nblkPerB + u;
    S  += part[((size_t)blk*Cc + o)*2];
    S2 += part[((size_t)blk*Cc + o)*2 + 1];
  }
  double mean = S / count;
  double var = S2 / count - mean*mean;
  if (var < 0.0) var = 0.0;
  stats[i*2] = (float)mean;
  stats[i*2 + 1] = (float)(1.0 / sqrt(var + 1e-5));
}

// act: 0 none, 1 relu, 2 lrelu(0.2)
__global__ void norm_act(const float* __restrict__ src, float* __restrict__ dst,
                         const float* __restrict__ stats, int J, int Cc, int act, int total) {
  int i = blockIdx.x * 256 + threadIdx.x;
  if (i >= total) return;
  int o = i % Cc;
  int r = i / (J*Cc);
  int b = r >> 11;
  float m = stats[(b*Cc + o)*2], rs = stats[(b*Cc + o)*2 + 1];
  float v = (src[i] - m) * rs;
  if (act == 1) v = fmaxf(v, 0.f);
  else if (act == 2) v = (v >= 0.f) ? v : 0.2f*v;
  dst[i] = v;
}

// ---------------- angle-feature conv1 ----------------
__global__ void cos_conv(const float* __restrict__ cosv, const float* __restrict__ gw1,
                         const float* __restrict__ gb1, float* __restrict__ ANG, int total) {
  int i = blockIdx.x * 256 + threadIdx.x;
  if (i >= total) return;
  int o = i & 127, w = (i >> 7) % 3;
  int r = i / 384;
  float acc = gb1[o];
#pragma unroll
  for (int t = 0; t < 3; t++) acc += cosv[(size_t)r*9 + w*3 + t] * gw1[o*3 + t];
  ANG[i] = acc;
}

// ---------------- gather + max over k + stats partials (x1o/x2o path, f64 stats) ----------------
__global__ __launch_bounds__(256) void gather_max_partial(const float* __restrict__ G, const int* __restrict__ idx,
                                                          float* __restrict__ maxbuf, double* __restrict__ part, int Cc) {
  int t = threadIdx.x;
  int o = t % Cc, sub = t / Cc, nsub = 256 / Cc;
  int r0 = blockIdx.x * 16;
  double s = 0.0, s2 = 0.0;
  for (int rr = sub; rr < 16; rr += nsub) {
    int r = r0 + rr, rb = r & ~2047;
    float g = G[(size_t)r*2*Cc + o];
    float mx = -3.4e38f;
#pragma unroll
    for (int k = 0; k < 9; k++) {
      int m = idx[(size_t)r*9 + k];
      float v = g + G[(size_t)(rb + m)*2*Cc + Cc + o];
      mx = fmaxf(mx, v); s += (double)v; s2 += (double)v*(double)v;
    }
    maxbuf[(size_t)r*Cc + o] = mx;
  }
  __shared__ double ls[256], ls2[256];
  ls[t] = s; ls2[t] = s2;
  __syncthreads();
  if (sub == 0) {
    for (int u = 1; u < nsub; u++) { s += ls[u*Cc + o]; s2 += ls2[u*Cc + o]; }
    part[((size_t)blockIdx.x*Cc + o)*2] = s;
    part[((size_t)blockIdx.x*Cc + o)*2 + 1] = s2;
  }
}

// ---------------- concats / add ----------------
__global__ void cat3(const float* __restrict__ x0, const float* __restrict__ x1, const float* __restrict__ fg,
                     const float* __restrict__ x2, float* __restrict__ out, int total) {
  int i = blockIdx.x * 256 + threadIdx.x;
  if (i >= total) return;
  int c = i % 384; int r = i / 384;
  float v;
  if (c < 128) v = x0[(size_t)r*128 + c];
  else if (c < 256) v = x1[(size_t)r*128 + c - 128] + fg[(size_t)r*128 + c - 128];
  else v = x2[(size_t)r*128 + c - 256] + fg[(size_t)r*128 + c - 256];
  out[i] = v;
}

__global__ void cat3b(const float* __restrict__ x0, const float* __restrict__ x1o, const float* __restrict__ x2o,
                      float* __restrict__ out, int total) {
  int i = blockIdx.x * 256 + threadIdx.x;
  if (i >= total) return;
  int c = i % 512; int r = i / 512;
  float v;
  if (c < 128) v = x0[(size_t)r*128 + c];
  else if (c < 256) v = x1o[(size_t)r*128 + c - 128];
  else v = x2o[(size_t)r*256 + c - 256];
  out[i] = v;
}

__global__ void cat2(const float* __restrict__ a, const float* __restrict__ b, float* __restrict__ out, int total) {
  int i = blockIdx.x * 256 + threadIdx.x;
  if (i >= total) return;
  int c = i % 256; int r = i / 256;
  out[i] = (c < 128) ? a[(size_t)r*128 + c] : b[(size_t)r*128 + c - 128];
}

__global__ void add2(const float* __restrict__ a, const float* __restrict__ b, float* __restrict__ out, int n) {
  int i = blockIdx.x * 256 + threadIdx.x;
  if (i >= n) return;
  out[i] = a[i] + b[i];
}

// ---------------- head pack: [r][c=d*4+h] -> [b][h][n][d] ----------------
__global__ void pack_heads(const float* __restrict__ src, float* __restrict__ dst) {
  int i = blockIdx.x * 256 + threadIdx.x;
  if (i >= RTOT*128) return;
  int d = i & 31, n = (i >> 5) & 2047, h = (i >> 16) & 3, b = i >> 18;
  dst[i] = src[((size_t)(b*NPTS + n))*128 + d*4 + h];
}

// ---------------- attention: wave per (b,h,n) row ----------------
__global__ __launch_bounds__(256) void attn_row(const float* __restrict__ Qp, const float* __restrict__ Kp,
                                                const float* __restrict__ Vp, float* __restrict__ out) {
  __shared__ float srow[4][NPTS];
  __shared__ float qs[4][32];
  int tid = threadIdx.x, wv = tid >> 6, lane = tid & 63;
  int gw = blockIdx.x * 4 + wv;       // 0..16383
  int bh = gw >> 11;                  // b*4 + h
  int n = gw & 2047;
  const float* Kh = Kp + (size_t)bh * NPTS * 32;
  const float* Vh = Vp + (size_t)bh * NPTS * 32;
  if (lane < 32) qs[wv][lane] = Qp[((size_t)bh*NPTS + n)*32 + lane];
  __syncthreads();
  float mx = -3.4e38f;
  for (int mi = lane; mi < NPTS; mi += 64) {
    const float* kr = Kh + (size_t)mi*32;
    float s = 0.f;
#pragma unroll
    for (int dd = 0; dd < 32; dd++) s = fmaf(qs[wv][dd], kr[dd], s);
    s *= 0.17677669529663687f;   // 1/sqrt(32)
    srow[wv][mi] = s;
    mx = fmaxf(mx, s);
  }
  for (int off = 32; off >= 1; off >>= 1) mx = fmaxf(mx, __shfl_xor(mx, off));
  float sum = 0.f;
  for (int mi = lane; mi < NPTS; mi += 64) {
    float p = expf(srow[wv][mi] - mx);
    srow[wv][mi] = p;
    sum += p;
  }
  for (int off = 32; off >= 1; off >>= 1) sum += __shfl_xor(sum, off);
  __syncthreads();
  int d = lane & 31, half = lane >> 5;
  float acc = 0.f;
  for (int m = half; m < NPTS; m += 2) acc = fmaf(srow[wv][m], Vh[(size_t)m*32 + d], acc);
  acc += __shfl_xor(acc, 32);
  if (lane < 32) {
    int b = bh >> 2, h = bh & 3;
    out[((size_t)(b*NPTS + n))*128 + d*4 + h] = acc / sum;
  }
}

// ================= host =================
extern "C" void kernel_launch(void* const* d_in, const int* in_sizes, int n_in,
                              void* d_out, int out_size, void* d_ws, size_t ws_size,
                              hipStream_t stream) {
  (void)in_sizes; (void)n_in; (void)out_size; (void)ws_size;
  const float* desc0  = (const float*)d_in[0];
  const float* desc1  = (const float*)d_in[1];
  const float* coords0= (const float*)d_in[2];
  const float* coords1= (const float*)d_in[3];
  const float* conv1w = (const float*)d_in[4];
  const float* conv2w = (const float*)d_in[5];
  const float* conv3w = (const float*)d_in[6];
  const float* conv3ow= (const float*)d_in[7];
  const float* a1w1 = (const float*)d_in[8];
  const float* a1b1 = (const float*)d_in[9];
  const float* a1w2 = (const float*)d_in[10];
  const float* a1b2 = (const float*)d_in[11];
  const float* a2w1 = (const float*)d_in[12];
  const float* a2b1 = (const float*)d_in[13];
  const float* a2w2 = (const float*)d_in[14];
  const float* a2b2 = (const float*)d_in[15];
  const float* gw1  = (const float*)d_in[16];
  const float* gb1  = (const float*)d_in[17];
  const float* gw2  = (const float*)d_in[18];
  const float* gb2  = (const float*)d_in[19];
  const float* wq = (const float*)d_in[20]; const float* bq = (const float*)d_in[21];
  const float* wk = (const float*)d_in[22]; const float* bk = (const float*)d_in[23];
  const float* wv = (const float*)d_in[24]; const float* bv = (const float*)d_in[25];
  const float* wm = (const float*)d_in[26]; const float* bm = (const float*)d_in[27];
  const float* mw1 = (const float*)d_in[28]; const float* mb1 = (const float*)d_in[29];
  const float* mw2 = (const float*)d_in[30]; const float* mb2 = (const float*)d_in[31];

  float* ws = (float*)d_ws;
  size_t off = 0;
  auto alloc = [&](size_t nel) { size_t r = off; off += (nel + 63) & ~(size_t)63; return r; };
  float* DW_A1 = ws + alloc(512*128);
  float* W_A1R = ws + alloc(128*384);
  float* DW_A2 = ws + alloc(512*128);
  float* W_A2R = ws + alloc(128*384);
  float* W_G2R = ws + alloc(128*384);
  float* DW_C1 = ws + alloc(256*128);
  float* DW_C2 = ws + alloc(512*128);
  float* SA0  = ws + alloc((size_t)RTOT*128);
  float* SA1  = ws + alloc((size_t)RTOT*128);
  float* XF0  = ws + alloc((size_t)RTOT*128);
  float* XF1  = ws + alloc((size_t)RTOT*128);
  int*   IDX  = (int*)(ws + alloc((size_t)RTOT*9));
  float* COSV = ws + alloc((size_t)RTOT*9);
  float* FT   = ws + alloc((size_t)RTOT*128);
  float* BIG  = ws + alloc((size_t)RTOT*512);
  float* ABUF = ws + alloc((size_t)RTOT*384);
  float* X1B  = ws + alloc((size_t)RTOT*128);
  float* FANG = ws + alloc((size_t)RTOT*128);
  float* X2B  = ws + alloc((size_t)RTOT*128);
  float* X3A  = ws + alloc((size_t)RTOT*128);
  float* X1O  = ws + alloc((size_t)RTOT*128);
  float* SM   = ws + alloc((size_t)RTOT*256);
  float* X3O  = ws + alloc((size_t)RTOT*128);
  double* PART = (double*)(ws + alloc(256*256*2*2));   // 131072 doubles
  float* STAT = ws + alloc(2*256*2);

  auto statnorm = [&](float* buf, int J, int Cc, int act, int count) {
    stats_partial<<<64, 256, 0, stream>>>(buf, PART, J, Cc);
    stats_final<<<2, 256, 0, stream>>>(PART, STAT, Cc, 32, count);
    int tot = RTOT*J*Cc;
    norm_act<<<(tot + 255)/256, 256, 0, stream>>>(buf, buf, STAT, J, Cc, act, tot);
  };
  auto gathermax = [&](float* G, float* mx, float* dstNorm, int Cc) {
    gather_max_partial<<<256, 256, 0, stream>>>(G, IDX, mx, PART, Cc);
    stats_final<<<2, 256, 0, stream>>>(PART, STAT, Cc, 128, 2048*9);
    int tot = RTOT*Cc;
    norm_act<<<(tot + 255)/256, 256, 0, stream>>>(mx, dstNorm, STAT, 1, Cc, 2, tot);
  };

  prep_weights<<<256, 256, 0, stream>>>(conv1w, conv2w, a1w1, a1w2, a2w1, a2w2, gw2,
                                        DW_A1, W_A1R, DW_A2, W_A2R, W_G2R, DW_C1, DW_C2);

  auto branch = [&](const float* F, const float* P, float* sa) {
    transpose_k<<<dim3(2048/32, 128/32, 2), dim3(32, 8), 0, stream>>>(F, FT, 128, 2048);
    knn_kernel<<<1024, 256, 0, stream>>>(P, IDX, COSV);
    // annu1 on graph feature of F
    gemm_nc<<<dim3(64, 8), 256, 0, stream>>>(FT, DW_A1, nullptr, BIG, 128, 512);
    combine_annu<<<RTOT, 384, 0, stream>>>(BIG, IDX, a1b1, ABUF);
    statnorm(ABUF, 3, 128, 1, 2048*3);
    gemm_nc<<<dim3(64, 2), 256, 0, stream>>>(ABUF, W_A1R, a1b2, X1B, 384, 128);
    statnorm(X1B, 1, 128, 1, 2048);
    // f_ang (shared by both uses since idx1 == idx2)
    cos_conv<<<(RTOT*384 + 255)/256, 256, 0, stream>>>(COSV, gw1, gb1, ABUF, RTOT*384);
    statnorm(ABUF, 3, 128, 1, 2048*3);
    gemm_nc<<<dim3(64, 2), 256, 0, stream>>>(ABUF, W_G2R, gb2, FANG, 384, 128);
    statnorm(FANG, 1, 128, 1, 2048);
    // annu2 on graph feature of x1
    gemm_nc<<<dim3(64, 8), 256, 0, stream>>>(X1B, DW_A2, nullptr, BIG, 128, 512);
    combine_annu<<<RTOT, 384, 0, stream>>>(BIG, IDX, a2b1, ABUF);
    statnorm(ABUF, 3, 128, 1, 2048*3);
    gemm_nc<<<dim3(64, 2), 256, 0, stream>>>(ABUF, W_A2R, a2b2, X2B, 384, 128);
    statnorm(X2B, 1, 128, 1, 2048);
    // x3 = lrelu(inorm(conv3 * [x0, x1+fang, x2+fang]))
    cat3<<<(RTOT*384 + 255)/256, 256, 0, stream>>>(FT, X1B, FANG, X2B, ABUF, RTOT*384);
    gemm_nc<<<dim3(64, 2), 256, 0, stream>>>(ABUF, conv3w, nullptr, X3A, 384, 128);
    statnorm(X3A, 1, 128, 2, 2048);
    // x1o = max_k lrelu(inorm(conv1 * gf(F)))
    gemm_nc<<<dim3(64, 4), 256, 0, stream>>>(FT, DW_C1, nullptr, BIG, 128, 256);
    gathermax(BIG, SM, X1O, 128);
    // x2o = max_k lrelu(inorm(conv2 * gf(x1o)))
    gemm_nc<<<dim3(64, 8), 256, 0, stream>>>(X1O, DW_C2, nullptr, BIG, 128, 512);
    gathermax(BIG, SM, SM, 256);
    // x3o
    cat3b<<<(RTOT*512 + 255)/256, 256, 0, stream>>>(FT, X1O, SM, BIG, RTOT*512);
    gemm_nc<<<dim3(64, 2), 256, 0, stream>>>(BIG, conv3ow, nullptr, X3O, 512, 128);
    statnorm(X3O, 1, 128, 2, 2048);
    add2<<<(RTOT*128 + 255)/256, 256, 0, stream>>>(X3A, X3O, sa, RTOT*128);
  };

  branch(desc0, coords0, SA0);
  branch(desc1, coords1, SA1);

  auto prop = [&](const float* xin, const float* src, float* dst) {
    gemm_nc<<<dim3(64, 2), 256, 0, stream>>>(xin, wq, bq, X1B, 128, 128);
    gemm_nc<<<dim3(64, 2), 256, 0, stream>>>(src, wk, bk, FANG, 128, 128);
    gemm_nc<<<dim3(64, 2), 256, 0, stream>>>(src, wv, bv, X2B, 128, 128);
    pack_heads<<<(RTOT*128 + 255)/256, 256, 0, stream>>>(X1B, X3A);
    pack_heads<<<(RTOT*128 + 255)/256, 256, 0, stream>>>(FANG, X1O);
    pack_heads<<<(RTOT*128 + 255)/256, 256, 0, stream>>>(X2B, X3O);
    attn_row<<<4096, 256, 0, stream>>>(X3A, X1O, X3O, ABUF);
    gemm_nc<<<dim3(64, 2), 256, 0, stream>>>(ABUF, wm, bm, SM, 128, 128);
    cat2<<<(RTOT*256 + 255)/256, 256, 0, stream>>>(xin, SM, BIG, RTOT*256);
    gemm_nc<<<dim3(64, 4), 256, 0, stream>>>(BIG, mw1, mb1, ABUF, 256, 256);
    statnorm(ABUF, 1, 256, 1, 2048);
    gemm_nc<<<dim3(64, 2), 256, 0, stream>>>(ABUF, mw2, mb2, SM, 256, 128);
    add2<<<(RTOT*128 + 255)/256, 256, 0, stream>>>(xin, SM, dst, RTOT*128);
  };

  prop(SA0, SA1, XF0);
  prop(SA1, XF0, XF1);

  transpose_k<<<dim3(128/32, 2048/32, 2), dim3(32, 8), 0, stream>>>(XF0, (float*)d_out, 2048, 128);
  transpose_k<<<dim3(128/32, 2048/32, 2), dim3(32, 8), 0, stream>>>(XF1, (float*)d_out + (size_t)RTOT*128, 2048, 128);
}

// Round 4
// 2025.244 us; speedup vs baseline: 2.2334x; 2.2334x over previous
//
#include <hip/hip_runtime.h>
#include <cfloat>
#include <math.h>

#define NPTS 2048
#define RTOT 4096   // B*N = 2*2048

// ---------------- prep: derived weight matrices ----------------
__global__ __launch_bounds__(256) void prep_weights(
    const float* __restrict__ conv1, const float* __restrict__ conv2,
    const float* __restrict__ a1w1, const float* __restrict__ a1w2,
    const float* __restrict__ a2w1, const float* __restrict__ a2w2,
    const float* __restrict__ gw2,
    float* __restrict__ dwA1, float* __restrict__ a1w2r,
    float* __restrict__ dwA2, float* __restrict__ a2w2r,
    float* __restrict__ gw2r, float* __restrict__ dwC1, float* __restrict__ dwC2)
{
  int i = blockIdx.x * 256 + threadIdx.x;
  if (i < 512*128) {
    int row = i >> 7, c = i & 127;
    float v1, v2;
    if (row < 128) {             // ctrW[o][c] = sum_t (w1[o,c,t] - w1[o,128+c,t])
      float s1 = 0.f, s2 = 0.f;
      for (int t = 0; t < 3; t++) {
        s1 += a1w1[(row*256 + c)*3 + t] - a1w1[(row*256 + 128 + c)*3 + t];
        s2 += a2w1[(row*256 + c)*3 + t] - a2w1[(row*256 + 128 + c)*3 + t];
      }
      v1 = s1; v2 = s2;
    } else {                     // row = 128 + t*128 + o : nbW_t[o][c] = w1[o,128+c,t]
      int t = (row - 128) >> 7, o = row & 127;
      v1 = a1w1[(o*256 + 128 + c)*3 + t];
      v2 = a2w1[(o*256 + 128 + c)*3 + t];
    }
    dwA1[i] = v1; dwA2[i] = v2;
    // dwC2 [512][128] from conv2 [256][256] (feats = x1o, C=128)
    dwC2[i] = (row < 256) ? (conv2[row*256 + c] - conv2[row*256 + 128 + c])
                          : conv2[(row-256)*256 + 128 + c];
  }
  if (i < 128*384) {             // w2r[o][w*128+c] = w2[o,c,w]
    int o = i / 384, rem = i % 384, w = rem >> 7, c = rem & 127;
    a1w2r[i] = a1w2[(o*128 + c)*3 + w];
    a2w2r[i] = a2w2[(o*128 + c)*3 + w];
    gw2r[i]  = gw2[(o*128 + c)*3 + w];
  }
  if (i < 256*128) {             // dwC1 [256][128] from conv1 [128][256]
    int row = i >> 7, c = i & 127;
    dwC1[i] = (row < 128) ? (conv1[row*256 + c] - conv1[row*256 + 128 + c])
                          : conv1[(row-128)*256 + 128 + c];
  }
}

// ---------------- transpose [b][I][J] -> [b][J][I] ----------------
__global__ void transpose_k(const float* __restrict__ in, float* __restrict__ out, int I, int J) {
  __shared__ float tile[32][33];
  int b = blockIdx.z;
  int i0 = blockIdx.y * 32, j0 = blockIdx.x * 32;
  int tx = threadIdx.x, ty = threadIdx.y;   // block (32,8)
  for (int s = 0; s < 32; s += 8)
    tile[ty + s][tx] = in[((size_t)b*I + (i0 + ty + s))*J + (j0 + tx)];
  __syncthreads();
  for (int s = 0; s < 32; s += 8)
    out[((size_t)b*J + (j0 + ty + s))*I + (i0 + tx)] = tile[tx][ty + s];
}

// ---------------- KNN: f32 distances EXACTLY as np computes them, (dist,idx)-lex order ----------------
__global__ __launch_bounds__(256) void knn_kernel(const float* __restrict__ P,
                                                  int* __restrict__ idx, float* __restrict__ cosv) {
  __shared__ float px[NPTS], py[NPTS], sq[NPTS];
  int tid = threadIdx.x;
  int gw = blockIdx.x * 4 + (tid >> 6);   // wave id = b*2048 + n
  int b = gw >> 11, n = gw & 2047;
  int lane = tid & 63;
  const float* Pb = P + (size_t)b * 2 * NPTS;
  for (int i = tid; i < NPTS; i += 256) {
    float x = Pb[i], y = Pb[NPTS + i];
    px[i] = x; py[i] = y;
    sq[i] = __fadd_rn(__fmul_rn(x, x), __fmul_rn(y, y));   // np: (pts**2).sum(-1), f32, no fma
  }
  __syncthreads();
  float xn = px[n], yn = py[n], sqn = sq[n];
  float d[10]; int id_[10];
#pragma unroll
  for (int j = 0; j < 10; j++) { d[j] = FLT_MAX; id_[j] = 0x7fffffff; }
  for (int m = lane; m < NPTS; m += 64) {
    // np: dist = sq[n] + sq[m] - 2.0*dot, all f32 ops, einsum dot = x*x' + y*y' (no fma)
    float dot  = __fadd_rn(__fmul_rn(xn, px[m]), __fmul_rn(yn, py[m]));
    float dist = __fsub_rn(__fadd_rn(sqn, sq[m]), __fmul_rn(2.0f, dot));
    dist = fmaxf(dist, 1e-12f);
    if (dist < d[9] || (dist == d[9] && m < id_[9])) {
      int p = 0;
#pragma unroll
      for (int j = 0; j < 10; j++) p += (d[j] < dist || (d[j] == dist && id_[j] < m)) ? 1 : 0;
#pragma unroll
      for (int j = 9; j >= 1; j--) if (j > p) { d[j] = d[j-1]; id_[j] = id_[j-1]; }
#pragma unroll
      for (int j = 0; j < 10; j++) if (j == p) { d[j] = dist; id_[j] = m; }
    }
  }
  int ptr = 0;
  for (int r = 0; r < 10; r++) {
    float bd = FLT_MAX; int bi = 0x7fffffff;
#pragma unroll
    for (int j = 0; j < 10; j++) if (j == ptr) { bd = d[j]; bi = id_[j]; }
    for (int off = 32; off >= 1; off >>= 1) {
      float od = __shfl_xor(bd, off);
      int   oi = __shfl_xor(bi, off);
      if (od < bd || (od == bd && oi < bi)) { bd = od; bi = oi; }
    }
    bool adv = false;
#pragma unroll
    for (int j = 0; j < 10; j++) if (j == ptr) adv = (d[j] == bd && id_[j] == bi);
    if (adv) ptr++;
    if (r > 0 && lane == 0) {
      size_t base = ((size_t)b*NPTS + n)*9 + (r - 1);
      idx[base] = bi;
      float dot = __fadd_rn(__fmul_rn(xn, px[bi]), __fmul_rn(yn, py[bi]));
      cosv[base] = __fdiv_rn(dot, __fmul_rn(__fsqrt_rn(sqn), __fsqrt_rn(sq[bi])));
    }
  }
}

// ---------------- generic f32 GEMM: Y[4096][O] = X[4096][Cin] * W[O][Cin]^T + bias ----------------
__global__ __launch_bounds__(256) void gemm_nc(const float* __restrict__ X, const float* __restrict__ W,
                                               const float* __restrict__ bias, float* __restrict__ Y,
                                               int Cin, int O) {
  __shared__ float Xs[64][36], Ws[64][36];
  int tid = threadIdx.x;
  int r0 = blockIdx.x * 64, c0 = blockIdx.y * 64;
  int tx = tid & 15, ty = tid >> 4;
  float acc[4][4] = {};
  for (int k0 = 0; k0 < Cin; k0 += 32) {
    int e = tid * 8, row = e >> 5, col = e & 31;
    {
      const float4* s = (const float4*)(X + (size_t)(r0 + row)*Cin + k0 + col);
      float4 v0 = s[0], v1 = s[1];
      Xs[row][col+0]=v0.x; Xs[row][col+1]=v0.y; Xs[row][col+2]=v0.z; Xs[row][col+3]=v0.w;
      Xs[row][col+4]=v1.x; Xs[row][col+5]=v1.y; Xs[row][col+6]=v1.z; Xs[row][col+7]=v1.w;
    }
    {
      const float4* s = (const float4*)(W + (size_t)(c0 + row)*Cin + k0 + col);
      float4 v0 = s[0], v1 = s[1];
      Ws[row][col+0]=v0.x; Ws[row][col+1]=v0.y; Ws[row][col+2]=v0.z; Ws[row][col+3]=v0.w;
      Ws[row][col+4]=v1.x; Ws[row][col+5]=v1.y; Ws[row][col+6]=v1.z; Ws[row][col+7]=v1.w;
    }
    __syncthreads();
#pragma unroll
    for (int kk = 0; kk < 32; kk++) {
      float av[4], bv[4];
#pragma unroll
      for (int i = 0; i < 4; i++) { av[i] = Xs[ty*4+i][kk]; bv[i] = Ws[tx*4+i][kk]; }
#pragma unroll
      for (int i = 0; i < 4; i++)
#pragma unroll
        for (int j = 0; j < 4; j++) acc[i][j] = fmaf(av[i], bv[j], acc[i][j]);
    }
    __syncthreads();
  }
#pragma unroll
  for (int i = 0; i < 4; i++) {
    int r = r0 + ty*4 + i;
#pragma unroll
    for (int j = 0; j < 4; j++) {
      int c = c0 + tx*4 + j;
      float v = acc[i][j] + (bias ? bias[c] : 0.f);
      Y[(size_t)r*O + c] = v;
    }
  }
}

// ---------------- annu conv1 combine: A[r][w*128+o] = G0 + sum_t Hnb + b1 ----------------
__global__ __launch_bounds__(384) void combine_annu(const float* __restrict__ GA, const int* __restrict__ idx,
                                                    const float* __restrict__ b1, float* __restrict__ A) {
  int r = blockIdx.x, t = threadIdx.x;
  int w = t >> 7, o = t & 127;
  int rb = r & ~2047;
  __shared__ int nb[9];
  if (t < 9) nb[t] = idx[(size_t)r*9 + t];
  __syncthreads();
  float acc = GA[(size_t)r*512 + o] + b1[o];
#pragma unroll
  for (int t3 = 0; t3 < 3; t3++) {
    int m = nb[w*3 + t3];
    acc += GA[(size_t)(rb + m)*512 + 128 + t3*128 + o];
  }
  A[(size_t)r*384 + w*128 + o] = acc;
}

// ---------------- instance-norm stats (two stage, f64 accumulation) ----------------
__global__ __launch_bounds__(256) void stats_partial(const float* __restrict__ X, double* __restrict__ part,
                                                     int J, int Cc) {
  int t = threadIdx.x;
  int o = t % Cc, sub = t / Cc, nsub = 256 / Cc;
  int r0 = blockIdx.x * 64;
  double s = 0.0, s2 = 0.0;
  for (int rr = sub; rr < 64; rr += nsub)
    for (int j = 0; j < J; j++) {
      double v = X[(((size_t)(r0 + rr))*J + j)*Cc + o];
      s += v; s2 += v*v;
    }
  __shared__ double ls[256], ls2[256];
  ls[t] = s; ls2[t] = s2;
  __syncthreads();
  if (sub == 0) {
    for (int u = 1; u < nsub; u++) { s += ls[u*Cc + o]; s2 += ls2[u*Cc + o]; }
    part[((size_t)blockIdx.x*Cc + o)*2] = s;
    part[((size_t)blockIdx.x*Cc + o)*2 + 1] = s2;
  }
}

__global__ void stats_final(const double* __restrict__ part, float* __restrict__ stats,
                            int Cc, int nblkPerB, int count) {
  int i = blockIdx.x * 256 + threadIdx.x;
  if (i >= 2*Cc) return;
  int b = i / Cc, o = i % Cc;
  double S = 0.0, S2 = 0.0;
  for (int u = 0; u < nblkPerB; u++) {
    int blk = b*nblkPerB + u;
    S  += part[((size_t)blk*Cc + o)*2];
    S2 += part[((size_t)blk*Cc + o)*2 + 1];
  }
  double mean = S / count;
  double var = S2 / count - mean*mean;
  if (var < 0.0) var = 0.0;
  stats[i*2] = (float)mean;
  stats[i*2 + 1] = (float)(1.0 / sqrt(var + 1e-5));
}

// act: 0 none, 1 relu, 2 lrelu(0.2)
__global__ void norm_act(const float* __restrict__ src, float* __restrict__ dst,
                         const float* __restrict__ stats, int J, int Cc, int act, int total) {
  int i = blockIdx.x * 256 + threadIdx.x;
  if (i >= total) return;
  int o = i % Cc;
  int r = i / (J*Cc);
  int b = r >> 11;
  float m = stats[(b*Cc + o)*2], rs = stats[(b*Cc + o)*2 + 1];
  float v = (src[i] - m) * rs;
  if (act == 1) v = fmaxf(v, 0.f);
  else if (act == 2) v = (v >= 0.f) ? v : 0.2f*v;
  dst[i] = v;
}

// ---------------- angle-feature conv1 ----------------
__global__ void cos_conv(const float* __restrict__ cosv, const float* __restrict__ gw1,
                         const float* __restrict__ gb1, float* __restrict__ ANG, int total) {
  int i = blockIdx.x * 256 + threadIdx.x;
  if (i >= total) return;
  int o = i & 127, w = (i >> 7) % 3;
  int r = i / 384;
  float acc = gb1[o];
#pragma unroll
  for (int t = 0; t < 3; t++) acc += cosv[(size_t)r*9 + w*3 + t] * gw1[o*3 + t];
  ANG[i] = acc;
}

// ---------------- gather + max over k + stats partials (x1o/x2o path, f64 stats) ----------------
__global__ __launch_bounds__(256) void gather_max_partial(const float* __restrict__ G, const int* __restrict__ idx,
                                                          float* __restrict__ maxbuf, double* __restrict__ part, int Cc) {
  int t = threadIdx.x;
  int o = t % Cc, sub = t / Cc, nsub = 256 / Cc;
  int r0 = blockIdx.x * 16;
  double s = 0.0, s2 = 0.0;
  for (int rr = sub; rr < 16; rr += nsub) {
    int r = r0 + rr, rb = r & ~2047;
    float g = G[(size_t)r*2*Cc + o];
    float mx = -3.4e38f;
#pragma unroll
    for (int k = 0; k < 9; k++) {
      int m = idx[(size_t)r*9 + k];
      float v = g + G[(size_t)(rb + m)*2*Cc + Cc + o];
      mx = fmaxf(mx, v); s += (double)v; s2 += (double)v*(double)v;
    }
    maxbuf[(size_t)r*Cc + o] = mx;
  }
  __shared__ double ls[256], ls2[256];
  ls[t] = s; ls2[t] = s2;
  __syncthreads();
  if (sub == 0) {
    for (int u = 1; u < nsub; u++) { s += ls[u*Cc + o]; s2 += ls2[u*Cc + o]; }
    part[((size_t)blockIdx.x*Cc + o)*2] = s;
    part[((size_t)blockIdx.x*Cc + o)*2 + 1] = s2;
  }
}

// ---------------- concats / add ----------------
__global__ void cat3(const float* __restrict__ x0, const float* __restrict__ x1, const float* __restrict__ fg,
                     const float* __restrict__ x2, float* __restrict__ out, int total) {
  int i = blockIdx.x * 256 + threadIdx.x;
  if (i >= total) return;
  int c = i % 384; int r = i / 384;
  float v;
  if (c < 128) v = x0[(size_t)r*128 + c];
  else if (c < 256) v = x1[(size_t)r*128 + c - 128] + fg[(size_t)r*128 + c - 128];
  else v = x2[(size_t)r*128 + c - 256] + fg[(size_t)r*128 + c - 256];
  out[i] = v;
}

__global__ void cat3b(const float* __restrict__ x0, const float* __restrict__ x1o, const float* __restrict__ x2o,
                      float* __restrict__ out, int total) {
  int i = blockIdx.x * 256 + threadIdx.x;
  if (i >= total) return;
  int c = i % 512; int r = i / 512;
  float v;
  if (c < 128) v = x0[(size_t)r*128 + c];
  else if (c < 256) v = x1o[(size_t)r*128 + c - 128];
  else v = x2o[(size_t)r*256 + c - 256];
  out[i] = v;
}

__global__ void cat2(const float* __restrict__ a, const float* __restrict__ b, float* __restrict__ out, int total) {
  int i = blockIdx.x * 256 + threadIdx.x;
  if (i >= total) return;
  int c = i % 256; int r = i / 256;
  out[i] = (c < 128) ? a[(size_t)r*128 + c] : b[(size_t)r*128 + c - 128];
}

__global__ void add2(const float* __restrict__ a, const float* __restrict__ b, float* __restrict__ out, int n) {
  int i = blockIdx.x * 256 + threadIdx.x;
  if (i >= n) return;
  out[i] = a[i] + b[i];
}

// ---------------- head pack: [r][c=d*4+h] -> [b][h][n][d] ----------------
__global__ void pack_heads(const float* __restrict__ src, float* __restrict__ dst) {
  int i = blockIdx.x * 256 + threadIdx.x;
  if (i >= RTOT*128) return;
  int d = i & 31, n = (i >> 5) & 2047, h = (i >> 16) & 3, b = i >> 18;
  dst[i] = src[((size_t)(b*NPTS + n))*128 + d*4 + h];
}

// ---------------- flash attention: block = 32 query rows × (b,h); loops 64-key tiles ----------------
// thread (tx=tid&15, ty=tid>>4): 2 rows (ty*2+i), 4 score-cols (tx*4+j), 2 out-dims (tx*2+dd)
__global__ __launch_bounds__(256) void attn_flash(const float* __restrict__ Qp, const float* __restrict__ Kp,
                                                  const float* __restrict__ Vp, float* __restrict__ out) {
  __shared__ float Qt[32][34];   // Qt[k][r]  (b64 reads &Qt[k][2ty])
  __shared__ float Kt[32][68];   // Kt[k][c]  (b128 reads &Kt[k][4tx])
  __shared__ float Vs[64][36];   // Vs[kk][d] (b64 reads &Vs[kk][2tx])
  __shared__ float Pt[64][34];   // Pt[c][r]  (b64 reads &Pt[kk][2ty]; intra-wave comm)
  int tid = threadIdx.x;
  int tx = tid & 15, ty = tid >> 4;
  int bh = blockIdx.y;
  int q0 = blockIdx.x * 32;
  const float* Qh = Qp + (size_t)bh * NPTS * 32;
  const float* Kh = Kp + (size_t)bh * NPTS * 32;
  const float* Vh = Vp + (size_t)bh * NPTS * 32;
  {
    int r = tid >> 3, c4 = (tid & 7) * 4;   // 32 rows × 8 float4
    float4 v = *(const float4*)(Qh + (size_t)(q0 + r)*32 + c4);
    Qt[c4+0][r] = v.x; Qt[c4+1][r] = v.y; Qt[c4+2][r] = v.z; Qt[c4+3][r] = v.w;
  }
  float m_[2] = {-FLT_MAX, -FLT_MAX};
  float l_[2] = {0.f, 0.f};
  float O_[2][2] = {};
  const float sc = 0.17677669529663687f;   // 1/sqrt(32)
  for (int k0 = 0; k0 < NPTS; k0 += 64) {
    __syncthreads();   // previous iteration's readers done before overwriting Kt/Vs
    {
      int r = tid >> 3, c4 = (tid & 7) * 4;
      float4 a = *(const float4*)(Kh + (size_t)(k0 + r)*32 + c4);
      Kt[c4+0][r] = a.x; Kt[c4+1][r] = a.y; Kt[c4+2][r] = a.z; Kt[c4+3][r] = a.w;
      float4 b = *(const float4*)(Kh + (size_t)(k0 + 32 + r)*32 + c4);
      Kt[c4+0][32+r] = b.x; Kt[c4+1][32+r] = b.y; Kt[c4+2][32+r] = b.z; Kt[c4+3][32+r] = b.w;
      *(float4*)&Vs[r][c4]      = *(const float4*)(Vh + (size_t)(k0 + r)*32 + c4);
      *(float4*)&Vs[32+r][c4]   = *(const float4*)(Vh + (size_t)(k0 + 32 + r)*32 + c4);
    }
    __syncthreads();
    // S tile: acc[2][4]
    float acc[2][4] = {};
#pragma unroll
    for (int k = 0; k < 32; k++) {
      float2 av = *(const float2*)&Qt[k][ty*2];
      float4 bv = *(const float4*)&Kt[k][tx*4];
      acc[0][0] = fmaf(av.x, bv.x, acc[0][0]);
      acc[0][1] = fmaf(av.x, bv.y, acc[0][1]);
      acc[0][2] = fmaf(av.x, bv.z, acc[0][2]);
      acc[0][3] = fmaf(av.x, bv.w, acc[0][3]);
      acc[1][0] = fmaf(av.y, bv.x, acc[1][0]);
      acc[1][1] = fmaf(av.y, bv.y, acc[1][1]);
      acc[1][2] = fmaf(av.y, bv.z, acc[1][2]);
      acc[1][3] = fmaf(av.y, bv.w, acc[1][3]);
    }
#pragma unroll
    for (int i = 0; i < 2; i++)
#pragma unroll
      for (int j = 0; j < 4; j++) acc[i][j] *= sc;
    // online softmax update
#pragma unroll
    for (int i = 0; i < 2; i++) {
      float tm = fmaxf(fmaxf(acc[i][0], acc[i][1]), fmaxf(acc[i][2], acc[i][3]));
      for (int s = 1; s < 16; s <<= 1) tm = fmaxf(tm, __shfl_xor(tm, s));
      float mn = fmaxf(m_[i], tm);
      float cf = __expf(m_[i] - mn);
      m_[i] = mn;
      l_[i] *= cf; O_[i][0] *= cf; O_[i][1] *= cf;
      float rs = 0.f;
#pragma unroll
      for (int j = 0; j < 4; j++) {
        float p = __expf(acc[i][j] - mn);
        rs += p;
        Pt[tx*4 + j][ty*2 + i] = p;
      }
      for (int s = 1; s < 16; s <<= 1) rs += __shfl_xor(rs, s);
      l_[i] += rs;
    }
    // PV: O[i][dd] += sum_kk Pt[kk][2ty+i] * Vs[kk][2tx+dd]   (Pt comm is intra-16-lane-group)
#pragma unroll 8
    for (int kk = 0; kk < 64; kk++) {
      float2 pv = *(const float2*)&Pt[kk][ty*2];
      float2 vv = *(const float2*)&Vs[kk][tx*2];
      O_[0][0] = fmaf(pv.x, vv.x, O_[0][0]);
      O_[0][1] = fmaf(pv.x, vv.y, O_[0][1]);
      O_[1][0] = fmaf(pv.y, vv.x, O_[1][0]);
      O_[1][1] = fmaf(pv.y, vv.y, O_[1][1]);
    }
  }
  int b = bh >> 2, h = bh & 3;
#pragma unroll
  for (int i = 0; i < 2; i++) {
    int n = q0 + ty*2 + i;
    float inv = 1.f / l_[i];
    out[((size_t)(b*NPTS + n))*128 + (tx*2+0)*4 + h] = O_[i][0] * inv;
    out[((size_t)(b*NPTS + n))*128 + (tx*2+1)*4 + h] = O_[i][1] * inv;
  }
}

// ================= host =================
extern "C" void kernel_launch(void* const* d_in, const int* in_sizes, int n_in,
                              void* d_out, int out_size, void* d_ws, size_t ws_size,
                              hipStream_t stream) {
  (void)in_sizes; (void)n_in; (void)out_size; (void)ws_size;
  const float* desc0  = (const float*)d_in[0];
  const float* desc1  = (const float*)d_in[1];
  const float* coords0= (const float*)d_in[2];
  const float* coords1= (const float*)d_in[3];
  const float* conv1w = (const float*)d_in[4];
  const float* conv2w = (const float*)d_in[5];
  const float* conv3w = (const float*)d_in[6];
  const float* conv3ow= (const float*)d_in[7];
  const float* a1w1 = (const float*)d_in[8];
  const float* a1b1 = (const float*)d_in[9];
  const float* a1w2 = (const float*)d_in[10];
  const float* a1b2 = (const float*)d_in[11];
  const float* a2w1 = (const float*)d_in[12];
  const float* a2b1 = (const float*)d_in[13];
  const float* a2w2 = (const float*)d_in[14];
  const float* a2b2 = (const float*)d_in[15];
  const float* gw1  = (const float*)d_in[16];
  const float* gb1  = (const float*)d_in[17];
  const float* gw2  = (const float*)d_in[18];
  const float* gb2  = (const float*)d_in[19];
  const float* wq = (const float*)d_in[20]; const float* bq = (const float*)d_in[21];
  const float* wk = (const float*)d_in[22]; const float* bk = (const float*)d_in[23];
  const float* wv = (const float*)d_in[24]; const float* bv = (const float*)d_in[25];
  const float* wm = (const float*)d_in[26]; const float* bm = (const float*)d_in[27];
  const float* mw1 = (const float*)d_in[28]; const float* mb1 = (const float*)d_in[29];
  const float* mw2 = (const float*)d_in[30]; const float* mb2 = (const float*)d_in[31];

  float* ws = (float*)d_ws;
  size_t off = 0;
  auto alloc = [&](size_t nel) { size_t r = off; off += (nel + 63) & ~(size_t)63; return r; };
  float* DW_A1 = ws + alloc(512*128);
  float* W_A1R = ws + alloc(128*384);
  float* DW_A2 = ws + alloc(512*128);
  float* W_A2R = ws + alloc(128*384);
  float* W_G2R = ws + alloc(128*384);
  float* DW_C1 = ws + alloc(256*128);
  float* DW_C2 = ws + alloc(512*128);
  float* SA0  = ws + alloc((size_t)RTOT*128);
  float* SA1  = ws + alloc((size_t)RTOT*128);
  float* XF0  = ws + alloc((size_t)RTOT*128);
  float* XF1  = ws + alloc((size_t)RTOT*128);
  int*   IDX  = (int*)(ws + alloc((size_t)RTOT*9));
  float* COSV = ws + alloc((size_t)RTOT*9);
  float* FT   = ws + alloc((size_t)RTOT*128);
  float* BIG  = ws + alloc((size_t)RTOT*512);
  float* ABUF = ws + alloc((size_t)RTOT*384);
  float* X1B  = ws + alloc((size_t)RTOT*128);
  float* FANG = ws + alloc((size_t)RTOT*128);
  float* X2B  = ws + alloc((size_t)RTOT*128);
  float* X3A  = ws + alloc((size_t)RTOT*128);
  float* X1O  = ws + alloc((size_t)RTOT*128);
  float* SM   = ws + alloc((size_t)RTOT*256);
  float* X3O  = ws + alloc((size_t)RTOT*128);
  double* PART = (double*)(ws + alloc(256*256*2*2));   // 131072 doubles
  float* STAT = ws + alloc(2*256*2);

  auto statnorm = [&](float* buf, int J, int Cc, int act, int count) {
    stats_partial<<<64, 256, 0, stream>>>(buf, PART, J, Cc);
    stats_final<<<2, 256, 0, stream>>>(PART, STAT, Cc, 32, count);
    int tot = RTOT*J*Cc;
    norm_act<<<(tot + 255)/256, 256, 0, stream>>>(buf, buf, STAT, J, Cc, act, tot);
  };
  auto gathermax = [&](float* G, float* mx, float* dstNorm, int Cc) {
    gather_max_partial<<<256, 256, 0, stream>>>(G, IDX, mx, PART, Cc);
    stats_final<<<2, 256, 0, stream>>>(PART, STAT, Cc, 128, 2048*9);
    int tot = RTOT*Cc;
    norm_act<<<(tot + 255)/256, 256, 0, stream>>>(mx, dstNorm, STAT, 1, Cc, 2, tot);
  };

  prep_weights<<<256, 256, 0, stream>>>(conv1w, conv2w, a1w1, a1w2, a2w1, a2w2, gw2,
                                        DW_A1, W_A1R, DW_A2, W_A2R, W_G2R, DW_C1, DW_C2);

  auto branch = [&](const float* F, const float* P, float* sa) {
    transpose_k<<<dim3(2048/32, 128/32, 2), dim3(32, 8), 0, stream>>>(F, FT, 128, 2048);
    knn_kernel<<<1024, 256, 0, stream>>>(P, IDX, COSV);
    // annu1 on graph feature of F
    gemm_nc<<<dim3(64, 8), 256, 0, stream>>>(FT, DW_A1, nullptr, BIG, 128, 512);
    combine_annu<<<RTOT, 384, 0, stream>>>(BIG, IDX, a1b1, ABUF);
    statnorm(ABUF, 3, 128, 1, 2048*3);
    gemm_nc<<<dim3(64, 2), 256, 0, stream>>>(ABUF, W_A1R, a1b2, X1B, 384, 128);
    statnorm(X1B, 1, 128, 1, 2048);
    // f_ang (shared by both uses since idx1 == idx2)
    cos_conv<<<(RTOT*384 + 255)/256, 256, 0, stream>>>(COSV, gw1, gb1, ABUF, RTOT*384);
    statnorm(ABUF, 3, 128, 1, 2048*3);
    gemm_nc<<<dim3(64, 2), 256, 0, stream>>>(ABUF, W_G2R, gb2, FANG, 384, 128);
    statnorm(FANG, 1, 128, 1, 2048);
    // annu2 on graph feature of x1
    gemm_nc<<<dim3(64, 8), 256, 0, stream>>>(X1B, DW_A2, nullptr, BIG, 128, 512);
    combine_annu<<<RTOT, 384, 0, stream>>>(BIG, IDX, a2b1, ABUF);
    statnorm(ABUF, 3, 128, 1, 2048*3);
    gemm_nc<<<dim3(64, 2), 256, 0, stream>>>(ABUF, W_A2R, a2b2, X2B, 384, 128);
    statnorm(X2B, 1, 128, 1, 2048);
    // x3 = lrelu(inorm(conv3 * [x0, x1+fang, x2+fang]))
    cat3<<<(RTOT*384 + 255)/256, 256, 0, stream>>>(FT, X1B, FANG, X2B, ABUF, RTOT*384);
    gemm_nc<<<dim3(64, 2), 256, 0, stream>>>(ABUF, conv3w, nullptr, X3A, 384, 128);
    statnorm(X3A, 1, 128, 2, 2048);
    // x1o = max_k lrelu(inorm(conv1 * gf(F)))
    gemm_nc<<<dim3(64, 4), 256, 0, stream>>>(FT, DW_C1, nullptr, BIG, 128, 256);
    gathermax(BIG, SM, X1O, 128);
    // x2o = max_k lrelu(inorm(conv2 * gf(x1o)))
    gemm_nc<<<dim3(64, 8), 256, 0, stream>>>(X1O, DW_C2, nullptr, BIG, 128, 512);
    gathermax(BIG, SM, SM, 256);
    // x3o
    cat3b<<<(RTOT*512 + 255)/256, 256, 0, stream>>>(FT, X1O, SM, BIG, RTOT*512);
    gemm_nc<<<dim3(64, 2), 256, 0, stream>>>(BIG, conv3ow, nullptr, X3O, 512, 128);
    statnorm(X3O, 1, 128, 2, 2048);
    add2<<<(RTOT*128 + 255)/256, 256, 0, stream>>>(X3A, X3O, sa, RTOT*128);
  };

  branch(desc0, coords0, SA0);
  branch(desc1, coords1, SA1);

  auto prop = [&](const float* xin, const float* src, float* dst) {
    gemm_nc<<<dim3(64, 2), 256, 0, stream>>>(xin, wq, bq, X1B, 128, 128);
    gemm_nc<<<dim3(64, 2), 256, 0, stream>>>(src, wk, bk, FANG, 128, 128);
    gemm_nc<<<dim3(64, 2), 256, 0, stream>>>(src, wv, bv, X2B, 128, 128);
    pack_heads<<<(RTOT*128 + 255)/256, 256, 0, stream>>>(X1B, X3A);
    pack_heads<<<(RTOT*128 + 255)/256, 256, 0, stream>>>(FANG, X1O);
    pack_heads<<<(RTOT*128 + 255)/256, 256, 0, stream>>>(X2B, X3O);
    attn_flash<<<dim3(64, 8), 256, 0, stream>>>(X3A, X1O, X3O, ABUF);
    gemm_nc<<<dim3(64, 2), 256, 0, stream>>>(ABUF, wm, bm, SM, 128, 128);
    cat2<<<(RTOT*256 + 255)/256, 256, 0, stream>>>(xin, SM, BIG, RTOT*256);
    gemm_nc<<<dim3(64, 4), 256, 0, stream>>>(BIG, mw1, mb1, ABUF, 256, 256);
    statnorm(ABUF, 1, 256, 1, 2048);
    gemm_nc<<<dim3(64, 2), 256, 0, stream>>>(ABUF, mw2, mb2, SM, 256, 128);
    add2<<<(RTOT*128 + 255)/256, 256, 0, stream>>>(xin, SM, dst, RTOT*128);
  };

  prop(SA0, SA1, XF0);
  prop(SA1, XF0, XF1);

  transpose_k<<<dim3(128/32, 2048/32, 2), dim3(32, 8), 0, stream>>>(XF0, (float*)d_out, 2048, 128);
  transpose_k<<<dim3(128/32, 2048/32, 2), dim3(32, 8), 0, stream>>>(XF1, (float*)d_out + (size_t)RTOT*128, 2048, 128);
}

// Round 5
// 1953.741 us; speedup vs baseline: 2.3151x; 1.0366x over previous
//
#include <hip/hip_runtime.h>
#include <cfloat>
#include <math.h>

#define NPTS 2048
#define RTOT 4096   // B*N = 2*2048

// ---------------- prep: derived weight matrices ----------------
__global__ __launch_bounds__(256) void prep_weights(
    const float* __restrict__ conv1, const float* __restrict__ conv2,
    const float* __restrict__ a1w1, const float* __restrict__ a1w2,
    const float* __restrict__ a2w1, const float* __restrict__ a2w2,
    const float* __restrict__ gw2,
    float* __restrict__ dwA1, float* __restrict__ a1w2r,
    float* __restrict__ dwA2, float* __restrict__ a2w2r,
    float* __restrict__ gw2r, float* __restrict__ dwC1, float* __restrict__ dwC2)
{
  int i = blockIdx.x * 256 + threadIdx.x;
  if (i < 512*128) {
    int row = i >> 7, c = i & 127;
    float v1, v2;
    if (row < 128) {             // ctrW[o][c] = sum_t (w1[o,c,t] - w1[o,128+c,t])
      float s1 = 0.f, s2 = 0.f;
      for (int t = 0; t < 3; t++) {
        s1 += a1w1[(row*256 + c)*3 + t] - a1w1[(row*256 + 128 + c)*3 + t];
        s2 += a2w1[(row*256 + c)*3 + t] - a2w1[(row*256 + 128 + c)*3 + t];
      }
      v1 = s1; v2 = s2;
    } else {                     // row = 128 + t*128 + o : nbW_t[o][c] = w1[o,128+c,t]
      int t = (row - 128) >> 7, o = row & 127;
      v1 = a1w1[(o*256 + 128 + c)*3 + t];
      v2 = a2w1[(o*256 + 128 + c)*3 + t];
    }
    dwA1[i] = v1; dwA2[i] = v2;
    dwC2[i] = (row < 256) ? (conv2[row*256 + c] - conv2[row*256 + 128 + c])
                          : conv2[(row-256)*256 + 128 + c];
  }
  if (i < 128*384) {             // w2r[o][w*128+c] = w2[o,c,w]
    int o = i / 384, rem = i % 384, w = rem >> 7, c = rem & 127;
    a1w2r[i] = a1w2[(o*128 + c)*3 + w];
    a2w2r[i] = a2w2[(o*128 + c)*3 + w];
    gw2r[i]  = gw2[(o*128 + c)*3 + w];
  }
  if (i < 256*128) {             // dwC1 [256][128] from conv1 [128][256]
    int row = i >> 7, c = i & 127;
    dwC1[i] = (row < 128) ? (conv1[row*256 + c] - conv1[row*256 + 128 + c])
                          : conv1[(row-128)*256 + 128 + c];
  }
}

// ---------------- transpose [b][I][J] -> [b][J][I] ----------------
__global__ void transpose_k(const float* __restrict__ in, float* __restrict__ out, int I, int J) {
  __shared__ float tile[32][33];
  int b = blockIdx.z;
  int i0 = blockIdx.y * 32, j0 = blockIdx.x * 32;
  int tx = threadIdx.x, ty = threadIdx.y;   // block (32,8)
  for (int s = 0; s < 32; s += 8)
    tile[ty + s][tx] = in[((size_t)b*I + (i0 + ty + s))*J + (j0 + tx)];
  __syncthreads();
  for (int s = 0; s < 32; s += 8)
    out[((size_t)b*J + (j0 + ty + s))*I + (i0 + tx)] = tile[tx][ty + s];
}

// ---------------- KNN: f32 distances EXACTLY as np computes them, (dist,idx)-lex order ----------------
__global__ __launch_bounds__(256) void knn_kernel(const float* __restrict__ P,
                                                  int* __restrict__ idx, float* __restrict__ cosv) {
  __shared__ float px[NPTS], py[NPTS], sq[NPTS];
  int tid = threadIdx.x;
  int gw = blockIdx.x * 4 + (tid >> 6);   // wave id = b*2048 + n
  int b = gw >> 11, n = gw & 2047;
  int lane = tid & 63;
  const float* Pb = P + (size_t)b * 2 * NPTS;
  for (int i = tid; i < NPTS; i += 256) {
    float x = Pb[i], y = Pb[NPTS + i];
    px[i] = x; py[i] = y;
    sq[i] = __fadd_rn(__fmul_rn(x, x), __fmul_rn(y, y));
  }
  __syncthreads();
  float xn = px[n], yn = py[n], sqn = sq[n];
  float d[10]; int id_[10];
#pragma unroll
  for (int j = 0; j < 10; j++) { d[j] = FLT_MAX; id_[j] = 0x7fffffff; }
  for (int m = lane; m < NPTS; m += 64) {
    float dot  = __fadd_rn(__fmul_rn(xn, px[m]), __fmul_rn(yn, py[m]));
    float dist = __fsub_rn(__fadd_rn(sqn, sq[m]), __fmul_rn(2.0f, dot));
    dist = fmaxf(dist, 1e-12f);
    if (dist < d[9] || (dist == d[9] && m < id_[9])) {
      int p = 0;
#pragma unroll
      for (int j = 0; j < 10; j++) p += (d[j] < dist || (d[j] == dist && id_[j] < m)) ? 1 : 0;
#pragma unroll
      for (int j = 9; j >= 1; j--) if (j > p) { d[j] = d[j-1]; id_[j] = id_[j-1]; }
#pragma unroll
      for (int j = 0; j < 10; j++) if (j == p) { d[j] = dist; id_[j] = m; }
    }
  }
  int ptr = 0;
  for (int r = 0; r < 10; r++) {
    float bd = FLT_MAX; int bi = 0x7fffffff;
#pragma unroll
    for (int j = 0; j < 10; j++) if (j == ptr) { bd = d[j]; bi = id_[j]; }
    for (int off = 32; off >= 1; off >>= 1) {
      float od = __shfl_xor(bd, off);
      int   oi = __shfl_xor(bi, off);
      if (od < bd || (od == bd && oi < bi)) { bd = od; bi = oi; }
    }
    bool adv = false;
#pragma unroll
    for (int j = 0; j < 10; j++) if (j == ptr) adv = (d[j] == bd && id_[j] == bi);
    if (adv) ptr++;
    if (r > 0 && lane == 0) {
      size_t base = ((size_t)b*NPTS + n)*9 + (r - 1);
      idx[base] = bi;
      float dot = __fadd_rn(__fmul_rn(xn, px[bi]), __fmul_rn(yn, py[bi]));
      cosv[base] = __fdiv_rn(dot, __fmul_rn(__fsqrt_rn(sqn), __fsqrt_rn(sq[bi])));
    }
  }
}

// ---------------- unified f32 GEMM: Y[4096][O] = X * W^T (+bias, +resid, pack, x-norm, concat-X) --
// X virtually = [p0(w0) | p1(w1) | p2(w2)]; if addp: cols>=128 get +addp[r][ (c-128)&127 ]
// if xstats: x = relu((x - m)*rs) with per (b, c & (xmod-1)) stats.
__global__ __launch_bounds__(256) void gemm_f(
    const float* __restrict__ p0, int w0,
    const float* __restrict__ p1, int w1,
    const float* __restrict__ p2, int w2,
    const float* __restrict__ addp,
    const float* __restrict__ xstats, int xmod,
    const float* __restrict__ W,
    const float* __restrict__ bias,
    const float* __restrict__ resid,
    float* __restrict__ Y, int Cin, int O, int pack)
{
  __shared__ float Xs[64][33], Ws[64][33];
  int tid = threadIdx.x;
  int r0 = blockIdx.x * 64, c0 = blockIdx.y * 64;
  int tx = tid & 15, ty = tid >> 4;
  int srow = tid >> 2, scol = (tid & 3) * 8;
  float acc[4][4] = {};
  for (int k0 = 0; k0 < Cin; k0 += 32) {
    // ---- stage X (with optional concat / add / norm-relu) ----
    {
      int r = r0 + srow;
      int ac = k0 + scol;
      const float* P; int cc, lw;
      if (ac < w0) { P = p0; cc = ac; lw = w0; }
      else if (ac < w0 + w1) { P = p1; cc = ac - w0; lw = w1; }
      else { P = p2; cc = ac - w0 - w1; lw = w2; }
      float4 v0 = *(const float4*)(P + (size_t)r*lw + cc);
      float4 v1 = *(const float4*)(P + (size_t)r*lw + cc + 4);
      float vv[8] = {v0.x, v0.y, v0.z, v0.w, v1.x, v1.y, v1.z, v1.w};
      if (addp && ac >= 128) {
        int fc = (ac - 128) & 127;
        float4 a0 = *(const float4*)(addp + (size_t)r*128 + fc);
        float4 a1 = *(const float4*)(addp + (size_t)r*128 + fc + 4);
        vv[0]+=a0.x; vv[1]+=a0.y; vv[2]+=a0.z; vv[3]+=a0.w;
        vv[4]+=a1.x; vv[5]+=a1.y; vv[6]+=a1.z; vv[7]+=a1.w;
      }
      if (xstats) {
        int b = r >> 11;
#pragma unroll
        for (int j = 0; j < 8; j++) {
          int o = (ac + j) & (xmod - 1);
          float m = xstats[(b*xmod + o)*2], rs = xstats[(b*xmod + o)*2 + 1];
          vv[j] = fmaxf((vv[j] - m) * rs, 0.f);
        }
      }
#pragma unroll
      for (int j = 0; j < 8; j++) Xs[srow][scol + j] = vv[j];
    }
    // ---- stage W ----
    {
      const float* s = W + (size_t)(c0 + srow)*Cin + k0 + scol;
      float4 v0 = *(const float4*)s, v1 = *(const float4*)(s + 4);
      Ws[srow][scol+0]=v0.x; Ws[srow][scol+1]=v0.y; Ws[srow][scol+2]=v0.z; Ws[srow][scol+3]=v0.w;
      Ws[srow][scol+4]=v1.x; Ws[srow][scol+5]=v1.y; Ws[srow][scol+6]=v1.z; Ws[srow][scol+7]=v1.w;
    }
    __syncthreads();
#pragma unroll
    for (int kk = 0; kk < 32; kk++) {
      float av[4], bv[4];
#pragma unroll
      for (int i = 0; i < 4; i++) { av[i] = Xs[ty*4+i][kk]; bv[i] = Ws[tx*4+i][kk]; }
#pragma unroll
      for (int i = 0; i < 4; i++)
#pragma unroll
        for (int j = 0; j < 4; j++) acc[i][j] = fmaf(av[i], bv[j], acc[i][j]);
    }
    __syncthreads();
  }
#pragma unroll
  for (int i = 0; i < 4; i++) {
    int r = r0 + ty*4 + i;
#pragma unroll
    for (int j = 0; j < 4; j++) {
      int c = c0 + tx*4 + j;
      float v = acc[i][j] + (bias ? bias[c] : 0.f);
      if (resid) v += resid[(size_t)r*O + c];
      if (pack) {
        int h = c & 3, dd = c >> 2, b = r >> 11, n = r & 2047;
        Y[(((size_t)(b*4 + h))*NPTS + n)*32 + dd] = v;
      } else {
        Y[(size_t)r*O + c] = v;
      }
    }
  }
}

// ---------------- annu conv1 combine: A[r][w*128+o] = G0 + sum_t Hnb + b1 ----------------
__global__ __launch_bounds__(384) void combine_annu(const float* __restrict__ GA, const int* __restrict__ idx,
                                                    const float* __restrict__ b1, float* __restrict__ A) {
  int r = blockIdx.x, t = threadIdx.x;
  int w = t >> 7, o = t & 127;
  int rb = r & ~2047;
  __shared__ int nb[9];
  if (t < 9) nb[t] = idx[(size_t)r*9 + t];
  __syncthreads();
  float acc = GA[(size_t)r*512 + o] + b1[o];
#pragma unroll
  for (int t3 = 0; t3 < 3; t3++) {
    int m = nb[w*3 + t3];
    acc += GA[(size_t)(rb + m)*512 + 128 + t3*128 + o];
  }
  A[(size_t)r*384 + w*128 + o] = acc;
}

// ---------------- instance-norm stats: partial + fenced tail-block final ----------------
__global__ __launch_bounds__(256) void stats_fused(const float* __restrict__ X, double* __restrict__ part,
                                                   float* __restrict__ stats, int J, int Cc,
                                                   int count, int nblkPerB, int* __restrict__ ctr) {
  int t = threadIdx.x;
  int o = t % Cc, sub = t / Cc, nsub = 256 / Cc;
  int r0 = blockIdx.x * 64;
  double s = 0.0, s2 = 0.0;
  for (int rr = sub; rr < 64; rr += nsub)
    for (int j = 0; j < J; j++) {
      double v = X[(((size_t)(r0 + rr))*J + j)*Cc + o];
      s += v; s2 += v*v;
    }
  __shared__ double ls[256], ls2[256];
  ls[t] = s; ls2[t] = s2;
  __syncthreads();
  if (sub == 0) {
    for (int u = 1; u < nsub; u++) { s += ls[u*Cc + o]; s2 += ls2[u*Cc + o]; }
    part[((size_t)blockIdx.x*Cc + o)*2] = s;
    part[((size_t)blockIdx.x*Cc + o)*2 + 1] = s2;
    __threadfence();
  }
  __syncthreads();
  __shared__ int lastBlk;
  if (t == 0) lastBlk = (atomicAdd(ctr, 1) == (int)gridDim.x - 1) ? 1 : 0;
  __syncthreads();
  if (!lastBlk) return;
  __threadfence();
  for (int i = t; i < 2*Cc; i += 256) {
    int b = i / Cc, oo = i % Cc;
    double S = 0.0, S2 = 0.0;
    for (int u = 0; u < nblkPerB; u++) {
      int blk = b*nblkPerB + u;
      S  += part[((size_t)blk*Cc + oo)*2];
      S2 += part[((size_t)blk*Cc + oo)*2 + 1];
    }
    double mean = S / count;
    double var = S2 / count - mean*mean;
    if (var < 0.0) var = 0.0;
    stats[i*2] = (float)mean;
    stats[i*2 + 1] = (float)(1.0 / sqrt(var + 1e-5));
  }
}

// act: 0 none, 1 relu, 2 lrelu(0.2); optional addend (J==1 layouts only)
__global__ void norm_act(const float* __restrict__ src, float* __restrict__ dst,
                         const float* __restrict__ stats, int J, int Cc, int act, int total,
                         const float* __restrict__ addend) {
  int i = blockIdx.x * 256 + threadIdx.x;
  if (i >= total) return;
  int o = i % Cc;
  int r = i / (J*Cc);
  int b = r >> 11;
  float m = stats[(b*Cc + o)*2], rs = stats[(b*Cc + o)*2 + 1];
  float v = (src[i] - m) * rs;
  if (act == 1) v = fmaxf(v, 0.f);
  else if (act == 2) v = (v >= 0.f) ? v : 0.2f*v;
  if (addend) v += addend[i];
  dst[i] = v;
}

// ---------------- angle-feature conv1 ----------------
__global__ void cos_conv(const float* __restrict__ cosv, const float* __restrict__ gw1,
                         const float* __restrict__ gb1, float* __restrict__ ANG, int total) {
  int i = blockIdx.x * 256 + threadIdx.x;
  if (i >= total) return;
  int o = i & 127, w = (i >> 7) % 3;
  int r = i / 384;
  float acc = gb1[o];
#pragma unroll
  for (int t = 0; t < 3; t++) acc += cosv[(size_t)r*9 + w*3 + t] * gw1[o*3 + t];
  ANG[i] = acc;
}

// ---------------- gather + max over k + fenced stats final ----------------
__global__ __launch_bounds__(256) void gather_max_fused(const float* __restrict__ G, const int* __restrict__ idx,
                                                        float* __restrict__ maxbuf, double* __restrict__ part,
                                                        float* __restrict__ stats, int Cc, int* __restrict__ ctr) {
  int t = threadIdx.x;
  int o = t % Cc, sub = t / Cc, nsub = 256 / Cc;
  int r0 = blockIdx.x * 16;
  double s = 0.0, s2 = 0.0;
  for (int rr = sub; rr < 16; rr += nsub) {
    int r = r0 + rr, rb = r & ~2047;
    float g = G[(size_t)r*2*Cc + o];
    float mx = -3.4e38f;
#pragma unroll
    for (int k = 0; k < 9; k++) {
      int m = idx[(size_t)r*9 + k];
      float v = g + G[(size_t)(rb + m)*2*Cc + Cc + o];
      mx = fmaxf(mx, v); s += (double)v; s2 += (double)v*(double)v;
    }
    maxbuf[(size_t)r*Cc + o] = mx;
  }
  __shared__ double ls[256], ls2[256];
  ls[t] = s; ls2[t] = s2;
  __syncthreads();
  if (sub == 0) {
    for (int u = 1; u < nsub; u++) { s += ls[u*Cc + o]; s2 += ls2[u*Cc + o]; }
    part[((size_t)blockIdx.x*Cc + o)*2] = s;
    part[((size_t)blockIdx.x*Cc + o)*2 + 1] = s2;
    __threadfence();
  }
  __syncthreads();
  __shared__ int lastBlk;
  if (t == 0) lastBlk = (atomicAdd(ctr, 1) == (int)gridDim.x - 1) ? 1 : 0;
  __syncthreads();
  if (!lastBlk) return;
  __threadfence();
  for (int i = t; i < 2*Cc; i += 256) {
    int b = i / Cc, oo = i % Cc;
    double S = 0.0, S2 = 0.0;
    for (int u = 0; u < 128; u++) {
      int blk = b*128 + u;
      S  += part[((size_t)blk*Cc + oo)*2];
      S2 += part[((size_t)blk*Cc + oo)*2 + 1];
    }
    double mean = S / (2048*9);
    double var = S2 / (2048*9) - mean*mean;
    if (var < 0.0) var = 0.0;
    stats[i*2] = (float)mean;
    stats[i*2 + 1] = (float)(1.0 / sqrt(var + 1e-5));
  }
}

// ---------------- flash attention: block = 16 query rows × (b,h); 64-key tiles ----------------
__global__ __launch_bounds__(256) void attn_flash(const float* __restrict__ Qp, const float* __restrict__ Kp,
                                                  const float* __restrict__ Vp, float* __restrict__ out) {
  __shared__ float Qt[32][17];   // [k][r]
  __shared__ float Kt[32][68];   // [k][c]
  __shared__ float Vs[64][36];   // [kk][d]
  __shared__ float Pt[64][17];   // [c][r]  (intra-16-lane-group comm)
  int tid = threadIdx.x;
  int tx = tid & 15, ty = tid >> 4;   // ty = row 0..15
  int bh = blockIdx.y;
  int q0 = blockIdx.x * 16;
  const float* Qh = Qp + (size_t)bh * NPTS * 32;
  const float* Kh = Kp + (size_t)bh * NPTS * 32;
  const float* Vh = Vp + (size_t)bh * NPTS * 32;
  if (tid < 128) {
    int r = tid >> 3, c4 = (tid & 7) * 4;
    float4 v = *(const float4*)(Qh + (size_t)(q0 + r)*32 + c4);
    Qt[c4+0][r] = v.x; Qt[c4+1][r] = v.y; Qt[c4+2][r] = v.z; Qt[c4+3][r] = v.w;
  }
  float m_ = -FLT_MAX, l_ = 0.f, O0 = 0.f, O1 = 0.f;
  const float sc = 0.17677669529663687f;   // 1/sqrt(32)
  for (int k0 = 0; k0 < NPTS; k0 += 64) {
    __syncthreads();
    {
      int r = tid >> 3, c4 = (tid & 7) * 4;
      float4 a = *(const float4*)(Kh + (size_t)(k0 + r)*32 + c4);
      Kt[c4+0][r] = a.x; Kt[c4+1][r] = a.y; Kt[c4+2][r] = a.z; Kt[c4+3][r] = a.w;
      float4 b = *(const float4*)(Kh + (size_t)(k0 + 32 + r)*32 + c4);
      Kt[c4+0][32+r] = b.x; Kt[c4+1][32+r] = b.y; Kt[c4+2][32+r] = b.z; Kt[c4+3][32+r] = b.w;
      *(float4*)&Vs[r][c4]    = *(const float4*)(Vh + (size_t)(k0 + r)*32 + c4);
      *(float4*)&Vs[32+r][c4] = *(const float4*)(Vh + (size_t)(k0 + 32 + r)*32 + c4);
    }
    __syncthreads();
    float acc[4] = {};
#pragma unroll
    for (int k = 0; k < 32; k++) {
      float a = Qt[k][ty];
      float4 b = *(const float4*)&Kt[k][tx*4];
      acc[0] = fmaf(a, b.x, acc[0]);
      acc[1] = fmaf(a, b.y, acc[1]);
      acc[2] = fmaf(a, b.z, acc[2]);
      acc[3] = fmaf(a, b.w, acc[3]);
    }
#pragma unroll
    for (int j = 0; j < 4; j++) acc[j] *= sc;
    float tm = fmaxf(fmaxf(acc[0], acc[1]), fmaxf(acc[2], acc[3]));
    for (int s = 1; s < 16; s <<= 1) tm = fmaxf(tm, __shfl_xor(tm, s));
    float mn = fmaxf(m_, tm);
    float cf = __expf(m_ - mn);
    m_ = mn; l_ *= cf; O0 *= cf; O1 *= cf;
    float rs = 0.f;
#pragma unroll
    for (int j = 0; j < 4; j++) {
      float p = __expf(acc[j] - mn);
      rs += p;
      Pt[tx*4 + j][ty] = p;
    }
    for (int s = 1; s < 16; s <<= 1) rs += __shfl_xor(rs, s);
    l_ += rs;
#pragma unroll 8
    for (int kk = 0; kk < 64; kk++) {
      float p = Pt[kk][ty];
      float2 vv = *(const float2*)&Vs[kk][tx*2];
      O0 = fmaf(p, vv.x, O0);
      O1 = fmaf(p, vv.y, O1);
    }
  }
  int b = bh >> 2, h = bh & 3;
  int n = q0 + ty;
  float inv = 1.f / l_;
  out[((size_t)(b*NPTS + n))*128 + (tx*2+0)*4 + h] = O0 * inv;
  out[((size_t)(b*NPTS + n))*128 + (tx*2+1)*4 + h] = O1 * inv;
}

// ================= host =================
extern "C" void kernel_launch(void* const* d_in, const int* in_sizes, int n_in,
                              void* d_out, int out_size, void* d_ws, size_t ws_size,
                              hipStream_t stream) {
  (void)in_sizes; (void)n_in; (void)out_size; (void)ws_size;
  const float* desc0  = (const float*)d_in[0];
  const float* desc1  = (const float*)d_in[1];
  const float* coords0= (const float*)d_in[2];
  const float* coords1= (const float*)d_in[3];
  const float* conv1w = (const float*)d_in[4];
  const float* conv2w = (const float*)d_in[5];
  const float* conv3w = (const float*)d_in[6];
  const float* conv3ow= (const float*)d_in[7];
  const float* a1w1 = (const float*)d_in[8];
  const float* a1b1 = (const float*)d_in[9];
  const float* a1w2 = (const float*)d_in[10];
  const float* a1b2 = (const float*)d_in[11];
  const float* a2w1 = (const float*)d_in[12];
  const float* a2b1 = (const float*)d_in[13];
  const float* a2w2 = (const float*)d_in[14];
  const float* a2b2 = (const float*)d_in[15];
  const float* gw1  = (const float*)d_in[16];
  const float* gb1  = (const float*)d_in[17];
  const float* gw2  = (const float*)d_in[18];
  const float* gb2  = (const float*)d_in[19];
  const float* wq = (const float*)d_in[20]; const float* bq = (const float*)d_in[21];
  const float* wk = (const float*)d_in[22]; const float* bk = (const float*)d_in[23];
  const float* wv = (const float*)d_in[24]; const float* bv = (const float*)d_in[25];
  const float* wm = (const float*)d_in[26]; const float* bm = (const float*)d_in[27];
  const float* mw1 = (const float*)d_in[28]; const float* mb1 = (const float*)d_in[29];
  const float* mw2 = (const float*)d_in[30]; const float* mb2 = (const float*)d_in[31];

  float* ws = (float*)d_ws;
  size_t off = 0;
  auto alloc = [&](size_t nel) { size_t r = off; off += (nel + 63) & ~(size_t)63; return r; };
  float* DW_A1 = ws + alloc(512*128);
  float* W_A1R = ws + alloc(128*384);
  float* DW_A2 = ws + alloc(512*128);
  float* W_A2R = ws + alloc(128*384);
  float* W_G2R = ws + alloc(128*384);
  float* DW_C1 = ws + alloc(256*128);
  float* DW_C2 = ws + alloc(512*128);
  float* SA0  = ws + alloc((size_t)RTOT*128);
  float* SA1  = ws + alloc((size_t)RTOT*128);
  float* XF0  = ws + alloc((size_t)RTOT*128);
  float* XF1  = ws + alloc((size_t)RTOT*128);
  int*   IDX  = (int*)(ws + alloc((size_t)RTOT*9));
  float* COSV = ws + alloc((size_t)RTOT*9);
  float* FT   = ws + alloc((size_t)RTOT*128);
  float* BIG  = ws + alloc((size_t)RTOT*512);
  float* ABUF = ws + alloc((size_t)RTOT*384);
  float* X1B  = ws + alloc((size_t)RTOT*128);
  float* FANG = ws + alloc((size_t)RTOT*128);
  float* X2B  = ws + alloc((size_t)RTOT*128);
  float* X3A  = ws + alloc((size_t)RTOT*128);
  float* X1O  = ws + alloc((size_t)RTOT*128);
  float* SM   = ws + alloc((size_t)RTOT*256);
  float* X3O  = ws + alloc((size_t)RTOT*128);
  double* PART = (double*)(ws + alloc(256*256*2*2));   // 131072 doubles
  float* STAT = ws + alloc(2*256*2);
  int*   CTR  = (int*)(ws + alloc(64));

  hipMemsetAsync(CTR, 0, 64*sizeof(int), stream);
  int ctr_id = 0;

  auto gemm1 = [&](const float* X, const float* W, const float* bias, float* Y, int Cin, int O,
                   const float* xst, int xmod, const float* resid, int pack) {
    gemm_f<<<dim3(64, O/64), 256, 0, stream>>>(X, Cin, nullptr, 0, nullptr, 0, nullptr,
                                               xst, xmod, W, bias, resid, Y, Cin, O, pack);
  };
  auto gemm3 = [&](const float* a, int wa, const float* b, int wb, const float* c, int wc,
                   const float* addp, const float* W, const float* bias, float* Y, int Cin, int O) {
    gemm_f<<<dim3(64, O/64), 256, 0, stream>>>(a, wa, b, wb, c, wc, addp,
                                               nullptr, 0, W, bias, nullptr, Y, Cin, O, 0);
  };
  auto stats_only = [&](float* buf, int J, int Cc, int count) {
    stats_fused<<<64, 256, 0, stream>>>(buf, PART, STAT, J, Cc, count, 32, CTR + ctr_id++);
  };
  auto statnorm = [&](float* buf, float* dst, int J, int Cc, int act, int count, const float* addend) {
    stats_only(buf, J, Cc, count);
    int tot = RTOT*J*Cc;
    norm_act<<<(tot + 255)/256, 256, 0, stream>>>(buf, dst, STAT, J, Cc, act, tot, addend);
  };
  auto gathermax = [&](float* G, float* mx, float* dstNorm, int Cc) {
    gather_max_fused<<<256, 256, 0, stream>>>(G, IDX, mx, PART, STAT, Cc, CTR + ctr_id++);
    int tot = RTOT*Cc;
    norm_act<<<(tot + 255)/256, 256, 0, stream>>>(mx, dstNorm, STAT, 1, Cc, 2, tot, nullptr);
  };

  prep_weights<<<256, 256, 0, stream>>>(conv1w, conv2w, a1w1, a1w2, a2w1, a2w2, gw2,
                                        DW_A1, W_A1R, DW_A2, W_A2R, W_G2R, DW_C1, DW_C2);

  auto branch = [&](const float* F, const float* P, float* sa) {
    transpose_k<<<dim3(2048/32, 128/32, 2), dim3(32, 8), 0, stream>>>(F, FT, 128, 2048);
    knn_kernel<<<1024, 256, 0, stream>>>(P, IDX, COSV);
    // annu1
    gemm1(FT, DW_A1, nullptr, BIG, 128, 512, nullptr, 0, nullptr, 0);
    combine_annu<<<RTOT, 384, 0, stream>>>(BIG, IDX, a1b1, ABUF);
    stats_only(ABUF, 3, 128, 2048*3);
    gemm1(ABUF, W_A1R, a1b2, X1B, 384, 128, STAT, 128, nullptr, 0);
    statnorm(X1B, X1B, 1, 128, 1, 2048, nullptr);
    // f_ang (shared: idx1 == idx2)
    cos_conv<<<(RTOT*384 + 255)/256, 256, 0, stream>>>(COSV, gw1, gb1, ABUF, RTOT*384);
    stats_only(ABUF, 3, 128, 2048*3);
    gemm1(ABUF, W_G2R, gb2, FANG, 384, 128, STAT, 128, nullptr, 0);
    statnorm(FANG, FANG, 1, 128, 1, 2048, nullptr);
    // annu2
    gemm1(X1B, DW_A2, nullptr, BIG, 128, 512, nullptr, 0, nullptr, 0);
    combine_annu<<<RTOT, 384, 0, stream>>>(BIG, IDX, a2b1, ABUF);
    stats_only(ABUF, 3, 128, 2048*3);
    gemm1(ABUF, W_A2R, a2b2, X2B, 384, 128, STAT, 128, nullptr, 0);
    statnorm(X2B, X2B, 1, 128, 1, 2048, nullptr);
    // x3 = lrelu(inorm(conv3 * [x0 | x1+fang | x2+fang]))
    gemm3(FT, 128, X1B, 128, X2B, 128, FANG, conv3w, nullptr, X3A, 384, 128);
    statnorm(X3A, X3A, 1, 128, 2, 2048, nullptr);
    // x1o
    gemm1(FT, DW_C1, nullptr, BIG, 128, 256, nullptr, 0, nullptr, 0);
    gathermax(BIG, SM, X1O, 128);
    // x2o
    gemm1(X1O, DW_C2, nullptr, BIG, 128, 512, nullptr, 0, nullptr, 0);
    gathermax(BIG, SM, SM, 256);
    // x3o = lrelu(inorm(conv3o * [x0 | x1o | x2o])) + x3
    gemm3(FT, 128, X1O, 128, SM, 256, nullptr, conv3ow, nullptr, X3O, 512, 128);
    statnorm(X3O, sa, 1, 128, 2, 2048, X3A);
  };

  branch(desc0, coords0, SA0);
  branch(desc1, coords1, SA1);

  auto prop = [&](const float* xin, const float* src, float* dst) {
    gemm1(xin, wq, bq, X3A, 128, 128, nullptr, 0, nullptr, 1);   // packed Q
    gemm1(src, wk, bk, X1O, 128, 128, nullptr, 0, nullptr, 1);   // packed K
    gemm1(src, wv, bv, X3O, 128, 128, nullptr, 0, nullptr, 1);   // packed V
    attn_flash<<<dim3(128, 8), 256, 0, stream>>>(X3A, X1O, X3O, ABUF);
    gemm1(ABUF, wm, bm, SM, 128, 128, nullptr, 0, nullptr, 0);
    gemm3(xin, 128, SM, 128, nullptr, 0, nullptr, mw1, mb1, ABUF, 256, 256);
    stats_only(ABUF, 1, 256, 2048);
    gemm1(ABUF, mw2, mb2, dst, 256, 128, STAT, 256, xin, 0);     // fused norm-relu + residual
  };

  prop(SA0, SA1, XF0);
  prop(SA1, XF0, XF1);

  transpose_k<<<dim3(128/32, 2048/32, 2), dim3(32, 8), 0, stream>>>(XF0, (float*)d_out, 2048, 128);
  transpose_k<<<dim3(128/32, 2048/32, 2), dim3(32, 8), 0, stream>>>(XF1, (float*)d_out + (size_t)RTOT*128, 2048, 128);
}

// Round 6
// 1782.216 us; speedup vs baseline: 2.5379x; 1.0962x over previous
//
#include <hip/hip_runtime.h>
#include <cfloat>
#include <math.h>

#define NPTS 2048
#define RTOT 4096   // B*N = 2*2048

// ---------------- prep: derived weight matrices ----------------
__global__ __launch_bounds__(256) void prep_weights(
    const float* __restrict__ conv1, const float* __restrict__ conv2,
    const float* __restrict__ a1w1, const float* __restrict__ a1w2,
    const float* __restrict__ a2w1, const float* __restrict__ a2w2,
    const float* __restrict__ gw2,
    float* __restrict__ dwA1, float* __restrict__ a1w2r,
    float* __restrict__ dwA2, float* __restrict__ a2w2r,
    float* __restrict__ gw2r, float* __restrict__ dwC1, float* __restrict__ dwC2)
{
  int i = blockIdx.x * 256 + threadIdx.x;
  if (i < 512*128) {
    int row = i >> 7, c = i & 127;
    float v1, v2;
    if (row < 128) {             // ctrW[o][c] = sum_t (w1[o,c,t] - w1[o,128+c,t])
      float s1 = 0.f, s2 = 0.f;
      for (int t = 0; t < 3; t++) {
        s1 += a1w1[(row*256 + c)*3 + t] - a1w1[(row*256 + 128 + c)*3 + t];
        s2 += a2w1[(row*256 + c)*3 + t] - a2w1[(row*256 + 128 + c)*3 + t];
      }
      v1 = s1; v2 = s2;
    } else {                     // row = 128 + t*128 + o : nbW_t[o][c] = w1[o,128+c,t]
      int t = (row - 128) >> 7, o = row & 127;
      v1 = a1w1[(o*256 + 128 + c)*3 + t];
      v2 = a2w1[(o*256 + 128 + c)*3 + t];
    }
    dwA1[i] = v1; dwA2[i] = v2;
    dwC2[i] = (row < 256) ? (conv2[row*256 + c] - conv2[row*256 + 128 + c])
                          : conv2[(row-256)*256 + 128 + c];
  }
  if (i < 128*384) {             // w2r[o][w*128+c] = w2[o,c,w]
    int o = i / 384, rem = i % 384, w = rem >> 7, c = rem & 127;
    a1w2r[i] = a1w2[(o*128 + c)*3 + w];
    a2w2r[i] = a2w2[(o*128 + c)*3 + w];
    gw2r[i]  = gw2[(o*128 + c)*3 + w];
  }
  if (i < 256*128) {             // dwC1 [256][128] from conv1 [128][256]
    int row = i >> 7, c = i & 127;
    dwC1[i] = (row < 128) ? (conv1[row*256 + c] - conv1[row*256 + 128 + c])
                          : conv1[(row-128)*256 + 128 + c];
  }
}

// ---------------- transpose [b][I][J] -> [b][J][I] ----------------
__global__ void transpose_k(const float* __restrict__ in, float* __restrict__ out, int I, int J) {
  __shared__ float tile[32][33];
  int b = blockIdx.z;
  int i0 = blockIdx.y * 32, j0 = blockIdx.x * 32;
  int tx = threadIdx.x, ty = threadIdx.y;   // block (32,8)
  for (int s = 0; s < 32; s += 8)
    tile[ty + s][tx] = in[((size_t)b*I + (i0 + ty + s))*J + (j0 + tx)];
  __syncthreads();
  for (int s = 0; s < 32; s += 8)
    out[((size_t)b*J + (j0 + ty + s))*I + (i0 + tx)] = tile[tx][ty + s];
}

// ---------------- KNN: f32 distances EXACTLY as np computes them, (dist,idx)-lex order ----------------
__global__ __launch_bounds__(256) void knn_kernel(const float* __restrict__ P,
                                                  int* __restrict__ idx, float* __restrict__ cosv) {
  __shared__ float px[NPTS], py[NPTS], sq[NPTS];
  int tid = threadIdx.x;
  int gw = blockIdx.x * 4 + (tid >> 6);   // wave id = b*2048 + n
  int b = gw >> 11, n = gw & 2047;
  int lane = tid & 63;
  const float* Pb = P + (size_t)b * 2 * NPTS;
  for (int i = tid; i < NPTS; i += 256) {
    float x = Pb[i], y = Pb[NPTS + i];
    px[i] = x; py[i] = y;
    sq[i] = __fadd_rn(__fmul_rn(x, x), __fmul_rn(y, y));
  }
  __syncthreads();
  float xn = px[n], yn = py[n], sqn = sq[n];
  float d[10]; int id_[10];
#pragma unroll
  for (int j = 0; j < 10; j++) { d[j] = FLT_MAX; id_[j] = 0x7fffffff; }
  for (int m = lane; m < NPTS; m += 64) {
    float dot  = __fadd_rn(__fmul_rn(xn, px[m]), __fmul_rn(yn, py[m]));
    float dist = __fsub_rn(__fadd_rn(sqn, sq[m]), __fmul_rn(2.0f, dot));
    dist = fmaxf(dist, 1e-12f);
    if (dist < d[9] || (dist == d[9] && m < id_[9])) {
      int p = 0;
#pragma unroll
      for (int j = 0; j < 10; j++) p += (d[j] < dist || (d[j] == dist && id_[j] < m)) ? 1 : 0;
#pragma unroll
      for (int j = 9; j >= 1; j--) if (j > p) { d[j] = d[j-1]; id_[j] = id_[j-1]; }
#pragma unroll
      for (int j = 0; j < 10; j++) if (j == p) { d[j] = dist; id_[j] = m; }
    }
  }
  int ptr = 0;
  for (int r = 0; r < 10; r++) {
    float bd = FLT_MAX; int bi = 0x7fffffff;
#pragma unroll
    for (int j = 0; j < 10; j++) if (j == ptr) { bd = d[j]; bi = id_[j]; }
    for (int off = 32; off >= 1; off >>= 1) {
      float od = __shfl_xor(bd, off);
      int   oi = __shfl_xor(bi, off);
      if (od < bd || (od == bd && oi < bi)) { bd = od; bi = oi; }
    }
    bool adv = false;
#pragma unroll
    for (int j = 0; j < 10; j++) if (j == ptr) adv = (d[j] == bd && id_[j] == bi);
    if (adv) ptr++;
    if (r > 0 && lane == 0) {
      size_t base = ((size_t)b*NPTS + n)*9 + (r - 1);
      idx[base] = bi;
      float dot = __fadd_rn(__fmul_rn(xn, px[bi]), __fmul_rn(yn, py[bi]));
      cosv[base] = __fdiv_rn(dot, __fmul_rn(__fsqrt_rn(sqn), __fsqrt_rn(sq[bi])));
    }
  }
}

// ---------------- unified f32 GEMM v2 (K-major LDS, b128 fragment reads) ----------------
// Y[4096][O] = X * W^T (+bias, +resid, pack, x-norm, concat-X)
// X virtually = [p0(w0) | p1(w1) | p2(w2)]; if addp: cols>=128 get +addp[r][(c-128)&127]
// if xstats: x = relu((x - m)*rs) with per (b, c & (xmod-1)) stats.
__global__ __launch_bounds__(256) void gemm_f(
    const float* __restrict__ p0, int w0,
    const float* __restrict__ p1, int w1,
    const float* __restrict__ p2, int w2,
    const float* __restrict__ addp,
    const float* __restrict__ xstats, int xmod,
    const float* __restrict__ W,
    const float* __restrict__ bias,
    const float* __restrict__ resid,
    float* __restrict__ Y, int Cin, int O, int pack)
{
  __shared__ float Xt[32][68], Wt[32][68];   // [k][row], [k][col]
  int tid = threadIdx.x;
  int r0 = blockIdx.x * 64, c0 = blockIdx.y * 64;
  int tx = tid & 15, ty = tid >> 4;
  int sr = tid & 63, scol = (tid >> 6) * 8;   // staging: row-major lanes (bank-balanced)
  float acc[4][4] = {};
  for (int k0 = 0; k0 < Cin; k0 += 32) {
    // ---- stage X transposed (with optional concat / add / norm-relu) ----
    {
      int r = r0 + sr;
      int ac = k0 + scol;                     // wave-uniform
      const float* P; int cc, lw;
      if (ac < w0) { P = p0; cc = ac; lw = w0; }
      else if (ac < w0 + w1) { P = p1; cc = ac - w0; lw = w1; }
      else { P = p2; cc = ac - w0 - w1; lw = w2; }
      float4 v0 = *(const float4*)(P + (size_t)r*lw + cc);
      float4 v1 = *(const float4*)(P + (size_t)r*lw + cc + 4);
      float vv[8] = {v0.x, v0.y, v0.z, v0.w, v1.x, v1.y, v1.z, v1.w};
      if (addp && ac >= 128) {
        int fc = (ac - 128) & 127;
        float4 a0 = *(const float4*)(addp + (size_t)r*128 + fc);
        float4 a1 = *(const float4*)(addp + (size_t)r*128 + fc + 4);
        vv[0]+=a0.x; vv[1]+=a0.y; vv[2]+=a0.z; vv[3]+=a0.w;
        vv[4]+=a1.x; vv[5]+=a1.y; vv[6]+=a1.z; vv[7]+=a1.w;
      }
      if (xstats) {
        int b = r >> 11;
#pragma unroll
        for (int j = 0; j < 8; j++) {
          int o = (ac + j) & (xmod - 1);
          float m = xstats[(b*xmod + o)*2], rs = xstats[(b*xmod + o)*2 + 1];
          vv[j] = fmaxf((vv[j] - m) * rs, 0.f);
        }
      }
#pragma unroll
      for (int j = 0; j < 8; j++) Xt[scol + j][sr] = vv[j];
    }
    // ---- stage W transposed ----
    {
      const float* s = W + (size_t)(c0 + sr)*Cin + k0 + scol;
      float4 v0 = *(const float4*)s, v1 = *(const float4*)(s + 4);
      Wt[scol+0][sr]=v0.x; Wt[scol+1][sr]=v0.y; Wt[scol+2][sr]=v0.z; Wt[scol+3][sr]=v0.w;
      Wt[scol+4][sr]=v1.x; Wt[scol+5][sr]=v1.y; Wt[scol+6][sr]=v1.z; Wt[scol+7][sr]=v1.w;
    }
    __syncthreads();
#pragma unroll
    for (int kk = 0; kk < 32; kk++) {
      float4 av = *(const float4*)&Xt[kk][ty*4];
      float4 bv = *(const float4*)&Wt[kk][tx*4];
      acc[0][0] = fmaf(av.x, bv.x, acc[0][0]);
      acc[0][1] = fmaf(av.x, bv.y, acc[0][1]);
      acc[0][2] = fmaf(av.x, bv.z, acc[0][2]);
      acc[0][3] = fmaf(av.x, bv.w, acc[0][3]);
      acc[1][0] = fmaf(av.y, bv.x, acc[1][0]);
      acc[1][1] = fmaf(av.y, bv.y, acc[1][1]);
      acc[1][2] = fmaf(av.y, bv.z, acc[1][2]);
      acc[1][3] = fmaf(av.y, bv.w, acc[1][3]);
      acc[2][0] = fmaf(av.z, bv.x, acc[2][0]);
      acc[2][1] = fmaf(av.z, bv.y, acc[2][1]);
      acc[2][2] = fmaf(av.z, bv.z, acc[2][2]);
      acc[2][3] = fmaf(av.z, bv.w, acc[2][3]);
      acc[3][0] = fmaf(av.w, bv.x, acc[3][0]);
      acc[3][1] = fmaf(av.w, bv.y, acc[3][1]);
      acc[3][2] = fmaf(av.w, bv.z, acc[3][2]);
      acc[3][3] = fmaf(av.w, bv.w, acc[3][3]);
    }
    __syncthreads();
  }
#pragma unroll
  for (int i = 0; i < 4; i++) {
    int r = r0 + ty*4 + i;
#pragma unroll
    for (int j = 0; j < 4; j++) {
      int c = c0 + tx*4 + j;
      float v = acc[i][j] + (bias ? bias[c] : 0.f);
      if (resid) v += resid[(size_t)r*O + c];
      if (pack) {
        int h = c & 3, dd = c >> 2, b = r >> 11, n = r & 2047;
        Y[(((size_t)(b*4 + h))*NPTS + n)*32 + dd] = v;
      } else {
        Y[(size_t)r*O + c] = v;
      }
    }
  }
}

// ---------------- annu conv1 combine: A[r][w*128+o] = G0 + sum_t Hnb + b1 ----------------
__global__ __launch_bounds__(384) void combine_annu(const float* __restrict__ GA, const int* __restrict__ idx,
                                                    const float* __restrict__ b1, float* __restrict__ A) {
  int r = blockIdx.x, t = threadIdx.x;
  int w = t >> 7, o = t & 127;
  int rb = r & ~2047;
  __shared__ int nb[9];
  if (t < 9) nb[t] = idx[(size_t)r*9 + t];
  __syncthreads();
  float acc = GA[(size_t)r*512 + o] + b1[o];
#pragma unroll
  for (int t3 = 0; t3 < 3; t3++) {
    int m = nb[w*3 + t3];
    acc += GA[(size_t)(rb + m)*512 + 128 + t3*128 + o];
  }
  A[(size_t)r*384 + w*128 + o] = acc;
}

// ---------------- instance-norm stats: partial + fenced tail-block final ----------------
__global__ __launch_bounds__(256) void stats_fused(const float* __restrict__ X, double* __restrict__ part,
                                                   float* __restrict__ stats, int J, int Cc,
                                                   int count, int nblkPerB, int* __restrict__ ctr) {
  int t = threadIdx.x;
  int o = t % Cc, sub = t / Cc, nsub = 256 / Cc;
  int r0 = blockIdx.x * 64;
  double s = 0.0, s2 = 0.0;
  for (int rr = sub; rr < 64; rr += nsub)
    for (int j = 0; j < J; j++) {
      double v = X[(((size_t)(r0 + rr))*J + j)*Cc + o];
      s += v; s2 += v*v;
    }
  __shared__ double ls[256], ls2[256];
  ls[t] = s; ls2[t] = s2;
  __syncthreads();
  if (sub == 0) {
    for (int u = 1; u < nsub; u++) { s += ls[u*Cc + o]; s2 += ls2[u*Cc + o]; }
    part[((size_t)blockIdx.x*Cc + o)*2] = s;
    part[((size_t)blockIdx.x*Cc + o)*2 + 1] = s2;
    __threadfence();
  }
  __syncthreads();
  __shared__ int lastBlk;
  if (t == 0) lastBlk = (atomicAdd(ctr, 1) == (int)gridDim.x - 1) ? 1 : 0;
  __syncthreads();
  if (!lastBlk) return;
  __threadfence();
  for (int i = t; i < 2*Cc; i += 256) {
    int b = i / Cc, oo = i % Cc;
    double S = 0.0, S2 = 0.0;
    for (int u = 0; u < nblkPerB; u++) {
      int blk = b*nblkPerB + u;
      S  += part[((size_t)blk*Cc + oo)*2];
      S2 += part[((size_t)blk*Cc + oo)*2 + 1];
    }
    double mean = S / count;
    double var = S2 / count - mean*mean;
    if (var < 0.0) var = 0.0;
    stats[i*2] = (float)mean;
    stats[i*2 + 1] = (float)(1.0 / sqrt(var + 1e-5));
  }
}

// act: 0 none, 1 relu, 2 lrelu(0.2); optional addend (J==1 layouts only)
__global__ void norm_act(const float* __restrict__ src, float* __restrict__ dst,
                         const float* __restrict__ stats, int J, int Cc, int act, int total,
                         const float* __restrict__ addend) {
  int i = blockIdx.x * 256 + threadIdx.x;
  if (i >= total) return;
  int o = i % Cc;
  int r = i / (J*Cc);
  int b = r >> 11;
  float m = stats[(b*Cc + o)*2], rs = stats[(b*Cc + o)*2 + 1];
  float v = (src[i] - m) * rs;
  if (act == 1) v = fmaxf(v, 0.f);
  else if (act == 2) v = (v >= 0.f) ? v : 0.2f*v;
  if (addend) v += addend[i];
  dst[i] = v;
}

// ---------------- angle-feature conv1 ----------------
__global__ void cos_conv(const float* __restrict__ cosv, const float* __restrict__ gw1,
                         const float* __restrict__ gb1, float* __restrict__ ANG, int total) {
  int i = blockIdx.x * 256 + threadIdx.x;
  if (i >= total) return;
  int o = i & 127, w = (i >> 7) % 3;
  int r = i / 384;
  float acc = gb1[o];
#pragma unroll
  for (int t = 0; t < 3; t++) acc += cosv[(size_t)r*9 + w*3 + t] * gw1[o*3 + t];
  ANG[i] = acc;
}

// ---------------- gather + max over k + fenced stats final ----------------
__global__ __launch_bounds__(256) void gather_max_fused(const float* __restrict__ G, const int* __restrict__ idx,
                                                        float* __restrict__ maxbuf, double* __restrict__ part,
                                                        float* __restrict__ stats, int Cc, int* __restrict__ ctr) {
  int t = threadIdx.x;
  int o = t % Cc, sub = t / Cc, nsub = 256 / Cc;
  int r0 = blockIdx.x * 16;
  double s = 0.0, s2 = 0.0;
  for (int rr = sub; rr < 16; rr += nsub) {
    int r = r0 + rr, rb = r & ~2047;
    float g = G[(size_t)r*2*Cc + o];
    float mx = -3.4e38f;
#pragma unroll
    for (int k = 0; k < 9; k++) {
      int m = idx[(size_t)r*9 + k];
      float v = g + G[(size_t)(rb + m)*2*Cc + Cc + o];
      mx = fmaxf(mx, v); s += (double)v; s2 += (double)v*(double)v;
    }
    maxbuf[(size_t)r*Cc + o] = mx;
  }
  __shared__ double ls[256], ls2[256];
  ls[t] = s; ls2[t] = s2;
  __syncthreads();
  if (sub == 0) {
    for (int u = 1; u < nsub; u++) { s += ls[u*Cc + o]; s2 += ls2[u*Cc + o]; }
    part[((size_t)blockIdx.x*Cc + o)*2] = s;
    part[((size_t)blockIdx.x*Cc + o)*2 + 1] = s2;
    __threadfence();
  }
  __syncthreads();
  __shared__ int lastBlk;
  if (t == 0) lastBlk = (atomicAdd(ctr, 1) == (int)gridDim.x - 1) ? 1 : 0;
  __syncthreads();
  if (!lastBlk) return;
  __threadfence();
  for (int i = t; i < 2*Cc; i += 256) {
    int b = i / Cc, oo = i % Cc;
    double S = 0.0, S2 = 0.0;
    for (int u = 0; u < 128; u++) {
      int blk = b*128 + u;
      S  += part[((size_t)blk*Cc + oo)*2];
      S2 += part[((size_t)blk*Cc + oo)*2 + 1];
    }
    double mean = S / (2048*9);
    double var = S2 / (2048*9) - mean*mean;
    if (var < 0.0) var = 0.0;
    stats[i*2] = (float)mean;
    stats[i*2 + 1] = (float)(1.0 / sqrt(var + 1e-5));
  }
}

// ---------------- flash attention v3: 32 q-rows/block, bank-balanced LDS ----------------
// thread (tx=tid&15, ty=tid>>4): score rows {ty, ty+16}, score cols 4tx..4tx+3, out dims {2tx, 2tx+1}
__global__ __launch_bounds__(256) void attn_flash(const float* __restrict__ Qp, const float* __restrict__ Kp,
                                                  const float* __restrict__ Vp, float* __restrict__ out) {
  __shared__ float Qt[32][33];   // [dim][row]
  __shared__ float Kt[32][68];   // [dim][key]
  __shared__ float Vs[64][36];   // [key][dim]
  __shared__ float Pt[64][33];   // [key][row]
  int tid = threadIdx.x;
  int tx = tid & 15, ty = tid >> 4;
  int bh = blockIdx.y;
  int q0 = blockIdx.x * 32;
  const float* Qh = Qp + (size_t)bh * NPTS * 32;
  const float* Kh = Kp + (size_t)bh * NPTS * 32;
  const float* Vh = Vp + (size_t)bh * NPTS * 32;
  // Q stage: r-major lanes -> bank-balanced transposed writes
  {
    int r = tid & 31, a4 = ((tid >> 5) & 7) * 4;
    float4 v = *(const float4*)(Qh + (size_t)(q0 + r)*32 + a4);
    Qt[a4+0][r] = v.x; Qt[a4+1][r] = v.y; Qt[a4+2][r] = v.z; Qt[a4+3][r] = v.w;
  }
  float m_[2] = {-FLT_MAX, -FLT_MAX};
  float l_[2] = {0.f, 0.f};
  float O_[2][2] = {};
  const float sc = 0.17677669529663687f;   // 1/sqrt(32)
  for (int k0 = 0; k0 < NPTS; k0 += 64) {
    __syncthreads();   // prev tile's readers done before overwriting Kt/Vs
    {
      int r = tid & 31, a4 = ((tid >> 5) & 7) * 4;
      float4 ka = *(const float4*)(Kh + (size_t)(k0 + r)*32 + a4);
      float4 kb = *(const float4*)(Kh + (size_t)(k0 + 32 + r)*32 + a4);
      Kt[a4+0][r] = ka.x; Kt[a4+1][r] = ka.y; Kt[a4+2][r] = ka.z; Kt[a4+3][r] = ka.w;
      Kt[a4+0][32+r] = kb.x; Kt[a4+1][32+r] = kb.y; Kt[a4+2][32+r] = kb.z; Kt[a4+3][32+r] = kb.w;
      int rv = tid & 63, av = (tid >> 6) * 4;
      *(float4*)&Vs[rv][av]      = *(const float4*)(Vh + (size_t)(k0 + rv)*32 + av);
      *(float4*)&Vs[rv][av + 16] = *(const float4*)(Vh + (size_t)(k0 + rv)*32 + av + 16);
    }
    __syncthreads();
    // S tile: acc[2][4] for rows {ty, ty+16}
    float acc[2][4] = {};
#pragma unroll
    for (int k = 0; k < 32; k++) {
      float a0 = Qt[k][ty], a1 = Qt[k][ty + 16];
      float4 bv = *(const float4*)&Kt[k][tx*4];
      acc[0][0] = fmaf(a0, bv.x, acc[0][0]);
      acc[0][1] = fmaf(a0, bv.y, acc[0][1]);
      acc[0][2] = fmaf(a0, bv.z, acc[0][2]);
      acc[0][3] = fmaf(a0, bv.w, acc[0][3]);
      acc[1][0] = fmaf(a1, bv.x, acc[1][0]);
      acc[1][1] = fmaf(a1, bv.y, acc[1][1]);
      acc[1][2] = fmaf(a1, bv.z, acc[1][2]);
      acc[1][3] = fmaf(a1, bv.w, acc[1][3]);
    }
#pragma unroll
    for (int i = 0; i < 2; i++)
#pragma unroll
      for (int j = 0; j < 4; j++) acc[i][j] *= sc;
    // online softmax
#pragma unroll
    for (int i = 0; i < 2; i++) {
      float tm = fmaxf(fmaxf(acc[i][0], acc[i][1]), fmaxf(acc[i][2], acc[i][3]));
      for (int s = 1; s < 16; s <<= 1) tm = fmaxf(tm, __shfl_xor(tm, s));
      float mn = fmaxf(m_[i], tm);
      float cf = __expf(m_[i] - mn);
      m_[i] = mn;
      l_[i] *= cf; O_[i][0] *= cf; O_[i][1] *= cf;
      float rs = 0.f;
#pragma unroll
      for (int j = 0; j < 4; j++) {
        float p = __expf(acc[i][j] - mn);
        rs += p;
        Pt[tx*4 + j][ty + 16*i] = p;   // bank = (4tx + j + ty + 16i) % 32 -> balanced
      }
      for (int s = 1; s < 16; s <<= 1) rs += __shfl_xor(rs, s);
      l_[i] += rs;
    }
    // PV (Pt comm is intra-16-lane-group; wave-ordered, no barrier needed)
#pragma unroll 8
    for (int kk = 0; kk < 64; kk++) {
      float p0 = Pt[kk][ty], p1 = Pt[kk][ty + 16];
      float2 vv = *(const float2*)&Vs[kk][tx*2];
      O_[0][0] = fmaf(p0, vv.x, O_[0][0]);
      O_[0][1] = fmaf(p0, vv.y, O_[0][1]);
      O_[1][0] = fmaf(p1, vv.x, O_[1][0]);
      O_[1][1] = fmaf(p1, vv.y, O_[1][1]);
    }
  }
  int b = bh >> 2, h = bh & 3;
#pragma unroll
  for (int i = 0; i < 2; i++) {
    int n = q0 + ty + 16*i;
    float inv = 1.f / l_[i];
    out[((size_t)(b*NPTS + n))*128 + (tx*2+0)*4 + h] = O_[i][0] * inv;
    out[((size_t)(b*NPTS + n))*128 + (tx*2+1)*4 + h] = O_[i][1] * inv;
  }
}

// ================= host =================
extern "C" void kernel_launch(void* const* d_in, const int* in_sizes, int n_in,
                              void* d_out, int out_size, void* d_ws, size_t ws_size,
                              hipStream_t stream) {
  (void)in_sizes; (void)n_in; (void)out_size; (void)ws_size;
  const float* desc0  = (const float*)d_in[0];
  const float* desc1  = (const float*)d_in[1];
  const float* coords0= (const float*)d_in[2];
  const float* coords1= (const float*)d_in[3];
  const float* conv1w = (const float*)d_in[4];
  const float* conv2w = (const float*)d_in[5];
  const float* conv3w = (const float*)d_in[6];
  const float* conv3ow= (const float*)d_in[7];
  const float* a1w1 = (const float*)d_in[8];
  const float* a1b1 = (const float*)d_in[9];
  const float* a1w2 = (const float*)d_in[10];
  const float* a1b2 = (const float*)d_in[11];
  const float* a2w1 = (const float*)d_in[12];
  const float* a2b1 = (const float*)d_in[13];
  const float* a2w2 = (const float*)d_in[14];
  const float* a2b2 = (const float*)d_in[15];
  const float* gw1  = (const float*)d_in[16];
  const float* gb1  = (const float*)d_in[17];
  const float* gw2  = (const float*)d_in[18];
  const float* gb2  = (const float*)d_in[19];
  const float* wq = (const float*)d_in[20]; const float* bq = (const float*)d_in[21];
  const float* wk = (const float*)d_in[22]; const float* bk = (const float*)d_in[23];
  const float* wv = (const float*)d_in[24]; const float* bv = (const float*)d_in[25];
  const float* wm = (const float*)d_in[26]; const float* bm = (const float*)d_in[27];
  const float* mw1 = (const float*)d_in[28]; const float* mb1 = (const float*)d_in[29];
  const float* mw2 = (const float*)d_in[30]; const float* mb2 = (const float*)d_in[31];

  float* ws = (float*)d_ws;
  size_t off = 0;
  auto alloc = [&](size_t nel) { size_t r = off; off += (nel + 63) & ~(size_t)63; return r; };
  float* DW_A1 = ws + alloc(512*128);
  float* W_A1R = ws + alloc(128*384);
  float* DW_A2 = ws + alloc(512*128);
  float* W_A2R = ws + alloc(128*384);
  float* W_G2R = ws + alloc(128*384);
  float* DW_C1 = ws + alloc(256*128);
  float* DW_C2 = ws + alloc(512*128);
  float* SA0  = ws + alloc((size_t)RTOT*128);
  float* SA1  = ws + alloc((size_t)RTOT*128);
  float* XF0  = ws + alloc((size_t)RTOT*128);
  float* XF1  = ws + alloc((size_t)RTOT*128);
  int*   IDX  = (int*)(ws + alloc((size_t)RTOT*9));
  float* COSV = ws + alloc((size_t)RTOT*9);
  float* FT   = ws + alloc((size_t)RTOT*128);
  float* BIG  = ws + alloc((size_t)RTOT*512);
  float* ABUF = ws + alloc((size_t)RTOT*384);
  float* X1B  = ws + alloc((size_t)RTOT*128);
  float* FANG = ws + alloc((size_t)RTOT*128);
  float* X2B  = ws + alloc((size_t)RTOT*128);
  float* X3A  = ws + alloc((size_t)RTOT*128);
  float* X1O  = ws + alloc((size_t)RTOT*128);
  float* SM   = ws + alloc((size_t)RTOT*256);
  float* X3O  = ws + alloc((size_t)RTOT*128);
  double* PART = (double*)(ws + alloc(256*256*2*2));   // 131072 doubles
  float* STAT = ws + alloc(2*256*2);
  int*   CTR  = (int*)(ws + alloc(64));

  hipMemsetAsync(CTR, 0, 64*sizeof(int), stream);
  int ctr_id = 0;

  auto gemm1 = [&](const float* X, const float* W, const float* bias, float* Y, int Cin, int O,
                   const float* xst, int xmod, const float* resid, int pack) {
    gemm_f<<<dim3(64, O/64), 256, 0, stream>>>(X, Cin, nullptr, 0, nullptr, 0, nullptr,
                                               xst, xmod, W, bias, resid, Y, Cin, O, pack);
  };
  auto gemm3 = [&](const float* a, int wa, const float* b, int wb, const float* c, int wc,
                   const float* addp, const float* W, const float* bias, float* Y, int Cin, int O) {
    gemm_f<<<dim3(64, O/64), 256, 0, stream>>>(a, wa, b, wb, c, wc, addp,
                                               nullptr, 0, W, bias, nullptr, Y, Cin, O, 0);
  };
  auto stats_only = [&](float* buf, int J, int Cc, int count) {
    stats_fused<<<64, 256, 0, stream>>>(buf, PART, STAT, J, Cc, count, 32, CTR + ctr_id++);
  };
  auto statnorm = [&](float* buf, float* dst, int J, int Cc, int act, int count, const float* addend) {
    stats_only(buf, J, Cc, count);
    int tot = RTOT*J*Cc;
    norm_act<<<(tot + 255)/256, 256, 0, stream>>>(buf, dst, STAT, J, Cc, act, tot, addend);
  };
  auto gathermax = [&](float* G, float* mx, float* dstNorm, int Cc) {
    gather_max_fused<<<256, 256, 0, stream>>>(G, IDX, mx, PART, STAT, Cc, CTR + ctr_id++);
    int tot = RTOT*Cc;
    norm_act<<<(tot + 255)/256, 256, 0, stream>>>(mx, dstNorm, STAT, 1, Cc, 2, tot, nullptr);
  };

  prep_weights<<<256, 256, 0, stream>>>(conv1w, conv2w, a1w1, a1w2, a2w1, a2w2, gw2,
                                        DW_A1, W_A1R, DW_A2, W_A2R, W_G2R, DW_C1, DW_C2);

  auto branch = [&](const float* F, const float* P, float* sa) {
    transpose_k<<<dim3(2048/32, 128/32, 2), dim3(32, 8), 0, stream>>>(F, FT, 128, 2048);
    knn_kernel<<<1024, 256, 0, stream>>>(P, IDX, COSV);
    // annu1
    gemm1(FT, DW_A1, nullptr, BIG, 128, 512, nullptr, 0, nullptr, 0);
    combine_annu<<<RTOT, 384, 0, stream>>>(BIG, IDX, a1b1, ABUF);
    stats_only(ABUF, 3, 128, 2048*3);
    gemm1(ABUF, W_A1R, a1b2, X1B, 384, 128, STAT, 128, nullptr, 0);
    statnorm(X1B, X1B, 1, 128, 1, 2048, nullptr);
    // f_ang (shared: idx1 == idx2)
    cos_conv<<<(RTOT*384 + 255)/256, 256, 0, stream>>>(COSV, gw1, gb1, ABUF, RTOT*384);
    stats_only(ABUF, 3, 128, 2048*3);
    gemm1(ABUF, W_G2R, gb2, FANG, 384, 128, STAT, 128, nullptr, 0);
    statnorm(FANG, FANG, 1, 128, 1, 2048, nullptr);
    // annu2
    gemm1(X1B, DW_A2, nullptr, BIG, 128, 512, nullptr, 0, nullptr, 0);
    combine_annu<<<RTOT, 384, 0, stream>>>(BIG, IDX, a2b1, ABUF);
    stats_only(ABUF, 3, 128, 2048*3);
    gemm1(ABUF, W_A2R, a2b2, X2B, 384, 128, STAT, 128, nullptr, 0);
    statnorm(X2B, X2B, 1, 128, 1, 2048, nullptr);
    // x3 = lrelu(inorm(conv3 * [x0 | x1+fang | x2+fang]))
    gemm3(FT, 128, X1B, 128, X2B, 128, FANG, conv3w, nullptr, X3A, 384, 128);
    statnorm(X3A, X3A, 1, 128, 2, 2048, nullptr);
    // x1o
    gemm1(FT, DW_C1, nullptr, BIG, 128, 256, nullptr, 0, nullptr, 0);
    gathermax(BIG, SM, X1O, 128);
    // x2o
    gemm1(X1O, DW_C2, nullptr, BIG, 128, 512, nullptr, 0, nullptr, 0);
    gathermax(BIG, SM, SM, 256);
    // x3o = lrelu(inorm(conv3o * [x0 | x1o | x2o])) + x3
    gemm3(FT, 128, X1O, 128, SM, 256, nullptr, conv3ow, nullptr, X3O, 512, 128);
    statnorm(X3O, sa, 1, 128, 2, 2048, X3A);
  };

  branch(desc0, coords0, SA0);
  branch(desc1, coords1, SA1);

  auto prop = [&](const float* xin, const float* src, float* dst) {
    gemm1(xin, wq, bq, X3A, 128, 128, nullptr, 0, nullptr, 1);   // packed Q
    gemm1(src, wk, bk, X1O, 128, 128, nullptr, 0, nullptr, 1);   // packed K
    gemm1(src, wv, bv, X3O, 128, 128, nullptr, 0, nullptr, 1);   // packed V
    attn_flash<<<dim3(64, 8), 256, 0, stream>>>(X3A, X1O, X3O, ABUF);
    gemm1(ABUF, wm, bm, SM, 128, 128, nullptr, 0, nullptr, 0);
    gemm3(xin, 128, SM, 128, nullptr, 0, nullptr, mw1, mb1, ABUF, 256, 256);
    stats_only(ABUF, 1, 256, 2048);
    gemm1(ABUF, mw2, mb2, dst, 256, 128, STAT, 256, xin, 0);     // fused norm-relu + residual
  };

  prop(SA0, SA1, XF0);
  prop(SA1, XF0, XF1);

  transpose_k<<<dim3(128/32, 2048/32, 2), dim3(32, 8), 0, stream>>>(XF0, (float*)d_out, 2048, 128);
  transpose_k<<<dim3(128/32, 2048/32, 2), dim3(32, 8), 0, stream>>>(XF1, (float*)d_out + (size_t)RTOT*128, 2048, 128);
}

// Round 7
// 1493.789 us; speedup vs baseline: 3.0280x; 1.1931x over previous
//
#include <hip/hip_runtime.h>
#include <cfloat>
#include <math.h>

#define NPTS 2048
#define R2   8192   // merged: 2 tensors x B=2 x N=2048

// ---------------- prep: derived weight matrices ----------------
__global__ __launch_bounds__(256) void prep_weights(
    const float* __restrict__ conv1, const float* __restrict__ conv2,
    const float* __restrict__ a1w1, const float* __restrict__ a1w2,
    const float* __restrict__ a2w1, const float* __restrict__ a2w2,
    const float* __restrict__ gw2,
    float* __restrict__ dwA1, float* __restrict__ a1w2r,
    float* __restrict__ dwA2, float* __restrict__ a2w2r,
    float* __restrict__ gw2r, float* __restrict__ dwC1, float* __restrict__ dwC2)
{
  int i = blockIdx.x * 256 + threadIdx.x;
  if (i < 512*128) {
    int row = i >> 7, c = i & 127;
    float v1, v2;
    if (row < 128) {             // ctrW[o][c] = sum_t (w1[o,c,t] - w1[o,128+c,t])
      float s1 = 0.f, s2 = 0.f;
      for (int t = 0; t < 3; t++) {
        s1 += a1w1[(row*256 + c)*3 + t] - a1w1[(row*256 + 128 + c)*3 + t];
        s2 += a2w1[(row*256 + c)*3 + t] - a2w1[(row*256 + 128 + c)*3 + t];
      }
      v1 = s1; v2 = s2;
    } else {                     // row = 128 + t*128 + o : nbW_t[o][c] = w1[o,128+c,t]
      int t = (row - 128) >> 7, o = row & 127;
      v1 = a1w1[(o*256 + 128 + c)*3 + t];
      v2 = a2w1[(o*256 + 128 + c)*3 + t];
    }
    dwA1[i] = v1; dwA2[i] = v2;
    dwC2[i] = (row < 256) ? (conv2[row*256 + c] - conv2[row*256 + 128 + c])
                          : conv2[(row-256)*256 + 128 + c];
  }
  if (i < 128*384) {             // w2r[o][w*128+c] = w2[o,c,w]
    int o = i / 384, rem = i % 384, w = rem >> 7, c = rem & 127;
    a1w2r[i] = a1w2[(o*128 + c)*3 + w];
    a2w2r[i] = a2w2[(o*128 + c)*3 + w];
    gw2r[i]  = gw2[(o*128 + c)*3 + w];
  }
  if (i < 256*128) {             // dwC1 [256][128] from conv1 [128][256]
    int row = i >> 7, c = i & 127;
    dwC1[i] = (row < 128) ? (conv1[row*256 + c] - conv1[row*256 + 128 + c])
                          : conv1[(row-128)*256 + 128 + c];
  }
}

// ---------------- transpose both descs: in [2][I][J] x2 -> out [4][J][I] ----------------
__global__ void transpose2(const float* __restrict__ in0, const float* __restrict__ in1,
                           float* __restrict__ out, int I, int J) {
  __shared__ float tile[32][33];
  int zb = blockIdx.z;
  const float* src = (zb < 2) ? (in0 + (size_t)zb*I*J) : (in1 + (size_t)(zb-2)*I*J);
  float* dst = out + (size_t)zb*J*I;
  int i0 = blockIdx.y * 32, j0 = blockIdx.x * 32;
  int tx = threadIdx.x, ty = threadIdx.y;
  for (int s = 0; s < 32; s += 8)
    tile[ty + s][tx] = src[(size_t)(i0 + ty + s)*J + (j0 + tx)];
  __syncthreads();
  for (int s = 0; s < 32; s += 8)
    dst[(size_t)(j0 + ty + s)*I + (i0 + tx)] = tile[tx][ty + s];
}

// ---------------- transpose [b][I][J] -> [b][J][I] (final output) ----------------
__global__ void transpose_k(const float* __restrict__ in, float* __restrict__ out, int I, int J) {
  __shared__ float tile[32][33];
  int b = blockIdx.z;
  int i0 = blockIdx.y * 32, j0 = blockIdx.x * 32;
  int tx = threadIdx.x, ty = threadIdx.y;
  for (int s = 0; s < 32; s += 8)
    tile[ty + s][tx] = in[((size_t)b*I + (i0 + ty + s))*J + (j0 + tx)];
  __syncthreads();
  for (int s = 0; s < 32; s += 8)
    out[((size_t)b*J + (j0 + ty + s))*I + (i0 + tx)] = tile[tx][ty + s];
}

// ---------------- KNN (both coord sets): f32 np-exact distances, (dist,idx)-lex ----------------
__global__ __launch_bounds__(256) void knn2_kernel(const float* __restrict__ P0, const float* __restrict__ P1,
                                                   int* __restrict__ idx, float* __restrict__ cosv) {
  __shared__ float px[NPTS], py[NPTS], sq[NPTS];
  int tid = threadIdx.x;
  int gw = blockIdx.x * 4 + (tid >> 6);   // 0..8191 : global point id
  int b4 = gw >> 11, n = gw & 2047;
  int lane = tid & 63;
  const float* Pb = (b4 < 2) ? (P0 + (size_t)b4 * 2 * NPTS) : (P1 + (size_t)(b4 - 2) * 2 * NPTS);
  for (int i = tid; i < NPTS; i += 256) {
    float x = Pb[i], y = Pb[NPTS + i];
    px[i] = x; py[i] = y;
    sq[i] = __fadd_rn(__fmul_rn(x, x), __fmul_rn(y, y));
  }
  __syncthreads();
  float xn = px[n], yn = py[n], sqn = sq[n];
  float d[10]; int id_[10];
#pragma unroll
  for (int j = 0; j < 10; j++) { d[j] = FLT_MAX; id_[j] = 0x7fffffff; }
  for (int m = lane; m < NPTS; m += 64) {
    float dot  = __fadd_rn(__fmul_rn(xn, px[m]), __fmul_rn(yn, py[m]));
    float dist = __fsub_rn(__fadd_rn(sqn, sq[m]), __fmul_rn(2.0f, dot));
    dist = fmaxf(dist, 1e-12f);
    if (dist < d[9] || (dist == d[9] && m < id_[9])) {
      int p = 0;
#pragma unroll
      for (int j = 0; j < 10; j++) p += (d[j] < dist || (d[j] == dist && id_[j] < m)) ? 1 : 0;
#pragma unroll
      for (int j = 9; j >= 1; j--) if (j > p) { d[j] = d[j-1]; id_[j] = id_[j-1]; }
#pragma unroll
      for (int j = 0; j < 10; j++) if (j == p) { d[j] = dist; id_[j] = m; }
    }
  }
  int ptr = 0;
  for (int r = 0; r < 10; r++) {
    float bd = FLT_MAX; int bi = 0x7fffffff;
#pragma unroll
    for (int j = 0; j < 10; j++) if (j == ptr) { bd = d[j]; bi = id_[j]; }
    for (int off = 32; off >= 1; off >>= 1) {
      float od = __shfl_xor(bd, off);
      int   oi = __shfl_xor(bi, off);
      if (od < bd || (od == bd && oi < bi)) { bd = od; bi = oi; }
    }
    bool adv = false;
#pragma unroll
    for (int j = 0; j < 10; j++) if (j == ptr) adv = (d[j] == bd && id_[j] == bi);
    if (adv) ptr++;
    if (r > 0 && lane == 0) {
      size_t base = (size_t)gw*9 + (r - 1);
      idx[base] = bi;   // local index within instance
      float dot = __fadd_rn(__fmul_rn(xn, px[bi]), __fmul_rn(yn, py[bi]));
      cosv[base] = __fdiv_rn(dot, __fmul_rn(__fsqrt_rn(sqn), __fsqrt_rn(sq[bi])));
    }
  }
}

// ---------------- unified f32 GEMM (K-major LDS, b128 fragment reads) ----------------
__global__ __launch_bounds__(256) void gemm_f(
    const float* __restrict__ p0, int w0,
    const float* __restrict__ p1, int w1,
    const float* __restrict__ p2, int w2,
    const float* __restrict__ addp,
    const float* __restrict__ xstats, int xmod,
    const float* __restrict__ W,
    const float* __restrict__ bias,
    const float* __restrict__ resid,
    float* __restrict__ Y, int Cin, int O, int pack)
{
  __shared__ float Xt[32][68], Wt[32][68];
  int tid = threadIdx.x;
  int r0 = blockIdx.x * 64, c0 = blockIdx.y * 64;
  int tx = tid & 15, ty = tid >> 4;
  int sr = tid & 63, scol = (tid >> 6) * 8;
  float acc[4][4] = {};
  for (int k0 = 0; k0 < Cin; k0 += 32) {
    {
      int r = r0 + sr;
      int ac = k0 + scol;
      const float* P; int cc, lw;
      if (ac < w0) { P = p0; cc = ac; lw = w0; }
      else if (ac < w0 + w1) { P = p1; cc = ac - w0; lw = w1; }
      else { P = p2; cc = ac - w0 - w1; lw = w2; }
      float4 v0 = *(const float4*)(P + (size_t)r*lw + cc);
      float4 v1 = *(const float4*)(P + (size_t)r*lw + cc + 4);
      float vv[8] = {v0.x, v0.y, v0.z, v0.w, v1.x, v1.y, v1.z, v1.w};
      if (addp && ac >= 128) {
        int fc = (ac - 128) & 127;
        float4 a0 = *(const float4*)(addp + (size_t)r*128 + fc);
        float4 a1 = *(const float4*)(addp + (size_t)r*128 + fc + 4);
        vv[0]+=a0.x; vv[1]+=a0.y; vv[2]+=a0.z; vv[3]+=a0.w;
        vv[4]+=a1.x; vv[5]+=a1.y; vv[6]+=a1.z; vv[7]+=a1.w;
      }
      if (xstats) {
        int b = r >> 11;
#pragma unroll
        for (int j = 0; j < 8; j++) {
          int o = (ac + j) & (xmod - 1);
          float m = xstats[(b*xmod + o)*2], rs = xstats[(b*xmod + o)*2 + 1];
          vv[j] = fmaxf((vv[j] - m) * rs, 0.f);
        }
      }
#pragma unroll
      for (int j = 0; j < 8; j++) Xt[scol + j][sr] = vv[j];
    }
    {
      const float* s = W + (size_t)(c0 + sr)*Cin + k0 + scol;
      float4 v0 = *(const float4*)s, v1 = *(const float4*)(s + 4);
      Wt[scol+0][sr]=v0.x; Wt[scol+1][sr]=v0.y; Wt[scol+2][sr]=v0.z; Wt[scol+3][sr]=v0.w;
      Wt[scol+4][sr]=v1.x; Wt[scol+5][sr]=v1.y; Wt[scol+6][sr]=v1.z; Wt[scol+7][sr]=v1.w;
    }
    __syncthreads();
#pragma unroll
    for (int kk = 0; kk < 32; kk++) {
      float4 av = *(const float4*)&Xt[kk][ty*4];
      float4 bv = *(const float4*)&Wt[kk][tx*4];
      acc[0][0] = fmaf(av.x, bv.x, acc[0][0]);
      acc[0][1] = fmaf(av.x, bv.y, acc[0][1]);
      acc[0][2] = fmaf(av.x, bv.z, acc[0][2]);
      acc[0][3] = fmaf(av.x, bv.w, acc[0][3]);
      acc[1][0] = fmaf(av.y, bv.x, acc[1][0]);
      acc[1][1] = fmaf(av.y, bv.y, acc[1][1]);
      acc[1][2] = fmaf(av.y, bv.z, acc[1][2]);
      acc[1][3] = fmaf(av.y, bv.w, acc[1][3]);
      acc[2][0] = fmaf(av.z, bv.x, acc[2][0]);
      acc[2][1] = fmaf(av.z, bv.y, acc[2][1]);
      acc[2][2] = fmaf(av.z, bv.z, acc[2][2]);
      acc[2][3] = fmaf(av.z, bv.w, acc[2][3]);
      acc[3][0] = fmaf(av.w, bv.x, acc[3][0]);
      acc[3][1] = fmaf(av.w, bv.y, acc[3][1]);
      acc[3][2] = fmaf(av.w, bv.z, acc[3][2]);
      acc[3][3] = fmaf(av.w, bv.w, acc[3][3]);
    }
    __syncthreads();
  }
#pragma unroll
  for (int i = 0; i < 4; i++) {
    int r = r0 + ty*4 + i;
#pragma unroll
    for (int j = 0; j < 4; j++) {
      int c = c0 + tx*4 + j;
      float v = acc[i][j] + (bias ? bias[c] : 0.f);
      if (resid) v += resid[(size_t)r*O + c];
      if (pack) {
        int h = c & 3, dd = c >> 2, b = r >> 11, n = r & 2047;
        Y[(((size_t)(b*4 + h))*NPTS + n)*32 + dd] = v;
      } else {
        Y[(size_t)r*O + c] = v;
      }
    }
  }
}

// ---------------- annu conv1 combine ----------------
__global__ __launch_bounds__(384) void combine_annu(const float* __restrict__ GA, const int* __restrict__ idx,
                                                    const float* __restrict__ b1, float* __restrict__ A) {
  int r = blockIdx.x, t = threadIdx.x;
  int w = t >> 7, o = t & 127;
  int rb = r & ~2047;
  __shared__ int nb[9];
  if (t < 9) nb[t] = idx[(size_t)r*9 + t];
  __syncthreads();
  float acc = GA[(size_t)r*512 + o] + b1[o];
#pragma unroll
  for (int t3 = 0; t3 < 3; t3++) {
    int m = nb[w*3 + t3];
    acc += GA[(size_t)(rb + m)*512 + 128 + t3*128 + o];
  }
  A[(size_t)r*384 + w*128 + o] = acc;
}

// ---------------- instance-norm stats: partial + fenced tail-block final ----------------
__global__ __launch_bounds__(256) void stats_fused(const float* __restrict__ X, double* __restrict__ part,
                                                   float* __restrict__ stats, int J, int Cc, int NB,
                                                   int count, int nblkPerB, int* __restrict__ ctr) {
  int t = threadIdx.x;
  int o = t % Cc, sub = t / Cc, nsub = 256 / Cc;
  int r0 = blockIdx.x * 64;
  double s = 0.0, s2 = 0.0;
  for (int rr = sub; rr < 64; rr += nsub)
    for (int j = 0; j < J; j++) {
      double v = X[(((size_t)(r0 + rr))*J + j)*Cc + o];
      s += v; s2 += v*v;
    }
  __shared__ double ls[256], ls2[256];
  ls[t] = s; ls2[t] = s2;
  __syncthreads();
  if (sub == 0) {
    for (int u = 1; u < nsub; u++) { s += ls[u*Cc + o]; s2 += ls2[u*Cc + o]; }
    part[((size_t)blockIdx.x*Cc + o)*2] = s;
    part[((size_t)blockIdx.x*Cc + o)*2 + 1] = s2;
    __threadfence();
  }
  __syncthreads();
  __shared__ int lastBlk;
  if (t == 0) lastBlk = (atomicAdd(ctr, 1) == (int)gridDim.x - 1) ? 1 : 0;
  __syncthreads();
  if (!lastBlk) return;
  __threadfence();
  for (int i = t; i < NB*Cc; i += 256) {
    int b = i / Cc, oo = i % Cc;
    double S = 0.0, S2 = 0.0;
    for (int u = 0; u < nblkPerB; u++) {
      int blk = b*nblkPerB + u;
      S  += part[((size_t)blk*Cc + oo)*2];
      S2 += part[((size_t)blk*Cc + oo)*2 + 1];
    }
    double mean = S / count;
    double var = S2 / count - mean*mean;
    if (var < 0.0) var = 0.0;
    stats[i*2] = (float)mean;
    stats[i*2 + 1] = (float)(1.0 / sqrt(var + 1e-5));
  }
}

// act: 0 none, 1 relu, 2 lrelu(0.2); optional addend
__global__ void norm_act(const float* __restrict__ src, float* __restrict__ dst,
                         const float* __restrict__ stats, int J, int Cc, int act, int total,
                         const float* __restrict__ addend) {
  int i = blockIdx.x * 256 + threadIdx.x;
  if (i >= total) return;
  int o = i % Cc;
  int r = i / (J*Cc);
  int b = r >> 11;
  float m = stats[(b*Cc + o)*2], rs = stats[(b*Cc + o)*2 + 1];
  float v = (src[i] - m) * rs;
  if (act == 1) v = fmaxf(v, 0.f);
  else if (act == 2) v = (v >= 0.f) ? v : 0.2f*v;
  if (addend) v += addend[i];
  dst[i] = v;
}

// ---------------- angle-feature conv1 ----------------
__global__ void cos_conv(const float* __restrict__ cosv, const float* __restrict__ gw1,
                         const float* __restrict__ gb1, float* __restrict__ ANG, int total) {
  int i = blockIdx.x * 256 + threadIdx.x;
  if (i >= total) return;
  int o = i & 127, w = (i >> 7) % 3;
  int r = i / 384;
  float acc = gb1[o];
#pragma unroll
  for (int t = 0; t < 3; t++) acc += cosv[(size_t)r*9 + w*3 + t] * gw1[o*3 + t];
  ANG[i] = acc;
}

// ---------------- gather + max over k + fenced stats final ----------------
__global__ __launch_bounds__(256) void gather_max_fused(const float* __restrict__ G, const int* __restrict__ idx,
                                                        float* __restrict__ maxbuf, double* __restrict__ part,
                                                        float* __restrict__ stats, int Cc, int NB,
                                                        int* __restrict__ ctr) {
  int t = threadIdx.x;
  int o = t % Cc, sub = t / Cc, nsub = 256 / Cc;
  int r0 = blockIdx.x * 16;
  double s = 0.0, s2 = 0.0;
  for (int rr = sub; rr < 16; rr += nsub) {
    int r = r0 + rr, rb = r & ~2047;
    float g = G[(size_t)r*2*Cc + o];
    float mx = -3.4e38f;
#pragma unroll
    for (int k = 0; k < 9; k++) {
      int m = idx[(size_t)r*9 + k];
      float v = g + G[(size_t)(rb + m)*2*Cc + Cc + o];
      mx = fmaxf(mx, v); s += (double)v; s2 += (double)v*(double)v;
    }
    maxbuf[(size_t)r*Cc + o] = mx;
  }
  __shared__ double ls[256], ls2[256];
  ls[t] = s; ls2[t] = s2;
  __syncthreads();
  if (sub == 0) {
    for (int u = 1; u < nsub; u++) { s += ls[u*Cc + o]; s2 += ls2[u*Cc + o]; }
    part[((size_t)blockIdx.x*Cc + o)*2] = s;
    part[((size_t)blockIdx.x*Cc + o)*2 + 1] = s2;
    __threadfence();
  }
  __syncthreads();
  __shared__ int lastBlk;
  if (t == 0) lastBlk = (atomicAdd(ctr, 1) == (int)gridDim.x - 1) ? 1 : 0;
  __syncthreads();
  if (!lastBlk) return;
  __threadfence();
  int nblkPerB = (int)gridDim.x / NB;
  for (int i = t; i < NB*Cc; i += 256) {
    int b = i / Cc, oo = i % Cc;
    double S = 0.0, S2 = 0.0;
    for (int u = 0; u < nblkPerB; u++) {
      int blk = b*nblkPerB + u;
      S  += part[((size_t)blk*Cc + oo)*2];
      S2 += part[((size_t)blk*Cc + oo)*2 + 1];
    }
    double mean = S / (2048*9);
    double var = S2 / (2048*9) - mean*mean;
    if (var < 0.0) var = 0.0;
    stats[i*2] = (float)mean;
    stats[i*2 + 1] = (float)(1.0 / sqrt(var + 1e-5));
  }
}

// ---------------- flash attention, split-K part: 32 q-rows x 1024 keys ----------------
__global__ __launch_bounds__(256) void attn_part(const float* __restrict__ Qp, const float* __restrict__ Kp,
                                                 const float* __restrict__ Vp,
                                                 float* __restrict__ OP, float* __restrict__ ML) {
  __shared__ float Qt[32][33];
  __shared__ float Kt[32][68];
  __shared__ float Vs[64][36];
  __shared__ float Pt[64][33];
  int tid = threadIdx.x;
  int tx = tid & 15, ty = tid >> 4;
  int kp = blockIdx.y;      // key half
  int bh = blockIdx.z;
  int q0 = blockIdx.x * 32;
  const float* Qh = Qp + (size_t)bh * NPTS * 32;
  const float* Kh = Kp + (size_t)bh * NPTS * 32;
  const float* Vh = Vp + (size_t)bh * NPTS * 32;
  {
    int r = tid & 31, a4 = ((tid >> 5) & 7) * 4;
    float4 v = *(const float4*)(Qh + (size_t)(q0 + r)*32 + a4);
    Qt[a4+0][r] = v.x; Qt[a4+1][r] = v.y; Qt[a4+2][r] = v.z; Qt[a4+3][r] = v.w;
  }
  float m_[2] = {-FLT_MAX, -FLT_MAX};
  float l_[2] = {0.f, 0.f};
  float O_[2][2] = {};
  const float sc = 0.17677669529663687f;
  int ks = kp * 1024;
  for (int k0 = ks; k0 < ks + 1024; k0 += 64) {
    __syncthreads();
    {
      int r = tid & 31, a4 = ((tid >> 5) & 7) * 4;
      float4 ka = *(const float4*)(Kh + (size_t)(k0 + r)*32 + a4);
      float4 kb = *(const float4*)(Kh + (size_t)(k0 + 32 + r)*32 + a4);
      Kt[a4+0][r] = ka.x; Kt[a4+1][r] = ka.y; Kt[a4+2][r] = ka.z; Kt[a4+3][r] = ka.w;
      Kt[a4+0][32+r] = kb.x; Kt[a4+1][32+r] = kb.y; Kt[a4+2][32+r] = kb.z; Kt[a4+3][32+r] = kb.w;
      int rv = tid & 63, av = (tid >> 6) * 4;
      *(float4*)&Vs[rv][av]      = *(const float4*)(Vh + (size_t)(k0 + rv)*32 + av);
      *(float4*)&Vs[rv][av + 16] = *(const float4*)(Vh + (size_t)(k0 + rv)*32 + av + 16);
    }
    __syncthreads();
    float acc[2][4] = {};
#pragma unroll
    for (int k = 0; k < 32; k++) {
      float a0 = Qt[k][ty], a1 = Qt[k][ty + 16];
      float4 bv = *(const float4*)&Kt[k][tx*4];
      acc[0][0] = fmaf(a0, bv.x, acc[0][0]);
      acc[0][1] = fmaf(a0, bv.y, acc[0][1]);
      acc[0][2] = fmaf(a0, bv.z, acc[0][2]);
      acc[0][3] = fmaf(a0, bv.w, acc[0][3]);
      acc[1][0] = fmaf(a1, bv.x, acc[1][0]);
      acc[1][1] = fmaf(a1, bv.y, acc[1][1]);
      acc[1][2] = fmaf(a1, bv.z, acc[1][2]);
      acc[1][3] = fmaf(a1, bv.w, acc[1][3]);
    }
#pragma unroll
    for (int i = 0; i < 2; i++)
#pragma unroll
      for (int j = 0; j < 4; j++) acc[i][j] *= sc;
#pragma unroll
    for (int i = 0; i < 2; i++) {
      float tm = fmaxf(fmaxf(acc[i][0], acc[i][1]), fmaxf(acc[i][2], acc[i][3]));
      for (int s = 1; s < 16; s <<= 1) tm = fmaxf(tm, __shfl_xor(tm, s));
      float mn = fmaxf(m_[i], tm);
      float cf = __expf(m_[i] - mn);
      m_[i] = mn;
      l_[i] *= cf; O_[i][0] *= cf; O_[i][1] *= cf;
      float rs = 0.f;
#pragma unroll
      for (int j = 0; j < 4; j++) {
        float p = __expf(acc[i][j] - mn);
        rs += p;
        Pt[tx*4 + j][ty + 16*i] = p;
      }
      for (int s = 1; s < 16; s <<= 1) rs += __shfl_xor(rs, s);
      l_[i] += rs;
    }
#pragma unroll 8
    for (int kk = 0; kk < 64; kk++) {
      float p0 = Pt[kk][ty], p1 = Pt[kk][ty + 16];
      float2 vv = *(const float2*)&Vs[kk][tx*2];
      O_[0][0] = fmaf(p0, vv.x, O_[0][0]);
      O_[0][1] = fmaf(p0, vv.y, O_[0][1]);
      O_[1][0] = fmaf(p1, vv.x, O_[1][0]);
      O_[1][1] = fmaf(p1, vv.y, O_[1][1]);
    }
  }
  size_t pb = (size_t)(kp*8 + bh) * NPTS;
#pragma unroll
  for (int i = 0; i < 2; i++) {
    int n = q0 + ty + 16*i;
    *(float2*)&OP[(pb + n)*32 + tx*2] = make_float2(O_[i][0], O_[i][1]);
    if (tx == 0) { ML[(pb + n)*2] = m_[i]; ML[(pb + n)*2 + 1] = l_[i]; }
  }
}

// ---------------- merge the two K-halves ----------------
__global__ void attn_merge(const float* __restrict__ OP, const float* __restrict__ ML,
                           float* __restrict__ out) {
  int i = blockIdx.x * 256 + threadIdx.x;   // 8*2048*16
  if (i >= 8*2048*16) return;
  int dp = (i & 15) * 2;
  int n  = (i >> 4) & 2047;
  int bh = i >> 15;
  size_t p0 = (size_t)bh * NPTS + n;
  size_t p1 = (size_t)(8 + bh) * NPTS + n;
  float m0 = ML[p0*2], l0 = ML[p0*2 + 1];
  float m1 = ML[p1*2], l1 = ML[p1*2 + 1];
  float m = fmaxf(m0, m1);
  float w0 = __expf(m0 - m), w1 = __expf(m1 - m);
  float inv = 1.f / (w0*l0 + w1*l1);
  float2 o0 = *(const float2*)&OP[p0*32 + dp];
  float2 o1 = *(const float2*)&OP[p1*32 + dp];
  int b = bh >> 2, h = bh & 3;
  out[((size_t)(b*NPTS + n))*128 + (dp+0)*4 + h] = (w0*o0.x + w1*o1.x) * inv;
  out[((size_t)(b*NPTS + n))*128 + (dp+1)*4 + h] = (w0*o0.y + w1*o1.y) * inv;
}

// ================= host =================
extern "C" void kernel_launch(void* const* d_in, const int* in_sizes, int n_in,
                              void* d_out, int out_size, void* d_ws, size_t ws_size,
                              hipStream_t stream) {
  (void)in_sizes; (void)n_in; (void)out_size; (void)ws_size;
  const float* desc0  = (const float*)d_in[0];
  const float* desc1  = (const float*)d_in[1];
  const float* coords0= (const float*)d_in[2];
  const float* coords1= (const float*)d_in[3];
  const float* conv1w = (const float*)d_in[4];
  const float* conv2w = (const float*)d_in[5];
  const float* conv3w = (const float*)d_in[6];
  const float* conv3ow= (const float*)d_in[7];
  const float* a1w1 = (const float*)d_in[8];
  const float* a1b1 = (const float*)d_in[9];
  const float* a1w2 = (const float*)d_in[10];
  const float* a1b2 = (const float*)d_in[11];
  const float* a2w1 = (const float*)d_in[12];
  const float* a2b1 = (const float*)d_in[13];
  const float* a2w2 = (const float*)d_in[14];
  const float* a2b2 = (const float*)d_in[15];
  const float* gw1  = (const float*)d_in[16];
  const float* gb1  = (const float*)d_in[17];
  const float* gw2  = (const float*)d_in[18];
  const float* gb2  = (const float*)d_in[19];
  const float* wq = (const float*)d_in[20]; const float* bq = (const float*)d_in[21];
  const float* wk = (const float*)d_in[22]; const float* bk = (const float*)d_in[23];
  const float* wv = (const float*)d_in[24]; const float* bv = (const float*)d_in[25];
  const float* wm = (const float*)d_in[26]; const float* bm = (const float*)d_in[27];
  const float* mw1 = (const float*)d_in[28]; const float* mb1 = (const float*)d_in[29];
  const float* mw2 = (const float*)d_in[30]; const float* mb2 = (const float*)d_in[31];

  float* ws = (float*)d_ws;
  size_t off = 0;
  auto alloc = [&](size_t nel) { size_t r = off; off += (nel + 63) & ~(size_t)63; return r; };
  float* DW_A1 = ws + alloc(512*128);
  float* W_A1R = ws + alloc(128*384);
  float* DW_A2 = ws + alloc(512*128);
  float* W_A2R = ws + alloc(128*384);
  float* W_G2R = ws + alloc(128*384);
  float* DW_C1 = ws + alloc(256*128);
  float* DW_C2 = ws + alloc(512*128);
  float* SA   = ws + alloc((size_t)R2*128);   // both branch outputs
  float* XF0  = ws + alloc((size_t)4096*128);
  float* XF1  = ws + alloc((size_t)4096*128);
  int*   IDX  = (int*)(ws + alloc((size_t)R2*9));
  float* COSV = ws + alloc((size_t)R2*9);
  float* FT   = ws + alloc((size_t)R2*128);
  float* BIG  = ws + alloc((size_t)R2*512);   // also X3O alias, attn OP/ML alias
  float* ABUF = ws + alloc((size_t)R2*384);
  float* X1B  = ws + alloc((size_t)R2*128);
  float* FANG = ws + alloc((size_t)R2*128);
  float* X2B  = ws + alloc((size_t)R2*128);
  float* X3A  = ws + alloc((size_t)R2*128);
  float* X1O  = ws + alloc((size_t)R2*128);
  double* PART = (double*)(ws + alloc(512*256*2*2));
  float* STAT = ws + alloc(4*256*2);
  int*   CTR  = (int*)(ws + alloc(64));
  float* X3O = BIG;                 // alias (BIG free at that point)
  float* OP  = BIG;                 // attn partials (prop phase)
  float* ML  = BIG + (size_t)2*8*NPTS*32;

  hipMemsetAsync(CTR, 0, 64*sizeof(int), stream);
  int ctr_id = 0;

  auto gemm1 = [&](const float* X, const float* W, const float* bias, float* Y, int R, int Cin, int O,
                   const float* xst, int xmod, const float* resid, int pack) {
    gemm_f<<<dim3(R/64, O/64), 256, 0, stream>>>(X, Cin, nullptr, 0, nullptr, 0, nullptr,
                                                 xst, xmod, W, bias, resid, Y, Cin, O, pack);
  };
  auto gemm3 = [&](const float* a, int wa, const float* b, int wb, const float* c, int wc,
                   const float* addp, const float* W, const float* bias, float* Y, int R, int Cin, int O) {
    gemm_f<<<dim3(R/64, O/64), 256, 0, stream>>>(a, wa, b, wb, c, wc, addp,
                                                 nullptr, 0, W, bias, nullptr, Y, Cin, O, 0);
  };
  auto stats_only = [&](const float* buf, int R, int J, int Cc, int count) {
    stats_fused<<<R/64, 256, 0, stream>>>(buf, PART, STAT, J, Cc, R/2048, count, 32, CTR + ctr_id++);
  };
  auto statnorm = [&](const float* buf, float* dst, int R, int J, int Cc, int act, int count,
                      const float* addend) {
    stats_only(buf, R, J, Cc, count);
    int tot = R*J*Cc;
    norm_act<<<(tot + 255)/256, 256, 0, stream>>>(buf, dst, STAT, J, Cc, act, tot, addend);
  };
  auto gathermax = [&](const float* G, float* mx, float* dstNorm, int Cc) {
    gather_max_fused<<<R2/16, 256, 0, stream>>>(G, IDX, mx, PART, STAT, Cc, 4, CTR + ctr_id++);
    int tot = R2*Cc;
    norm_act<<<(tot + 255)/256, 256, 0, stream>>>(mx, dstNorm, STAT, 1, Cc, 2, tot, nullptr);
  };

  prep_weights<<<256, 256, 0, stream>>>(conv1w, conv2w, a1w1, a1w2, a2w1, a2w2, gw2,
                                        DW_A1, W_A1R, DW_A2, W_A2R, W_G2R, DW_C1, DW_C2);

  // ===== merged branch section (both descs, R2 = 8192 rows, 4 instances) =====
  transpose2<<<dim3(2048/32, 128/32, 4), dim3(32, 8), 0, stream>>>(desc0, desc1, FT, 128, 2048);
  knn2_kernel<<<2048, 256, 0, stream>>>(coords0, coords1, IDX, COSV);
  // annu1
  gemm1(FT, DW_A1, nullptr, BIG, R2, 128, 512, nullptr, 0, nullptr, 0);
  combine_annu<<<R2, 384, 0, stream>>>(BIG, IDX, a1b1, ABUF);
  stats_only(ABUF, R2, 3, 128, 2048*3);
  gemm1(ABUF, W_A1R, a1b2, X1B, R2, 384, 128, STAT, 128, nullptr, 0);
  statnorm(X1B, X1B, R2, 1, 128, 1, 2048, nullptr);
  // f_ang (idx1 == idx2)
  cos_conv<<<(R2*384 + 255)/256, 256, 0, stream>>>(COSV, gw1, gb1, ABUF, R2*384);
  stats_only(ABUF, R2, 3, 128, 2048*3);
  gemm1(ABUF, W_G2R, gb2, FANG, R2, 384, 128, STAT, 128, nullptr, 0);
  statnorm(FANG, FANG, R2, 1, 128, 1, 2048, nullptr);
  // annu2
  gemm1(X1B, DW_A2, nullptr, BIG, R2, 128, 512, nullptr, 0, nullptr, 0);
  combine_annu<<<R2, 384, 0, stream>>>(BIG, IDX, a2b1, ABUF);
  stats_only(ABUF, R2, 3, 128, 2048*3);
  gemm1(ABUF, W_A2R, a2b2, X2B, R2, 384, 128, STAT, 128, nullptr, 0);
  statnorm(X2B, X2B, R2, 1, 128, 1, 2048, nullptr);
  // x3
  gemm3(FT, 128, X1B, 128, X2B, 128, FANG, conv3w, nullptr, X3A, R2, 384, 128);
  statnorm(X3A, X3A, R2, 1, 128, 2, 2048, nullptr);
  // x1o
  gemm1(FT, DW_C1, nullptr, BIG, R2, 128, 256, nullptr, 0, nullptr, 0);
  gathermax(BIG, ABUF, X1O, 128);
  // x2o (max + norm in-place in ABUF viewed as [R2][256])
  gemm1(X1O, DW_C2, nullptr, BIG, R2, 128, 512, nullptr, 0, nullptr, 0);
  gathermax(BIG, ABUF, ABUF, 256);
  // x3o -> SA (= x3 + x3o)
  gemm3(FT, 128, X1O, 128, ABUF, 256, nullptr, conv3ow, nullptr, X3O, R2, 512, 128);
  statnorm(X3O, SA, R2, 1, 128, 2, 2048, X3A);

  // ===== cross-attention props (rows 4096 each) =====
  float* SA0 = SA;
  float* SA1 = SA + (size_t)4096*128;
  auto prop = [&](const float* xin, const float* src, float* dst) {
    gemm1(xin, wq, bq, X1B, 4096, 128, 128, nullptr, 0, nullptr, 1);   // packed Q
    gemm1(src, wk, bk, X2B, 4096, 128, 128, nullptr, 0, nullptr, 1);   // packed K
    gemm1(src, wv, bv, X3A, 4096, 128, 128, nullptr, 0, nullptr, 1);   // packed V
    attn_part<<<dim3(64, 2, 8), 256, 0, stream>>>(X1B, X2B, X3A, OP, ML);
    attn_merge<<<(8*2048*16 + 255)/256, 256, 0, stream>>>(OP, ML, FANG);
    gemm1(FANG, wm, bm, X1O, 4096, 128, 128, nullptr, 0, nullptr, 0);
    gemm3(xin, 128, X1O, 128, nullptr, 0, nullptr, mw1, mb1, ABUF, 4096, 256, 256);
    stats_only(ABUF, 4096, 1, 256, 2048);
    gemm1(ABUF, mw2, mb2, dst, 4096, 256, 128, STAT, 256, xin, 0);
  };

  prop(SA0, SA1, XF0);
  prop(SA1, XF0, XF1);

  transpose_k<<<dim3(128/32, 2048/32, 2), dim3(32, 8), 0, stream>>>(XF0, (float*)d_out, 2048, 128);
  transpose_k<<<dim3(128/32, 2048/32, 2), dim3(32, 8), 0, stream>>>(XF1, (float*)d_out + (size_t)4096*128, 2048, 128);
}

// Round 8
// 1245.411 us; speedup vs baseline: 3.6318x; 1.1994x over previous
//
#include <hip/hip_runtime.h>
#include <cfloat>
#include <math.h>

#define NPTS 2048
#define R2   8192   // merged: 2 tensors x B=2 x N=2048

// ---------------- prep: derived weight matrices ----------------
__global__ __launch_bounds__(256) void prep_weights(
    const float* __restrict__ conv1, const float* __restrict__ conv2,
    const float* __restrict__ a1w1, const float* __restrict__ a1w2,
    const float* __restrict__ a2w1, const float* __restrict__ a2w2,
    const float* __restrict__ gw2,
    float* __restrict__ dwA1, float* __restrict__ a1w2r,
    float* __restrict__ dwA2, float* __restrict__ a2w2r,
    float* __restrict__ gw2r, float* __restrict__ dwC1, float* __restrict__ dwC2)
{
  int i = blockIdx.x * 256 + threadIdx.x;
  if (i < 512*128) {
    int row = i >> 7, c = i & 127;
    float v1, v2;
    if (row < 128) {             // ctrW[o][c] = sum_t (w1[o,c,t] - w1[o,128+c,t])
      float s1 = 0.f, s2 = 0.f;
      for (int t = 0; t < 3; t++) {
        s1 += a1w1[(row*256 + c)*3 + t] - a1w1[(row*256 + 128 + c)*3 + t];
        s2 += a2w1[(row*256 + c)*3 + t] - a2w1[(row*256 + 128 + c)*3 + t];
      }
      v1 = s1; v2 = s2;
    } else {                     // row = 128 + t*128 + o : nbW_t[o][c] = w1[o,128+c,t]
      int t = (row - 128) >> 7, o = row & 127;
      v1 = a1w1[(o*256 + 128 + c)*3 + t];
      v2 = a2w1[(o*256 + 128 + c)*3 + t];
    }
    dwA1[i] = v1; dwA2[i] = v2;
    dwC2[i] = (row < 256) ? (conv2[row*256 + c] - conv2[row*256 + 128 + c])
                          : conv2[(row-256)*256 + 128 + c];
  }
  if (i < 128*384) {             // w2r[o][w*128+c] = w2[o,c,w]
    int o = i / 384, rem = i % 384, w = rem >> 7, c = rem & 127;
    a1w2r[i] = a1w2[(o*128 + c)*3 + w];
    a2w2r[i] = a2w2[(o*128 + c)*3 + w];
    gw2r[i]  = gw2[(o*128 + c)*3 + w];
  }
  if (i < 256*128) {             // dwC1 [256][128] from conv1 [128][256]
    int row = i >> 7, c = i & 127;
    dwC1[i] = (row < 128) ? (conv1[row*256 + c] - conv1[row*256 + 128 + c])
                          : conv1[(row-128)*256 + 128 + c];
  }
}

// ---------------- transpose both descs: in [2][I][J] x2 -> out [4][J][I] ----------------
__global__ void transpose2(const float* __restrict__ in0, const float* __restrict__ in1,
                           float* __restrict__ out, int I, int J) {
  __shared__ float tile[32][33];
  int zb = blockIdx.z;
  const float* src = (zb < 2) ? (in0 + (size_t)zb*I*J) : (in1 + (size_t)(zb-2)*I*J);
  float* dst = out + (size_t)zb*J*I;
  int i0 = blockIdx.y * 32, j0 = blockIdx.x * 32;
  int tx = threadIdx.x, ty = threadIdx.y;
  for (int s = 0; s < 32; s += 8)
    tile[ty + s][tx] = src[(size_t)(i0 + ty + s)*J + (j0 + tx)];
  __syncthreads();
  for (int s = 0; s < 32; s += 8)
    dst[(size_t)(j0 + ty + s)*I + (i0 + tx)] = tile[tx][ty + s];
}

// ---------------- transpose [b][I][J] -> [b][J][I] (final output) ----------------
__global__ void transpose_k(const float* __restrict__ in, float* __restrict__ out, int I, int J) {
  __shared__ float tile[32][33];
  int b = blockIdx.z;
  int i0 = blockIdx.y * 32, j0 = blockIdx.x * 32;
  int tx = threadIdx.x, ty = threadIdx.y;
  for (int s = 0; s < 32; s += 8)
    tile[ty + s][tx] = in[((size_t)b*I + (i0 + ty + s))*J + (j0 + tx)];
  __syncthreads();
  for (int s = 0; s < 32; s += 8)
    out[((size_t)b*J + (j0 + ty + s))*I + (i0 + tx)] = tile[tx][ty + s];
}

// ---------------- KNN (both coord sets): f32 np-exact distances, (dist,idx)-lex ----------------
__global__ __launch_bounds__(256) void knn2_kernel(const float* __restrict__ P0, const float* __restrict__ P1,
                                                   int* __restrict__ idx, float* __restrict__ cosv) {
  __shared__ float px[NPTS], py[NPTS], sq[NPTS];
  int tid = threadIdx.x;
  int gw = blockIdx.x * 4 + (tid >> 6);   // 0..8191 : global point id
  int b4 = gw >> 11, n = gw & 2047;
  int lane = tid & 63;
  const float* Pb = (b4 < 2) ? (P0 + (size_t)b4 * 2 * NPTS) : (P1 + (size_t)(b4 - 2) * 2 * NPTS);
  for (int i = tid; i < NPTS; i += 256) {
    float x = Pb[i], y = Pb[NPTS + i];
    px[i] = x; py[i] = y;
    sq[i] = __fadd_rn(__fmul_rn(x, x), __fmul_rn(y, y));
  }
  __syncthreads();
  float xn = px[n], yn = py[n], sqn = sq[n];
  float d[10]; int id_[10];
#pragma unroll
  for (int j = 0; j < 10; j++) { d[j] = FLT_MAX; id_[j] = 0x7fffffff; }
  for (int m = lane; m < NPTS; m += 64) {
    float dot  = __fadd_rn(__fmul_rn(xn, px[m]), __fmul_rn(yn, py[m]));
    float dist = __fsub_rn(__fadd_rn(sqn, sq[m]), __fmul_rn(2.0f, dot));
    dist = fmaxf(dist, 1e-12f);
    if (dist < d[9] || (dist == d[9] && m < id_[9])) {
      int p = 0;
#pragma unroll
      for (int j = 0; j < 10; j++) p += (d[j] < dist || (d[j] == dist && id_[j] < m)) ? 1 : 0;
#pragma unroll
      for (int j = 9; j >= 1; j--) if (j > p) { d[j] = d[j-1]; id_[j] = id_[j-1]; }
#pragma unroll
      for (int j = 0; j < 10; j++) if (j == p) { d[j] = dist; id_[j] = m; }
    }
  }
  int ptr = 0;
  for (int r = 0; r < 10; r++) {
    float bd = FLT_MAX; int bi = 0x7fffffff;
#pragma unroll
    for (int j = 0; j < 10; j++) if (j == ptr) { bd = d[j]; bi = id_[j]; }
    for (int off = 32; off >= 1; off >>= 1) {
      float od = __shfl_xor(bd, off);
      int   oi = __shfl_xor(bi, off);
      if (od < bd || (od == bd && oi < bi)) { bd = od; bi = oi; }
    }
    bool adv = false;
#pragma unroll
    for (int j = 0; j < 10; j++) if (j == ptr) adv = (d[j] == bd && id_[j] == bi);
    if (adv) ptr++;
    if (r > 0 && lane == 0) {
      size_t base = (size_t)gw*9 + (r - 1);
      idx[base] = bi;   // local index within instance
      float dot = __fadd_rn(__fmul_rn(xn, px[bi]), __fmul_rn(yn, py[bi]));
      cosv[base] = __fdiv_rn(dot, __fmul_rn(__fsqrt_rn(sqn), __fsqrt_rn(sq[bi])));
    }
  }
}

// ---------------- unified f32 GEMM (K-major LDS, b128 fragment reads) ----------------
__global__ __launch_bounds__(256) void gemm_f(
    const float* __restrict__ p0, int w0,
    const float* __restrict__ p1, int w1,
    const float* __restrict__ p2, int w2,
    const float* __restrict__ addp,
    const float* __restrict__ xstats, int xmod,
    const float* __restrict__ W,
    const float* __restrict__ bias,
    const float* __restrict__ resid,
    float* __restrict__ Y, int Cin, int O, int pack)
{
  __shared__ float Xt[32][68], Wt[32][68];
  int tid = threadIdx.x;
  int r0 = blockIdx.x * 64, c0 = blockIdx.y * 64;
  int tx = tid & 15, ty = tid >> 4;
  int sr = tid & 63, scol = (tid >> 6) * 8;
  float acc[4][4] = {};
  for (int k0 = 0; k0 < Cin; k0 += 32) {
    {
      int r = r0 + sr;
      int ac = k0 + scol;
      const float* P; int cc, lw;
      if (ac < w0) { P = p0; cc = ac; lw = w0; }
      else if (ac < w0 + w1) { P = p1; cc = ac - w0; lw = w1; }
      else { P = p2; cc = ac - w0 - w1; lw = w2; }
      float4 v0 = *(const float4*)(P + (size_t)r*lw + cc);
      float4 v1 = *(const float4*)(P + (size_t)r*lw + cc + 4);
      float vv[8] = {v0.x, v0.y, v0.z, v0.w, v1.x, v1.y, v1.z, v1.w};
      if (addp && ac >= 128) {
        int fc = (ac - 128) & 127;
        float4 a0 = *(const float4*)(addp + (size_t)r*128 + fc);
        float4 a1 = *(const float4*)(addp + (size_t)r*128 + fc + 4);
        vv[0]+=a0.x; vv[1]+=a0.y; vv[2]+=a0.z; vv[3]+=a0.w;
        vv[4]+=a1.x; vv[5]+=a1.y; vv[6]+=a1.z; vv[7]+=a1.w;
      }
      if (xstats) {
        int b = r >> 11;
#pragma unroll
        for (int j = 0; j < 8; j++) {
          int o = (ac + j) & (xmod - 1);
          float m = xstats[(b*xmod + o)*2], rs = xstats[(b*xmod + o)*2 + 1];
          vv[j] = fmaxf((vv[j] - m) * rs, 0.f);
        }
      }
#pragma unroll
      for (int j = 0; j < 8; j++) Xt[scol + j][sr] = vv[j];
    }
    {
      const float* s = W + (size_t)(c0 + sr)*Cin + k0 + scol;
      float4 v0 = *(const float4*)s, v1 = *(const float4*)(s + 4);
      Wt[scol+0][sr]=v0.x; Wt[scol+1][sr]=v0.y; Wt[scol+2][sr]=v0.z; Wt[scol+3][sr]=v0.w;
      Wt[scol+4][sr]=v1.x; Wt[scol+5][sr]=v1.y; Wt[scol+6][sr]=v1.z; Wt[scol+7][sr]=v1.w;
    }
    __syncthreads();
#pragma unroll
    for (int kk = 0; kk < 32; kk++) {
      float4 av = *(const float4*)&Xt[kk][ty*4];
      float4 bv = *(const float4*)&Wt[kk][tx*4];
      acc[0][0] = fmaf(av.x, bv.x, acc[0][0]);
      acc[0][1] = fmaf(av.x, bv.y, acc[0][1]);
      acc[0][2] = fmaf(av.x, bv.z, acc[0][2]);
      acc[0][3] = fmaf(av.x, bv.w, acc[0][3]);
      acc[1][0] = fmaf(av.y, bv.x, acc[1][0]);
      acc[1][1] = fmaf(av.y, bv.y, acc[1][1]);
      acc[1][2] = fmaf(av.y, bv.z, acc[1][2]);
      acc[1][3] = fmaf(av.y, bv.w, acc[1][3]);
      acc[2][0] = fmaf(av.z, bv.x, acc[2][0]);
      acc[2][1] = fmaf(av.z, bv.y, acc[2][1]);
      acc[2][2] = fmaf(av.z, bv.z, acc[2][2]);
      acc[2][3] = fmaf(av.z, bv.w, acc[2][3]);
      acc[3][0] = fmaf(av.w, bv.x, acc[3][0]);
      acc[3][1] = fmaf(av.w, bv.y, acc[3][1]);
      acc[3][2] = fmaf(av.w, bv.z, acc[3][2]);
      acc[3][3] = fmaf(av.w, bv.w, acc[3][3]);
    }
    __syncthreads();
  }
#pragma unroll
  for (int i = 0; i < 4; i++) {
    int r = r0 + ty*4 + i;
#pragma unroll
    for (int j = 0; j < 4; j++) {
      int c = c0 + tx*4 + j;
      float v = acc[i][j] + (bias ? bias[c] : 0.f);
      if (resid) v += resid[(size_t)r*O + c];
      if (pack) {
        int h = c & 3, dd = c >> 2, b = r >> 11, n = r & 2047;
        Y[(((size_t)(b*4 + h))*NPTS + n)*32 + dd] = v;
      } else {
        Y[(size_t)r*O + c] = v;
      }
    }
  }
}

// ---------------- annu conv1 combine ----------------
__global__ __launch_bounds__(384) void combine_annu(const float* __restrict__ GA, const int* __restrict__ idx,
                                                    const float* __restrict__ b1, float* __restrict__ A) {
  int r = blockIdx.x, t = threadIdx.x;
  int w = t >> 7, o = t & 127;
  int rb = r & ~2047;
  __shared__ int nb[9];
  if (t < 9) nb[t] = idx[(size_t)r*9 + t];
  __syncthreads();
  float acc = GA[(size_t)r*512 + o] + b1[o];
#pragma unroll
  for (int t3 = 0; t3 < 3; t3++) {
    int m = nb[w*3 + t3];
    acc += GA[(size_t)(rb + m)*512 + 128 + t3*128 + o];
  }
  A[(size_t)r*384 + w*128 + o] = acc;
}

// ---------------- instance-norm stats: partial + fenced tail-block final ----------------
__global__ __launch_bounds__(256) void stats_fused(const float* __restrict__ X, double* __restrict__ part,
                                                   float* __restrict__ stats, int J, int Cc, int NB,
                                                   int count, int nblkPerB, int* __restrict__ ctr) {
  int t = threadIdx.x;
  int o = t % Cc, sub = t / Cc, nsub = 256 / Cc;
  int r0 = blockIdx.x * 64;
  double s = 0.0, s2 = 0.0;
  for (int rr = sub; rr < 64; rr += nsub)
    for (int j = 0; j < J; j++) {
      double v = X[(((size_t)(r0 + rr))*J + j)*Cc + o];
      s += v; s2 += v*v;
    }
  __shared__ double ls[256], ls2[256];
  ls[t] = s; ls2[t] = s2;
  __syncthreads();
  if (sub == 0) {
    for (int u = 1; u < nsub; u++) { s += ls[u*Cc + o]; s2 += ls2[u*Cc + o]; }
    part[((size_t)blockIdx.x*Cc + o)*2] = s;
    part[((size_t)blockIdx.x*Cc + o)*2 + 1] = s2;
    __threadfence();
  }
  __syncthreads();
  __shared__ int lastBlk;
  if (t == 0) lastBlk = (atomicAdd(ctr, 1) == (int)gridDim.x - 1) ? 1 : 0;
  __syncthreads();
  if (!lastBlk) return;
  __threadfence();
  for (int i = t; i < NB*Cc; i += 256) {
    int b = i / Cc, oo = i % Cc;
    double S = 0.0, S2 = 0.0;
    for (int u = 0; u < nblkPerB; u++) {
      int blk = b*nblkPerB + u;
      S  += part[((size_t)blk*Cc + oo)*2];
      S2 += part[((size_t)blk*Cc + oo)*2 + 1];
    }
    double mean = S / count;
    double var = S2 / count - mean*mean;
    if (var < 0.0) var = 0.0;
    stats[i*2] = (float)mean;
    stats[i*2 + 1] = (float)(1.0 / sqrt(var + 1e-5));
  }
}

// act: 0 none, 1 relu, 2 lrelu(0.2); optional addend
__global__ void norm_act(const float* __restrict__ src, float* __restrict__ dst,
                         const float* __restrict__ stats, int J, int Cc, int act, int total,
                         const float* __restrict__ addend) {
  int i = blockIdx.x * 256 + threadIdx.x;
  if (i >= total) return;
  int o = i % Cc;
  int r = i / (J*Cc);
  int b = r >> 11;
  float m = stats[(b*Cc + o)*2], rs = stats[(b*Cc + o)*2 + 1];
  float v = (src[i] - m) * rs;
  if (act == 1) v = fmaxf(v, 0.f);
  else if (act == 2) v = (v >= 0.f) ? v : 0.2f*v;
  if (addend) v += addend[i];
  dst[i] = v;
}

// ---------------- angle-feature conv1 ----------------
__global__ void cos_conv(const float* __restrict__ cosv, const float* __restrict__ gw1,
                         const float* __restrict__ gb1, float* __restrict__ ANG, int total) {
  int i = blockIdx.x * 256 + threadIdx.x;
  if (i >= total) return;
  int o = i & 127, w = (i >> 7) % 3;
  int r = i / 384;
  float acc = gb1[o];
#pragma unroll
  for (int t = 0; t < 3; t++) acc += cosv[(size_t)r*9 + w*3 + t] * gw1[o*3 + t];
  ANG[i] = acc;
}

// ---------------- gather + max over k + f64 partials (4 rows/block, idx in LDS) ----------------
__global__ __launch_bounds__(256) void gather_max_partial(const float* __restrict__ G, const int* __restrict__ idx,
                                                          float* __restrict__ maxbuf, double* __restrict__ part,
                                                          int Cc) {
  int t = threadIdx.x;
  int o = t % Cc, sub = t / Cc, nsub = 256 / Cc;
  int r0 = blockIdx.x * 4;
  __shared__ int nbs[4][9];
  if (t < 36) nbs[t / 9][t % 9] = idx[(size_t)(r0 + t/9)*9 + (t % 9)];
  __syncthreads();
  double s = 0.0, s2 = 0.0;
  for (int rr = sub; rr < 4; rr += nsub) {
    int r = r0 + rr, rb = r & ~2047;
    float g = G[(size_t)r*2*Cc + o];
    float mx = -3.4e38f;
#pragma unroll
    for (int k = 0; k < 9; k++) {
      int m = nbs[rr][k];
      float v = g + G[(size_t)(rb + m)*2*Cc + Cc + o];
      mx = fmaxf(mx, v); s += (double)v; s2 += (double)v*(double)v;
    }
    maxbuf[(size_t)r*Cc + o] = mx;
  }
  if (nsub == 2) {
    __shared__ double ls[256], ls2[256];
    ls[t] = s; ls2[t] = s2;
    __syncthreads();
    if (sub == 0) { s += ls[Cc + o]; s2 += ls2[Cc + o]; }
  }
  if (sub == 0) {
    part[((size_t)blockIdx.x*Cc + o)*2] = s;
    part[((size_t)blockIdx.x*Cc + o)*2 + 1] = s2;
  }
}

// ---------------- parallel stats final: 32-lane group per (instance, channel) ----------------
__global__ __launch_bounds__(256) void gm_final(const double* __restrict__ part, float* __restrict__ stats,
                                                int Cc, int NB, int nblk, int count) {
  int g = blockIdx.x * 8 + (threadIdx.x >> 5);
  int lane = threadIdx.x & 31;
  if (g >= NB*Cc) return;
  int b = g / Cc, o = g % Cc;
  double S = 0.0, S2 = 0.0;
  for (int u = lane; u < nblk; u += 32) {
    size_t blk = (size_t)(b*nblk + u);
    S  += part[(blk*Cc + o)*2];
    S2 += part[(blk*Cc + o)*2 + 1];
  }
  for (int off = 16; off >= 1; off >>= 1) {
    S  += __shfl_down(S, off, 32);
    S2 += __shfl_down(S2, off, 32);
  }
  if (lane == 0) {
    double mean = S / count;
    double var = S2 / count - mean*mean;
    if (var < 0.0) var = 0.0;
    stats[g*2] = (float)mean;
    stats[g*2 + 1] = (float)(1.0 / sqrt(var + 1e-5));
  }
}

// ---------------- flash attention, split-K part: 32 q-rows x 1024 keys ----------------
__global__ __launch_bounds__(256) void attn_part(const float* __restrict__ Qp, const float* __restrict__ Kp,
                                                 const float* __restrict__ Vp,
                                                 float* __restrict__ OP, float* __restrict__ ML) {
  __shared__ float Qt[32][33];
  __shared__ float Kt[32][68];
  __shared__ float Vs[64][36];
  __shared__ float Pt[64][33];
  int tid = threadIdx.x;
  int tx = tid & 15, ty = tid >> 4;
  int kp = blockIdx.y;      // key half
  int bh = blockIdx.z;
  int q0 = blockIdx.x * 32;
  const float* Qh = Qp + (size_t)bh * NPTS * 32;
  const float* Kh = Kp + (size_t)bh * NPTS * 32;
  const float* Vh = Vp + (size_t)bh * NPTS * 32;
  {
    int r = tid & 31, a4 = ((tid >> 5) & 7) * 4;
    float4 v = *(const float4*)(Qh + (size_t)(q0 + r)*32 + a4);
    Qt[a4+0][r] = v.x; Qt[a4+1][r] = v.y; Qt[a4+2][r] = v.z; Qt[a4+3][r] = v.w;
  }
  float m_[2] = {-FLT_MAX, -FLT_MAX};
  float l_[2] = {0.f, 0.f};
  float O_[2][2] = {};
  const float sc = 0.17677669529663687f;
  int ks = kp * 1024;
  for (int k0 = ks; k0 < ks + 1024; k0 += 64) {
    __syncthreads();
    {
      int r = tid & 31, a4 = ((tid >> 5) & 7) * 4;
      float4 ka = *(const float4*)(Kh + (size_t)(k0 + r)*32 + a4);
      float4 kb = *(const float4*)(Kh + (size_t)(k0 + 32 + r)*32 + a4);
      Kt[a4+0][r] = ka.x; Kt[a4+1][r] = ka.y; Kt[a4+2][r] = ka.z; Kt[a4+3][r] = ka.w;
      Kt[a4+0][32+r] = kb.x; Kt[a4+1][32+r] = kb.y; Kt[a4+2][32+r] = kb.z; Kt[a4+3][32+r] = kb.w;
      int rv = tid & 63, av = (tid >> 6) * 4;
      *(float4*)&Vs[rv][av]      = *(const float4*)(Vh + (size_t)(k0 + rv)*32 + av);
      *(float4*)&Vs[rv][av + 16] = *(const float4*)(Vh + (size_t)(k0 + rv)*32 + av + 16);
    }
    __syncthreads();
    float acc[2][4] = {};
#pragma unroll
    for (int k = 0; k < 32; k++) {
      float a0 = Qt[k][ty], a1 = Qt[k][ty + 16];
      float4 bv = *(const float4*)&Kt[k][tx*4];
      acc[0][0] = fmaf(a0, bv.x, acc[0][0]);
      acc[0][1] = fmaf(a0, bv.y, acc[0][1]);
      acc[0][2] = fmaf(a0, bv.z, acc[0][2]);
      acc[0][3] = fmaf(a0, bv.w, acc[0][3]);
      acc[1][0] = fmaf(a1, bv.x, acc[1][0]);
      acc[1][1] = fmaf(a1, bv.y, acc[1][1]);
      acc[1][2] = fmaf(a1, bv.z, acc[1][2]);
      acc[1][3] = fmaf(a1, bv.w, acc[1][3]);
    }
#pragma unroll
    for (int i = 0; i < 2; i++)
#pragma unroll
      for (int j = 0; j < 4; j++) acc[i][j] *= sc;
#pragma unroll
    for (int i = 0; i < 2; i++) {
      float tm = fmaxf(fmaxf(acc[i][0], acc[i][1]), fmaxf(acc[i][2], acc[i][3]));
      for (int s = 1; s < 16; s <<= 1) tm = fmaxf(tm, __shfl_xor(tm, s));
      float mn = fmaxf(m_[i], tm);
      float cf = __expf(m_[i] - mn);
      m_[i] = mn;
      l_[i] *= cf; O_[i][0] *= cf; O_[i][1] *= cf;
      float rs = 0.f;
#pragma unroll
      for (int j = 0; j < 4; j++) {
        float p = __expf(acc[i][j] - mn);
        rs += p;
        Pt[tx*4 + j][ty + 16*i] = p;
      }
      for (int s = 1; s < 16; s <<= 1) rs += __shfl_xor(rs, s);
      l_[i] += rs;
    }
#pragma unroll 8
    for (int kk = 0; kk < 64; kk++) {
      float p0 = Pt[kk][ty], p1 = Pt[kk][ty + 16];
      float2 vv = *(const float2*)&Vs[kk][tx*2];
      O_[0][0] = fmaf(p0, vv.x, O_[0][0]);
      O_[0][1] = fmaf(p0, vv.y, O_[0][1]);
      O_[1][0] = fmaf(p1, vv.x, O_[1][0]);
      O_[1][1] = fmaf(p1, vv.y, O_[1][1]);
    }
  }
  size_t pb = (size_t)(kp*8 + bh) * NPTS;
#pragma unroll
  for (int i = 0; i < 2; i++) {
    int n = q0 + ty + 16*i;
    *(float2*)&OP[(pb + n)*32 + tx*2] = make_float2(O_[i][0], O_[i][1]);
    if (tx == 0) { ML[(pb + n)*2] = m_[i]; ML[(pb + n)*2 + 1] = l_[i]; }
  }
}

// ---------------- merge the two K-halves ----------------
__global__ void attn_merge(const float* __restrict__ OP, const float* __restrict__ ML,
                           float* __restrict__ out) {
  int i = blockIdx.x * 256 + threadIdx.x;   // 8*2048*16
  if (i >= 8*2048*16) return;
  int dp = (i & 15) * 2;
  int n  = (i >> 4) & 2047;
  int bh = i >> 15;
  size_t p0 = (size_t)bh * NPTS + n;
  size_t p1 = (size_t)(8 + bh) * NPTS + n;
  float m0 = ML[p0*2], l0 = ML[p0*2 + 1];
  float m1 = ML[p1*2], l1 = ML[p1*2 + 1];
  float m = fmaxf(m0, m1);
  float w0 = __expf(m0 - m), w1 = __expf(m1 - m);
  float inv = 1.f / (w0*l0 + w1*l1);
  float2 o0 = *(const float2*)&OP[p0*32 + dp];
  float2 o1 = *(const float2*)&OP[p1*32 + dp];
  int b = bh >> 2, h = bh & 3;
  out[((size_t)(b*NPTS + n))*128 + (dp+0)*4 + h] = (w0*o0.x + w1*o1.x) * inv;
  out[((size_t)(b*NPTS + n))*128 + (dp+1)*4 + h] = (w0*o0.y + w1*o1.y) * inv;
}

// ================= host =================
extern "C" void kernel_launch(void* const* d_in, const int* in_sizes, int n_in,
                              void* d_out, int out_size, void* d_ws, size_t ws_size,
                              hipStream_t stream) {
  (void)in_sizes; (void)n_in; (void)out_size; (void)ws_size;
  const float* desc0  = (const float*)d_in[0];
  const float* desc1  = (const float*)d_in[1];
  const float* coords0= (const float*)d_in[2];
  const float* coords1= (const float*)d_in[3];
  const float* conv1w = (const float*)d_in[4];
  const float* conv2w = (const float*)d_in[5];
  const float* conv3w = (const float*)d_in[6];
  const float* conv3ow= (const float*)d_in[7];
  const float* a1w1 = (const float*)d_in[8];
  const float* a1b1 = (const float*)d_in[9];
  const float* a1w2 = (const float*)d_in[10];
  const float* a1b2 = (const float*)d_in[11];
  const float* a2w1 = (const float*)d_in[12];
  const float* a2b1 = (const float*)d_in[13];
  const float* a2w2 = (const float*)d_in[14];
  const float* a2b2 = (const float*)d_in[15];
  const float* gw1  = (const float*)d_in[16];
  const float* gb1  = (const float*)d_in[17];
  const float* gw2  = (const float*)d_in[18];
  const float* gb2  = (const float*)d_in[19];
  const float* wq = (const float*)d_in[20]; const float* bq = (const float*)d_in[21];
  const float* wk = (const float*)d_in[22]; const float* bk = (const float*)d_in[23];
  const float* wv = (const float*)d_in[24]; const float* bv = (const float*)d_in[25];
  const float* wm = (const float*)d_in[26]; const float* bm = (const float*)d_in[27];
  const float* mw1 = (const float*)d_in[28]; const float* mb1 = (const float*)d_in[29];
  const float* mw2 = (const float*)d_in[30]; const float* mb2 = (const float*)d_in[31];

  float* ws = (float*)d_ws;
  size_t off = 0;
  auto alloc = [&](size_t nel) { size_t r = off; off += (nel + 63) & ~(size_t)63; return r; };
  float* DW_A1 = ws + alloc(512*128);
  float* W_A1R = ws + alloc(128*384);
  float* DW_A2 = ws + alloc(512*128);
  float* W_A2R = ws + alloc(128*384);
  float* W_G2R = ws + alloc(128*384);
  float* DW_C1 = ws + alloc(256*128);
  float* DW_C2 = ws + alloc(512*128);
  float* SA   = ws + alloc((size_t)R2*128);   // both branch outputs
  float* XF0  = ws + alloc((size_t)4096*128);
  float* XF1  = ws + alloc((size_t)4096*128);
  int*   IDX  = (int*)(ws + alloc((size_t)R2*9));
  float* COSV = ws + alloc((size_t)R2*9);
  float* FT   = ws + alloc((size_t)R2*128);
  float* BIG  = ws + alloc((size_t)R2*512);   // also X3O alias, attn OP/ML alias
  float* ABUF = ws + alloc((size_t)R2*384);
  float* X1B  = ws + alloc((size_t)R2*128);
  float* FANG = ws + alloc((size_t)R2*128);
  float* X2B  = ws + alloc((size_t)R2*128);
  float* X3A  = ws + alloc((size_t)R2*128);
  float* X1O  = ws + alloc((size_t)R2*128);
  double* PART = (double*)(ws + alloc((size_t)2048*256*2*2));   // 1M doubles (8 MB)
  float* STAT = ws + alloc(4*256*2);
  int*   CTR  = (int*)(ws + alloc(64));
  float* X3O = BIG;                 // alias (BIG free at that point)
  float* OP  = BIG;                 // attn partials (prop phase)
  float* ML  = BIG + (size_t)2*8*NPTS*32;

  hipMemsetAsync(CTR, 0, 64*sizeof(int), stream);
  int ctr_id = 0;

  auto gemm1 = [&](const float* X, const float* W, const float* bias, float* Y, int R, int Cin, int O,
                   const float* xst, int xmod, const float* resid, int pack) {
    gemm_f<<<dim3(R/64, O/64), 256, 0, stream>>>(X, Cin, nullptr, 0, nullptr, 0, nullptr,
                                                 xst, xmod, W, bias, resid, Y, Cin, O, pack);
  };
  auto gemm3 = [&](const float* a, int wa, const float* b, int wb, const float* c, int wc,
                   const float* addp, const float* W, const float* bias, float* Y, int R, int Cin, int O) {
    gemm_f<<<dim3(R/64, O/64), 256, 0, stream>>>(a, wa, b, wb, c, wc, addp,
                                                 nullptr, 0, W, bias, nullptr, Y, Cin, O, 0);
  };
  auto stats_only = [&](const float* buf, int R, int J, int Cc, int count) {
    stats_fused<<<R/64, 256, 0, stream>>>(buf, PART, STAT, J, Cc, R/2048, count, 32, CTR + ctr_id++);
  };
  auto statnorm = [&](const float* buf, float* dst, int R, int J, int Cc, int act, int count,
                      const float* addend) {
    stats_only(buf, R, J, Cc, count);
    int tot = R*J*Cc;
    norm_act<<<(tot + 255)/256, 256, 0, stream>>>(buf, dst, STAT, J, Cc, act, tot, addend);
  };
  auto gathermax = [&](const float* G, float* mx, float* dstNorm, int Cc) {
    gather_max_partial<<<R2/4, 256, 0, stream>>>(G, IDX, mx, PART, Cc);
    gm_final<<<(4*Cc + 7)/8, 256, 0, stream>>>(PART, STAT, Cc, 4, (R2/4)/4, 2048*9);
    int tot = R2*Cc;
    norm_act<<<(tot + 255)/256, 256, 0, stream>>>(mx, dstNorm, STAT, 1, Cc, 2, tot, nullptr);
  };

  prep_weights<<<256, 256, 0, stream>>>(conv1w, conv2w, a1w1, a1w2, a2w1, a2w2, gw2,
                                        DW_A1, W_A1R, DW_A2, W_A2R, W_G2R, DW_C1, DW_C2);

  // ===== merged branch section (both descs, R2 = 8192 rows, 4 instances) =====
  transpose2<<<dim3(2048/32, 128/32, 4), dim3(32, 8), 0, stream>>>(desc0, desc1, FT, 128, 2048);
  knn2_kernel<<<2048, 256, 0, stream>>>(coords0, coords1, IDX, COSV);
  // annu1
  gemm1(FT, DW_A1, nullptr, BIG, R2, 128, 512, nullptr, 0, nullptr, 0);
  combine_annu<<<R2, 384, 0, stream>>>(BIG, IDX, a1b1, ABUF);
  stats_only(ABUF, R2, 3, 128, 2048*3);
  gemm1(ABUF, W_A1R, a1b2, X1B, R2, 384, 128, STAT, 128, nullptr, 0);
  statnorm(X1B, X1B, R2, 1, 128, 1, 2048, nullptr);
  // f_ang (idx1 == idx2)
  cos_conv<<<(R2*384 + 255)/256, 256, 0, stream>>>(COSV, gw1, gb1, ABUF, R2*384);
  stats_only(ABUF, R2, 3, 128, 2048*3);
  gemm1(ABUF, W_G2R, gb2, FANG, R2, 384, 128, STAT, 128, nullptr, 0);
  statnorm(FANG, FANG, R2, 1, 128, 1, 2048, nullptr);
  // annu2
  gemm1(X1B, DW_A2, nullptr, BIG, R2, 128, 512, nullptr, 0, nullptr, 0);
  combine_annu<<<R2, 384, 0, stream>>>(BIG, IDX, a2b1, ABUF);
  stats_only(ABUF, R2, 3, 128, 2048*3);
  gemm1(ABUF, W_A2R, a2b2, X2B, R2, 384, 128, STAT, 128, nullptr, 0);
  statnorm(X2B, X2B, R2, 1, 128, 1, 2048, nullptr);
  // x3
  gemm3(FT, 128, X1B, 128, X2B, 128, FANG, conv3w, nullptr, X3A, R2, 384, 128);
  statnorm(X3A, X3A, R2, 1, 128, 2, 2048, nullptr);
  // x1o
  gemm1(FT, DW_C1, nullptr, BIG, R2, 128, 256, nullptr, 0, nullptr, 0);
  gathermax(BIG, ABUF, X1O, 128);
  // x2o (max + norm in-place in ABUF viewed as [R2][256])
  gemm1(X1O, DW_C2, nullptr, BIG, R2, 128, 512, nullptr, 0, nullptr, 0);
  gathermax(BIG, ABUF, ABUF, 256);
  // x3o -> SA (= x3 + x3o)
  gemm3(FT, 128, X1O, 128, ABUF, 256, nullptr, conv3ow, nullptr, X3O, R2, 512, 128);
  statnorm(X3O, SA, R2, 1, 128, 2, 2048, X3A);

  // ===== cross-attention props (rows 4096 each) =====
  float* SA0 = SA;
  float* SA1 = SA + (size_t)4096*128;
  auto prop = [&](const float* xin, const float* src, float* dst) {
    gemm1(xin, wq, bq, X1B, 4096, 128, 128, nullptr, 0, nullptr, 1);   // packed Q
    gemm1(src, wk, bk, X2B, 4096, 128, 128, nullptr, 0, nullptr, 1);   // packed K
    gemm1(src, wv, bv, X3A, 4096, 128, 128, nullptr, 0, nullptr, 1);   // packed V
    attn_part<<<dim3(64, 2, 8), 256, 0, stream>>>(X1B, X2B, X3A, OP, ML);
    attn_merge<<<(8*2048*16 + 255)/256, 256, 0, stream>>>(OP, ML, FANG);
    gemm1(FANG, wm, bm, X1O, 4096, 128, 128, nullptr, 0, nullptr, 0);
    gemm3(xin, 128, X1O, 128, nullptr, 0, nullptr, mw1, mb1, ABUF, 4096, 256, 256);
    stats_only(ABUF, 4096, 1, 256, 2048);
    gemm1(ABUF, mw2, mb2, dst, 4096, 256, 128, STAT, 256, xin, 0);
  };

  prop(SA0, SA1, XF0);
  prop(SA1, XF0, XF1);

  transpose_k<<<dim3(128/32, 2048/32, 2), dim3(32, 8), 0, stream>>>(XF0, (float*)d_out, 2048, 128);
  transpose_k<<<dim3(128/32, 2048/32, 2), dim3(32, 8), 0, stream>>>(XF1, (float*)d_out + (size_t)4096*128, 2048, 128);
}

// Round 9
// 1234.986 us; speedup vs baseline: 3.6625x; 1.0084x over previous
//
#include <hip/hip_runtime.h>
#include <cfloat>
#include <math.h>

#define NPTS 2048
#define R2   8192   // merged: 2 tensors x B=2 x N=2048

// ---------------- prep: derived weight matrices ----------------
__global__ __launch_bounds__(256) void prep_weights(
    const float* __restrict__ conv1, const float* __restrict__ conv2,
    const float* __restrict__ a1w1, const float* __restrict__ a1w2,
    const float* __restrict__ a2w1, const float* __restrict__ a2w2,
    const float* __restrict__ gw2,
    const float* __restrict__ wk, const float* __restrict__ bk,
    const float* __restrict__ wv, const float* __restrict__ bv,
    float* __restrict__ dwA1, float* __restrict__ a1w2r,
    float* __restrict__ dwA2, float* __restrict__ a2w2r,
    float* __restrict__ gw2r, float* __restrict__ dwC1, float* __restrict__ dwC2,
    float* __restrict__ wkv, float* __restrict__ bkv)
{
  int i = blockIdx.x * 256 + threadIdx.x;
  if (i < 512*128) {
    int row = i >> 7, c = i & 127;
    float v1, v2;
    if (row < 128) {             // ctrW[o][c] = sum_t (w1[o,c,t] - w1[o,128+c,t])
      float s1 = 0.f, s2 = 0.f;
      for (int t = 0; t < 3; t++) {
        s1 += a1w1[(row*256 + c)*3 + t] - a1w1[(row*256 + 128 + c)*3 + t];
        s2 += a2w1[(row*256 + c)*3 + t] - a2w1[(row*256 + 128 + c)*3 + t];
      }
      v1 = s1; v2 = s2;
    } else {                     // row = 128 + t*128 + o : nbW_t[o][c] = w1[o,128+c,t]
      int t = (row - 128) >> 7, o = row & 127;
      v1 = a1w1[(o*256 + 128 + c)*3 + t];
      v2 = a2w1[(o*256 + 128 + c)*3 + t];
    }
    dwA1[i] = v1; dwA2[i] = v2;
    dwC2[i] = (row < 256) ? (conv2[row*256 + c] - conv2[row*256 + 128 + c])
                          : conv2[(row-256)*256 + 128 + c];
  }
  if (i < 128*384) {             // w2r[o][w*128+c] = w2[o,c,w]
    int o = i / 384, rem = i % 384, w = rem >> 7, c = rem & 127;
    a1w2r[i] = a1w2[(o*128 + c)*3 + w];
    a2w2r[i] = a2w2[(o*128 + c)*3 + w];
    gw2r[i]  = gw2[(o*128 + c)*3 + w];
  }
  if (i < 256*128) {             // dwC1 [256][128] from conv1 [128][256]
    int row = i >> 7, c = i & 127;
    dwC1[i] = (row < 128) ? (conv1[row*256 + c] - conv1[row*256 + 128 + c])
                          : conv1[(row-128)*256 + 128 + c];
    // wkv [256][128] = [wk ; wv]
    wkv[i] = (row < 128) ? wk[row*128 + c] : wv[(row-128)*128 + c];
  }
  if (i < 256) bkv[i] = (i < 128) ? bk[i] : bv[i - 128];
}

// ---------------- transpose both descs: in [2][I][J] x2 -> out [4][J][I] ----------------
__global__ void transpose2(const float* __restrict__ in0, const float* __restrict__ in1,
                           float* __restrict__ out, int I, int J) {
  __shared__ float tile[32][33];
  int zb = blockIdx.z;
  const float* src = (zb < 2) ? (in0 + (size_t)zb*I*J) : (in1 + (size_t)(zb-2)*I*J);
  float* dst = out + (size_t)zb*J*I;
  int i0 = blockIdx.y * 32, j0 = blockIdx.x * 32;
  int tx = threadIdx.x, ty = threadIdx.y;
  for (int s = 0; s < 32; s += 8)
    tile[ty + s][tx] = src[(size_t)(i0 + ty + s)*J + (j0 + tx)];
  __syncthreads();
  for (int s = 0; s < 32; s += 8)
    dst[(size_t)(j0 + ty + s)*I + (i0 + tx)] = tile[tx][ty + s];
}

// ---------------- transpose [b][I][J] -> [b][J][I] (final output) ----------------
__global__ void transpose_k(const float* __restrict__ in, float* __restrict__ out, int I, int J) {
  __shared__ float tile[32][33];
  int b = blockIdx.z;
  int i0 = blockIdx.y * 32, j0 = blockIdx.x * 32;
  int tx = threadIdx.x, ty = threadIdx.y;
  for (int s = 0; s < 32; s += 8)
    tile[ty + s][tx] = in[((size_t)b*I + (i0 + ty + s))*J + (j0 + tx)];
  __syncthreads();
  for (int s = 0; s < 32; s += 8)
    out[((size_t)b*J + (j0 + ty + s))*I + (i0 + tx)] = tile[tx][ty + s];
}

// ---------------- KNN (both coord sets): f32 np-exact distances, (dist,idx)-lex ----------------
__global__ __launch_bounds__(256) void knn2_kernel(const float* __restrict__ P0, const float* __restrict__ P1,
                                                   int* __restrict__ idx, float* __restrict__ cosv) {
  __shared__ float px[NPTS], py[NPTS], sq[NPTS];
  int tid = threadIdx.x;
  int gw = blockIdx.x * 4 + (tid >> 6);   // 0..8191 : global point id
  int b4 = gw >> 11, n = gw & 2047;
  int lane = tid & 63;
  const float* Pb = (b4 < 2) ? (P0 + (size_t)b4 * 2 * NPTS) : (P1 + (size_t)(b4 - 2) * 2 * NPTS);
  for (int i = tid; i < NPTS; i += 256) {
    float x = Pb[i], y = Pb[NPTS + i];
    px[i] = x; py[i] = y;
    sq[i] = __fadd_rn(__fmul_rn(x, x), __fmul_rn(y, y));
  }
  __syncthreads();
  float xn = px[n], yn = py[n], sqn = sq[n];
  float d[10]; int id_[10];
#pragma unroll
  for (int j = 0; j < 10; j++) { d[j] = FLT_MAX; id_[j] = 0x7fffffff; }
  for (int m = lane; m < NPTS; m += 64) {
    float dot  = __fadd_rn(__fmul_rn(xn, px[m]), __fmul_rn(yn, py[m]));
    float dist = __fsub_rn(__fadd_rn(sqn, sq[m]), __fmul_rn(2.0f, dot));
    dist = fmaxf(dist, 1e-12f);
    if (dist < d[9] || (dist == d[9] && m < id_[9])) {
      int p = 0;
#pragma unroll
      for (int j = 0; j < 10; j++) p += (d[j] < dist || (d[j] == dist && id_[j] < m)) ? 1 : 0;
#pragma unroll
      for (int j = 9; j >= 1; j--) if (j > p) { d[j] = d[j-1]; id_[j] = id_[j-1]; }
#pragma unroll
      for (int j = 0; j < 10; j++) if (j == p) { d[j] = dist; id_[j] = m; }
    }
  }
  int ptr = 0;
  for (int r = 0; r < 10; r++) {
    float bd = FLT_MAX; int bi = 0x7fffffff;
#pragma unroll
    for (int j = 0; j < 10; j++) if (j == ptr) { bd = d[j]; bi = id_[j]; }
    for (int off = 32; off >= 1; off >>= 1) {
      float od = __shfl_xor(bd, off);
      int   oi = __shfl_xor(bi, off);
      if (od < bd || (od == bd && oi < bi)) { bd = od; bi = oi; }
    }
    bool adv = false;
#pragma unroll
    for (int j = 0; j < 10; j++) if (j == ptr) adv = (d[j] == bd && id_[j] == bi);
    if (adv) ptr++;
    if (r > 0 && lane == 0) {
      size_t base = (size_t)gw*9 + (r - 1);
      idx[base] = bi;   // local index within instance
      float dot = __fadd_rn(__fmul_rn(xn, px[bi]), __fmul_rn(yn, py[bi]));
      cosv[base] = __fdiv_rn(dot, __fmul_rn(__fsqrt_rn(sqn), __fsqrt_rn(sq[bi])));
    }
  }
}

// ---------------- unified f32 GEMM (K-major LDS, b128 fragment reads) ----------------
__global__ __launch_bounds__(256) void gemm_f(
    const float* __restrict__ p0, int w0,
    const float* __restrict__ p1, int w1,
    const float* __restrict__ p2, int w2,
    const float* __restrict__ addp,
    const float* __restrict__ xstats, int xmod,
    const float* __restrict__ W,
    const float* __restrict__ bias,
    const float* __restrict__ resid,
    float* __restrict__ Y, int Cin, int O, int pack, float* __restrict__ Y2)
{
  __shared__ float Xt[32][68], Wt[32][68];
  int tid = threadIdx.x;
  int r0 = blockIdx.x * 64, c0 = blockIdx.y * 64;
  int tx = tid & 15, ty = tid >> 4;
  int sr = tid & 63, scol = (tid >> 6) * 8;
  float acc[4][4] = {};
  for (int k0 = 0; k0 < Cin; k0 += 32) {
    {
      int r = r0 + sr;
      int ac = k0 + scol;
      const float* P; int cc, lw;
      if (ac < w0) { P = p0; cc = ac; lw = w0; }
      else if (ac < w0 + w1) { P = p1; cc = ac - w0; lw = w1; }
      else { P = p2; cc = ac - w0 - w1; lw = w2; }
      float4 v0 = *(const float4*)(P + (size_t)r*lw + cc);
      float4 v1 = *(const float4*)(P + (size_t)r*lw + cc + 4);
      float vv[8] = {v0.x, v0.y, v0.z, v0.w, v1.x, v1.y, v1.z, v1.w};
      if (addp && ac >= 128) {
        int fc = (ac - 128) & 127;
        float4 a0 = *(const float4*)(addp + (size_t)r*128 + fc);
        float4 a1 = *(const float4*)(addp + (size_t)r*128 + fc + 4);
        vv[0]+=a0.x; vv[1]+=a0.y; vv[2]+=a0.z; vv[3]+=a0.w;
        vv[4]+=a1.x; vv[5]+=a1.y; vv[6]+=a1.z; vv[7]+=a1.w;
      }
      if (xstats) {
        int b = r >> 11;
#pragma unroll
        for (int j = 0; j < 8; j++) {
          int o = (ac + j) & (xmod - 1);
          float m = xstats[(b*xmod + o)*2], rs = xstats[(b*xmod + o)*2 + 1];
          vv[j] = fmaxf((vv[j] - m) * rs, 0.f);
        }
      }
#pragma unroll
      for (int j = 0; j < 8; j++) Xt[scol + j][sr] = vv[j];
    }
    {
      const float* s = W + (size_t)(c0 + sr)*Cin + k0 + scol;
      float4 v0 = *(const float4*)s, v1 = *(const float4*)(s + 4);
      Wt[scol+0][sr]=v0.x; Wt[scol+1][sr]=v0.y; Wt[scol+2][sr]=v0.z; Wt[scol+3][sr]=v0.w;
      Wt[scol+4][sr]=v1.x; Wt[scol+5][sr]=v1.y; Wt[scol+6][sr]=v1.z; Wt[scol+7][sr]=v1.w;
    }
    __syncthreads();
#pragma unroll
    for (int kk = 0; kk < 32; kk++) {
      float4 av = *(const float4*)&Xt[kk][ty*4];
      float4 bv = *(const float4*)&Wt[kk][tx*4];
      acc[0][0] = fmaf(av.x, bv.x, acc[0][0]);
      acc[0][1] = fmaf(av.x, bv.y, acc[0][1]);
      acc[0][2] = fmaf(av.x, bv.z, acc[0][2]);
      acc[0][3] = fmaf(av.x, bv.w, acc[0][3]);
      acc[1][0] = fmaf(av.y, bv.x, acc[1][0]);
      acc[1][1] = fmaf(av.y, bv.y, acc[1][1]);
      acc[1][2] = fmaf(av.y, bv.z, acc[1][2]);
      acc[1][3] = fmaf(av.y, bv.w, acc[1][3]);
      acc[2][0] = fmaf(av.z, bv.x, acc[2][0]);
      acc[2][1] = fmaf(av.z, bv.y, acc[2][1]);
      acc[2][2] = fmaf(av.z, bv.z, acc[2][2]);
      acc[2][3] = fmaf(av.z, bv.w, acc[2][3]);
      acc[3][0] = fmaf(av.w, bv.x, acc[3][0]);
      acc[3][1] = fmaf(av.w, bv.y, acc[3][1]);
      acc[3][2] = fmaf(av.w, bv.z, acc[3][2]);
      acc[3][3] = fmaf(av.w, bv.w, acc[3][3]);
    }
    __syncthreads();
  }
#pragma unroll
  for (int i = 0; i < 4; i++) {
    int r = r0 + ty*4 + i;
#pragma unroll
    for (int j = 0; j < 4; j++) {
      int c = c0 + tx*4 + j;
      float v = acc[i][j] + (bias ? bias[c] : 0.f);
      if (resid) v += resid[(size_t)r*O + c];
      if (pack) {
        int cc2 = c & 127;
        int h = cc2 & 3, dd = cc2 >> 2, b = r >> 11, n = r & 2047;
        float* T = (pack == 1 || c < 128) ? Y : Y2;
        T[(((size_t)(b*4 + h))*NPTS + n)*32 + dd] = v;
      } else {
        Y[(size_t)r*O + c] = v;
      }
    }
  }
}

// ---------------- annu conv1 combine ----------------
__global__ __launch_bounds__(384) void combine_annu(const float* __restrict__ GA, const int* __restrict__ idx,
                                                    const float* __restrict__ b1, float* __restrict__ A) {
  int r = blockIdx.x, t = threadIdx.x;
  int w = t >> 7, o = t & 127;
  int rb = r & ~2047;
  __shared__ int nb[9];
  if (t < 9) nb[t] = idx[(size_t)r*9 + t];
  __syncthreads();
  float acc = GA[(size_t)r*512 + o] + b1[o];
#pragma unroll
  for (int t3 = 0; t3 < 3; t3++) {
    int m = nb[w*3 + t3];
    acc += GA[(size_t)(rb + m)*512 + 128 + t3*128 + o];
  }
  A[(size_t)r*384 + w*128 + o] = acc;
}

// ---------------- instance-norm stats: partial + fenced tail-block final ----------------
__global__ __launch_bounds__(256) void stats_fused(const float* __restrict__ X, double* __restrict__ part,
                                                   float* __restrict__ stats, int J, int Cc, int NB,
                                                   int count, int nblkPerB, int* __restrict__ ctr) {
  int t = threadIdx.x;
  int o = t % Cc, sub = t / Cc, nsub = 256 / Cc;
  int r0 = blockIdx.x * 64;
  double s = 0.0, s2 = 0.0;
  for (int rr = sub; rr < 64; rr += nsub)
    for (int j = 0; j < J; j++) {
      double v = X[(((size_t)(r0 + rr))*J + j)*Cc + o];
      s += v; s2 += v*v;
    }
  __shared__ double ls[256], ls2[256];
  ls[t] = s; ls2[t] = s2;
  __syncthreads();
  if (sub == 0) {
    for (int u = 1; u < nsub; u++) { s += ls[u*Cc + o]; s2 += ls2[u*Cc + o]; }
    part[((size_t)blockIdx.x*Cc + o)*2] = s;
    part[((size_t)blockIdx.x*Cc + o)*2 + 1] = s2;
    __threadfence();
  }
  __syncthreads();
  __shared__ int lastBlk;
  if (t == 0) lastBlk = (atomicAdd(ctr, 1) == (int)gridDim.x - 1) ? 1 : 0;
  __syncthreads();
  if (!lastBlk) return;
  __threadfence();
  for (int i = t; i < NB*Cc; i += 256) {
    int b = i / Cc, oo = i % Cc;
    double S = 0.0, S2 = 0.0;
    for (int u = 0; u < nblkPerB; u++) {
      int blk = b*nblkPerB + u;
      S  += part[((size_t)blk*Cc + oo)*2];
      S2 += part[((size_t)blk*Cc + oo)*2 + 1];
    }
    double mean = S / count;
    double var = S2 / count - mean*mean;
    if (var < 0.0) var = 0.0;
    stats[i*2] = (float)mean;
    stats[i*2 + 1] = (float)(1.0 / sqrt(var + 1e-5));
  }
}

// act: 0 none, 1 relu, 2 lrelu(0.2); optional addend
__global__ void norm_act(const float* __restrict__ src, float* __restrict__ dst,
                         const float* __restrict__ stats, int J, int Cc, int act, int total,
                         const float* __restrict__ addend) {
  int i = blockIdx.x * 256 + threadIdx.x;
  if (i >= total) return;
  int o = i % Cc;
  int r = i / (J*Cc);
  int b = r >> 11;
  float m = stats[(b*Cc + o)*2], rs = stats[(b*Cc + o)*2 + 1];
  float v = (src[i] - m) * rs;
  if (act == 1) v = fmaxf(v, 0.f);
  else if (act == 2) v = (v >= 0.f) ? v : 0.2f*v;
  if (addend) v += addend[i];
  dst[i] = v;
}

// ---------------- angle-feature conv1 ----------------
__global__ void cos_conv(const float* __restrict__ cosv, const float* __restrict__ gw1,
                         const float* __restrict__ gb1, float* __restrict__ ANG, int total) {
  int i = blockIdx.x * 256 + threadIdx.x;
  if (i >= total) return;
  int o = i & 127, w = (i >> 7) % 3;
  int r = i / 384;
  float acc = gb1[o];
#pragma unroll
  for (int t = 0; t < 3; t++) acc += cosv[(size_t)r*9 + w*3 + t] * gw1[o*3 + t];
  ANG[i] = acc;
}

// ---------------- gather + max over k + f64 partials (4 rows/block, idx in LDS) ----------------
__global__ __launch_bounds__(256) void gather_max_partial(const float* __restrict__ G, const int* __restrict__ idx,
                                                          float* __restrict__ maxbuf, double* __restrict__ part,
                                                          int Cc) {
  int t = threadIdx.x;
  int o = t % Cc, sub = t / Cc, nsub = 256 / Cc;
  int r0 = blockIdx.x * 4;
  __shared__ int nbs[4][9];
  if (t < 36) nbs[t / 9][t % 9] = idx[(size_t)(r0 + t/9)*9 + (t % 9)];
  __syncthreads();
  double s = 0.0, s2 = 0.0;
  for (int rr = sub; rr < 4; rr += nsub) {
    int r = r0 + rr, rb = r & ~2047;
    float g = G[(size_t)r*2*Cc + o];
    float mx = -3.4e38f;
#pragma unroll
    for (int k = 0; k < 9; k++) {
      int m = nbs[rr][k];
      float v = g + G[(size_t)(rb + m)*2*Cc + Cc + o];
      mx = fmaxf(mx, v); s += (double)v; s2 += (double)v*(double)v;
    }
    maxbuf[(size_t)r*Cc + o] = mx;
  }
  if (nsub == 2) {
    __shared__ double ls[256], ls2[256];
    ls[t] = s; ls2[t] = s2;
    __syncthreads();
    if (sub == 0) { s += ls[Cc + o]; s2 += ls2[Cc + o]; }
  }
  if (sub == 0) {
    part[((size_t)blockIdx.x*Cc + o)*2] = s;
    part[((size_t)blockIdx.x*Cc + o)*2 + 1] = s2;
  }
}

// ---------------- parallel stats final: 32-lane group per (instance, channel) ----------------
__global__ __launch_bounds__(256) void gm_final(const double* __restrict__ part, float* __restrict__ stats,
                                                int Cc, int NB, int nblk, int count) {
  int g = blockIdx.x * 8 + (threadIdx.x >> 5);
  int lane = threadIdx.x & 31;
  if (g >= NB*Cc) return;
  int b = g / Cc, o = g % Cc;
  double S = 0.0, S2 = 0.0;
  for (int u = lane; u < nblk; u += 32) {
    size_t blk = (size_t)(b*nblk + u);
    S  += part[(blk*Cc + o)*2];
    S2 += part[(blk*Cc + o)*2 + 1];
  }
  for (int off = 16; off >= 1; off >>= 1) {
    S  += __shfl_down(S, off, 32);
    S2 += __shfl_down(S2, off, 32);
  }
  if (lane == 0) {
    double mean = S / count;
    double var = S2 / count - mean*mean;
    if (var < 0.0) var = 0.0;
    stats[g*2] = (float)mean;
    stats[g*2 + 1] = (float)(1.0 / sqrt(var + 1e-5));
  }
}

// ---------------- flash attention v4: reg-Q, row-major Pt, transposed Vt, all-b128 ----------------
// thread (tx=tid&15, ty=tid>>4): q-rows {ty, ty+16}, score cols 4tx..4tx+3, out dims {tx, tx+16}
__global__ __launch_bounds__(256) void attn_part(const float* __restrict__ Qp, const float* __restrict__ Kp,
                                                 const float* __restrict__ Vp,
                                                 float* __restrict__ OP, float* __restrict__ ML) {
  __shared__ float Kt[32][68];   // [dim][key]
  __shared__ float Vt[32][68];   // [dim][key]
  __shared__ float Pt[32][68];   // [row][key]; front 32x33 doubles as Q staging
  int tid = threadIdx.x;
  int tx = tid & 15, ty = tid >> 4;
  int kp = blockIdx.y;      // key half
  int bh = blockIdx.z;
  int q0 = blockIdx.x * 32;
  const float* Qh = Qp + (size_t)bh * NPTS * 32;
  const float* Kh = Kp + (size_t)bh * NPTS * 32;
  const float* Vh = Vp + (size_t)bh * NPTS * 32;
  // stage Q into (aliased) LDS as [dim][row] stride 33, then pull into registers
  float* Qs = &Pt[0][0];
  {
    int r = tid & 31, a4 = ((tid >> 5) & 7) * 4;
    float4 v = *(const float4*)(Qh + (size_t)(q0 + r)*32 + a4);
    Qs[(a4+0)*33 + r] = v.x; Qs[(a4+1)*33 + r] = v.y;
    Qs[(a4+2)*33 + r] = v.z; Qs[(a4+3)*33 + r] = v.w;
  }
  __syncthreads();
  float q[2][32];
#pragma unroll
  for (int k = 0; k < 32; k++) {
    q[0][k] = Qs[k*33 + ty];
    q[1][k] = Qs[k*33 + ty + 16];
  }
  float m_[2] = {-FLT_MAX, -FLT_MAX};
  float l_[2] = {0.f, 0.f};
  float O_[2][2] = {};
  const float sc = 0.17677669529663687f;
  int ks = kp * 1024;
  for (int k0 = ks; k0 < ks + 1024; k0 += 64) {
    __syncthreads();   // prev tile readers done (and iter0: Q reg-loads done) before overwrite
    {
      int r = tid & 31, a4 = ((tid >> 5) & 7) * 4;
      float4 ka = *(const float4*)(Kh + (size_t)(k0 + r)*32 + a4);
      float4 kb = *(const float4*)(Kh + (size_t)(k0 + 32 + r)*32 + a4);
      Kt[a4+0][r] = ka.x; Kt[a4+1][r] = ka.y; Kt[a4+2][r] = ka.z; Kt[a4+3][r] = ka.w;
      Kt[a4+0][32+r] = kb.x; Kt[a4+1][32+r] = kb.y; Kt[a4+2][32+r] = kb.z; Kt[a4+3][32+r] = kb.w;
      float4 va = *(const float4*)(Vh + (size_t)(k0 + r)*32 + a4);
      float4 vb = *(const float4*)(Vh + (size_t)(k0 + 32 + r)*32 + a4);
      Vt[a4+0][r] = va.x; Vt[a4+1][r] = va.y; Vt[a4+2][r] = va.z; Vt[a4+3][r] = va.w;
      Vt[a4+0][32+r] = vb.x; Vt[a4+1][32+r] = vb.y; Vt[a4+2][32+r] = vb.z; Vt[a4+3][32+r] = vb.w;
    }
    __syncthreads();
    float acc[2][4] = {};
#pragma unroll
    for (int k = 0; k < 32; k++) {
      float4 bv = *(const float4*)&Kt[k][tx*4];
      acc[0][0] = fmaf(q[0][k], bv.x, acc[0][0]);
      acc[0][1] = fmaf(q[0][k], bv.y, acc[0][1]);
      acc[0][2] = fmaf(q[0][k], bv.z, acc[0][2]);
      acc[0][3] = fmaf(q[0][k], bv.w, acc[0][3]);
      acc[1][0] = fmaf(q[1][k], bv.x, acc[1][0]);
      acc[1][1] = fmaf(q[1][k], bv.y, acc[1][1]);
      acc[1][2] = fmaf(q[1][k], bv.z, acc[1][2]);
      acc[1][3] = fmaf(q[1][k], bv.w, acc[1][3]);
    }
#pragma unroll
    for (int i = 0; i < 2; i++)
#pragma unroll
      for (int j = 0; j < 4; j++) acc[i][j] *= sc;
    // online softmax (16-lane tx-group reductions; Pt comm intra-group, wave-ordered)
#pragma unroll
    for (int i = 0; i < 2; i++) {
      float tm = fmaxf(fmaxf(acc[i][0], acc[i][1]), fmaxf(acc[i][2], acc[i][3]));
      for (int s = 1; s < 16; s <<= 1) tm = fmaxf(tm, __shfl_xor(tm, s));
      float mn = fmaxf(m_[i], tm);
      float cf = __expf(m_[i] - mn);
      m_[i] = mn;
      l_[i] *= cf; O_[i][0] *= cf; O_[i][1] *= cf;
      float4 p;
      p.x = __expf(acc[i][0] - mn);
      p.y = __expf(acc[i][1] - mn);
      p.z = __expf(acc[i][2] - mn);
      p.w = __expf(acc[i][3] - mn);
      float rs = p.x + p.y + p.z + p.w;
      *(float4*)&Pt[ty + 16*i][tx*4] = p;
      for (int s = 1; s < 16; s <<= 1) rs += __shfl_xor(rs, s);
      l_[i] += rs;
    }
    // PV: all-b128 (Pt rows {ty,ty+16} and Vt rows {tx,tx+16})
#pragma unroll
    for (int kb = 0; kb < 64; kb += 4) {
      float4 p0 = *(const float4*)&Pt[ty][kb];
      float4 p1 = *(const float4*)&Pt[ty + 16][kb];
      float4 va = *(const float4*)&Vt[tx][kb];
      float4 vb = *(const float4*)&Vt[tx + 16][kb];
      O_[0][0] = fmaf(p0.x, va.x, O_[0][0]); O_[0][0] = fmaf(p0.y, va.y, O_[0][0]);
      O_[0][0] = fmaf(p0.z, va.z, O_[0][0]); O_[0][0] = fmaf(p0.w, va.w, O_[0][0]);
      O_[0][1] = fmaf(p0.x, vb.x, O_[0][1]); O_[0][1] = fmaf(p0.y, vb.y, O_[0][1]);
      O_[0][1] = fmaf(p0.z, vb.z, O_[0][1]); O_[0][1] = fmaf(p0.w, vb.w, O_[0][1]);
      O_[1][0] = fmaf(p1.x, va.x, O_[1][0]); O_[1][0] = fmaf(p1.y, va.y, O_[1][0]);
      O_[1][0] = fmaf(p1.z, va.z, O_[1][0]); O_[1][0] = fmaf(p1.w, va.w, O_[1][0]);
      O_[1][1] = fmaf(p1.x, vb.x, O_[1][1]); O_[1][1] = fmaf(p1.y, vb.y, O_[1][1]);
      O_[1][1] = fmaf(p1.z, vb.z, O_[1][1]); O_[1][1] = fmaf(p1.w, vb.w, O_[1][1]);
    }
  }
  size_t pb = (size_t)(kp*8 + bh) * NPTS;
#pragma unroll
  for (int i = 0; i < 2; i++) {
    int n = q0 + ty + 16*i;
    OP[(pb + n)*32 + tx]      = O_[i][0];
    OP[(pb + n)*32 + tx + 16] = O_[i][1];
    if (tx == 0) { ML[(pb + n)*2] = m_[i]; ML[(pb + n)*2 + 1] = l_[i]; }
  }
}

// ---------------- merge the two K-halves ----------------
__global__ void attn_merge(const float* __restrict__ OP, const float* __restrict__ ML,
                           float* __restrict__ out) {
  int i = blockIdx.x * 256 + threadIdx.x;   // 8*2048*16
  if (i >= 8*2048*16) return;
  int dp = (i & 15) * 2;
  int n  = (i >> 4) & 2047;
  int bh = i >> 15;
  size_t p0 = (size_t)bh * NPTS + n;
  size_t p1 = (size_t)(8 + bh) * NPTS + n;
  float m0 = ML[p0*2], l0 = ML[p0*2 + 1];
  float m1 = ML[p1*2], l1 = ML[p1*2 + 1];
  float m = fmaxf(m0, m1);
  float w0 = __expf(m0 - m), w1 = __expf(m1 - m);
  float inv = 1.f / (w0*l0 + w1*l1);
  float2 o0 = *(const float2*)&OP[p0*32 + dp];
  float2 o1 = *(const float2*)&OP[p1*32 + dp];
  int b = bh >> 2, h = bh & 3;
  out[((size_t)(b*NPTS + n))*128 + (dp+0)*4 + h] = (w0*o0.x + w1*o1.x) * inv;
  out[((size_t)(b*NPTS + n))*128 + (dp+1)*4 + h] = (w0*o0.y + w1*o1.y) * inv;
}

// ================= host =================
extern "C" void kernel_launch(void* const* d_in, const int* in_sizes, int n_in,
                              void* d_out, int out_size, void* d_ws, size_t ws_size,
                              hipStream_t stream) {
  (void)in_sizes; (void)n_in; (void)out_size; (void)ws_size;
  const float* desc0  = (const float*)d_in[0];
  const float* desc1  = (const float*)d_in[1];
  const float* coords0= (const float*)d_in[2];
  const float* coords1= (const float*)d_in[3];
  const float* conv1w = (const float*)d_in[4];
  const float* conv2w = (const float*)d_in[5];
  const float* conv3w = (const float*)d_in[6];
  const float* conv3ow= (const float*)d_in[7];
  const float* a1w1 = (const float*)d_in[8];
  const float* a1b1 = (const float*)d_in[9];
  const float* a1w2 = (const float*)d_in[10];
  const float* a1b2 = (const float*)d_in[11];
  const float* a2w1 = (const float*)d_in[12];
  const float* a2b1 = (const float*)d_in[13];
  const float* a2w2 = (const float*)d_in[14];
  const float* a2b2 = (const float*)d_in[15];
  const float* gw1  = (const float*)d_in[16];
  const float* gb1  = (const float*)d_in[17];
  const float* gw2  = (const float*)d_in[18];
  const float* gb2  = (const float*)d_in[19];
  const float* wq = (const float*)d_in[20]; const float* bq = (const float*)d_in[21];
  const float* wk = (const float*)d_in[22]; const float* bk = (const float*)d_in[23];
  const float* wv = (const float*)d_in[24]; const float* bv = (const float*)d_in[25];
  const float* wm = (const float*)d_in[26]; const float* bm = (const float*)d_in[27];
  const float* mw1 = (const float*)d_in[28]; const float* mb1 = (const float*)d_in[29];
  const float* mw2 = (const float*)d_in[30]; const float* mb2 = (const float*)d_in[31];

  float* ws = (float*)d_ws;
  size_t off = 0;
  auto alloc = [&](size_t nel) { size_t r = off; off += (nel + 63) & ~(size_t)63; return r; };
  float* DW_A1 = ws + alloc(512*128);
  float* W_A1R = ws + alloc(128*384);
  float* DW_A2 = ws + alloc(512*128);
  float* W_A2R = ws + alloc(128*384);
  float* W_G2R = ws + alloc(128*384);
  float* DW_C1 = ws + alloc(256*128);
  float* DW_C2 = ws + alloc(512*128);
  float* W_KV  = ws + alloc(256*128);
  float* B_KV  = ws + alloc(256);
  float* SA   = ws + alloc((size_t)R2*128);
  float* XF0  = ws + alloc((size_t)4096*128);
  float* XF1  = ws + alloc((size_t)4096*128);
  int*   IDX  = (int*)(ws + alloc((size_t)R2*9));
  float* COSV = ws + alloc((size_t)R2*9);
  float* FT   = ws + alloc((size_t)R2*128);
  float* BIG  = ws + alloc((size_t)R2*512);
  float* ABUF = ws + alloc((size_t)R2*384);
  float* X1B  = ws + alloc((size_t)R2*128);
  float* FANG = ws + alloc((size_t)R2*128);
  float* X2B  = ws + alloc((size_t)R2*128);
  float* X3A  = ws + alloc((size_t)R2*128);
  float* X1O  = ws + alloc((size_t)R2*128);
  double* PART = (double*)(ws + alloc((size_t)2048*256*2*2));   // 1M doubles (8 MB)
  float* STAT = ws + alloc(4*256*2);
  int*   CTR  = (int*)(ws + alloc(64));
  float* X3O = BIG;                 // alias (BIG free at that point)
  float* OP  = BIG;                 // attn partials (prop phase)
  float* ML  = BIG + (size_t)2*8*NPTS*32;

  hipMemsetAsync(CTR, 0, 64*sizeof(int), stream);
  int ctr_id = 0;

  auto gemm1 = [&](const float* X, const float* W, const float* bias, float* Y, int R, int Cin, int O,
                   const float* xst, int xmod, const float* resid, int pack) {
    gemm_f<<<dim3(R/64, O/64), 256, 0, stream>>>(X, Cin, nullptr, 0, nullptr, 0, nullptr,
                                                 xst, xmod, W, bias, resid, Y, Cin, O, pack, nullptr);
  };
  auto gemm3 = [&](const float* a, int wa, const float* b, int wb, const float* c, int wc,
                   const float* addp, const float* W, const float* bias, float* Y, int R, int Cin, int O) {
    gemm_f<<<dim3(R/64, O/64), 256, 0, stream>>>(a, wa, b, wb, c, wc, addp,
                                                 nullptr, 0, W, bias, nullptr, Y, Cin, O, 0, nullptr);
  };
  auto stats_only = [&](const float* buf, int R, int J, int Cc, int count) {
    stats_fused<<<R/64, 256, 0, stream>>>(buf, PART, STAT, J, Cc, R/2048, count, 32, CTR + ctr_id++);
  };
  auto statnorm = [&](const float* buf, float* dst, int R, int J, int Cc, int act, int count,
                      const float* addend) {
    stats_only(buf, R, J, Cc, count);
    int tot = R*J*Cc;
    norm_act<<<(tot + 255)/256, 256, 0, stream>>>(buf, dst, STAT, J, Cc, act, tot, addend);
  };
  auto gathermax = [&](const float* G, float* mx, float* dstNorm, int Cc) {
    gather_max_partial<<<R2/4, 256, 0, stream>>>(G, IDX, mx, PART, Cc);
    gm_final<<<(4*Cc + 7)/8, 256, 0, stream>>>(PART, STAT, Cc, 4, (R2/4)/4, 2048*9);
    int tot = R2*Cc;
    norm_act<<<(tot + 255)/256, 256, 0, stream>>>(mx, dstNorm, STAT, 1, Cc, 2, tot, nullptr);
  };

  prep_weights<<<256, 256, 0, stream>>>(conv1w, conv2w, a1w1, a1w2, a2w1, a2w2, gw2,
                                        wk, bk, wv, bv,
                                        DW_A1, W_A1R, DW_A2, W_A2R, W_G2R, DW_C1, DW_C2,
                                        W_KV, B_KV);

  // ===== merged branch section (both descs, R2 = 8192 rows, 4 instances) =====
  transpose2<<<dim3(2048/32, 128/32, 4), dim3(32, 8), 0, stream>>>(desc0, desc1, FT, 128, 2048);
  knn2_kernel<<<2048, 256, 0, stream>>>(coords0, coords1, IDX, COSV);
  // annu1
  gemm1(FT, DW_A1, nullptr, BIG, R2, 128, 512, nullptr, 0, nullptr, 0);
  combine_annu<<<R2, 384, 0, stream>>>(BIG, IDX, a1b1, ABUF);
  stats_only(ABUF, R2, 3, 128, 2048*3);
  gemm1(ABUF, W_A1R, a1b2, X1B, R2, 384, 128, STAT, 128, nullptr, 0);
  statnorm(X1B, X1B, R2, 1, 128, 1, 2048, nullptr);
  // f_ang (idx1 == idx2)
  cos_conv<<<(R2*384 + 255)/256, 256, 0, stream>>>(COSV, gw1, gb1, ABUF, R2*384);
  stats_only(ABUF, R2, 3, 128, 2048*3);
  gemm1(ABUF, W_G2R, gb2, FANG, R2, 384, 128, STAT, 128, nullptr, 0);
  statnorm(FANG, FANG, R2, 1, 128, 1, 2048, nullptr);
  // annu2
  gemm1(X1B, DW_A2, nullptr, BIG, R2, 128, 512, nullptr, 0, nullptr, 0);
  combine_annu<<<R2, 384, 0, stream>>>(BIG, IDX, a2b1, ABUF);
  stats_only(ABUF, R2, 3, 128, 2048*3);
  gemm1(ABUF, W_A2R, a2b2, X2B, R2, 384, 128, STAT, 128, nullptr, 0);
  statnorm(X2B, X2B, R2, 1, 128, 1, 2048, nullptr);
  // x3
  gemm3(FT, 128, X1B, 128, X2B, 128, FANG, conv3w, nullptr, X3A, R2, 384, 128);
  statnorm(X3A, X3A, R2, 1, 128, 2, 2048, nullptr);
  // x1o
  gemm1(FT, DW_C1, nullptr, BIG, R2, 128, 256, nullptr, 0, nullptr, 0);
  gathermax(BIG, ABUF, X1O, 128);
  // x2o (max + norm in-place in ABUF viewed as [R2][256])
  gemm1(X1O, DW_C2, nullptr, BIG, R2, 128, 512, nullptr, 0, nullptr, 0);
  gathermax(BIG, ABUF, ABUF, 256);
  // x3o -> SA (= x3 + x3o)
  gemm3(FT, 128, X1O, 128, ABUF, 256, nullptr, conv3ow, nullptr, X3O, R2, 512, 128);
  statnorm(X3O, SA, R2, 1, 128, 2, 2048, X3A);

  // ===== cross-attention props (rows 4096 each) =====
  float* SA0 = SA;
  float* SA1 = SA + (size_t)4096*128;
  auto prop = [&](const float* xin, const float* src, float* dst) {
    gemm1(xin, wq, bq, X1B, 4096, 128, 128, nullptr, 0, nullptr, 1);   // packed Q
    // packed K (X2B) + packed V (X3A) in one launch
    gemm_f<<<dim3(4096/64, 4), 256, 0, stream>>>(src, 128, nullptr, 0, nullptr, 0, nullptr,
                                                 nullptr, 0, W_KV, B_KV, nullptr,
                                                 X2B, 128, 256, 2, X3A);
    attn_part<<<dim3(64, 2, 8), 256, 0, stream>>>(X1B, X2B, X3A, OP, ML);
    attn_merge<<<(8*2048*16 + 255)/256, 256, 0, stream>>>(OP, ML, FANG);
    gemm1(FANG, wm, bm, X1O, 4096, 128, 128, nullptr, 0, nullptr, 0);
    gemm3(xin, 128, X1O, 128, nullptr, 0, nullptr, mw1, mb1, ABUF, 4096, 256, 256);
    stats_only(ABUF, 4096, 1, 256, 2048);
    gemm1(ABUF, mw2, mb2, dst, 4096, 256, 128, STAT, 256, xin, 0);
  };

  prop(SA0, SA1, XF0);
  prop(SA1, XF0, XF1);

  transpose_k<<<dim3(128/32, 2048/32, 2), dim3(32, 8), 0, stream>>>(XF0, (float*)d_out, 2048, 128);
  transpose_k<<<dim3(128/32, 2048/32, 2), dim3(32, 8), 0, stream>>>(XF1, (float*)d_out + (size_t)4096*128, 2048, 128);
}

// Round 10
// 878.118 us; speedup vs baseline: 5.1509x; 1.4064x over previous
//
#include <hip/hip_runtime.h>
#include <cfloat>
#include <math.h>

#define NPTS 2048
#define R2   8192   // merged: 2 tensors x B=2 x N=2048

// ---------------- prep: derived weight matrices ----------------
__global__ __launch_bounds__(256) void prep_weights(
    const float* __restrict__ conv1, const float* __restrict__ conv2,
    const float* __restrict__ a1w1, const float* __restrict__ a1w2,
    const float* __restrict__ a2w1, const float* __restrict__ a2w2,
    const float* __restrict__ gw2,
    const float* __restrict__ wk, const float* __restrict__ bk,
    const float* __restrict__ wv, const float* __restrict__ bv,
    float* __restrict__ dwA1, float* __restrict__ a1w2r,
    float* __restrict__ dwA2, float* __restrict__ a2w2r,
    float* __restrict__ gw2r, float* __restrict__ dwC1, float* __restrict__ dwC2,
    float* __restrict__ wkv, float* __restrict__ bkv)
{
  int i = blockIdx.x * 256 + threadIdx.x;
  if (i < 512*128) {
    int row = i >> 7, c = i & 127;
    float v1, v2;
    if (row < 128) {             // ctrW[o][c] = sum_t (w1[o,c,t] - w1[o,128+c,t])
      float s1 = 0.f, s2 = 0.f;
      for (int t = 0; t < 3; t++) {
        s1 += a1w1[(row*256 + c)*3 + t] - a1w1[(row*256 + 128 + c)*3 + t];
        s2 += a2w1[(row*256 + c)*3 + t] - a2w1[(row*256 + 128 + c)*3 + t];
      }
      v1 = s1; v2 = s2;
    } else {                     // row = 128 + t*128 + o : nbW_t[o][c] = w1[o,128+c,t]
      int t = (row - 128) >> 7, o = row & 127;
      v1 = a1w1[(o*256 + 128 + c)*3 + t];
      v2 = a2w1[(o*256 + 128 + c)*3 + t];
    }
    dwA1[i] = v1; dwA2[i] = v2;
    dwC2[i] = (row < 256) ? (conv2[row*256 + c] - conv2[row*256 + 128 + c])
                          : conv2[(row-256)*256 + 128 + c];
  }
  if (i < 128*384) {             // w2r[o][w*128+c] = w2[o,c,w]
    int o = i / 384, rem = i % 384, w = rem >> 7, c = rem & 127;
    a1w2r[i] = a1w2[(o*128 + c)*3 + w];
    a2w2r[i] = a2w2[(o*128 + c)*3 + w];
    gw2r[i]  = gw2[(o*128 + c)*3 + w];
  }
  if (i < 256*128) {             // dwC1 [256][128] from conv1 [128][256]
    int row = i >> 7, c = i & 127;
    dwC1[i] = (row < 128) ? (conv1[row*256 + c] - conv1[row*256 + 128 + c])
                          : conv1[(row-128)*256 + 128 + c];
    wkv[i] = (row < 128) ? wk[row*128 + c] : wv[(row-128)*128 + c];
  }
  if (i < 256) bkv[i] = (i < 128) ? bk[i] : bv[i - 128];
}

// ---------------- transpose both descs: in [2][I][J] x2 -> out [4][J][I] ----------------
__global__ void transpose2(const float* __restrict__ in0, const float* __restrict__ in1,
                           float* __restrict__ out, int I, int J) {
  __shared__ float tile[32][33];
  int zb = blockIdx.z;
  const float* src = (zb < 2) ? (in0 + (size_t)zb*I*J) : (in1 + (size_t)(zb-2)*I*J);
  float* dst = out + (size_t)zb*J*I;
  int i0 = blockIdx.y * 32, j0 = blockIdx.x * 32;
  int tx = threadIdx.x, ty = threadIdx.y;
  for (int s = 0; s < 32; s += 8)
    tile[ty + s][tx] = src[(size_t)(i0 + ty + s)*J + (j0 + tx)];
  __syncthreads();
  for (int s = 0; s < 32; s += 8)
    dst[(size_t)(j0 + ty + s)*I + (i0 + tx)] = tile[tx][ty + s];
}

// ---------------- transpose [b][I][J] -> [b][J][I] (final output) ----------------
__global__ void transpose_k(const float* __restrict__ in, float* __restrict__ out, int I, int J) {
  __shared__ float tile[32][33];
  int b = blockIdx.z;
  int i0 = blockIdx.y * 32, j0 = blockIdx.x * 32;
  int tx = threadIdx.x, ty = threadIdx.y;
  for (int s = 0; s < 32; s += 8)
    tile[ty + s][tx] = in[((size_t)b*I + (i0 + ty + s))*J + (j0 + tx)];
  __syncthreads();
  for (int s = 0; s < 32; s += 8)
    out[((size_t)b*J + (j0 + ty + s))*I + (i0 + tx)] = tile[tx][ty + s];
}

// ---------------- KNN (both coord sets): f32 np-exact distances, (dist,idx)-lex ----------------
__global__ __launch_bounds__(256) void knn2_kernel(const float* __restrict__ P0, const float* __restrict__ P1,
                                                   int* __restrict__ idx, float* __restrict__ cosv) {
  __shared__ float px[NPTS], py[NPTS], sq[NPTS];
  int tid = threadIdx.x;
  int gw = blockIdx.x * 4 + (tid >> 6);   // 0..8191 : global point id
  int b4 = gw >> 11, n = gw & 2047;
  int lane = tid & 63;
  const float* Pb = (b4 < 2) ? (P0 + (size_t)b4 * 2 * NPTS) : (P1 + (size_t)(b4 - 2) * 2 * NPTS);
  for (int i = tid; i < NPTS; i += 256) {
    float x = Pb[i], y = Pb[NPTS + i];
    px[i] = x; py[i] = y;
    sq[i] = __fadd_rn(__fmul_rn(x, x), __fmul_rn(y, y));
  }
  __syncthreads();
  float xn = px[n], yn = py[n], sqn = sq[n];
  float d[10]; int id_[10];
#pragma unroll
  for (int j = 0; j < 10; j++) { d[j] = FLT_MAX; id_[j] = 0x7fffffff; }
  for (int m = lane; m < NPTS; m += 64) {
    float dot  = __fadd_rn(__fmul_rn(xn, px[m]), __fmul_rn(yn, py[m]));
    float dist = __fsub_rn(__fadd_rn(sqn, sq[m]), __fmul_rn(2.0f, dot));
    dist = fmaxf(dist, 1e-12f);
    if (dist < d[9] || (dist == d[9] && m < id_[9])) {
      int p = 0;
#pragma unroll
      for (int j = 0; j < 10; j++) p += (d[j] < dist || (d[j] == dist && id_[j] < m)) ? 1 : 0;
#pragma unroll
      for (int j = 9; j >= 1; j--) if (j > p) { d[j] = d[j-1]; id_[j] = id_[j-1]; }
#pragma unroll
      for (int j = 0; j < 10; j++) if (j == p) { d[j] = dist; id_[j] = m; }
    }
  }
  int ptr = 0;
  for (int r = 0; r < 10; r++) {
    float bd = FLT_MAX; int bi = 0x7fffffff;
#pragma unroll
    for (int j = 0; j < 10; j++) if (j == ptr) { bd = d[j]; bi = id_[j]; }
    for (int off = 32; off >= 1; off >>= 1) {
      float od = __shfl_xor(bd, off);
      int   oi = __shfl_xor(bi, off);
      if (od < bd || (od == bd && oi < bi)) { bd = od; bi = oi; }
    }
    bool adv = false;
#pragma unroll
    for (int j = 0; j < 10; j++) if (j == ptr) adv = (d[j] == bd && id_[j] == bi);
    if (adv) ptr++;
    if (r > 0 && lane == 0) {
      size_t base = (size_t)gw*9 + (r - 1);
      idx[base] = bi;
      float dot = __fadd_rn(__fmul_rn(xn, px[bi]), __fmul_rn(yn, py[bi]));
      cosv[base] = __fdiv_rn(dot, __fmul_rn(__fsqrt_rn(sqn), __fsqrt_rn(sq[bi])));
    }
  }
}

// ---------------- unified f32 GEMM: template BM (64/32), per-segment norm-act fusion ----------------
// X virtually = [p0(w0)|p1(w1)|p2(w2)]; each segment has optional (stats, act, xmod).
// addp (cols>=128): addend (ac-128)&127, optionally normed with addst (relu).
// act: 1 relu, 2 lrelu(0.2).
template<int BM>
__global__ __launch_bounds__(256) void gemm_t(
    const float* __restrict__ p0, int w0, const float* __restrict__ st0, int a0, int xm0,
    const float* __restrict__ p1, int w1, const float* __restrict__ st1, int a1, int xm1,
    const float* __restrict__ p2, int w2, const float* __restrict__ st2, int a2, int xm2,
    const float* __restrict__ addp, const float* __restrict__ addst,
    const float* __restrict__ W, const float* __restrict__ bias,
    const float* __restrict__ resid,
    float* __restrict__ Y, int Cin, int O, int pack, float* __restrict__ Y2)
{
  __shared__ float Xt[32][BM + 4];   // [k][row]
  __shared__ float Wt[32][68];       // [k][col]
  constexpr int RPT = BM / 16;       // output rows per thread
  constexpr int XF  = BM / 8;        // floats per thread for X staging
  int tid = threadIdx.x;
  int r0 = blockIdx.x * BM, c0 = blockIdx.y * 64;
  int tx = tid & 15, ty = tid >> 4;
  int sxr = tid & (BM - 1), sxc = (tid / BM) * XF;
  int swr = tid & 63, swc = (tid >> 6) * 8;
  float acc[RPT][4] = {};
  for (int k0 = 0; k0 < Cin; k0 += 32) {
    // ---- stage X (transposed) with per-segment norm-act + addend ----
    {
      int r = r0 + sxr;
      int ac = k0 + sxc;                        // wave-uniform segment select
      const float* P; const float* st; int cc, lw, act, xm;
      if (ac < w0)            { P = p0; cc = ac;          lw = w0; st = st0; act = a0; xm = xm0; }
      else if (ac < w0 + w1)  { P = p1; cc = ac - w0;     lw = w1; st = st1; act = a1; xm = xm1; }
      else                    { P = p2; cc = ac - w0 - w1; lw = w2; st = st2; act = a2; xm = xm2; }
      float vv[XF];
#pragma unroll
      for (int q = 0; q < XF; q += 4)
        *(float4*)&vv[q] = *(const float4*)(P + (size_t)r*lw + cc + q);
      int b = r >> 11;
      if (st) {
#pragma unroll
        for (int j = 0; j < XF; j++) {
          int o = (cc + j) & (xm - 1);
          float m = st[(b*xm + o)*2], rs = st[(b*xm + o)*2 + 1];
          float v = (vv[j] - m) * rs;
          vv[j] = (act == 1) ? fmaxf(v, 0.f) : ((v >= 0.f) ? v : 0.2f*v);
        }
      }
      if (addp && ac >= 128) {
        int fc = (ac - 128) & 127;
        float av[XF];
#pragma unroll
        for (int q = 0; q < XF; q += 4)
          *(float4*)&av[q] = *(const float4*)(addp + (size_t)r*128 + fc + q);
        if (addst) {
#pragma unroll
          for (int j = 0; j < XF; j++) {
            int o = (fc + j) & 127;
            float m = addst[(b*128 + o)*2], rs = addst[(b*128 + o)*2 + 1];
            av[j] = fmaxf((av[j] - m) * rs, 0.f);
          }
        }
#pragma unroll
        for (int j = 0; j < XF; j++) vv[j] += av[j];
      }
#pragma unroll
      for (int j = 0; j < XF; j++) Xt[sxc + j][sxr] = vv[j];
    }
    // ---- stage W (transposed) ----
    {
      const float* s = W + (size_t)(c0 + swr)*Cin + k0 + swc;
      float4 v0 = *(const float4*)s, v1 = *(const float4*)(s + 4);
      Wt[swc+0][swr]=v0.x; Wt[swc+1][swr]=v0.y; Wt[swc+2][swr]=v0.z; Wt[swc+3][swr]=v0.w;
      Wt[swc+4][swr]=v1.x; Wt[swc+5][swr]=v1.y; Wt[swc+6][swr]=v1.z; Wt[swc+7][swr]=v1.w;
    }
    __syncthreads();
#pragma unroll
    for (int kk = 0; kk < 32; kk++) {
      float4 bv = *(const float4*)&Wt[kk][tx*4];
      if (BM == 64) {
        float4 av = *(const float4*)&Xt[kk][ty*4];
        acc[0][0] = fmaf(av.x, bv.x, acc[0][0]); acc[0][1] = fmaf(av.x, bv.y, acc[0][1]);
        acc[0][2] = fmaf(av.x, bv.z, acc[0][2]); acc[0][3] = fmaf(av.x, bv.w, acc[0][3]);
        acc[1][0] = fmaf(av.y, bv.x, acc[1][0]); acc[1][1] = fmaf(av.y, bv.y, acc[1][1]);
        acc[1][2] = fmaf(av.y, bv.z, acc[1][2]); acc[1][3] = fmaf(av.y, bv.w, acc[1][3]);
        acc[RPT-2][0] = fmaf(av.z, bv.x, acc[RPT-2][0]); acc[RPT-2][1] = fmaf(av.z, bv.y, acc[RPT-2][1]);
        acc[RPT-2][2] = fmaf(av.z, bv.z, acc[RPT-2][2]); acc[RPT-2][3] = fmaf(av.z, bv.w, acc[RPT-2][3]);
        acc[RPT-1][0] = fmaf(av.w, bv.x, acc[RPT-1][0]); acc[RPT-1][1] = fmaf(av.w, bv.y, acc[RPT-1][1]);
        acc[RPT-1][2] = fmaf(av.w, bv.z, acc[RPT-1][2]); acc[RPT-1][3] = fmaf(av.w, bv.w, acc[RPT-1][3]);
      } else {
        float2 av = *(const float2*)&Xt[kk][ty*2];
        acc[0][0] = fmaf(av.x, bv.x, acc[0][0]); acc[0][1] = fmaf(av.x, bv.y, acc[0][1]);
        acc[0][2] = fmaf(av.x, bv.z, acc[0][2]); acc[0][3] = fmaf(av.x, bv.w, acc[0][3]);
        acc[RPT-1][0] = fmaf(av.y, bv.x, acc[RPT-1][0]); acc[RPT-1][1] = fmaf(av.y, bv.y, acc[RPT-1][1]);
        acc[RPT-1][2] = fmaf(av.y, bv.z, acc[RPT-1][2]); acc[RPT-1][3] = fmaf(av.y, bv.w, acc[RPT-1][3]);
      }
    }
    __syncthreads();
  }
#pragma unroll
  for (int i = 0; i < RPT; i++) {
    int r = r0 + ty*RPT + i;
#pragma unroll
    for (int j = 0; j < 4; j++) {
      int c = c0 + tx*4 + j;
      float v = acc[i][j] + (bias ? bias[c] : 0.f);
      if (resid) v += resid[(size_t)r*O + c];
      if (pack) {
        int cc2 = c & 127;
        int h = cc2 & 3, dd = cc2 >> 2, b = r >> 11, n = r & 2047;
        float* T = (pack == 1 || c < 128) ? Y : Y2;
        T[(((size_t)(b*4 + h))*NPTS + n)*32 + dd] = v;
      } else {
        Y[(size_t)r*O + c] = v;
      }
    }
  }
}

// ---------------- annu conv1 combine ----------------
__global__ __launch_bounds__(384) void combine_annu(const float* __restrict__ GA, const int* __restrict__ idx,
                                                    const float* __restrict__ b1, float* __restrict__ A) {
  int r = blockIdx.x, t = threadIdx.x;
  int w = t >> 7, o = t & 127;
  int rb = r & ~2047;
  __shared__ int nb[9];
  if (t < 9) nb[t] = idx[(size_t)r*9 + t];
  __syncthreads();
  float acc = GA[(size_t)r*512 + o] + b1[o];
#pragma unroll
  for (int t3 = 0; t3 < 3; t3++) {
    int m = nb[w*3 + t3];
    acc += GA[(size_t)(rb + m)*512 + 128 + t3*128 + o];
  }
  A[(size_t)r*384 + w*128 + o] = acc;
}

// ---------------- stats partial: 16 rows/block, f64 ----------------
__global__ __launch_bounds__(256) void stats_partial(const float* __restrict__ X, double* __restrict__ part,
                                                     int J, int Cc) {
  int t = threadIdx.x;
  int o = t % Cc, sub = t / Cc, nsub = 256 / Cc;
  int r0 = blockIdx.x * 16;
  double s = 0.0, s2 = 0.0;
  for (int rr = sub; rr < 16; rr += nsub)
    for (int j = 0; j < J; j++) {
      double v = X[(((size_t)(r0 + rr))*J + j)*Cc + o];
      s += v; s2 += v*v;
    }
  if (nsub == 2) {
    __shared__ double ls[256], ls2[256];
    ls[t] = s; ls2[t] = s2;
    __syncthreads();
    if (sub == 0) { s += ls[Cc + o]; s2 += ls2[Cc + o]; }
  }
  if (sub == 0) {
    part[((size_t)blockIdx.x*Cc + o)*2] = s;
    part[((size_t)blockIdx.x*Cc + o)*2 + 1] = s2;
  }
}

// ---------------- parallel stats final: 32-lane group per (instance, channel) ----------------
__global__ __launch_bounds__(256) void gm_final(const double* __restrict__ part, float* __restrict__ stats,
                                                int Cc, int NB, int nblk, int count) {
  int g = blockIdx.x * 8 + (threadIdx.x >> 5);
  int lane = threadIdx.x & 31;
  if (g >= NB*Cc) return;
  int b = g / Cc, o = g % Cc;
  double S = 0.0, S2 = 0.0;
  for (int u = lane; u < nblk; u += 32) {
    size_t blk = (size_t)(b*nblk + u);
    S  += part[(blk*Cc + o)*2];
    S2 += part[(blk*Cc + o)*2 + 1];
  }
  for (int off = 16; off >= 1; off >>= 1) {
    S  += __shfl_down(S, off, 32);
    S2 += __shfl_down(S2, off, 32);
  }
  if (lane == 0) {
    double mean = S / count;
    double var = S2 / count - mean*mean;
    if (var < 0.0) var = 0.0;
    stats[g*2] = (float)mean;
    stats[g*2 + 1] = (float)(1.0 / sqrt(var + 1e-5));
  }
}

// ---------------- angle-feature conv1 ----------------
__global__ void cos_conv(const float* __restrict__ cosv, const float* __restrict__ gw1,
                         const float* __restrict__ gb1, float* __restrict__ ANG, int total) {
  int i = blockIdx.x * 256 + threadIdx.x;
  if (i >= total) return;
  int o = i & 127, w = (i >> 7) % 3;
  int r = i / 384;
  float acc = gb1[o];
#pragma unroll
  for (int t = 0; t < 3; t++) acc += cosv[(size_t)r*9 + w*3 + t] * gw1[o*3 + t];
  ANG[i] = acc;
}

// ---------------- gather + max over k + f64 partials (4 rows/block, idx in LDS) ----------------
__global__ __launch_bounds__(256) void gather_max_partial(const float* __restrict__ G, const int* __restrict__ idx,
                                                          float* __restrict__ maxbuf, double* __restrict__ part,
                                                          int Cc) {
  int t = threadIdx.x;
  int o = t % Cc, sub = t / Cc, nsub = 256 / Cc;
  int r0 = blockIdx.x * 4;
  __shared__ int nbs[4][9];
  if (t < 36) nbs[t / 9][t % 9] = idx[(size_t)(r0 + t/9)*9 + (t % 9)];
  __syncthreads();
  double s = 0.0, s2 = 0.0;
  for (int rr = sub; rr < 4; rr += nsub) {
    int r = r0 + rr, rb = r & ~2047;
    float g = G[(size_t)r*2*Cc + o];
    float mx = -3.4e38f;
#pragma unroll
    for (int k = 0; k < 9; k++) {
      int m = nbs[rr][k];
      float v = g + G[(size_t)(rb + m)*2*Cc + Cc + o];
      mx = fmaxf(mx, v); s += (double)v; s2 += (double)v*(double)v;
    }
    maxbuf[(size_t)r*Cc + o] = mx;
  }
  if (nsub == 2) {
    __shared__ double ls[256], ls2[256];
    ls[t] = s; ls2[t] = s2;
    __syncthreads();
    if (sub == 0) { s += ls[Cc + o]; s2 += ls2[Cc + o]; }
  }
  if (sub == 0) {
    part[((size_t)blockIdx.x*Cc + o)*2] = s;
    part[((size_t)blockIdx.x*Cc + o)*2 + 1] = s2;
  }
}

// ---------------- final: SA = lrelu(inorm(X3O)) + lrelu(inorm(X3A)) ----------------
__global__ void norm_add2(const float* __restrict__ src, float* __restrict__ dst,
                          const float* __restrict__ stats,
                          const float* __restrict__ addend, const float* __restrict__ astats,
                          int total) {
  int i = blockIdx.x * 256 + threadIdx.x;
  if (i >= total) return;
  int o = i & 127;
  int b = i >> 18;
  float m = stats[(b*128 + o)*2], rs = stats[(b*128 + o)*2 + 1];
  float v = (src[i] - m) * rs;
  v = (v >= 0.f) ? v : 0.2f*v;
  float ma = astats[(b*128 + o)*2], rsa = astats[(b*128 + o)*2 + 1];
  float a = (addend[i] - ma) * rsa;
  a = (a >= 0.f) ? a : 0.2f*a;
  dst[i] = v + a;
}

// ---------------- flash attention (v3): 32 q-rows x 1024 keys, bank-balanced LDS ----------------
__global__ __launch_bounds__(256) void attn_part(const float* __restrict__ Qp, const float* __restrict__ Kp,
                                                 const float* __restrict__ Vp,
                                                 float* __restrict__ OP, float* __restrict__ ML) {
  __shared__ float Qt[32][33];
  __shared__ float Kt[32][68];
  __shared__ float Vs[64][36];
  __shared__ float Pt[64][33];
  int tid = threadIdx.x;
  int tx = tid & 15, ty = tid >> 4;
  int kp = blockIdx.y;
  int bh = blockIdx.z;
  int q0 = blockIdx.x * 32;
  const float* Qh = Qp + (size_t)bh * NPTS * 32;
  const float* Kh = Kp + (size_t)bh * NPTS * 32;
  const float* Vh = Vp + (size_t)bh * NPTS * 32;
  {
    int r = tid & 31, a4 = ((tid >> 5) & 7) * 4;
    float4 v = *(const float4*)(Qh + (size_t)(q0 + r)*32 + a4);
    Qt[a4+0][r] = v.x; Qt[a4+1][r] = v.y; Qt[a4+2][r] = v.z; Qt[a4+3][r] = v.w;
  }
  float m_[2] = {-FLT_MAX, -FLT_MAX};
  float l_[2] = {0.f, 0.f};
  float O_[2][2] = {};
  const float sc = 0.17677669529663687f;
  int ks = kp * 1024;
  for (int k0 = ks; k0 < ks + 1024; k0 += 64) {
    __syncthreads();
    {
      int r = tid & 31, a4 = ((tid >> 5) & 7) * 4;
      float4 ka = *(const float4*)(Kh + (size_t)(k0 + r)*32 + a4);
      float4 kb = *(const float4*)(Kh + (size_t)(k0 + 32 + r)*32 + a4);
      Kt[a4+0][r] = ka.x; Kt[a4+1][r] = ka.y; Kt[a4+2][r] = ka.z; Kt[a4+3][r] = ka.w;
      Kt[a4+0][32+r] = kb.x; Kt[a4+1][32+r] = kb.y; Kt[a4+2][32+r] = kb.z; Kt[a4+3][32+r] = kb.w;
      int rv = tid & 63, av = (tid >> 6) * 4;
      *(float4*)&Vs[rv][av]      = *(const float4*)(Vh + (size_t)(k0 + rv)*32 + av);
      *(float4*)&Vs[rv][av + 16] = *(const float4*)(Vh + (size_t)(k0 + rv)*32 + av + 16);
    }
    __syncthreads();
    float acc[2][4] = {};
#pragma unroll
    for (int k = 0; k < 32; k++) {
      float a0 = Qt[k][ty], a1 = Qt[k][ty + 16];
      float4 bv = *(const float4*)&Kt[k][tx*4];
      acc[0][0] = fmaf(a0, bv.x, acc[0][0]);
      acc[0][1] = fmaf(a0, bv.y, acc[0][1]);
      acc[0][2] = fmaf(a0, bv.z, acc[0][2]);
      acc[0][3] = fmaf(a0, bv.w, acc[0][3]);
      acc[1][0] = fmaf(a1, bv.x, acc[1][0]);
      acc[1][1] = fmaf(a1, bv.y, acc[1][1]);
      acc[1][2] = fmaf(a1, bv.z, acc[1][2]);
      acc[1][3] = fmaf(a1, bv.w, acc[1][3]);
    }
#pragma unroll
    for (int i = 0; i < 2; i++)
#pragma unroll
      for (int j = 0; j < 4; j++) acc[i][j] *= sc;
#pragma unroll
    for (int i = 0; i < 2; i++) {
      float tm = fmaxf(fmaxf(acc[i][0], acc[i][1]), fmaxf(acc[i][2], acc[i][3]));
      for (int s = 1; s < 16; s <<= 1) tm = fmaxf(tm, __shfl_xor(tm, s));
      float mn = fmaxf(m_[i], tm);
      float cf = __expf(m_[i] - mn);
      m_[i] = mn;
      l_[i] *= cf; O_[i][0] *= cf; O_[i][1] *= cf;
      float rs = 0.f;
#pragma unroll
      for (int j = 0; j < 4; j++) {
        float p = __expf(acc[i][j] - mn);
        rs += p;
        Pt[tx*4 + j][ty + 16*i] = p;
      }
      for (int s = 1; s < 16; s <<= 1) rs += __shfl_xor(rs, s);
      l_[i] += rs;
    }
#pragma unroll 8
    for (int kk = 0; kk < 64; kk++) {
      float p0 = Pt[kk][ty], p1 = Pt[kk][ty + 16];
      float2 vv = *(const float2*)&Vs[kk][tx*2];
      O_[0][0] = fmaf(p0, vv.x, O_[0][0]);
      O_[0][1] = fmaf(p0, vv.y, O_[0][1]);
      O_[1][0] = fmaf(p1, vv.x, O_[1][0]);
      O_[1][1] = fmaf(p1, vv.y, O_[1][1]);
    }
  }
  size_t pb = (size_t)(kp*8 + bh) * NPTS;
#pragma unroll
  for (int i = 0; i < 2; i++) {
    int n = q0 + ty + 16*i;
    *(float2*)&OP[(pb + n)*32 + tx*2] = make_float2(O_[i][0], O_[i][1]);
    if (tx == 0) { ML[(pb + n)*2] = m_[i]; ML[(pb + n)*2 + 1] = l_[i]; }
  }
}

// ---------------- merge the two K-halves ----------------
__global__ void attn_merge(const float* __restrict__ OP, const float* __restrict__ ML,
                           float* __restrict__ out) {
  int i = blockIdx.x * 256 + threadIdx.x;   // 8*2048*16
  if (i >= 8*2048*16) return;
  int dp = (i & 15) * 2;
  int n  = (i >> 4) & 2047;
  int bh = i >> 15;
  size_t p0 = (size_t)bh * NPTS + n;
  size_t p1 = (size_t)(8 + bh) * NPTS + n;
  float m0 = ML[p0*2], l0 = ML[p0*2 + 1];
  float m1 = ML[p1*2], l1 = ML[p1*2 + 1];
  float m = fmaxf(m0, m1);
  float w0 = __expf(m0 - m), w1 = __expf(m1 - m);
  float inv = 1.f / (w0*l0 + w1*l1);
  float2 o0 = *(const float2*)&OP[p0*32 + dp];
  float2 o1 = *(const float2*)&OP[p1*32 + dp];
  int b = bh >> 2, h = bh & 3;
  out[((size_t)(b*NPTS + n))*128 + (dp+0)*4 + h] = (w0*o0.x + w1*o1.x) * inv;
  out[((size_t)(b*NPTS + n))*128 + (dp+1)*4 + h] = (w0*o0.y + w1*o1.y) * inv;
}

// ================= host =================
extern "C" void kernel_launch(void* const* d_in, const int* in_sizes, int n_in,
                              void* d_out, int out_size, void* d_ws, size_t ws_size,
                              hipStream_t stream) {
  (void)in_sizes; (void)n_in; (void)out_size; (void)ws_size;
  const float* desc0  = (const float*)d_in[0];
  const float* desc1  = (const float*)d_in[1];
  const float* coords0= (const float*)d_in[2];
  const float* coords1= (const float*)d_in[3];
  const float* conv1w = (const float*)d_in[4];
  const float* conv2w = (const float*)d_in[5];
  const float* conv3w = (const float*)d_in[6];
  const float* conv3ow= (const float*)d_in[7];
  const float* a1w1 = (const float*)d_in[8];
  const float* a1b1 = (const float*)d_in[9];
  const float* a1w2 = (const float*)d_in[10];
  const float* a1b2 = (const float*)d_in[11];
  const float* a2w1 = (const float*)d_in[12];
  const float* a2b1 = (const float*)d_in[13];
  const float* a2w2 = (const float*)d_in[14];
  const float* a2b2 = (const float*)d_in[15];
  const float* gw1  = (const float*)d_in[16];
  const float* gb1  = (const float*)d_in[17];
  const float* gw2  = (const float*)d_in[18];
  const float* gb2  = (const float*)d_in[19];
  const float* wq = (const float*)d_in[20]; const float* bq = (const float*)d_in[21];
  const float* wk = (const float*)d_in[22]; const float* bk = (const float*)d_in[23];
  const float* wv = (const float*)d_in[24]; const float* bv = (const float*)d_in[25];
  const float* wm = (const float*)d_in[26]; const float* bm = (const float*)d_in[27];
  const float* mw1 = (const float*)d_in[28]; const float* mb1 = (const float*)d_in[29];
  const float* mw2 = (const float*)d_in[30]; const float* mb2 = (const float*)d_in[31];

  float* ws = (float*)d_ws;
  size_t off = 0;
  auto alloc = [&](size_t nel) { size_t r = off; off += (nel + 63) & ~(size_t)63; return r; };
  float* DW_A1 = ws + alloc(512*128);
  float* W_A1R = ws + alloc(128*384);
  float* DW_A2 = ws + alloc(512*128);
  float* W_A2R = ws + alloc(128*384);
  float* W_G2R = ws + alloc(128*384);
  float* DW_C1 = ws + alloc(256*128);
  float* DW_C2 = ws + alloc(512*128);
  float* W_KV  = ws + alloc(256*128);
  float* B_KV  = ws + alloc(256);
  float* SA   = ws + alloc((size_t)R2*128);
  float* XF0  = ws + alloc((size_t)4096*128);
  float* XF1  = ws + alloc((size_t)4096*128);
  int*   IDX  = (int*)(ws + alloc((size_t)R2*9));
  float* COSV = ws + alloc((size_t)R2*9);
  float* FT   = ws + alloc((size_t)R2*128);
  float* BIG  = ws + alloc((size_t)R2*512);
  float* ABUF = ws + alloc((size_t)R2*384);
  float* X1B  = ws + alloc((size_t)R2*128);
  float* FANG = ws + alloc((size_t)R2*128);
  float* X2B  = ws + alloc((size_t)R2*128);
  float* X3A  = ws + alloc((size_t)R2*128);
  float* X1O  = ws + alloc((size_t)R2*128);
  float* AB2  = ws + alloc((size_t)R2*256);
  float* X3O  = ws + alloc((size_t)R2*128);
  double* PART = (double*)(ws + alloc((size_t)2048*256*2*2));   // 1M doubles (8 MB)
  float* STATS = ws + alloc(8*2048);
  float* ST_T   = STATS;
  float* ST_X1B = STATS + 2048;
  float* ST_FANG= STATS + 4096;
  float* ST_X2B = STATS + 6144;
  float* ST_X3A = STATS + 8192;
  float* ST_X1O = STATS + 10240;
  float* ST_AB  = STATS + 12288;
  float* ST_X3O = STATS + 14336;
  float* OP  = BIG;                 // attn partials (prop phase; BIG free then)
  float* ML  = BIG + (size_t)2*8*NPTS*32;

  auto g64 = [&](const float* p0,int w0,const float* st0,int a0,int x0,
                 const float* p1,int w1,const float* st1,int a1,int x1,
                 const float* p2,int w2,const float* st2,int a2,int x2,
                 const float* addp,const float* addst,
                 const float* W,const float* bias,const float* resid,
                 float* Y,int R,int Cin,int O,int pack,float* Y2) {
    gemm_t<64><<<dim3(R/64, O/64), 256, 0, stream>>>(p0,w0,st0,a0,x0, p1,w1,st1,a1,x1,
        p2,w2,st2,a2,x2, addp,addst, W,bias,resid, Y,Cin,O,pack,Y2);
  };
  auto g32 = [&](const float* p0,int w0,const float* st0,int a0,int x0,
                 const float* p1,int w1,const float* st1,int a1,int x1,
                 const float* p2,int w2,const float* st2,int a2,int x2,
                 const float* addp,const float* addst,
                 const float* W,const float* bias,const float* resid,
                 float* Y,int R,int Cin,int O,int pack,float* Y2) {
    gemm_t<32><<<dim3(R/32, O/64), 256, 0, stream>>>(p0,w0,st0,a0,x0, p1,w1,st1,a1,x1,
        p2,w2,st2,a2,x2, addp,addst, W,bias,resid, Y,Cin,O,pack,Y2);
  };
  auto statsP = [&](const float* buf, int R, int J, int Cc, int count, float* stat) {
    stats_partial<<<R/16, 256, 0, stream>>>(buf, PART, J, Cc);
    gm_final<<<((R/2048)*Cc + 7)/8, 256, 0, stream>>>(PART, stat, Cc, R/2048, 128, count);
  };
  auto gathermax = [&](const float* G, float* mx, int Cc, float* stat) {
    gather_max_partial<<<R2/4, 256, 0, stream>>>(G, IDX, mx, PART, Cc);
    gm_final<<<(4*Cc + 7)/8, 256, 0, stream>>>(PART, stat, Cc, 4, 512, 2048*9);
  };

  prep_weights<<<256, 256, 0, stream>>>(conv1w, conv2w, a1w1, a1w2, a2w1, a2w2, gw2,
                                        wk, bk, wv, bv,
                                        DW_A1, W_A1R, DW_A2, W_A2R, W_G2R, DW_C1, DW_C2,
                                        W_KV, B_KV);

  // ===== merged branch section (both descs, R2 = 8192 rows, 4 instances) =====
  transpose2<<<dim3(2048/32, 128/32, 4), dim3(32, 8), 0, stream>>>(desc0, desc1, FT, 128, 2048);
  knn2_kernel<<<2048, 256, 0, stream>>>(coords0, coords1, IDX, COSV);
  // annu1
  g64(FT,128,nullptr,0,0, nullptr,0,nullptr,0,0, nullptr,0,nullptr,0,0, nullptr,nullptr,
      DW_A1, nullptr, nullptr, BIG, R2, 128, 512, 0, nullptr);
  combine_annu<<<R2, 384, 0, stream>>>(BIG, IDX, a1b1, ABUF);
  statsP(ABUF, R2, 3, 128, 2048*3, ST_T);
  g32(ABUF,384,ST_T,1,128, nullptr,0,nullptr,0,0, nullptr,0,nullptr,0,0, nullptr,nullptr,
      W_A1R, a1b2, nullptr, X1B, R2, 384, 128, 0, nullptr);
  statsP(X1B, R2, 1, 128, 2048, ST_X1B);
  // f_ang (idx1 == idx2)
  cos_conv<<<(R2*384 + 255)/256, 256, 0, stream>>>(COSV, gw1, gb1, ABUF, R2*384);
  statsP(ABUF, R2, 3, 128, 2048*3, ST_T);
  g32(ABUF,384,ST_T,1,128, nullptr,0,nullptr,0,0, nullptr,0,nullptr,0,0, nullptr,nullptr,
      W_G2R, gb2, nullptr, FANG, R2, 384, 128, 0, nullptr);
  statsP(FANG, R2, 1, 128, 2048, ST_FANG);
  // annu2 (X1B raw, normed in staging)
  g64(X1B,128,ST_X1B,1,128, nullptr,0,nullptr,0,0, nullptr,0,nullptr,0,0, nullptr,nullptr,
      DW_A2, nullptr, nullptr, BIG, R2, 128, 512, 0, nullptr);
  combine_annu<<<R2, 384, 0, stream>>>(BIG, IDX, a2b1, ABUF);
  statsP(ABUF, R2, 3, 128, 2048*3, ST_T);
  g32(ABUF,384,ST_T,1,128, nullptr,0,nullptr,0,0, nullptr,0,nullptr,0,0, nullptr,nullptr,
      W_A2R, a2b2, nullptr, X2B, R2, 384, 128, 0, nullptr);
  statsP(X2B, R2, 1, 128, 2048, ST_X2B);
  // x3 = conv3 @ [x0 | n(x1)+n(fang) | n(x2)+n(fang)]
  g32(FT,128,nullptr,0,0, X1B,128,ST_X1B,1,128, X2B,128,ST_X2B,1,128, FANG,ST_FANG,
      conv3w, nullptr, nullptr, X3A, R2, 384, 128, 0, nullptr);
  statsP(X3A, R2, 1, 128, 2048, ST_X3A);
  // x1o
  g64(FT,128,nullptr,0,0, nullptr,0,nullptr,0,0, nullptr,0,nullptr,0,0, nullptr,nullptr,
      DW_C1, nullptr, nullptr, BIG, R2, 128, 256, 0, nullptr);
  gathermax(BIG, X1O, 128, ST_X1O);
  // x2o (X1O = raw max, normed lrelu in staging)
  g64(X1O,128,ST_X1O,2,128, nullptr,0,nullptr,0,0, nullptr,0,nullptr,0,0, nullptr,nullptr,
      DW_C2, nullptr, nullptr, BIG, R2, 128, 512, 0, nullptr);
  gathermax(BIG, AB2, 256, ST_AB);
  // x3o = conv3o @ [x0 | n(x1o) | n(x2o)]
  g32(FT,128,nullptr,0,0, X1O,128,ST_X1O,2,128, AB2,256,ST_AB,2,256, nullptr,nullptr,
      conv3ow, nullptr, nullptr, X3O, R2, 512, 128, 0, nullptr);
  statsP(X3O, R2, 1, 128, 2048, ST_X3O);
  norm_add2<<<(R2*128 + 255)/256, 256, 0, stream>>>(X3O, SA, ST_X3O, X3A, ST_X3A, R2*128);

  // ===== cross-attention props (rows 4096 each) =====
  float* SA0 = SA;
  float* SA1 = SA + (size_t)4096*128;
  auto prop = [&](const float* xin, const float* src, float* dst) {
    g32(xin,128,nullptr,0,0, nullptr,0,nullptr,0,0, nullptr,0,nullptr,0,0, nullptr,nullptr,
        wq, bq, nullptr, X1B, 4096, 128, 128, 1, nullptr);                  // packed Q
    g32(src,128,nullptr,0,0, nullptr,0,nullptr,0,0, nullptr,0,nullptr,0,0, nullptr,nullptr,
        W_KV, B_KV, nullptr, X2B, 4096, 128, 256, 2, X3A);                  // packed K + V
    attn_part<<<dim3(64, 2, 8), 256, 0, stream>>>(X1B, X2B, X3A, OP, ML);
    attn_merge<<<(8*2048*16 + 255)/256, 256, 0, stream>>>(OP, ML, FANG);
    g32(FANG,128,nullptr,0,0, nullptr,0,nullptr,0,0, nullptr,0,nullptr,0,0, nullptr,nullptr,
        wm, bm, nullptr, X1O, 4096, 128, 128, 0, nullptr);
    g32(xin,128,nullptr,0,0, X1O,128,nullptr,0,0, nullptr,0,nullptr,0,0, nullptr,nullptr,
        mw1, mb1, nullptr, ABUF, 4096, 256, 256, 0, nullptr);
    statsP(ABUF, 4096, 1, 256, 2048, ST_T);
    g32(ABUF,256,ST_T,1,256, nullptr,0,nullptr,0,0, nullptr,0,nullptr,0,0, nullptr,nullptr,
        mw2, mb2, xin, dst, 4096, 256, 128, 0, nullptr);
  };

  prop(SA0, SA1, XF0);
  prop(SA1, XF0, XF1);

  transpose_k<<<dim3(128/32, 2048/32, 2), dim3(32, 8), 0, stream>>>(XF0, (float*)d_out, 2048, 128);
  transpose_k<<<dim3(128/32, 2048/32, 2), dim3(32, 8), 0, stream>>>(XF1, (float*)d_out + (size_t)4096*128, 2048, 128);
}

// Round 11
// 802.964 us; speedup vs baseline: 5.6330x; 1.0936x over previous
//
#include <hip/hip_runtime.h>
#include <cfloat>
#include <math.h>

#define NPTS 2048
#define R2   8192   // merged: 2 tensors x B=2 x N=2048

// ---------------- prep: derived weight matrices ----------------
__global__ __launch_bounds__(256) void prep_weights(
    const float* __restrict__ conv1, const float* __restrict__ conv2,
    const float* __restrict__ a1w1, const float* __restrict__ a1w2,
    const float* __restrict__ a2w1, const float* __restrict__ a2w2,
    const float* __restrict__ gw2,
    const float* __restrict__ wk, const float* __restrict__ bk,
    const float* __restrict__ wv, const float* __restrict__ bv,
    float* __restrict__ dwA1, float* __restrict__ a1w2r,
    float* __restrict__ dwA2, float* __restrict__ a2w2r,
    float* __restrict__ gw2r, float* __restrict__ dwC1, float* __restrict__ dwC2,
    float* __restrict__ wkv, float* __restrict__ bkv)
{
  int i = blockIdx.x * 256 + threadIdx.x;
  if (i < 512*128) {
    int row = i >> 7, c = i & 127;
    float v1, v2;
    if (row < 128) {             // ctrW[o][c] = sum_t (w1[o,c,t] - w1[o,128+c,t])
      float s1 = 0.f, s2 = 0.f;
      for (int t = 0; t < 3; t++) {
        s1 += a1w1[(row*256 + c)*3 + t] - a1w1[(row*256 + 128 + c)*3 + t];
        s2 += a2w1[(row*256 + c)*3 + t] - a2w1[(row*256 + 128 + c)*3 + t];
      }
      v1 = s1; v2 = s2;
    } else {                     // row = 128 + t*128 + o : nbW_t[o][c] = w1[o,128+c,t]
      int t = (row - 128) >> 7, o = row & 127;
      v1 = a1w1[(o*256 + 128 + c)*3 + t];
      v2 = a2w1[(o*256 + 128 + c)*3 + t];
    }
    dwA1[i] = v1; dwA2[i] = v2;
    dwC2[i] = (row < 256) ? (conv2[row*256 + c] - conv2[row*256 + 128 + c])
                          : conv2[(row-256)*256 + 128 + c];
  }
  if (i < 128*384) {             // w2r[o][w*128+c] = w2[o,c,w]
    int o = i / 384, rem = i % 384, w = rem >> 7, c = rem & 127;
    a1w2r[i] = a1w2[(o*128 + c)*3 + w];
    a2w2r[i] = a2w2[(o*128 + c)*3 + w];
    gw2r[i]  = gw2[(o*128 + c)*3 + w];
  }
  if (i < 256*128) {             // dwC1 [256][128] from conv1 [128][256]
    int row = i >> 7, c = i & 127;
    dwC1[i] = (row < 128) ? (conv1[row*256 + c] - conv1[row*256 + 128 + c])
                          : conv1[(row-128)*256 + 128 + c];
    wkv[i] = (row < 128) ? wk[row*128 + c] : wv[(row-128)*128 + c];
  }
  if (i < 256) bkv[i] = (i < 128) ? bk[i] : bv[i - 128];
}

// ---------------- transpose both descs: in [2][I][J] x2 -> out [4][J][I] ----------------
__global__ void transpose2(const float* __restrict__ in0, const float* __restrict__ in1,
                           float* __restrict__ out, int I, int J) {
  __shared__ float tile[32][33];
  int zb = blockIdx.z;
  const float* src = (zb < 2) ? (in0 + (size_t)zb*I*J) : (in1 + (size_t)(zb-2)*I*J);
  float* dst = out + (size_t)zb*J*I;
  int i0 = blockIdx.y * 32, j0 = blockIdx.x * 32;
  int tx = threadIdx.x, ty = threadIdx.y;
  for (int s = 0; s < 32; s += 8)
    tile[ty + s][tx] = src[(size_t)(i0 + ty + s)*J + (j0 + tx)];
  __syncthreads();
  for (int s = 0; s < 32; s += 8)
    dst[(size_t)(j0 + ty + s)*I + (i0 + tx)] = tile[tx][ty + s];
}

// ---------------- transpose [b][I][J] -> [b][J][I] (final output) ----------------
__global__ void transpose_k(const float* __restrict__ in, float* __restrict__ out, int I, int J) {
  __shared__ float tile[32][33];
  int b = blockIdx.z;
  int i0 = blockIdx.y * 32, j0 = blockIdx.x * 32;
  int tx = threadIdx.x, ty = threadIdx.y;
  for (int s = 0; s < 32; s += 8)
    tile[ty + s][tx] = in[((size_t)b*I + (i0 + ty + s))*J + (j0 + tx)];
  __syncthreads();
  for (int s = 0; s < 32; s += 8)
    out[((size_t)b*J + (j0 + ty + s))*I + (i0 + tx)] = tile[tx][ty + s];
}

// ---------------- KNN (both coord sets): f32 np-exact distances, (dist,idx)-lex ----------------
__global__ __launch_bounds__(256) void knn2_kernel(const float* __restrict__ P0, const float* __restrict__ P1,
                                                   int* __restrict__ idx, float* __restrict__ cosv) {
  __shared__ float px[NPTS], py[NPTS], sq[NPTS];
  int tid = threadIdx.x;
  int gw = blockIdx.x * 4 + (tid >> 6);   // 0..8191 : global point id
  int b4 = gw >> 11, n = gw & 2047;
  int lane = tid & 63;
  const float* Pb = (b4 < 2) ? (P0 + (size_t)b4 * 2 * NPTS) : (P1 + (size_t)(b4 - 2) * 2 * NPTS);
  for (int i = tid; i < NPTS; i += 256) {
    float x = Pb[i], y = Pb[NPTS + i];
    px[i] = x; py[i] = y;
    sq[i] = __fadd_rn(__fmul_rn(x, x), __fmul_rn(y, y));
  }
  __syncthreads();
  float xn = px[n], yn = py[n], sqn = sq[n];
  float d[10]; int id_[10];
#pragma unroll
  for (int j = 0; j < 10; j++) { d[j] = FLT_MAX; id_[j] = 0x7fffffff; }
  for (int m = lane; m < NPTS; m += 64) {
    float dot  = __fadd_rn(__fmul_rn(xn, px[m]), __fmul_rn(yn, py[m]));
    float dist = __fsub_rn(__fadd_rn(sqn, sq[m]), __fmul_rn(2.0f, dot));
    dist = fmaxf(dist, 1e-12f);
    if (dist < d[9] || (dist == d[9] && m < id_[9])) {
      int p = 0;
#pragma unroll
      for (int j = 0; j < 10; j++) p += (d[j] < dist || (d[j] == dist && id_[j] < m)) ? 1 : 0;
#pragma unroll
      for (int j = 9; j >= 1; j--) if (j > p) { d[j] = d[j-1]; id_[j] = id_[j-1]; }
#pragma unroll
      for (int j = 0; j < 10; j++) if (j == p) { d[j] = dist; id_[j] = m; }
    }
  }
  int ptr = 0;
  for (int r = 0; r < 10; r++) {
    float bd = FLT_MAX; int bi = 0x7fffffff;
#pragma unroll
    for (int j = 0; j < 10; j++) if (j == ptr) { bd = d[j]; bi = id_[j]; }
    for (int off = 32; off >= 1; off >>= 1) {
      float od = __shfl_xor(bd, off);
      int   oi = __shfl_xor(bi, off);
      if (od < bd || (od == bd && oi < bi)) { bd = od; bi = oi; }
    }
    bool adv = false;
#pragma unroll
    for (int j = 0; j < 10; j++) if (j == ptr) adv = (d[j] == bd && id_[j] == bi);
    if (adv) ptr++;
    if (r > 0 && lane == 0) {
      size_t base = (size_t)gw*9 + (r - 1);
      idx[base] = bi;
      float dot = __fadd_rn(__fmul_rn(xn, px[bi]), __fmul_rn(yn, py[bi]));
      cosv[base] = __fdiv_rn(dot, __fmul_rn(__fsqrt_rn(sqn), __fsqrt_rn(sq[bi])));
    }
  }
}

// ---------------- unified f32 GEMM: template BM, per-segment norm-act, fused output stats --------
template<int BM>
__global__ __launch_bounds__(256) void gemm_t(
    const float* __restrict__ p0, int w0, const float* __restrict__ st0, int a0, int xm0,
    const float* __restrict__ p1, int w1, const float* __restrict__ st1, int a1, int xm1,
    const float* __restrict__ p2, int w2, const float* __restrict__ st2, int a2, int xm2,
    const float* __restrict__ addp, const float* __restrict__ addst,
    const float* __restrict__ W, const float* __restrict__ bias,
    const float* __restrict__ resid,
    float* __restrict__ Y, int Cin, int O, int pack, float* __restrict__ Y2,
    float* __restrict__ part)
{
  __shared__ float Xt[32][BM + 4];   // [k][row]
  __shared__ float Wt[32][68];       // [k][col]
  constexpr int RPT = BM / 16;
  constexpr int XF  = BM / 8;
  int tid = threadIdx.x;
  int r0 = blockIdx.x * BM, c0 = blockIdx.y * 64;
  int tx = tid & 15, ty = tid >> 4;
  int sxr = tid & (BM - 1), sxc = (tid / BM) * XF;
  int swr = tid & 63, swc = (tid >> 6) * 8;
  float acc[RPT][4] = {};
  for (int k0 = 0; k0 < Cin; k0 += 32) {
    {
      int r = r0 + sxr;
      int ac = k0 + sxc;
      const float* P; const float* st; int cc, lw, act, xm;
      if (ac < w0)            { P = p0; cc = ac;          lw = w0; st = st0; act = a0; xm = xm0; }
      else if (ac < w0 + w1)  { P = p1; cc = ac - w0;     lw = w1; st = st1; act = a1; xm = xm1; }
      else                    { P = p2; cc = ac - w0 - w1; lw = w2; st = st2; act = a2; xm = xm2; }
      float vv[XF];
#pragma unroll
      for (int q = 0; q < XF; q += 4)
        *(float4*)&vv[q] = *(const float4*)(P + (size_t)r*lw + cc + q);
      int b = r >> 11;
      if (st) {
#pragma unroll
        for (int j = 0; j < XF; j++) {
          int o = (cc + j) & (xm - 1);
          float m = st[(b*xm + o)*2], rs = st[(b*xm + o)*2 + 1];
          float v = (vv[j] - m) * rs;
          vv[j] = (act == 1) ? fmaxf(v, 0.f) : ((v >= 0.f) ? v : 0.2f*v);
        }
      }
      if (addp && ac >= 128) {
        int fc = (ac - 128) & 127;
        float av[XF];
#pragma unroll
        for (int q = 0; q < XF; q += 4)
          *(float4*)&av[q] = *(const float4*)(addp + (size_t)r*128 + fc + q);
        if (addst) {
#pragma unroll
          for (int j = 0; j < XF; j++) {
            int o = (fc + j) & 127;
            float m = addst[(b*128 + o)*2], rs = addst[(b*128 + o)*2 + 1];
            av[j] = fmaxf((av[j] - m) * rs, 0.f);
          }
        }
#pragma unroll
        for (int j = 0; j < XF; j++) vv[j] += av[j];
      }
#pragma unroll
      for (int j = 0; j < XF; j++) Xt[sxc + j][sxr] = vv[j];
    }
    {
      const float* s = W + (size_t)(c0 + swr)*Cin + k0 + swc;
      float4 v0 = *(const float4*)s, v1 = *(const float4*)(s + 4);
      Wt[swc+0][swr]=v0.x; Wt[swc+1][swr]=v0.y; Wt[swc+2][swr]=v0.z; Wt[swc+3][swr]=v0.w;
      Wt[swc+4][swr]=v1.x; Wt[swc+5][swr]=v1.y; Wt[swc+6][swr]=v1.z; Wt[swc+7][swr]=v1.w;
    }
    __syncthreads();
#pragma unroll
    for (int kk = 0; kk < 32; kk++) {
      float4 bv = *(const float4*)&Wt[kk][tx*4];
      if (BM == 64) {
        float4 av = *(const float4*)&Xt[kk][ty*4];
        acc[0][0] = fmaf(av.x, bv.x, acc[0][0]); acc[0][1] = fmaf(av.x, bv.y, acc[0][1]);
        acc[0][2] = fmaf(av.x, bv.z, acc[0][2]); acc[0][3] = fmaf(av.x, bv.w, acc[0][3]);
        acc[1][0] = fmaf(av.y, bv.x, acc[1][0]); acc[1][1] = fmaf(av.y, bv.y, acc[1][1]);
        acc[1][2] = fmaf(av.y, bv.z, acc[1][2]); acc[1][3] = fmaf(av.y, bv.w, acc[1][3]);
        acc[RPT-2][0] = fmaf(av.z, bv.x, acc[RPT-2][0]); acc[RPT-2][1] = fmaf(av.z, bv.y, acc[RPT-2][1]);
        acc[RPT-2][2] = fmaf(av.z, bv.z, acc[RPT-2][2]); acc[RPT-2][3] = fmaf(av.z, bv.w, acc[RPT-2][3]);
        acc[RPT-1][0] = fmaf(av.w, bv.x, acc[RPT-1][0]); acc[RPT-1][1] = fmaf(av.w, bv.y, acc[RPT-1][1]);
        acc[RPT-1][2] = fmaf(av.w, bv.z, acc[RPT-1][2]); acc[RPT-1][3] = fmaf(av.w, bv.w, acc[RPT-1][3]);
      } else {
        float2 av = *(const float2*)&Xt[kk][ty*2];
        acc[0][0] = fmaf(av.x, bv.x, acc[0][0]); acc[0][1] = fmaf(av.x, bv.y, acc[0][1]);
        acc[0][2] = fmaf(av.x, bv.z, acc[0][2]); acc[0][3] = fmaf(av.x, bv.w, acc[0][3]);
        acc[RPT-1][0] = fmaf(av.y, bv.x, acc[RPT-1][0]); acc[RPT-1][1] = fmaf(av.y, bv.y, acc[RPT-1][1]);
        acc[RPT-1][2] = fmaf(av.y, bv.z, acc[RPT-1][2]); acc[RPT-1][3] = fmaf(av.y, bv.w, acc[RPT-1][3]);
      }
    }
    __syncthreads();
  }
  float ps[4] = {}, ps2[4] = {};
#pragma unroll
  for (int i = 0; i < RPT; i++) {
    int r = r0 + ty*RPT + i;
#pragma unroll
    for (int j = 0; j < 4; j++) {
      int c = c0 + tx*4 + j;
      float v = acc[i][j] + (bias ? bias[c] : 0.f);
      if (resid) v += resid[(size_t)r*O + c];
      if (pack) {
        int cc2 = c & 127;
        int h = cc2 & 3, dd = cc2 >> 2, b = r >> 11, n = r & 2047;
        float* T = (pack == 1 || c < 128) ? Y : Y2;
        T[(((size_t)(b*4 + h))*NPTS + n)*32 + dd] = v;
      } else {
        Y[(size_t)r*O + c] = v;
      }
      ps[j] += v; ps2[j] = fmaf(v, v, ps2[j]);
    }
  }
  if (part) {
    // block-level per-column reduction (reuse Wt; all threads past final barrier)
#pragma unroll
    for (int j = 0; j < 4; j++) { Wt[ty][tx*4 + j] = ps[j]; Wt[16 + ty][tx*4 + j] = ps2[j]; }
    __syncthreads();
    if (tid < 64) {
      float S = 0.f, S2 = 0.f;
      for (int u = 0; u < 16; u++) { S += Wt[u][tid]; S2 += Wt[16 + u][tid]; }
      part[((size_t)blockIdx.x*O + c0 + tid)*2]     = S;
      part[((size_t)blockIdx.x*O + c0 + tid)*2 + 1] = S2;
    }
  }
}

// ---------------- annu conv1 combine: 4 rows/block + fused f64 stats partials ----------------
__global__ __launch_bounds__(256) void combine_annu(const float* __restrict__ GA, const int* __restrict__ idx,
                                                    const float* __restrict__ b1, float* __restrict__ A,
                                                    double* __restrict__ part) {
  int t = threadIdx.x;
  int o = t & 127, sub = t >> 7;
  int r0 = blockIdx.x * 4;
  __shared__ int nbs[4][9];
  if (t < 36) nbs[t / 9][t % 9] = idx[(size_t)(r0 + t/9)*9 + (t % 9)];
  __syncthreads();
  float bo = b1[o];
  double s = 0.0, s2 = 0.0;
  for (int rr = sub; rr < 4; rr += 2) {
    int r = r0 + rr, rb = r & ~2047;
    float ctr = GA[(size_t)r*512 + o] + bo;
#pragma unroll
    for (int w = 0; w < 3; w++) {
      float acc = ctr;
#pragma unroll
      for (int t3 = 0; t3 < 3; t3++) {
        int m = nbs[rr][w*3 + t3];
        acc += GA[(size_t)(rb + m)*512 + 128 + t3*128 + o];
      }
      A[(size_t)r*384 + w*128 + o] = acc;
      s += (double)acc; s2 += (double)acc * (double)acc;
    }
  }
  __shared__ double ls[256], ls2[256];
  ls[t] = s; ls2[t] = s2;
  __syncthreads();
  if (sub == 0) {
    s += ls[128 + o]; s2 += ls2[128 + o];
    part[((size_t)blockIdx.x*128 + o)*2] = s;
    part[((size_t)blockIdx.x*128 + o)*2 + 1] = s2;
  }
}

// ---------------- angle-feature conv1: 16 rows/block + fused f64 stats ----------------
__global__ __launch_bounds__(256) void cos_conv(const float* __restrict__ cosv, const float* __restrict__ gw1,
                                                const float* __restrict__ gb1, float* __restrict__ ANG,
                                                double* __restrict__ part) {
  int t = threadIdx.x;
  int o = t & 127, sub = t >> 7;
  int r0 = blockIdx.x * 16;
  float g0 = gw1[o*3], g1 = gw1[o*3+1], g2 = gw1[o*3+2], gb = gb1[o];
  __shared__ float cs[16][12];
  for (int i = t; i < 16*9; i += 256) cs[i / 9][i % 9] = cosv[(size_t)(r0 + i/9)*9 + (i % 9)];
  __syncthreads();
  double s = 0.0, s2 = 0.0;
  for (int rr = sub; rr < 16; rr += 2) {
    int r = r0 + rr;
#pragma unroll
    for (int w = 0; w < 3; w++) {
      float acc = gb;
      acc += cs[rr][w*3+0]*g0;
      acc += cs[rr][w*3+1]*g1;
      acc += cs[rr][w*3+2]*g2;
      ANG[(size_t)r*384 + w*128 + o] = acc;
      s += (double)acc; s2 += (double)acc * (double)acc;
    }
  }
  __shared__ double ls[256], ls2[256];
  ls[t] = s; ls2[t] = s2;
  __syncthreads();
  if (sub == 0) {
    s += ls[128 + o]; s2 += ls2[128 + o];
    part[((size_t)blockIdx.x*128 + o)*2] = s;
    part[((size_t)blockIdx.x*128 + o)*2 + 1] = s2;
  }
}

// ---------------- parallel stats final (f64 partials) ----------------
__global__ __launch_bounds__(256) void gm_final(const double* __restrict__ part, float* __restrict__ stats,
                                                int Cc, int NB, int nblk, int count) {
  int g = blockIdx.x * 8 + (threadIdx.x >> 5);
  int lane = threadIdx.x & 31;
  if (g >= NB*Cc) return;
  int b = g / Cc, o = g % Cc;
  double S = 0.0, S2 = 0.0;
  for (int u = lane; u < nblk; u += 32) {
    size_t blk = (size_t)(b*nblk + u);
    S  += part[(blk*Cc + o)*2];
    S2 += part[(blk*Cc + o)*2 + 1];
  }
  for (int off = 16; off >= 1; off >>= 1) {
    S  += __shfl_down(S, off, 32);
    S2 += __shfl_down(S2, off, 32);
  }
  if (lane == 0) {
    double mean = S / count;
    double var = S2 / count - mean*mean;
    if (var < 0.0) var = 0.0;
    stats[g*2] = (float)mean;
    stats[g*2 + 1] = (float)(1.0 / sqrt(var + 1e-5));
  }
}

// ---------------- parallel stats final (f32 partials, f64 accumulate) ----------------
__global__ __launch_bounds__(256) void gm_final_f(const float* __restrict__ part, float* __restrict__ stats,
                                                  int Cc, int NB, int nblk, int count) {
  int g = blockIdx.x * 8 + (threadIdx.x >> 5);
  int lane = threadIdx.x & 31;
  if (g >= NB*Cc) return;
  int b = g / Cc, o = g % Cc;
  double S = 0.0, S2 = 0.0;
  for (int u = lane; u < nblk; u += 32) {
    size_t blk = (size_t)(b*nblk + u);
    S  += (double)part[(blk*Cc + o)*2];
    S2 += (double)part[(blk*Cc + o)*2 + 1];
  }
  for (int off = 16; off >= 1; off >>= 1) {
    S  += __shfl_down(S, off, 32);
    S2 += __shfl_down(S2, off, 32);
  }
  if (lane == 0) {
    double mean = S / count;
    double var = S2 / count - mean*mean;
    if (var < 0.0) var = 0.0;
    stats[g*2] = (float)mean;
    stats[g*2 + 1] = (float)(1.0 / sqrt(var + 1e-5));
  }
}

// ---------------- gather + max over k + f64 partials (4 rows/block, idx in LDS) ----------------
__global__ __launch_bounds__(256) void gather_max_partial(const float* __restrict__ G, const int* __restrict__ idx,
                                                          float* __restrict__ maxbuf, double* __restrict__ part,
                                                          int Cc) {
  int t = threadIdx.x;
  int o = t % Cc, sub = t / Cc, nsub = 256 / Cc;
  int r0 = blockIdx.x * 4;
  __shared__ int nbs[4][9];
  if (t < 36) nbs[t / 9][t % 9] = idx[(size_t)(r0 + t/9)*9 + (t % 9)];
  __syncthreads();
  double s = 0.0, s2 = 0.0;
  for (int rr = sub; rr < 4; rr += nsub) {
    int r = r0 + rr, rb = r & ~2047;
    float g = G[(size_t)r*2*Cc + o];
    float mx = -3.4e38f;
#pragma unroll
    for (int k = 0; k < 9; k++) {
      int m = nbs[rr][k];
      float v = g + G[(size_t)(rb + m)*2*Cc + Cc + o];
      mx = fmaxf(mx, v); s += (double)v; s2 += (double)v*(double)v;
    }
    maxbuf[(size_t)r*Cc + o] = mx;
  }
  if (nsub == 2) {
    __shared__ double ls[256], ls2[256];
    ls[t] = s; ls2[t] = s2;
    __syncthreads();
    if (sub == 0) { s += ls[Cc + o]; s2 += ls2[Cc + o]; }
  }
  if (sub == 0) {
    part[((size_t)blockIdx.x*Cc + o)*2] = s;
    part[((size_t)blockIdx.x*Cc + o)*2 + 1] = s2;
  }
}

// ---------------- final: SA = lrelu(inorm(X3O)) + lrelu(inorm(X3A)) ----------------
__global__ void norm_add2(const float* __restrict__ src, float* __restrict__ dst,
                          const float* __restrict__ stats,
                          const float* __restrict__ addend, const float* __restrict__ astats,
                          int total) {
  int i = blockIdx.x * 256 + threadIdx.x;
  if (i >= total) return;
  int o = i & 127;
  int b = i >> 18;
  float m = stats[(b*128 + o)*2], rs = stats[(b*128 + o)*2 + 1];
  float v = (src[i] - m) * rs;
  v = (v >= 0.f) ? v : 0.2f*v;
  float ma = astats[(b*128 + o)*2], rsa = astats[(b*128 + o)*2 + 1];
  float a = (addend[i] - ma) * rsa;
  a = (a >= 0.f) ? a : 0.2f*a;
  dst[i] = v + a;
}

// ---------------- flash attention: 32 q-rows x 512 keys (split-K 4), bank-balanced LDS ----------------
__global__ __launch_bounds__(256) void attn_part(const float* __restrict__ Qp, const float* __restrict__ Kp,
                                                 const float* __restrict__ Vp,
                                                 float* __restrict__ OP, float* __restrict__ ML) {
  __shared__ float Qt[32][33];
  __shared__ float Kt[32][68];
  __shared__ float Vs[64][36];
  __shared__ float Pt[64][33];
  int tid = threadIdx.x;
  int tx = tid & 15, ty = tid >> 4;
  int kp = blockIdx.y;
  int bh = blockIdx.z;
  int q0 = blockIdx.x * 32;
  const float* Qh = Qp + (size_t)bh * NPTS * 32;
  const float* Kh = Kp + (size_t)bh * NPTS * 32;
  const float* Vh = Vp + (size_t)bh * NPTS * 32;
  {
    int r = tid & 31, a4 = ((tid >> 5) & 7) * 4;
    float4 v = *(const float4*)(Qh + (size_t)(q0 + r)*32 + a4);
    Qt[a4+0][r] = v.x; Qt[a4+1][r] = v.y; Qt[a4+2][r] = v.z; Qt[a4+3][r] = v.w;
  }
  float m_[2] = {-FLT_MAX, -FLT_MAX};
  float l_[2] = {0.f, 0.f};
  float O_[2][2] = {};
  const float sc = 0.17677669529663687f;
  int ks = kp * 512;
  for (int k0 = ks; k0 < ks + 512; k0 += 64) {
    __syncthreads();
    {
      int r = tid & 31, a4 = ((tid >> 5) & 7) * 4;
      float4 ka = *(const float4*)(Kh + (size_t)(k0 + r)*32 + a4);
      float4 kb = *(const float4*)(Kh + (size_t)(k0 + 32 + r)*32 + a4);
      Kt[a4+0][r] = ka.x; Kt[a4+1][r] = ka.y; Kt[a4+2][r] = ka.z; Kt[a4+3][r] = ka.w;
      Kt[a4+0][32+r] = kb.x; Kt[a4+1][32+r] = kb.y; Kt[a4+2][32+r] = kb.z; Kt[a4+3][32+r] = kb.w;
      int rv = tid & 63, av = (tid >> 6) * 4;
      *(float4*)&Vs[rv][av]      = *(const float4*)(Vh + (size_t)(k0 + rv)*32 + av);
      *(float4*)&Vs[rv][av + 16] = *(const float4*)(Vh + (size_t)(k0 + rv)*32 + av + 16);
    }
    __syncthreads();
    float acc[2][4] = {};
#pragma unroll
    for (int k = 0; k < 32; k++) {
      float a0 = Qt[k][ty], a1 = Qt[k][ty + 16];
      float4 bv = *(const float4*)&Kt[k][tx*4];
      acc[0][0] = fmaf(a0, bv.x, acc[0][0]);
      acc[0][1] = fmaf(a0, bv.y, acc[0][1]);
      acc[0][2] = fmaf(a0, bv.z, acc[0][2]);
      acc[0][3] = fmaf(a0, bv.w, acc[0][3]);
      acc[1][0] = fmaf(a1, bv.x, acc[1][0]);
      acc[1][1] = fmaf(a1, bv.y, acc[1][1]);
      acc[1][2] = fmaf(a1, bv.z, acc[1][2]);
      acc[1][3] = fmaf(a1, bv.w, acc[1][3]);
    }
#pragma unroll
    for (int i = 0; i < 2; i++)
#pragma unroll
      for (int j = 0; j < 4; j++) acc[i][j] *= sc;
#pragma unroll
    for (int i = 0; i < 2; i++) {
      float tm = fmaxf(fmaxf(acc[i][0], acc[i][1]), fmaxf(acc[i][2], acc[i][3]));
      for (int s = 1; s < 16; s <<= 1) tm = fmaxf(tm, __shfl_xor(tm, s));
      float mn = fmaxf(m_[i], tm);
      float cf = __expf(m_[i] - mn);
      m_[i] = mn;
      l_[i] *= cf; O_[i][0] *= cf; O_[i][1] *= cf;
      float rs = 0.f;
#pragma unroll
      for (int j = 0; j < 4; j++) {
        float p = __expf(acc[i][j] - mn);
        rs += p;
        Pt[tx*4 + j][ty + 16*i] = p;
      }
      for (int s = 1; s < 16; s <<= 1) rs += __shfl_xor(rs, s);
      l_[i] += rs;
    }
#pragma unroll 8
    for (int kk = 0; kk < 64; kk++) {
      float p0 = Pt[kk][ty], p1 = Pt[kk][ty + 16];
      float2 vv = *(const float2*)&Vs[kk][tx*2];
      O_[0][0] = fmaf(p0, vv.x, O_[0][0]);
      O_[0][1] = fmaf(p0, vv.y, O_[0][1]);
      O_[1][0] = fmaf(p1, vv.x, O_[1][0]);
      O_[1][1] = fmaf(p1, vv.y, O_[1][1]);
    }
  }
  size_t pb = (size_t)(kp*8 + bh) * NPTS;
#pragma unroll
  for (int i = 0; i < 2; i++) {
    int n = q0 + ty + 16*i;
    *(float2*)&OP[(pb + n)*32 + tx*2] = make_float2(O_[i][0], O_[i][1]);
    if (tx == 0) { ML[(pb + n)*2] = m_[i]; ML[(pb + n)*2 + 1] = l_[i]; }
  }
}

// ---------------- merge the four K-quarters ----------------
__global__ void attn_merge(const float* __restrict__ OP, const float* __restrict__ ML,
                           float* __restrict__ out) {
  int i = blockIdx.x * 256 + threadIdx.x;   // 8*2048*16
  if (i >= 8*2048*16) return;
  int dp = (i & 15) * 2;
  int n  = (i >> 4) & 2047;
  int bh = i >> 15;
  float mv[4], lv[4];
  float mm = -FLT_MAX;
#pragma unroll
  for (int p = 0; p < 4; p++) {
    size_t pp = ((size_t)(p*8 + bh) * NPTS + n);
    mv[p] = ML[pp*2]; lv[p] = ML[pp*2 + 1];
    mm = fmaxf(mm, mv[p]);
  }
  float L = 0.f, ox = 0.f, oy = 0.f;
#pragma unroll
  for (int p = 0; p < 4; p++) {
    size_t pp = ((size_t)(p*8 + bh) * NPTS + n);
    float w = __expf(mv[p] - mm);
    L += w * lv[p];
    float2 o = *(const float2*)&OP[pp*32 + dp];
    ox += w * o.x; oy += w * o.y;
  }
  float inv = 1.f / L;
  int b = bh >> 2, h = bh & 3;
  out[((size_t)(b*NPTS + n))*128 + (dp+0)*4 + h] = ox * inv;
  out[((size_t)(b*NPTS + n))*128 + (dp+1)*4 + h] = oy * inv;
}

// ================= host =================
extern "C" void kernel_launch(void* const* d_in, const int* in_sizes, int n_in,
                              void* d_out, int out_size, void* d_ws, size_t ws_size,
                              hipStream_t stream) {
  (void)in_sizes; (void)n_in; (void)out_size; (void)ws_size;
  const float* desc0  = (const float*)d_in[0];
  const float* desc1  = (const float*)d_in[1];
  const float* coords0= (const float*)d_in[2];
  const float* coords1= (const float*)d_in[3];
  const float* conv1w = (const float*)d_in[4];
  const float* conv2w = (const float*)d_in[5];
  const float* conv3w = (const float*)d_in[6];
  const float* conv3ow= (const float*)d_in[7];
  const float* a1w1 = (const float*)d_in[8];
  const float* a1b1 = (const float*)d_in[9];
  const float* a1w2 = (const float*)d_in[10];
  const float* a1b2 = (const float*)d_in[11];
  const float* a2w1 = (const float*)d_in[12];
  const float* a2b1 = (const float*)d_in[13];
  const float* a2w2 = (const float*)d_in[14];
  const float* a2b2 = (const float*)d_in[15];
  const float* gw1  = (const float*)d_in[16];
  const float* gb1  = (const float*)d_in[17];
  const float* gw2  = (const float*)d_in[18];
  const float* gb2  = (const float*)d_in[19];
  const float* wq = (const float*)d_in[20]; const float* bq = (const float*)d_in[21];
  const float* wk = (const float*)d_in[22]; const float* bk = (const float*)d_in[23];
  const float* wv = (const float*)d_in[24]; const float* bv = (const float*)d_in[25];
  const float* wm = (const float*)d_in[26]; const float* bm = (const float*)d_in[27];
  const float* mw1 = (const float*)d_in[28]; const float* mb1 = (const float*)d_in[29];
  const float* mw2 = (const float*)d_in[30]; const float* mb2 = (const float*)d_in[31];

  float* ws = (float*)d_ws;
  size_t off = 0;
  auto alloc = [&](size_t nel) { size_t r = off; off += (nel + 63) & ~(size_t)63; return r; };
  float* DW_A1 = ws + alloc(512*128);
  float* W_A1R = ws + alloc(128*384);
  float* DW_A2 = ws + alloc(512*128);
  float* W_A2R = ws + alloc(128*384);
  float* W_G2R = ws + alloc(128*384);
  float* DW_C1 = ws + alloc(256*128);
  float* DW_C2 = ws + alloc(512*128);
  float* W_KV  = ws + alloc(256*128);
  float* B_KV  = ws + alloc(256);
  float* SA   = ws + alloc((size_t)R2*128);
  float* XF0  = ws + alloc((size_t)4096*128);
  float* XF1  = ws + alloc((size_t)4096*128);
  int*   IDX  = (int*)(ws + alloc((size_t)R2*9));
  float* COSV = ws + alloc((size_t)R2*9);
  float* FT   = ws + alloc((size_t)R2*128);
  float* BIG  = ws + alloc((size_t)R2*512);
  float* ABUF = ws + alloc((size_t)R2*384);
  float* X1B  = ws + alloc((size_t)R2*128);
  float* FANG = ws + alloc((size_t)R2*128);
  float* X2B  = ws + alloc((size_t)R2*128);
  float* X3A  = ws + alloc((size_t)R2*128);
  float* X1O  = ws + alloc((size_t)R2*128);
  float* AB2  = ws + alloc((size_t)R2*256);
  float* X3O  = ws + alloc((size_t)R2*128);
  double* PART = (double*)(ws + alloc((size_t)2048*256*2*2));   // 1M doubles (8 MB)
  float*  PARTF = (float*)PART;                                  // aliased f32 partials
  float* STATS = ws + alloc(8*2048);
  float* ST_T   = STATS;
  float* ST_X1B = STATS + 2048;
  float* ST_FANG= STATS + 4096;
  float* ST_X2B = STATS + 6144;
  float* ST_X3A = STATS + 8192;
  float* ST_X1O = STATS + 10240;
  float* ST_AB  = STATS + 12288;
  float* ST_X3O = STATS + 14336;
  float* OP  = BIG;                           // attn partials (prop phase; BIG free then)
  float* ML  = BIG + (size_t)4*8*NPTS*32;     // after 4 K-part O-partials

  auto g64 = [&](const float* p0,int w0,const float* st0,int a0,int x0,
                 const float* p1,int w1,const float* st1,int a1,int x1,
                 const float* p2,int w2,const float* st2,int a2,int x2,
                 const float* addp,const float* addst,
                 const float* W,const float* bias,const float* resid,
                 float* Y,int R,int Cin,int O,int pack,float* Y2,float* part) {
    gemm_t<64><<<dim3(R/64, O/64), 256, 0, stream>>>(p0,w0,st0,a0,x0, p1,w1,st1,a1,x1,
        p2,w2,st2,a2,x2, addp,addst, W,bias,resid, Y,Cin,O,pack,Y2,part);
  };
  auto g32 = [&](const float* p0,int w0,const float* st0,int a0,int x0,
                 const float* p1,int w1,const float* st1,int a1,int x1,
                 const float* p2,int w2,const float* st2,int a2,int x2,
                 const float* addp,const float* addst,
                 const float* W,const float* bias,const float* resid,
                 float* Y,int R,int Cin,int O,int pack,float* Y2,float* part) {
    gemm_t<32><<<dim3(R/32, O/64), 256, 0, stream>>>(p0,w0,st0,a0,x0, p1,w1,st1,a1,x1,
        p2,w2,st2,a2,x2, addp,addst, W,bias,resid, Y,Cin,O,pack,Y2,part);
  };
  auto statsF = [&](float* stat, int O, int NB, int nblk, int count) {
    gm_final_f<<<(NB*O + 7)/8, 256, 0, stream>>>(PARTF, stat, O, NB, nblk, count);
  };
  auto statsD = [&](float* stat, int O, int NB, int nblk, int count) {
    gm_final<<<(NB*O + 7)/8, 256, 0, stream>>>(PART, stat, O, NB, nblk, count);
  };
  auto gathermax = [&](const float* G, float* mx, int Cc, float* stat) {
    gather_max_partial<<<R2/4, 256, 0, stream>>>(G, IDX, mx, PART, Cc);
    statsD(stat, Cc, 4, 512, 2048*9);
  };

  prep_weights<<<256, 256, 0, stream>>>(conv1w, conv2w, a1w1, a1w2, a2w1, a2w2, gw2,
                                        wk, bk, wv, bv,
                                        DW_A1, W_A1R, DW_A2, W_A2R, W_G2R, DW_C1, DW_C2,
                                        W_KV, B_KV);

  // ===== merged branch section (both descs, R2 = 8192 rows, 4 instances) =====
  transpose2<<<dim3(2048/32, 128/32, 4), dim3(32, 8), 0, stream>>>(desc0, desc1, FT, 128, 2048);
  knn2_kernel<<<2048, 256, 0, stream>>>(coords0, coords1, IDX, COSV);
  // annu1
  g64(FT,128,nullptr,0,0, nullptr,0,nullptr,0,0, nullptr,0,nullptr,0,0, nullptr,nullptr,
      DW_A1, nullptr, nullptr, BIG, R2, 128, 512, 0, nullptr, nullptr);
  combine_annu<<<R2/4, 256, 0, stream>>>(BIG, IDX, a1b1, ABUF, PART);
  statsD(ST_T, 128, 4, 512, 2048*3);
  g32(ABUF,384,ST_T,1,128, nullptr,0,nullptr,0,0, nullptr,0,nullptr,0,0, nullptr,nullptr,
      W_A1R, a1b2, nullptr, X1B, R2, 384, 128, 0, nullptr, PARTF);
  statsF(ST_X1B, 128, 4, 64, 2048);
  // f_ang (idx1 == idx2)
  cos_conv<<<R2/16, 256, 0, stream>>>(COSV, gw1, gb1, ABUF, PART);
  statsD(ST_T, 128, 4, 128, 2048*3);
  g32(ABUF,384,ST_T,1,128, nullptr,0,nullptr,0,0, nullptr,0,nullptr,0,0, nullptr,nullptr,
      W_G2R, gb2, nullptr, FANG, R2, 384, 128, 0, nullptr, PARTF);
  statsF(ST_FANG, 128, 4, 64, 2048);
  // annu2 (X1B raw, normed in staging)
  g64(X1B,128,ST_X1B,1,128, nullptr,0,nullptr,0,0, nullptr,0,nullptr,0,0, nullptr,nullptr,
      DW_A2, nullptr, nullptr, BIG, R2, 128, 512, 0, nullptr, nullptr);
  combine_annu<<<R2/4, 256, 0, stream>>>(BIG, IDX, a2b1, ABUF, PART);
  statsD(ST_T, 128, 4, 512, 2048*3);
  g32(ABUF,384,ST_T,1,128, nullptr,0,nullptr,0,0, nullptr,0,nullptr,0,0, nullptr,nullptr,
      W_A2R, a2b2, nullptr, X2B, R2, 384, 128, 0, nullptr, PARTF);
  statsF(ST_X2B, 128, 4, 64, 2048);
  // x3 = conv3 @ [x0 | n(x1)+n(fang) | n(x2)+n(fang)]
  g32(FT,128,nullptr,0,0, X1B,128,ST_X1B,1,128, X2B,128,ST_X2B,1,128, FANG,ST_FANG,
      conv3w, nullptr, nullptr, X3A, R2, 384, 128, 0, nullptr, PARTF);
  statsF(ST_X3A, 128, 4, 64, 2048);
  // x1o
  g64(FT,128,nullptr,0,0, nullptr,0,nullptr,0,0, nullptr,0,nullptr,0,0, nullptr,nullptr,
      DW_C1, nullptr, nullptr, BIG, R2, 128, 256, 0, nullptr, nullptr);
  gathermax(BIG, X1O, 128, ST_X1O);
  // x2o (X1O = raw max, normed lrelu in staging)
  g64(X1O,128,ST_X1O,2,128, nullptr,0,nullptr,0,0, nullptr,0,nullptr,0,0, nullptr,nullptr,
      DW_C2, nullptr, nullptr, BIG, R2, 128, 512, 0, nullptr, nullptr);
  gathermax(BIG, AB2, 256, ST_AB);
  // x3o = conv3o @ [x0 | n(x1o) | n(x2o)]
  g32(FT,128,nullptr,0,0, X1O,128,ST_X1O,2,128, AB2,256,ST_AB,2,256, nullptr,nullptr,
      conv3ow, nullptr, nullptr, X3O, R2, 512, 128, 0, nullptr, PARTF);
  statsF(ST_X3O, 128, 4, 64, 2048);
  norm_add2<<<(R2*128 + 255)/256, 256, 0, stream>>>(X3O, SA, ST_X3O, X3A, ST_X3A, R2*128);

  // ===== cross-attention props (rows 4096 each) =====
  float* SA0 = SA;
  float* SA1 = SA + (size_t)4096*128;
  auto prop = [&](const float* xin, const float* src, float* dst) {
    g32(xin,128,nullptr,0,0, nullptr,0,nullptr,0,0, nullptr,0,nullptr,0,0, nullptr,nullptr,
        wq, bq, nullptr, X1B, 4096, 128, 128, 1, nullptr, nullptr);                  // packed Q
    g32(src,128,nullptr,0,0, nullptr,0,nullptr,0,0, nullptr,0,nullptr,0,0, nullptr,nullptr,
        W_KV, B_KV, nullptr, X2B, 4096, 128, 256, 2, X3A, nullptr);                  // packed K + V
    attn_part<<<dim3(64, 4, 8), 256, 0, stream>>>(X1B, X2B, X3A, OP, ML);
    attn_merge<<<(8*2048*16 + 255)/256, 256, 0, stream>>>(OP, ML, FANG);
    g32(FANG,128,nullptr,0,0, nullptr,0,nullptr,0,0, nullptr,0,nullptr,0,0, nullptr,nullptr,
        wm, bm, nullptr, X1O, 4096, 128, 128, 0, nullptr, nullptr);
    g32(xin,128,nullptr,0,0, X1O,128,nullptr,0,0, nullptr,0,nullptr,0,0, nullptr,nullptr,
        mw1, mb1, nullptr, ABUF, 4096, 256, 256, 0, nullptr, PARTF);
    statsF(ST_T, 256, 2, 64, 2048);
    g32(ABUF,256,ST_T,1,256, nullptr,0,nullptr,0,0, nullptr,0,nullptr,0,0, nullptr,nullptr,
        mw2, mb2, xin, dst, 4096, 256, 128, 0, nullptr, nullptr);
  };

  prop(SA0, SA1, XF0);
  prop(SA1, XF0, XF1);

  transpose_k<<<dim3(128/32, 2048/32, 2), dim3(32, 8), 0, stream>>>(XF0, (float*)d_out, 2048, 128);
  transpose_k<<<dim3(128/32, 2048/32, 2), dim3(32, 8), 0, stream>>>(XF1, (float*)d_out + (size_t)4096*128, 2048, 128);
}

// Round 12
// 688.560 us; speedup vs baseline: 6.5690x; 1.1661x over previous
//
#include <hip/hip_runtime.h>
#include <cfloat>
#include <math.h>

#define NPTS 2048
#define R2   8192   // merged: 2 tensors x B=2 x N=2048

typedef __attribute__((ext_vector_type(8))) short bfrag;
typedef __attribute__((ext_vector_type(4))) float f32x4;

__device__ inline ushort f2bf(float f) {
  unsigned u = __float_as_uint(f);
  return (ushort)((u + 0x7fffu + ((u >> 16) & 1u)) >> 16);
}

// ---------------- prep: derived weight matrices ----------------
__global__ __launch_bounds__(256) void prep_weights(
    const float* __restrict__ conv1, const float* __restrict__ conv2,
    const float* __restrict__ a1w1, const float* __restrict__ a1w2,
    const float* __restrict__ a2w1, const float* __restrict__ a2w2,
    const float* __restrict__ gw2,
    const float* __restrict__ wk, const float* __restrict__ bk,
    const float* __restrict__ wv, const float* __restrict__ bv,
    float* __restrict__ dwA1, float* __restrict__ a1w2r,
    float* __restrict__ dwA2, float* __restrict__ a2w2r,
    float* __restrict__ gw2r, float* __restrict__ dwC1, float* __restrict__ dwC2,
    float* __restrict__ wkv, float* __restrict__ bkv)
{
  int i = blockIdx.x * 256 + threadIdx.x;
  if (i < 512*128) {
    int row = i >> 7, c = i & 127;
    float v1, v2;
    if (row < 128) {             // ctrW[o][c] = sum_t (w1[o,c,t] - w1[o,128+c,t])
      float s1 = 0.f, s2 = 0.f;
      for (int t = 0; t < 3; t++) {
        s1 += a1w1[(row*256 + c)*3 + t] - a1w1[(row*256 + 128 + c)*3 + t];
        s2 += a2w1[(row*256 + c)*3 + t] - a2w1[(row*256 + 128 + c)*3 + t];
      }
      v1 = s1; v2 = s2;
    } else {                     // row = 128 + t*128 + o : nbW_t[o][c] = w1[o,128+c,t]
      int t = (row - 128) >> 7, o = row & 127;
      v1 = a1w1[(o*256 + 128 + c)*3 + t];
      v2 = a2w1[(o*256 + 128 + c)*3 + t];
    }
    dwA1[i] = v1; dwA2[i] = v2;
    dwC2[i] = (row < 256) ? (conv2[row*256 + c] - conv2[row*256 + 128 + c])
                          : conv2[(row-256)*256 + 128 + c];
  }
  if (i < 128*384) {             // w2r[o][w*128+c] = w2[o,c,w]
    int o = i / 384, rem = i % 384, w = rem >> 7, c = rem & 127;
    a1w2r[i] = a1w2[(o*128 + c)*3 + w];
    a2w2r[i] = a2w2[(o*128 + c)*3 + w];
    gw2r[i]  = gw2[(o*128 + c)*3 + w];
  }
  if (i < 256*128) {             // dwC1 [256][128] from conv1 [128][256]
    int row = i >> 7, c = i & 127;
    dwC1[i] = (row < 128) ? (conv1[row*256 + c] - conv1[row*256 + 128 + c])
                          : conv1[(row-128)*256 + 128 + c];
    wkv[i] = (row < 128) ? wk[row*128 + c] : wv[(row-128)*128 + c];
  }
  if (i < 256) bkv[i] = (i < 128) ? bk[i] : bv[i - 128];
}

// ---------------- transpose both descs: in [2][I][J] x2 -> out [4][J][I] ----------------
__global__ void transpose2(const float* __restrict__ in0, const float* __restrict__ in1,
                           float* __restrict__ out, int I, int J) {
  __shared__ float tile[32][33];
  int zb = blockIdx.z;
  const float* src = (zb < 2) ? (in0 + (size_t)zb*I*J) : (in1 + (size_t)(zb-2)*I*J);
  float* dst = out + (size_t)zb*J*I;
  int i0 = blockIdx.y * 32, j0 = blockIdx.x * 32;
  int tx = threadIdx.x, ty = threadIdx.y;
  for (int s = 0; s < 32; s += 8)
    tile[ty + s][tx] = src[(size_t)(i0 + ty + s)*J + (j0 + tx)];
  __syncthreads();
  for (int s = 0; s < 32; s += 8)
    dst[(size_t)(j0 + ty + s)*I + (i0 + tx)] = tile[tx][ty + s];
}

// ---------------- transpose [b][I][J] -> [b][J][I] (final output) ----------------
__global__ void transpose_k(const float* __restrict__ in, float* __restrict__ out, int I, int J) {
  __shared__ float tile[32][33];
  int b = blockIdx.z;
  int i0 = blockIdx.y * 32, j0 = blockIdx.x * 32;
  int tx = threadIdx.x, ty = threadIdx.y;
  for (int s = 0; s < 32; s += 8)
    tile[ty + s][tx] = in[((size_t)b*I + (i0 + ty + s))*J + (j0 + tx)];
  __syncthreads();
  for (int s = 0; s < 32; s += 8)
    out[((size_t)b*J + (j0 + ty + s))*I + (i0 + tx)] = tile[tx][ty + s];
}

// ---------------- KNN (both coord sets): f32 np-exact distances, (dist,idx)-lex ----------------
__global__ __launch_bounds__(256) void knn2_kernel(const float* __restrict__ P0, const float* __restrict__ P1,
                                                   int* __restrict__ idx, float* __restrict__ cosv) {
  __shared__ float px[NPTS], py[NPTS], sq[NPTS];
  int tid = threadIdx.x;
  int gw = blockIdx.x * 4 + (tid >> 6);   // 0..8191 : global point id
  int b4 = gw >> 11, n = gw & 2047;
  int lane = tid & 63;
  const float* Pb = (b4 < 2) ? (P0 + (size_t)b4 * 2 * NPTS) : (P1 + (size_t)(b4 - 2) * 2 * NPTS);
  for (int i = tid; i < NPTS; i += 256) {
    float x = Pb[i], y = Pb[NPTS + i];
    px[i] = x; py[i] = y;
    sq[i] = __fadd_rn(__fmul_rn(x, x), __fmul_rn(y, y));
  }
  __syncthreads();
  float xn = px[n], yn = py[n], sqn = sq[n];
  float d[10]; int id_[10];
#pragma unroll
  for (int j = 0; j < 10; j++) { d[j] = FLT_MAX; id_[j] = 0x7fffffff; }
  for (int m = lane; m < NPTS; m += 64) {
    float dot  = __fadd_rn(__fmul_rn(xn, px[m]), __fmul_rn(yn, py[m]));
    float dist = __fsub_rn(__fadd_rn(sqn, sq[m]), __fmul_rn(2.0f, dot));
    dist = fmaxf(dist, 1e-12f);
    if (dist < d[9] || (dist == d[9] && m < id_[9])) {
      int p = 0;
#pragma unroll
      for (int j = 0; j < 10; j++) p += (d[j] < dist || (d[j] == dist && id_[j] < m)) ? 1 : 0;
#pragma unroll
      for (int j = 9; j >= 1; j--) if (j > p) { d[j] = d[j-1]; id_[j] = id_[j-1]; }
#pragma unroll
      for (int j = 0; j < 10; j++) if (j == p) { d[j] = dist; id_[j] = m; }
    }
  }
  int ptr = 0;
  for (int r = 0; r < 10; r++) {
    float bd = FLT_MAX; int bi = 0x7fffffff;
#pragma unroll
    for (int j = 0; j < 10; j++) if (j == ptr) { bd = d[j]; bi = id_[j]; }
    for (int off = 32; off >= 1; off >>= 1) {
      float od = __shfl_xor(bd, off);
      int   oi = __shfl_xor(bi, off);
      if (od < bd || (od == bd && oi < bi)) { bd = od; bi = oi; }
    }
    bool adv = false;
#pragma unroll
    for (int j = 0; j < 10; j++) if (j == ptr) adv = (d[j] == bd && id_[j] == bi);
    if (adv) ptr++;
    if (r > 0 && lane == 0) {
      size_t base = (size_t)gw*9 + (r - 1);
      idx[base] = bi;
      float dot = __fadd_rn(__fmul_rn(xn, px[bi]), __fmul_rn(yn, py[bi]));
      cosv[base] = __fdiv_rn(dot, __fmul_rn(__fsqrt_rn(sqn), __fsqrt_rn(sq[bi])));
    }
  }
}

// ---------------- unified bf16-MFMA GEMM: template BM, per-segment norm-act, fused stats --------
template<int BM>
__global__ __launch_bounds__(256) void gemm_m(
    const float* __restrict__ p0, int w0, const float* __restrict__ st0, int a0, int xm0,
    const float* __restrict__ p1, int w1, const float* __restrict__ st1, int a1, int xm1,
    const float* __restrict__ p2, int w2, const float* __restrict__ st2, int a2, int xm2,
    const float* __restrict__ addp, const float* __restrict__ addst,
    const float* __restrict__ W, const float* __restrict__ bias,
    const float* __restrict__ resid,
    float* __restrict__ Y, int Cin, int O, int pack, float* __restrict__ Y2,
    float* __restrict__ part)
{
  __shared__ ushort Xs[BM][40];   // bf16, 80B row stride (16B-aligned frag reads)
  __shared__ ushort Ws[64][40];
  constexpr int RT = BM / 16;     // 16-row tiles per block
  constexpr int XF = BM / 8;      // X elems per thread per K-chunk
  int tid = threadIdx.x;
  int wv = tid >> 6, l = tid & 63;
  int m16 = l & 15, kq = l >> 4;         // fragment coords
  int r0 = blockIdx.x * BM, c0 = blockIdx.y * 64;
  int sxr = tid & (BM - 1), sxc = (tid / BM) * XF;
  int swr = tid & 63, swc = (tid >> 6) * 8;
  f32x4 acc[RT];
#pragma unroll
  for (int t = 0; t < RT; t++) acc[t] = (f32x4){0.f, 0.f, 0.f, 0.f};
  for (int k0 = 0; k0 < Cin; k0 += 32) {
    // ---- stage X (f32 -> norm/act/add -> bf16) ----
    {
      int r = r0 + sxr;
      int ac = k0 + sxc;
      const float* P; const float* st; int cc, lw, act, xm;
      if (ac < w0)            { P = p0; cc = ac;          lw = w0; st = st0; act = a0; xm = xm0; }
      else if (ac < w0 + w1)  { P = p1; cc = ac - w0;     lw = w1; st = st1; act = a1; xm = xm1; }
      else                    { P = p2; cc = ac - w0 - w1; lw = w2; st = st2; act = a2; xm = xm2; }
      float vv[XF];
#pragma unroll
      for (int q = 0; q < XF; q += 4)
        *(float4*)&vv[q] = *(const float4*)(P + (size_t)r*lw + cc + q);
      int b = r >> 11;
      if (st) {
#pragma unroll
        for (int j = 0; j < XF; j++) {
          int o = (cc + j) & (xm - 1);
          float m = st[(b*xm + o)*2], rs = st[(b*xm + o)*2 + 1];
          float v = (vv[j] - m) * rs;
          vv[j] = (act == 1) ? fmaxf(v, 0.f) : ((v >= 0.f) ? v : 0.2f*v);
        }
      }
      if (addp && ac >= 128) {
        int fc = (ac - 128) & 127;
        float av[XF];
#pragma unroll
        for (int q = 0; q < XF; q += 4)
          *(float4*)&av[q] = *(const float4*)(addp + (size_t)r*128 + fc + q);
        if (addst) {
#pragma unroll
          for (int j = 0; j < XF; j++) {
            int o = (fc + j) & 127;
            float m = addst[(b*128 + o)*2], rs = addst[(b*128 + o)*2 + 1];
            av[j] = fmaxf((av[j] - m) * rs, 0.f);
          }
        }
#pragma unroll
        for (int j = 0; j < XF; j++) vv[j] += av[j];
      }
      union { ushort u[XF]; ushort4 v4[XF/4]; } pk;
#pragma unroll
      for (int j = 0; j < XF; j++) pk.u[j] = f2bf(vv[j]);
#pragma unroll
      for (int q = 0; q < XF/4; q++) *(ushort4*)&Xs[sxr][sxc + q*4] = pk.v4[q];
    }
    // ---- stage W (f32 -> bf16) ----
    {
      const float* s = W + (size_t)(c0 + swr)*Cin + k0 + swc;
      float4 v0 = *(const float4*)s, v1 = *(const float4*)(s + 4);
      union { ushort u[8]; ushort4 v4[2]; } pk;
      pk.u[0]=f2bf(v0.x); pk.u[1]=f2bf(v0.y); pk.u[2]=f2bf(v0.z); pk.u[3]=f2bf(v0.w);
      pk.u[4]=f2bf(v1.x); pk.u[5]=f2bf(v1.y); pk.u[6]=f2bf(v1.z); pk.u[7]=f2bf(v1.w);
      *(ushort4*)&Ws[swr][swc]     = pk.v4[0];
      *(ushort4*)&Ws[swr][swc + 4] = pk.v4[1];
    }
    __syncthreads();
    bfrag bf = *(const bfrag*)&Ws[wv*16 + m16][kq*8];
#pragma unroll
    for (int t = 0; t < RT; t++) {
      bfrag af = *(const bfrag*)&Xs[t*16 + m16][kq*8];
      acc[t] = __builtin_amdgcn_mfma_f32_16x16x32_bf16(af, bf, acc[t], 0, 0, 0);
    }
    __syncthreads();
  }
  // ---- epilogue: bias / resid / pack / write / fused per-column stats ----
  int c = c0 + wv*16 + m16;
  float bi = bias ? bias[c] : 0.f;
  float ps = 0.f, ps2 = 0.f;
#pragma unroll
  for (int t = 0; t < RT; t++) {
#pragma unroll
    for (int i = 0; i < 4; i++) {
      int r = r0 + t*16 + kq*4 + i;
      float v = acc[t][i] + bi;
      if (resid) v += resid[(size_t)r*O + c];
      if (pack) {
        int cc2 = c & 127;
        int h = cc2 & 3, dd = cc2 >> 2, b = r >> 11, n = r & 2047;
        float* T = (pack == 1 || c < 128) ? Y : Y2;
        T[(((size_t)(b*4 + h))*NPTS + n)*32 + dd] = v;
      } else {
        Y[(size_t)r*O + c] = v;
      }
      ps += v; ps2 = fmaf(v, v, ps2);
    }
  }
  if (part) {
    ps  += __shfl_xor(ps, 16);  ps  += __shfl_xor(ps, 32);
    ps2 += __shfl_xor(ps2, 16); ps2 += __shfl_xor(ps2, 32);
    if (kq == 0) {
      part[((size_t)blockIdx.x*O + c)*2]     = ps;
      part[((size_t)blockIdx.x*O + c)*2 + 1] = ps2;
    }
  }
}

// ---------------- annu conv1 combine: 4 rows/block + fused f64 stats partials ----------------
__global__ __launch_bounds__(256) void combine_annu(const float* __restrict__ GA, const int* __restrict__ idx,
                                                    const float* __restrict__ b1, float* __restrict__ A,
                                                    double* __restrict__ part) {
  int t = threadIdx.x;
  int o = t & 127, sub = t >> 7;
  int r0 = blockIdx.x * 4;
  __shared__ int nbs[4][9];
  if (t < 36) nbs[t / 9][t % 9] = idx[(size_t)(r0 + t/9)*9 + (t % 9)];
  __syncthreads();
  float bo = b1[o];
  double s = 0.0, s2 = 0.0;
  for (int rr = sub; rr < 4; rr += 2) {
    int r = r0 + rr, rb = r & ~2047;
    float ctr = GA[(size_t)r*512 + o] + bo;
#pragma unroll
    for (int w = 0; w < 3; w++) {
      float acc = ctr;
#pragma unroll
      for (int t3 = 0; t3 < 3; t3++) {
        int m = nbs[rr][w*3 + t3];
        acc += GA[(size_t)(rb + m)*512 + 128 + t3*128 + o];
      }
      A[(size_t)r*384 + w*128 + o] = acc;
      s += (double)acc; s2 += (double)acc * (double)acc;
    }
  }
  __shared__ double ls[256], ls2[256];
  ls[t] = s; ls2[t] = s2;
  __syncthreads();
  if (sub == 0) {
    s += ls[128 + o]; s2 += ls2[128 + o];
    part[((size_t)blockIdx.x*128 + o)*2] = s;
    part[((size_t)blockIdx.x*128 + o)*2 + 1] = s2;
  }
}

// ---------------- angle-feature conv1: 16 rows/block + fused f64 stats ----------------
__global__ __launch_bounds__(256) void cos_conv(const float* __restrict__ cosv, const float* __restrict__ gw1,
                                                const float* __restrict__ gb1, float* __restrict__ ANG,
                                                double* __restrict__ part) {
  int t = threadIdx.x;
  int o = t & 127, sub = t >> 7;
  int r0 = blockIdx.x * 16;
  float g0 = gw1[o*3], g1 = gw1[o*3+1], g2 = gw1[o*3+2], gb = gb1[o];
  __shared__ float cs[16][12];
  for (int i = t; i < 16*9; i += 256) cs[i / 9][i % 9] = cosv[(size_t)(r0 + i/9)*9 + (i % 9)];
  __syncthreads();
  double s = 0.0, s2 = 0.0;
  for (int rr = sub; rr < 16; rr += 2) {
    int r = r0 + rr;
#pragma unroll
    for (int w = 0; w < 3; w++) {
      float acc = gb;
      acc += cs[rr][w*3+0]*g0;
      acc += cs[rr][w*3+1]*g1;
      acc += cs[rr][w*3+2]*g2;
      ANG[(size_t)r*384 + w*128 + o] = acc;
      s += (double)acc; s2 += (double)acc * (double)acc;
    }
  }
  __shared__ double ls[256], ls2[256];
  ls[t] = s; ls2[t] = s2;
  __syncthreads();
  if (sub == 0) {
    s += ls[128 + o]; s2 += ls2[128 + o];
    part[((size_t)blockIdx.x*128 + o)*2] = s;
    part[((size_t)blockIdx.x*128 + o)*2 + 1] = s2;
  }
}

// ---------------- parallel stats final (f64 partials) ----------------
__global__ __launch_bounds__(256) void gm_final(const double* __restrict__ part, float* __restrict__ stats,
                                                int Cc, int NB, int nblk, int count) {
  int g = blockIdx.x * 8 + (threadIdx.x >> 5);
  int lane = threadIdx.x & 31;
  if (g >= NB*Cc) return;
  int b = g / Cc, o = g % Cc;
  double S = 0.0, S2 = 0.0;
  for (int u = lane; u < nblk; u += 32) {
    size_t blk = (size_t)(b*nblk + u);
    S  += part[(blk*Cc + o)*2];
    S2 += part[(blk*Cc + o)*2 + 1];
  }
  for (int off = 16; off >= 1; off >>= 1) {
    S  += __shfl_down(S, off, 32);
    S2 += __shfl_down(S2, off, 32);
  }
  if (lane == 0) {
    double mean = S / count;
    double var = S2 / count - mean*mean;
    if (var < 0.0) var = 0.0;
    stats[g*2] = (float)mean;
    stats[g*2 + 1] = (float)(1.0 / sqrt(var + 1e-5));
  }
}

// ---------------- parallel stats final (f32 partials, f64 accumulate) ----------------
__global__ __launch_bounds__(256) void gm_final_f(const float* __restrict__ part, float* __restrict__ stats,
                                                  int Cc, int NB, int nblk, int count) {
  int g = blockIdx.x * 8 + (threadIdx.x >> 5);
  int lane = threadIdx.x & 31;
  if (g >= NB*Cc) return;
  int b = g / Cc, o = g % Cc;
  double S = 0.0, S2 = 0.0;
  for (int u = lane; u < nblk; u += 32) {
    size_t blk = (size_t)(b*nblk + u);
    S  += (double)part[(blk*Cc + o)*2];
    S2 += (double)part[(blk*Cc + o)*2 + 1];
  }
  for (int off = 16; off >= 1; off >>= 1) {
    S  += __shfl_down(S, off, 32);
    S2 += __shfl_down(S2, off, 32);
  }
  if (lane == 0) {
    double mean = S / count;
    double var = S2 / count - mean*mean;
    if (var < 0.0) var = 0.0;
    stats[g*2] = (float)mean;
    stats[g*2 + 1] = (float)(1.0 / sqrt(var + 1e-5));
  }
}

// ---------------- gather + max over k + f64 partials (4 rows/block, idx in LDS) ----------------
__global__ __launch_bounds__(256) void gather_max_partial(const float* __restrict__ G, const int* __restrict__ idx,
                                                          float* __restrict__ maxbuf, double* __restrict__ part,
                                                          int Cc) {
  int t = threadIdx.x;
  int o = t % Cc, sub = t / Cc, nsub = 256 / Cc;
  int r0 = blockIdx.x * 4;
  __shared__ int nbs[4][9];
  if (t < 36) nbs[t / 9][t % 9] = idx[(size_t)(r0 + t/9)*9 + (t % 9)];
  __syncthreads();
  double s = 0.0, s2 = 0.0;
  for (int rr = sub; rr < 4; rr += nsub) {
    int r = r0 + rr, rb = r & ~2047;
    float g = G[(size_t)r*2*Cc + o];
    float mx = -3.4e38f;
#pragma unroll
    for (int k = 0; k < 9; k++) {
      int m = nbs[rr][k];
      float v = g + G[(size_t)(rb + m)*2*Cc + Cc + o];
      mx = fmaxf(mx, v); s += (double)v; s2 += (double)v*(double)v;
    }
    maxbuf[(size_t)r*Cc + o] = mx;
  }
  if (nsub == 2) {
    __shared__ double ls[256], ls2[256];
    ls[t] = s; ls2[t] = s2;
    __syncthreads();
    if (sub == 0) { s += ls[Cc + o]; s2 += ls2[Cc + o]; }
  }
  if (sub == 0) {
    part[((size_t)blockIdx.x*Cc + o)*2] = s;
    part[((size_t)blockIdx.x*Cc + o)*2 + 1] = s2;
  }
}

// ---------------- final: SA = lrelu(inorm(X3O)) + lrelu(inorm(X3A)) ----------------
__global__ void norm_add2(const float* __restrict__ src, float* __restrict__ dst,
                          const float* __restrict__ stats,
                          const float* __restrict__ addend, const float* __restrict__ astats,
                          int total) {
  int i = blockIdx.x * 256 + threadIdx.x;
  if (i >= total) return;
  int o = i & 127;
  int b = i >> 18;
  float m = stats[(b*128 + o)*2], rs = stats[(b*128 + o)*2 + 1];
  float v = (src[i] - m) * rs;
  v = (v >= 0.f) ? v : 0.2f*v;
  float ma = astats[(b*128 + o)*2], rsa = astats[(b*128 + o)*2 + 1];
  float a = (addend[i] - ma) * rsa;
  a = (a >= 0.f) ? a : 0.2f*a;
  dst[i] = v + a;
}

// ---------------- flash attention: 32 q-rows x 512 keys (split-K 4), bank-balanced LDS ----------------
__global__ __launch_bounds__(256) void attn_part(const float* __restrict__ Qp, const float* __restrict__ Kp,
                                                 const float* __restrict__ Vp,
                                                 float* __restrict__ OP, float* __restrict__ ML) {
  __shared__ float Qt[32][33];
  __shared__ float Kt[32][68];
  __shared__ float Vs[64][36];
  __shared__ float Pt[64][33];
  int tid = threadIdx.x;
  int tx = tid & 15, ty = tid >> 4;
  int kp = blockIdx.y;
  int bh = blockIdx.z;
  int q0 = blockIdx.x * 32;
  const float* Qh = Qp + (size_t)bh * NPTS * 32;
  const float* Kh = Kp + (size_t)bh * NPTS * 32;
  const float* Vh = Vp + (size_t)bh * NPTS * 32;
  {
    int r = tid & 31, a4 = ((tid >> 5) & 7) * 4;
    float4 v = *(const float4*)(Qh + (size_t)(q0 + r)*32 + a4);
    Qt[a4+0][r] = v.x; Qt[a4+1][r] = v.y; Qt[a4+2][r] = v.z; Qt[a4+3][r] = v.w;
  }
  float m_[2] = {-FLT_MAX, -FLT_MAX};
  float l_[2] = {0.f, 0.f};
  float O_[2][2] = {};
  const float sc = 0.17677669529663687f;
  int ks = kp * 512;
  for (int k0 = ks; k0 < ks + 512; k0 += 64) {
    __syncthreads();
    {
      int r = tid & 31, a4 = ((tid >> 5) & 7) * 4;
      float4 ka = *(const float4*)(Kh + (size_t)(k0 + r)*32 + a4);
      float4 kb = *(const float4*)(Kh + (size_t)(k0 + 32 + r)*32 + a4);
      Kt[a4+0][r] = ka.x; Kt[a4+1][r] = ka.y; Kt[a4+2][r] = ka.z; Kt[a4+3][r] = ka.w;
      Kt[a4+0][32+r] = kb.x; Kt[a4+1][32+r] = kb.y; Kt[a4+2][32+r] = kb.z; Kt[a4+3][32+r] = kb.w;
      int rv = tid & 63, av = (tid >> 6) * 4;
      *(float4*)&Vs[rv][av]      = *(const float4*)(Vh + (size_t)(k0 + rv)*32 + av);
      *(float4*)&Vs[rv][av + 16] = *(const float4*)(Vh + (size_t)(k0 + rv)*32 + av + 16);
    }
    __syncthreads();
    float acc[2][4] = {};
#pragma unroll
    for (int k = 0; k < 32; k++) {
      float a0 = Qt[k][ty], a1 = Qt[k][ty + 16];
      float4 bv = *(const float4*)&Kt[k][tx*4];
      acc[0][0] = fmaf(a0, bv.x, acc[0][0]);
      acc[0][1] = fmaf(a0, bv.y, acc[0][1]);
      acc[0][2] = fmaf(a0, bv.z, acc[0][2]);
      acc[0][3] = fmaf(a0, bv.w, acc[0][3]);
      acc[1][0] = fmaf(a1, bv.x, acc[1][0]);
      acc[1][1] = fmaf(a1, bv.y, acc[1][1]);
      acc[1][2] = fmaf(a1, bv.z, acc[1][2]);
      acc[1][3] = fmaf(a1, bv.w, acc[1][3]);
    }
#pragma unroll
    for (int i = 0; i < 2; i++)
#pragma unroll
      for (int j = 0; j < 4; j++) acc[i][j] *= sc;
#pragma unroll
    for (int i = 0; i < 2; i++) {
      float tm = fmaxf(fmaxf(acc[i][0], acc[i][1]), fmaxf(acc[i][2], acc[i][3]));
      for (int s = 1; s < 16; s <<= 1) tm = fmaxf(tm, __shfl_xor(tm, s));
      float mn = fmaxf(m_[i], tm);
      float cf = __expf(m_[i] - mn);
      m_[i] = mn;
      l_[i] *= cf; O_[i][0] *= cf; O_[i][1] *= cf;
      float rs = 0.f;
#pragma unroll
      for (int j = 0; j < 4; j++) {
        float p = __expf(acc[i][j] - mn);
        rs += p;
        Pt[tx*4 + j][ty + 16*i] = p;
      }
      for (int s = 1; s < 16; s <<= 1) rs += __shfl_xor(rs, s);
      l_[i] += rs;
    }
#pragma unroll 8
    for (int kk = 0; kk < 64; kk++) {
      float p0 = Pt[kk][ty], p1 = Pt[kk][ty + 16];
      float2 vv = *(const float2*)&Vs[kk][tx*2];
      O_[0][0] = fmaf(p0, vv.x, O_[0][0]);
      O_[0][1] = fmaf(p0, vv.y, O_[0][1]);
      O_[1][0] = fmaf(p1, vv.x, O_[1][0]);
      O_[1][1] = fmaf(p1, vv.y, O_[1][1]);
    }
  }
  size_t pb = (size_t)(kp*8 + bh) * NPTS;
#pragma unroll
  for (int i = 0; i < 2; i++) {
    int n = q0 + ty + 16*i;
    *(float2*)&OP[(pb + n)*32 + tx*2] = make_float2(O_[i][0], O_[i][1]);
    if (tx == 0) { ML[(pb + n)*2] = m_[i]; ML[(pb + n)*2 + 1] = l_[i]; }
  }
}

// ---------------- merge the four K-quarters ----------------
__global__ void attn_merge(const float* __restrict__ OP, const float* __restrict__ ML,
                           float* __restrict__ out) {
  int i = blockIdx.x * 256 + threadIdx.x;   // 8*2048*16
  if (i >= 8*2048*16) return;
  int dp = (i & 15) * 2;
  int n  = (i >> 4) & 2047;
  int bh = i >> 15;
  float mv[4], lv[4];
  float mm = -FLT_MAX;
#pragma unroll
  for (int p = 0; p < 4; p++) {
    size_t pp = ((size_t)(p*8 + bh) * NPTS + n);
    mv[p] = ML[pp*2]; lv[p] = ML[pp*2 + 1];
    mm = fmaxf(mm, mv[p]);
  }
  float L = 0.f, ox = 0.f, oy = 0.f;
#pragma unroll
  for (int p = 0; p < 4; p++) {
    size_t pp = ((size_t)(p*8 + bh) * NPTS + n);
    float w = __expf(mv[p] - mm);
    L += w * lv[p];
    float2 o = *(const float2*)&OP[pp*32 + dp];
    ox += w * o.x; oy += w * o.y;
  }
  float inv = 1.f / L;
  int b = bh >> 2, h = bh & 3;
  out[((size_t)(b*NPTS + n))*128 + (dp+0)*4 + h] = ox * inv;
  out[((size_t)(b*NPTS + n))*128 + (dp+1)*4 + h] = oy * inv;
}

// ================= host =================
extern "C" void kernel_launch(void* const* d_in, const int* in_sizes, int n_in,
                              void* d_out, int out_size, void* d_ws, size_t ws_size,
                              hipStream_t stream) {
  (void)in_sizes; (void)n_in; (void)out_size; (void)ws_size;
  const float* desc0  = (const float*)d_in[0];
  const float* desc1  = (const float*)d_in[1];
  const float* coords0= (const float*)d_in[2];
  const float* coords1= (const float*)d_in[3];
  const float* conv1w = (const float*)d_in[4];
  const float* conv2w = (const float*)d_in[5];
  const float* conv3w = (const float*)d_in[6];
  const float* conv3ow= (const float*)d_in[7];
  const float* a1w1 = (const float*)d_in[8];
  const float* a1b1 = (const float*)d_in[9];
  const float* a1w2 = (const float*)d_in[10];
  const float* a1b2 = (const float*)d_in[11];
  const float* a2w1 = (const float*)d_in[12];
  const float* a2b1 = (const float*)d_in[13];
  const float* a2w2 = (const float*)d_in[14];
  const float* a2b2 = (const float*)d_in[15];
  const float* gw1  = (const float*)d_in[16];
  const float* gb1  = (const float*)d_in[17];
  const float* gw2  = (const float*)d_in[18];
  const float* gb2  = (const float*)d_in[19];
  const float* wq = (const float*)d_in[20]; const float* bq = (const float*)d_in[21];
  const float* wk = (const float*)d_in[22]; const float* bk = (const float*)d_in[23];
  const float* wv = (const float*)d_in[24]; const float* bv = (const float*)d_in[25];
  const float* wm = (const float*)d_in[26]; const float* bm = (const float*)d_in[27];
  const float* mw1 = (const float*)d_in[28]; const float* mb1 = (const float*)d_in[29];
  const float* mw2 = (const float*)d_in[30]; const float* mb2 = (const float*)d_in[31];

  float* ws = (float*)d_ws;
  size_t off = 0;
  auto alloc = [&](size_t nel) { size_t r = off; off += (nel + 63) & ~(size_t)63; return r; };
  float* DW_A1 = ws + alloc(512*128);
  float* W_A1R = ws + alloc(128*384);
  float* DW_A2 = ws + alloc(512*128);
  float* W_A2R = ws + alloc(128*384);
  float* W_G2R = ws + alloc(128*384);
  float* DW_C1 = ws + alloc(256*128);
  float* DW_C2 = ws + alloc(512*128);
  float* W_KV  = ws + alloc(256*128);
  float* B_KV  = ws + alloc(256);
  float* SA   = ws + alloc((size_t)R2*128);
  float* XF0  = ws + alloc((size_t)4096*128);
  float* XF1  = ws + alloc((size_t)4096*128);
  int*   IDX  = (int*)(ws + alloc((size_t)R2*9));
  float* COSV = ws + alloc((size_t)R2*9);
  float* FT   = ws + alloc((size_t)R2*128);
  float* BIG  = ws + alloc((size_t)R2*512);
  float* ABUF = ws + alloc((size_t)R2*384);
  float* X1B  = ws + alloc((size_t)R2*128);
  float* FANG = ws + alloc((size_t)R2*128);
  float* X2B  = ws + alloc((size_t)R2*128);
  float* X3A  = ws + alloc((size_t)R2*128);
  float* X1O  = ws + alloc((size_t)R2*128);
  float* AB2  = ws + alloc((size_t)R2*256);
  float* X3O  = ws + alloc((size_t)R2*128);
  double* PART = (double*)(ws + alloc((size_t)2048*256*2*2));   // 1M doubles (8 MB)
  float*  PARTF = (float*)PART;                                  // aliased f32 partials
  float* STATS = ws + alloc(8*2048);
  float* ST_T   = STATS;
  float* ST_X1B = STATS + 2048;
  float* ST_FANG= STATS + 4096;
  float* ST_X2B = STATS + 6144;
  float* ST_X3A = STATS + 8192;
  float* ST_X1O = STATS + 10240;
  float* ST_AB  = STATS + 12288;
  float* ST_X3O = STATS + 14336;
  float* OP  = BIG;                           // attn partials (prop phase; BIG free then)
  float* ML  = BIG + (size_t)4*8*NPTS*32;     // after 4 K-part O-partials

  auto g64 = [&](const float* p0,int w0,const float* st0,int a0,int x0,
                 const float* p1,int w1,const float* st1,int a1,int x1,
                 const float* p2,int w2,const float* st2,int a2,int x2,
                 const float* addp,const float* addst,
                 const float* W,const float* bias,const float* resid,
                 float* Y,int R,int Cin,int O,int pack,float* Y2,float* part) {
    gemm_m<64><<<dim3(R/64, O/64), 256, 0, stream>>>(p0,w0,st0,a0,x0, p1,w1,st1,a1,x1,
        p2,w2,st2,a2,x2, addp,addst, W,bias,resid, Y,Cin,O,pack,Y2,part);
  };
  auto g32 = [&](const float* p0,int w0,const float* st0,int a0,int x0,
                 const float* p1,int w1,const float* st1,int a1,int x1,
                 const float* p2,int w2,const float* st2,int a2,int x2,
                 const float* addp,const float* addst,
                 const float* W,const float* bias,const float* resid,
                 float* Y,int R,int Cin,int O,int pack,float* Y2,float* part) {
    gemm_m<32><<<dim3(R/32, O/64), 256, 0, stream>>>(p0,w0,st0,a0,x0, p1,w1,st1,a1,x1,
        p2,w2,st2,a2,x2, addp,addst, W,bias,resid, Y,Cin,O,pack,Y2,part);
  };
  auto statsF = [&](float* stat, int O, int NB, int nblk, int count) {
    gm_final_f<<<(NB*O + 7)/8, 256, 0, stream>>>(PARTF, stat, O, NB, nblk, count);
  };
  auto statsD = [&](float* stat, int O, int NB, int nblk, int count) {
    gm_final<<<(NB*O + 7)/8, 256, 0, stream>>>(PART, stat, O, NB, nblk, count);
  };
  auto gathermax = [&](const float* G, float* mx, int Cc, float* stat) {
    gather_max_partial<<<R2/4, 256, 0, stream>>>(G, IDX, mx, PART, Cc);
    statsD(stat, Cc, 4, 512, 2048*9);
  };

  prep_weights<<<256, 256, 0, stream>>>(conv1w, conv2w, a1w1, a1w2, a2w1, a2w2, gw2,
                                        wk, bk, wv, bv,
                                        DW_A1, W_A1R, DW_A2, W_A2R, W_G2R, DW_C1, DW_C2,
                                        W_KV, B_KV);

  // ===== merged branch section (both descs, R2 = 8192 rows, 4 instances) =====
  transpose2<<<dim3(2048/32, 128/32, 4), dim3(32, 8), 0, stream>>>(desc0, desc1, FT, 128, 2048);
  knn2_kernel<<<2048, 256, 0, stream>>>(coords0, coords1, IDX, COSV);
  // annu1
  g64(FT,128,nullptr,0,0, nullptr,0,nullptr,0,0, nullptr,0,nullptr,0,0, nullptr,nullptr,
      DW_A1, nullptr, nullptr, BIG, R2, 128, 512, 0, nullptr, nullptr);
  combine_annu<<<R2/4, 256, 0, stream>>>(BIG, IDX, a1b1, ABUF, PART);
  statsD(ST_T, 128, 4, 512, 2048*3);
  g32(ABUF,384,ST_T,1,128, nullptr,0,nullptr,0,0, nullptr,0,nullptr,0,0, nullptr,nullptr,
      W_A1R, a1b2, nullptr, X1B, R2, 384, 128, 0, nullptr, PARTF);
  statsF(ST_X1B, 128, 4, 64, 2048);
  // f_ang (idx1 == idx2)
  cos_conv<<<R2/16, 256, 0, stream>>>(COSV, gw1, gb1, ABUF, PART);
  statsD(ST_T, 128, 4, 128, 2048*3);
  g32(ABUF,384,ST_T,1,128, nullptr,0,nullptr,0,0, nullptr,0,nullptr,0,0, nullptr,nullptr,
      W_G2R, gb2, nullptr, FANG, R2, 384, 128, 0, nullptr, PARTF);
  statsF(ST_FANG, 128, 4, 64, 2048);
  // annu2 (X1B raw, normed in staging)
  g64(X1B,128,ST_X1B,1,128, nullptr,0,nullptr,0,0, nullptr,0,nullptr,0,0, nullptr,nullptr,
      DW_A2, nullptr, nullptr, BIG, R2, 128, 512, 0, nullptr, nullptr);
  combine_annu<<<R2/4, 256, 0, stream>>>(BIG, IDX, a2b1, ABUF, PART);
  statsD(ST_T, 128, 4, 512, 2048*3);
  g32(ABUF,384,ST_T,1,128, nullptr,0,nullptr,0,0, nullptr,0,nullptr,0,0, nullptr,nullptr,
      W_A2R, a2b2, nullptr, X2B, R2, 384, 128, 0, nullptr, PARTF);
  statsF(ST_X2B, 128, 4, 64, 2048);
  // x3 = conv3 @ [x0 | n(x1)+n(fang) | n(x2)+n(fang)]
  g32(FT,128,nullptr,0,0, X1B,128,ST_X1B,1,128, X2B,128,ST_X2B,1,128, FANG,ST_FANG,
      conv3w, nullptr, nullptr, X3A, R2, 384, 128, 0, nullptr, PARTF);
  statsF(ST_X3A, 128, 4, 64, 2048);
  // x1o
  g64(FT,128,nullptr,0,0, nullptr,0,nullptr,0,0, nullptr,0,nullptr,0,0, nullptr,nullptr,
      DW_C1, nullptr, nullptr, BIG, R2, 128, 256, 0, nullptr, nullptr);
  gathermax(BIG, X1O, 128, ST_X1O);
  // x2o (X1O = raw max, normed lrelu in staging)
  g64(X1O,128,ST_X1O,2,128, nullptr,0,nullptr,0,0, nullptr,0,nullptr,0,0, nullptr,nullptr,
      DW_C2, nullptr, nullptr, BIG, R2, 128, 512, 0, nullptr, nullptr);
  gathermax(BIG, AB2, 256, ST_AB);
  // x3o = conv3o @ [x0 | n(x1o) | n(x2o)]
  g32(FT,128,nullptr,0,0, X1O,128,ST_X1O,2,128, AB2,256,ST_AB,2,256, nullptr,nullptr,
      conv3ow, nullptr, nullptr, X3O, R2, 512, 128, 0, nullptr, PARTF);
  statsF(ST_X3O, 128, 4, 64, 2048);
  norm_add2<<<(R2*128 + 255)/256, 256, 0, stream>>>(X3O, SA, ST_X3O, X3A, ST_X3A, R2*128);

  // ===== cross-attention props (rows 4096 each) =====
  float* SA0 = SA;
  float* SA1 = SA + (size_t)4096*128;
  auto prop = [&](const float* xin, const float* src, float* dst) {
    g32(xin,128,nullptr,0,0, nullptr,0,nullptr,0,0, nullptr,0,nullptr,0,0, nullptr,nullptr,
        wq, bq, nullptr, X1B, 4096, 128, 128, 1, nullptr, nullptr);                  // packed Q
    g32(src,128,nullptr,0,0, nullptr,0,nullptr,0,0, nullptr,0,nullptr,0,0, nullptr,nullptr,
        W_KV, B_KV, nullptr, X2B, 4096, 128, 256, 2, X3A, nullptr);                  // packed K + V
    attn_part<<<dim3(64, 4, 8), 256, 0, stream>>>(X1B, X2B, X3A, OP, ML);
    attn_merge<<<(8*2048*16 + 255)/256, 256, 0, stream>>>(OP, ML, FANG);
    g32(FANG,128,nullptr,0,0, nullptr,0,nullptr,0,0, nullptr,0,nullptr,0,0, nullptr,nullptr,
        wm, bm, nullptr, X1O, 4096, 128, 128, 0, nullptr, nullptr);
    g32(xin,128,nullptr,0,0, X1O,128,nullptr,0,0, nullptr,0,nullptr,0,0, nullptr,nullptr,
        mw1, mb1, nullptr, ABUF, 4096, 256, 256, 0, nullptr, PARTF);
    statsF(ST_T, 256, 2, 64, 2048);
    g32(ABUF,256,ST_T,1,256, nullptr,0,nullptr,0,0, nullptr,0,nullptr,0,0, nullptr,nullptr,
        mw2, mb2, xin, dst, 4096, 256, 128, 0, nullptr, nullptr);
  };

  prop(SA0, SA1, XF0);
  prop(SA1, XF0, XF1);

  transpose_k<<<dim3(128/32, 2048/32, 2), dim3(32, 8), 0, stream>>>(XF0, (float*)d_out, 2048, 128);
  transpose_k<<<dim3(128/32, 2048/32, 2), dim3(32, 8), 0, stream>>>(XF1, (float*)d_out + (size_t)4096*128, 2048, 128);
}

// Round 14
// 520.804 us; speedup vs baseline: 8.6849x; 1.3221x over previous
//
#include <hip/hip_runtime.h>
#include <cfloat>
#include <math.h>

#define NPTS 2048
#define R2   8192   // merged: 2 tensors x B=2 x N=2048
#define SPLITK 8

typedef __attribute__((ext_vector_type(8))) short bfrag;
typedef __attribute__((ext_vector_type(4))) float f32x4;

__device__ inline ushort f2bf(float f) {
  unsigned u = __float_as_uint(f);
  return (ushort)((u + 0x7fffu + ((u >> 16) & 1u)) >> 16);
}

// ---------------- prep: derived weight matrices ----------------
__global__ __launch_bounds__(256) void prep_weights(
    const float* __restrict__ conv1, const float* __restrict__ conv2,
    const float* __restrict__ a1w1, const float* __restrict__ a1w2,
    const float* __restrict__ a2w1, const float* __restrict__ a2w2,
    const float* __restrict__ gw2,
    const float* __restrict__ wk, const float* __restrict__ bk,
    const float* __restrict__ wv, const float* __restrict__ bv,
    float* __restrict__ dwA1, float* __restrict__ a1w2r,
    float* __restrict__ dwA2, float* __restrict__ a2w2r,
    float* __restrict__ gw2r, float* __restrict__ dwC1, float* __restrict__ dwC2,
    float* __restrict__ wkv, float* __restrict__ bkv)
{
  int i = blockIdx.x * 256 + threadIdx.x;
  if (i < 512*128) {
    int row = i >> 7, c = i & 127;
    float v1, v2;
    if (row < 128) {             // ctrW[o][c] = sum_t (w1[o,c,t] - w1[o,128+c,t])
      float s1 = 0.f, s2 = 0.f;
      for (int t = 0; t < 3; t++) {
        s1 += a1w1[(row*256 + c)*3 + t] - a1w1[(row*256 + 128 + c)*3 + t];
        s2 += a2w1[(row*256 + c)*3 + t] - a2w1[(row*256 + 128 + c)*3 + t];
      }
      v1 = s1; v2 = s2;
    } else {                     // row = 128 + t*128 + o : nbW_t[o][c] = w1[o,128+c,t]
      int t = (row - 128) >> 7, o = row & 127;
      v1 = a1w1[(o*256 + 128 + c)*3 + t];
      v2 = a2w1[(o*256 + 128 + c)*3 + t];
    }
    dwA1[i] = v1; dwA2[i] = v2;
    dwC2[i] = (row < 256) ? (conv2[row*256 + c] - conv2[row*256 + 128 + c])
                          : conv2[(row-256)*256 + 128 + c];
  }
  if (i < 128*384) {             // w2r[o][w*128+c] = w2[o,c,w]
    int o = i / 384, rem = i % 384, w = rem >> 7, c = rem & 127;
    a1w2r[i] = a1w2[(o*128 + c)*3 + w];
    a2w2r[i] = a2w2[(o*128 + c)*3 + w];
    gw2r[i]  = gw2[(o*128 + c)*3 + w];
  }
  if (i < 256*128) {             // dwC1 [256][128] from conv1 [128][256]
    int row = i >> 7, c = i & 127;
    dwC1[i] = (row < 128) ? (conv1[row*256 + c] - conv1[row*256 + 128 + c])
                          : conv1[(row-128)*256 + 128 + c];
    wkv[i] = (row < 128) ? wk[row*128 + c] : wv[(row-128)*128 + c];
  }
  if (i < 256) bkv[i] = (i < 128) ? bk[i] : bv[i - 128];
}

// ---------------- transpose both descs: in [2][I][J] x2 -> out [4][J][I] ----------------
__global__ void transpose2(const float* __restrict__ in0, const float* __restrict__ in1,
                           float* __restrict__ out, int I, int J) {
  __shared__ float tile[32][33];
  int zb = blockIdx.z;
  const float* src = (zb < 2) ? (in0 + (size_t)zb*I*J) : (in1 + (size_t)(zb-2)*I*J);
  float* dst = out + (size_t)zb*J*I;
  int i0 = blockIdx.y * 32, j0 = blockIdx.x * 32;
  int tx = threadIdx.x, ty = threadIdx.y;
  for (int s = 0; s < 32; s += 8)
    tile[ty + s][tx] = src[(size_t)(i0 + ty + s)*J + (j0 + tx)];
  __syncthreads();
  for (int s = 0; s < 32; s += 8)
    dst[(size_t)(j0 + ty + s)*I + (i0 + tx)] = tile[tx][ty + s];
}

// ---------------- transpose [b][I][J] -> [b][J][I] (final output) ----------------
__global__ void transpose_k(const float* __restrict__ in, float* __restrict__ out, int I, int J) {
  __shared__ float tile[32][33];
  int b = blockIdx.z;
  int i0 = blockIdx.y * 32, j0 = blockIdx.x * 32;
  int tx = threadIdx.x, ty = threadIdx.y;
  for (int s = 0; s < 32; s += 8)
    tile[ty + s][tx] = in[((size_t)b*I + (i0 + ty + s))*J + (j0 + tx)];
  __syncthreads();
  for (int s = 0; s < 32; s += 8)
    out[((size_t)b*J + (j0 + ty + s))*I + (i0 + tx)] = tile[tx][ty + s];
}

// ---------------- KNN (both coord sets): f32 np-exact distances, (dist,idx)-lex ----------------
__global__ __launch_bounds__(256) void knn2_kernel(const float* __restrict__ P0, const float* __restrict__ P1,
                                                   int* __restrict__ idx, float* __restrict__ cosv) {
  __shared__ float px[NPTS], py[NPTS], sq[NPTS];
  int tid = threadIdx.x;
  int gw = blockIdx.x * 4 + (tid >> 6);   // 0..8191 : global point id
  int b4 = gw >> 11, n = gw & 2047;
  int lane = tid & 63;
  const float* Pb = (b4 < 2) ? (P0 + (size_t)b4 * 2 * NPTS) : (P1 + (size_t)(b4 - 2) * 2 * NPTS);
  for (int i = tid; i < NPTS; i += 256) {
    float x = Pb[i], y = Pb[NPTS + i];
    px[i] = x; py[i] = y;
    sq[i] = __fadd_rn(__fmul_rn(x, x), __fmul_rn(y, y));
  }
  __syncthreads();
  float xn = px[n], yn = py[n], sqn = sq[n];
  float d[10]; int id_[10];
#pragma unroll
  for (int j = 0; j < 10; j++) { d[j] = FLT_MAX; id_[j] = 0x7fffffff; }
  for (int m = lane; m < NPTS; m += 64) {
    float dot  = __fadd_rn(__fmul_rn(xn, px[m]), __fmul_rn(yn, py[m]));
    float dist = __fsub_rn(__fadd_rn(sqn, sq[m]), __fmul_rn(2.0f, dot));
    dist = fmaxf(dist, 1e-12f);
    if (dist < d[9] || (dist == d[9] && m < id_[9])) {
      int p = 0;
#pragma unroll
      for (int j = 0; j < 10; j++) p += (d[j] < dist || (d[j] == dist && id_[j] < m)) ? 1 : 0;
#pragma unroll
      for (int j = 9; j >= 1; j--) if (j > p) { d[j] = d[j-1]; id_[j] = id_[j-1]; }
#pragma unroll
      for (int j = 0; j < 10; j++) if (j == p) { d[j] = dist; id_[j] = m; }
    }
  }
  int ptr = 0;
  for (int r = 0; r < 10; r++) {
    float bd = FLT_MAX; int bi = 0x7fffffff;
#pragma unroll
    for (int j = 0; j < 10; j++) if (j == ptr) { bd = d[j]; bi = id_[j]; }
    for (int off = 32; off >= 1; off >>= 1) {
      float od = __shfl_xor(bd, off);
      int   oi = __shfl_xor(bi, off);
      if (od < bd || (od == bd && oi < bi)) { bd = od; bi = oi; }
    }
    bool adv = false;
#pragma unroll
    for (int j = 0; j < 10; j++) if (j == ptr) adv = (d[j] == bd && id_[j] == bi);
    if (adv) ptr++;
    if (r > 0 && lane == 0) {
      size_t base = (size_t)gw*9 + (r - 1);
      idx[base] = bi;
      float dot = __fadd_rn(__fmul_rn(xn, px[bi]), __fmul_rn(yn, py[bi]));
      cosv[base] = __fdiv_rn(dot, __fmul_rn(__fsqrt_rn(sqn), __fsqrt_rn(sq[bi])));
    }
  }
}

// ---------------- unified bf16-MFMA GEMM: template BM, per-segment norm-act, fused stats --------
template<int BM>
__global__ __launch_bounds__(256) void gemm_m(
    const float* __restrict__ p0, int w0, const float* __restrict__ st0, int a0, int xm0,
    const float* __restrict__ p1, int w1, const float* __restrict__ st1, int a1, int xm1,
    const float* __restrict__ p2, int w2, const float* __restrict__ st2, int a2, int xm2,
    const float* __restrict__ addp, const float* __restrict__ addst,
    const float* __restrict__ W, const float* __restrict__ bias,
    const float* __restrict__ resid,
    float* __restrict__ Y, int Cin, int O, int pack, float* __restrict__ Y2,
    float* __restrict__ part)
{
  __shared__ ushort Xs[BM][40];   // bf16, 80B row stride (16B-aligned frag reads)
  __shared__ ushort Ws[64][40];
  constexpr int RT = BM / 16;     // 16-row tiles per block
  constexpr int XF = BM / 8;      // X elems per thread per K-chunk
  int tid = threadIdx.x;
  int wv = tid >> 6, l = tid & 63;
  int m16 = l & 15, kq = l >> 4;         // fragment coords
  int r0 = blockIdx.x * BM, c0 = blockIdx.y * 64;
  int sxr = tid & (BM - 1), sxc = (tid / BM) * XF;
  int swr = tid & 63, swc = (tid >> 6) * 8;
  f32x4 acc[RT];
#pragma unroll
  for (int t = 0; t < RT; t++) acc[t] = (f32x4){0.f, 0.f, 0.f, 0.f};
  for (int k0 = 0; k0 < Cin; k0 += 32) {
    // ---- stage X (f32 -> norm/act/add -> bf16) ----
    {
      int r = r0 + sxr;
      int ac = k0 + sxc;
      const float* P; const float* st; int cc, lw, act, xm;
      if (ac < w0)            { P = p0; cc = ac;          lw = w0; st = st0; act = a0; xm = xm0; }
      else if (ac < w0 + w1)  { P = p1; cc = ac - w0;     lw = w1; st = st1; act = a1; xm = xm1; }
      else                    { P = p2; cc = ac - w0 - w1; lw = w2; st = st2; act = a2; xm = xm2; }
      float vv[XF];
#pragma unroll
      for (int q = 0; q < XF; q += 4)
        *(float4*)&vv[q] = *(const float4*)(P + (size_t)r*lw + cc + q);
      int b = r >> 11;
      if (st) {
#pragma unroll
        for (int j = 0; j < XF; j++) {
          int o = (cc + j) & (xm - 1);
          float m = st[(b*xm + o)*2], rs = st[(b*xm + o)*2 + 1];
          float v = (vv[j] - m) * rs;
          vv[j] = (act == 1) ? fmaxf(v, 0.f) : ((v >= 0.f) ? v : 0.2f*v);
        }
      }
      if (addp && ac >= 128) {
        int fc = (ac - 128) & 127;
        float av[XF];
#pragma unroll
        for (int q = 0; q < XF; q += 4)
          *(float4*)&av[q] = *(const float4*)(addp + (size_t)r*128 + fc + q);
        if (addst) {
#pragma unroll
          for (int j = 0; j < XF; j++) {
            int o = (fc + j) & 127;
            float m = addst[(b*128 + o)*2], rs = addst[(b*128 + o)*2 + 1];
            av[j] = fmaxf((av[j] - m) * rs, 0.f);
          }
        }
#pragma unroll
        for (int j = 0; j < XF; j++) vv[j] += av[j];
      }
      union { ushort u[XF]; ushort4 v4[XF/4]; } pk;
#pragma unroll
      for (int j = 0; j < XF; j++) pk.u[j] = f2bf(vv[j]);
#pragma unroll
      for (int q = 0; q < XF/4; q++) *(ushort4*)&Xs[sxr][sxc + q*4] = pk.v4[q];
    }
    // ---- stage W (f32 -> bf16) ----
    {
      const float* s = W + (size_t)(c0 + swr)*Cin + k0 + swc;
      float4 v0 = *(const float4*)s, v1 = *(const float4*)(s + 4);
      union { ushort u[8]; ushort4 v4[2]; } pk;
      pk.u[0]=f2bf(v0.x); pk.u[1]=f2bf(v0.y); pk.u[2]=f2bf(v0.z); pk.u[3]=f2bf(v0.w);
      pk.u[4]=f2bf(v1.x); pk.u[5]=f2bf(v1.y); pk.u[6]=f2bf(v1.z); pk.u[7]=f2bf(v1.w);
      *(ushort4*)&Ws[swr][swc]     = pk.v4[0];
      *(ushort4*)&Ws[swr][swc + 4] = pk.v4[1];
    }
    __syncthreads();
    bfrag bf = *(const bfrag*)&Ws[wv*16 + m16][kq*8];
#pragma unroll
    for (int t = 0; t < RT; t++) {
      bfrag af = *(const bfrag*)&Xs[t*16 + m16][kq*8];
      acc[t] = __builtin_amdgcn_mfma_f32_16x16x32_bf16(af, bf, acc[t], 0, 0, 0);
    }
    __syncthreads();
  }
  // ---- epilogue: bias / resid / pack / write / fused per-column stats ----
  int c = c0 + wv*16 + m16;
  float bi = bias ? bias[c] : 0.f;
  float ps = 0.f, ps2 = 0.f;
#pragma unroll
  for (int t = 0; t < RT; t++) {
#pragma unroll
    for (int i = 0; i < 4; i++) {
      int r = r0 + t*16 + kq*4 + i;
      float v = acc[t][i] + bi;
      if (resid) v += resid[(size_t)r*O + c];
      if (pack) {
        int cc2 = c & 127;
        int h = cc2 & 3, dd = cc2 >> 2, b = r >> 11, n = r & 2047;
        float* T = (pack == 1 || c < 128) ? Y : Y2;
        T[(((size_t)(b*4 + h))*NPTS + n)*32 + dd] = v;
      } else {
        Y[(size_t)r*O + c] = v;
      }
      ps += v; ps2 = fmaf(v, v, ps2);
    }
  }
  if (part) {
    ps  += __shfl_xor(ps, 16);  ps  += __shfl_xor(ps, 32);
    ps2 += __shfl_xor(ps2, 16); ps2 += __shfl_xor(ps2, 32);
    if (kq == 0) {
      part[((size_t)blockIdx.x*O + c)*2]     = ps;
      part[((size_t)blockIdx.x*O + c)*2 + 1] = ps2;
    }
  }
}

// ---------------- annu conv1 combine: 4 rows/block + fused f64 stats partials ----------------
__global__ __launch_bounds__(256) void combine_annu(const float* __restrict__ GA, const int* __restrict__ idx,
                                                    const float* __restrict__ b1, float* __restrict__ A,
                                                    double* __restrict__ part) {
  int t = threadIdx.x;
  int o = t & 127, sub = t >> 7;
  int r0 = blockIdx.x * 4;
  __shared__ int nbs[4][9];
  if (t < 36) nbs[t / 9][t % 9] = idx[(size_t)(r0 + t/9)*9 + (t % 9)];
  __syncthreads();
  float bo = b1[o];
  double s = 0.0, s2 = 0.0;
  for (int rr = sub; rr < 4; rr += 2) {
    int r = r0 + rr, rb = r & ~2047;
    float ctr = GA[(size_t)r*512 + o] + bo;
#pragma unroll
    for (int w = 0; w < 3; w++) {
      float acc = ctr;
#pragma unroll
      for (int t3 = 0; t3 < 3; t3++) {
        int m = nbs[rr][w*3 + t3];
        acc += GA[(size_t)(rb + m)*512 + 128 + t3*128 + o];
      }
      A[(size_t)r*384 + w*128 + o] = acc;
      s += (double)acc; s2 += (double)acc * (double)acc;
    }
  }
  __shared__ double ls[256], ls2[256];
  ls[t] = s; ls2[t] = s2;
  __syncthreads();
  if (sub == 0) {
    s += ls[128 + o]; s2 += ls2[128 + o];
    part[((size_t)blockIdx.x*128 + o)*2] = s;
    part[((size_t)blockIdx.x*128 + o)*2 + 1] = s2;
  }
}

// ---------------- angle-feature conv1: 16 rows/block + fused f64 stats ----------------
__global__ __launch_bounds__(256) void cos_conv(const float* __restrict__ cosv, const float* __restrict__ gw1,
                                                const float* __restrict__ gb1, float* __restrict__ ANG,
                                                double* __restrict__ part) {
  int t = threadIdx.x;
  int o = t & 127, sub = t >> 7;
  int r0 = blockIdx.x * 16;
  float g0 = gw1[o*3], g1 = gw1[o*3+1], g2 = gw1[o*3+2], gb = gb1[o];
  __shared__ float cs[16][12];
  for (int i = t; i < 16*9; i += 256) cs[i / 9][i % 9] = cosv[(size_t)(r0 + i/9)*9 + (i % 9)];
  __syncthreads();
  double s = 0.0, s2 = 0.0;
  for (int rr = sub; rr < 16; rr += 2) {
    int r = r0 + rr;
#pragma unroll
    for (int w = 0; w < 3; w++) {
      float acc = gb;
      acc += cs[rr][w*3+0]*g0;
      acc += cs[rr][w*3+1]*g1;
      acc += cs[rr][w*3+2]*g2;
      ANG[(size_t)r*384 + w*128 + o] = acc;
      s += (double)acc; s2 += (double)acc * (double)acc;
    }
  }
  __shared__ double ls[256], ls2[256];
  ls[t] = s; ls2[t] = s2;
  __syncthreads();
  if (sub == 0) {
    s += ls[128 + o]; s2 += ls2[128 + o];
    part[((size_t)blockIdx.x*128 + o)*2] = s;
    part[((size_t)blockIdx.x*128 + o)*2 + 1] = s2;
  }
}

// ---------------- parallel stats final (f64 partials) ----------------
__global__ __launch_bounds__(256) void gm_final(const double* __restrict__ part, float* __restrict__ stats,
                                                int Cc, int NB, int nblk, int count) {
  int g = blockIdx.x * 8 + (threadIdx.x >> 5);
  int lane = threadIdx.x & 31;
  if (g >= NB*Cc) return;
  int b = g / Cc, o = g % Cc;
  double S = 0.0, S2 = 0.0;
  for (int u = lane; u < nblk; u += 32) {
    size_t blk = (size_t)(b*nblk + u);
    S  += part[(blk*Cc + o)*2];
    S2 += part[(blk*Cc + o)*2 + 1];
  }
  for (int off = 16; off >= 1; off >>= 1) {
    S  += __shfl_down(S, off, 32);
    S2 += __shfl_down(S2, off, 32);
  }
  if (lane == 0) {
    double mean = S / count;
    double var = S2 / count - mean*mean;
    if (var < 0.0) var = 0.0;
    stats[g*2] = (float)mean;
    stats[g*2 + 1] = (float)(1.0 / sqrt(var + 1e-5));
  }
}

// ---------------- parallel stats final (f32 partials, f64 accumulate) ----------------
__global__ __launch_bounds__(256) void gm_final_f(const float* __restrict__ part, float* __restrict__ stats,
                                                  int Cc, int NB, int nblk, int count) {
  int g = blockIdx.x * 8 + (threadIdx.x >> 5);
  int lane = threadIdx.x & 31;
  if (g >= NB*Cc) return;
  int b = g / Cc, o = g % Cc;
  double S = 0.0, S2 = 0.0;
  for (int u = lane; u < nblk; u += 32) {
    size_t blk = (size_t)(b*nblk + u);
    S  += (double)part[(blk*Cc + o)*2];
    S2 += (double)part[(blk*Cc + o)*2 + 1];
  }
  for (int off = 16; off >= 1; off >>= 1) {
    S  += __shfl_down(S, off, 32);
    S2 += __shfl_down(S2, off, 32);
  }
  if (lane == 0) {
    double mean = S / count;
    double var = S2 / count - mean*mean;
    if (var < 0.0) var = 0.0;
    stats[g*2] = (float)mean;
    stats[g*2 + 1] = (float)(1.0 / sqrt(var + 1e-5));
  }
}

// ---------------- gather + max over k + f64 partials (4 rows/block, idx in LDS) ----------------
__global__ __launch_bounds__(256) void gather_max_partial(const float* __restrict__ G, const int* __restrict__ idx,
                                                          float* __restrict__ maxbuf, double* __restrict__ part,
                                                          int Cc) {
  int t = threadIdx.x;
  int o = t % Cc, sub = t / Cc, nsub = 256 / Cc;
  int r0 = blockIdx.x * 4;
  __shared__ int nbs[4][9];
  if (t < 36) nbs[t / 9][t % 9] = idx[(size_t)(r0 + t/9)*9 + (t % 9)];
  __syncthreads();
  double s = 0.0, s2 = 0.0;
  for (int rr = sub; rr < 4; rr += nsub) {
    int r = r0 + rr, rb = r & ~2047;
    float g = G[(size_t)r*2*Cc + o];
    float mx = -3.4e38f;
#pragma unroll
    for (int k = 0; k < 9; k++) {
      int m = nbs[rr][k];
      float v = g + G[(size_t)(rb + m)*2*Cc + Cc + o];
      mx = fmaxf(mx, v); s += (double)v; s2 += (double)v*(double)v;
    }
    maxbuf[(size_t)r*Cc + o] = mx;
  }
  if (nsub == 2) {
    __shared__ double ls[256], ls2[256];
    ls[t] = s; ls2[t] = s2;
    __syncthreads();
    if (sub == 0) { s += ls[Cc + o]; s2 += ls2[Cc + o]; }
  }
  if (sub == 0) {
    part[((size_t)blockIdx.x*Cc + o)*2] = s;
    part[((size_t)blockIdx.x*Cc + o)*2 + 1] = s2;
  }
}

// ---------------- final: SA = lrelu(inorm(X3O)) + lrelu(inorm(X3A)) ----------------
__global__ void norm_add2(const float* __restrict__ src, float* __restrict__ dst,
                          const float* __restrict__ stats,
                          const float* __restrict__ addend, const float* __restrict__ astats,
                          int total) {
  int i = blockIdx.x * 256 + threadIdx.x;
  if (i >= total) return;
  int o = i & 127;
  int b = i >> 18;
  float m = stats[(b*128 + o)*2], rs = stats[(b*128 + o)*2 + 1];
  float v = (src[i] - m) * rs;
  v = (v >= 0.f) ? v : 0.2f*v;
  float ma = astats[(b*128 + o)*2], rsa = astats[(b*128 + o)*2 + 1];
  float a = (addend[i] - ma) * rsa;
  a = (a >= 0.f) ? a : 0.2f*a;
  dst[i] = v + a;
}

// ---------------- MFMA flash attention: 64 q-rows/block, split-K 8 (256 keys/part) ----------------
// wave wv owns q-row-tile 16*wv; per 64-key tile: 4 QK MFMA + 4 PV MFMA, intra-wave softmax.
__global__ __launch_bounds__(256) void attn_part(const float* __restrict__ Qp, const float* __restrict__ Kp,
                                                 const float* __restrict__ Vp,
                                                 float* __restrict__ OP, float* __restrict__ ML) {
  __shared__ ushort Ks[64][40];   // K rows [key][dim], bf16
  __shared__ ushort Vt[32][72];   // V transposed [dim][key], bf16
  __shared__ ushort Pb[64][72];   // P rows [q-row][key 0..63], bf16 (front doubles as Q staging)
  int tid = threadIdx.x;
  int wv = tid >> 6, l = tid & 63;
  int d = l & 15, g = l >> 4;
  int kp = blockIdx.y, bh = blockIdx.z;
  int q0 = blockIdx.x * 64;
  const float* Qh = Qp + (size_t)bh * NPTS * 32;
  const float* Kh = Kp + (size_t)bh * NPTS * 32;
  const float* Vh = Vp + (size_t)bh * NPTS * 32;
  // stage Q (64 rows x 32 dims) into Pb
  {
    int r = tid >> 2, c8 = (tid & 3) * 8;
    const float* q = Qh + (size_t)(q0 + r)*32 + c8;
    float4 v0 = *(const float4*)q, v1 = *(const float4*)(q + 4);
    union { ushort u[8]; ushort4 v4[2]; } pk;
    pk.u[0]=f2bf(v0.x); pk.u[1]=f2bf(v0.y); pk.u[2]=f2bf(v0.z); pk.u[3]=f2bf(v0.w);
    pk.u[4]=f2bf(v1.x); pk.u[5]=f2bf(v1.y); pk.u[6]=f2bf(v1.z); pk.u[7]=f2bf(v1.w);
    *(ushort4*)&Pb[r][c8]     = pk.v4[0];
    *(ushort4*)&Pb[r][c8 + 4] = pk.v4[1];
  }
  __syncthreads();
  bfrag qf = *(const bfrag*)&Pb[wv*16 + d][g*8];
  f32x4 Oc[2];
  Oc[0] = (f32x4){0.f,0.f,0.f,0.f}; Oc[1] = (f32x4){0.f,0.f,0.f,0.f};
  float m_[4] = {-FLT_MAX, -FLT_MAX, -FLT_MAX, -FLT_MAX};
  float l_[4] = {0.f, 0.f, 0.f, 0.f};
  const float sc = 0.17677669529663687f;   // 1/sqrt(32)
  int ks0 = kp * (NPTS / SPLITK);
  for (int k0 = ks0; k0 < ks0 + NPTS/SPLITK; k0 += 64) {
    __syncthreads();   // prior tile's Ks/Vt readers done (iter0: Q reg-loads done)
    {
      int r = tid >> 2, c8 = (tid & 3) * 8;
      const float* kr = Kh + (size_t)(k0 + r)*32 + c8;
      float4 a0 = *(const float4*)kr, a1 = *(const float4*)(kr + 4);
      union { ushort u[8]; ushort4 v4[2]; } pk;
      pk.u[0]=f2bf(a0.x); pk.u[1]=f2bf(a0.y); pk.u[2]=f2bf(a0.z); pk.u[3]=f2bf(a0.w);
      pk.u[4]=f2bf(a1.x); pk.u[5]=f2bf(a1.y); pk.u[6]=f2bf(a1.z); pk.u[7]=f2bf(a1.w);
      *(ushort4*)&Ks[r][c8]     = pk.v4[0];
      *(ushort4*)&Ks[r][c8 + 4] = pk.v4[1];
      int vr = tid & 63, vd = (tid >> 6) * 8;
      const float* vp = Vh + (size_t)(k0 + vr)*32 + vd;
      float4 b0 = *(const float4*)vp, b1 = *(const float4*)(vp + 4);
      Vt[vd+0][vr] = f2bf(b0.x); Vt[vd+1][vr] = f2bf(b0.y);
      Vt[vd+2][vr] = f2bf(b0.z); Vt[vd+3][vr] = f2bf(b0.w);
      Vt[vd+4][vr] = f2bf(b1.x); Vt[vd+5][vr] = f2bf(b1.y);
      Vt[vd+6][vr] = f2bf(b1.z); Vt[vd+7][vr] = f2bf(b1.w);
    }
    __syncthreads();
    // QK^T: S[c][i] = scores for row (16wv + 4g + i), key (16c + d)
    f32x4 S[4];
#pragma unroll
    for (int c = 0; c < 4; c++) {
      S[c] = (f32x4){0.f,0.f,0.f,0.f};
      bfrag kf = *(const bfrag*)&Ks[c*16 + d][g*8];
      S[c] = __builtin_amdgcn_mfma_f32_16x16x32_bf16(qf, kf, S[c], 0, 0, 0);
    }
    float cf[4];
#pragma unroll
    for (int i = 0; i < 4; i++) {
      float tm = fmaxf(fmaxf(S[0][i], S[1][i]), fmaxf(S[2][i], S[3][i])) * sc;
      for (int off = 1; off < 16; off <<= 1) tm = fmaxf(tm, __shfl_xor(tm, off));
      float mn = fmaxf(m_[i], tm);
      cf[i] = __expf(m_[i] - mn);
      m_[i] = mn;
    }
    float rs[4] = {0.f, 0.f, 0.f, 0.f};
    ushort pu[4][4];
#pragma unroll
    for (int c = 0; c < 4; c++)
#pragma unroll
      for (int i = 0; i < 4; i++) {
        float p = __expf(fmaf(S[c][i], sc, -m_[i]));
        rs[i] += p;
        pu[c][i] = f2bf(p);
      }
#pragma unroll
    for (int i = 0; i < 4; i++) {
      float r2 = rs[i];
      for (int off = 1; off < 16; off <<= 1) r2 += __shfl_xor(r2, off);
      l_[i] = l_[i]*cf[i] + r2;
      Oc[0][i] *= cf[i]; Oc[1][i] *= cf[i];
    }
    // write P (wave-private rows; wave-ordered write->read, no barrier)
#pragma unroll
    for (int c = 0; c < 4; c++)
#pragma unroll
      for (int i = 0; i < 4; i++)
        Pb[wv*16 + g*4 + i][c*16 + d] = pu[c][i];
    // PV
#pragma unroll
    for (int s5 = 0; s5 < 2; s5++) {
      bfrag pf = *(const bfrag*)&Pb[wv*16 + d][g*8 + 32*s5];
#pragma unroll
      for (int td = 0; td < 2; td++) {
        union { ushort4 v4[2]; bfrag f; } vu;
        vu.v4[0] = *(const ushort4*)&Vt[td*16 + d][g*8 + 32*s5];
        vu.v4[1] = *(const ushort4*)&Vt[td*16 + d][g*8 + 32*s5 + 4];
        Oc[td] = __builtin_amdgcn_mfma_f32_16x16x32_bf16(pf, vu.f, Oc[td], 0, 0, 0);
      }
    }
  }
  size_t pb = (size_t)(kp*8 + bh) * NPTS;
#pragma unroll
  for (int i = 0; i < 4; i++) {
    int n = q0 + wv*16 + g*4 + i;
    OP[(pb + n)*32 + d]      = Oc[0][i];
    OP[(pb + n)*32 + 16 + d] = Oc[1][i];
    if (d == 0) { ML[(pb + n)*2] = m_[i]; ML[(pb + n)*2 + 1] = l_[i]; }
  }
}

// ---------------- merge the eight K-slices ----------------
__global__ void attn_merge(const float* __restrict__ OP, const float* __restrict__ ML,
                           float* __restrict__ out) {
  int i = blockIdx.x * 256 + threadIdx.x;   // 8*2048*16
  if (i >= 8*2048*16) return;
  int dp = (i & 15) * 2;
  int n  = (i >> 4) & 2047;
  int bh = i >> 15;
  float mv[SPLITK], lv[SPLITK];
  float mm = -FLT_MAX;
#pragma unroll
  for (int p = 0; p < SPLITK; p++) {
    size_t pp = ((size_t)(p*8 + bh) * NPTS + n);
    mv[p] = ML[pp*2]; lv[p] = ML[pp*2 + 1];
    mm = fmaxf(mm, mv[p]);
  }
  float L = 0.f, ox = 0.f, oy = 0.f;
#pragma unroll
  for (int p = 0; p < SPLITK; p++) {
    size_t pp = ((size_t)(p*8 + bh) * NPTS + n);
    float w = __expf(mv[p] - mm);
    L += w * lv[p];
    float2 o = *(const float2*)&OP[pp*32 + dp];
    ox += w * o.x; oy += w * o.y;
  }
  float inv = 1.f / L;
  int b = bh >> 2, h = bh & 3;
  out[((size_t)(b*NPTS + n))*128 + (dp+0)*4 + h] = ox * inv;
  out[((size_t)(b*NPTS + n))*128 + (dp+1)*4 + h] = oy * inv;
}

// ================= host =================
extern "C" void kernel_launch(void* const* d_in, const int* in_sizes, int n_in,
                              void* d_out, int out_size, void* d_ws, size_t ws_size,
                              hipStream_t stream) {
  (void)in_sizes; (void)n_in; (void)out_size; (void)ws_size;
  const float* desc0  = (const float*)d_in[0];
  const float* desc1  = (const float*)d_in[1];
  const float* coords0= (const float*)d_in[2];
  const float* coords1= (const float*)d_in[3];
  const float* conv1w = (const float*)d_in[4];
  const float* conv2w = (const float*)d_in[5];
  const float* conv3w = (const float*)d_in[6];
  const float* conv3ow= (const float*)d_in[7];
  const float* a1w1 = (const float*)d_in[8];
  const float* a1b1 = (const float*)d_in[9];
  const float* a1w2 = (const float*)d_in[10];
  const float* a1b2 = (const float*)d_in[11];
  const float* a2w1 = (const float*)d_in[12];
  const float* a2b1 = (const float*)d_in[13];
  const float* a2w2 = (const float*)d_in[14];
  const float* a2b2 = (const float*)d_in[15];
  const float* gw1  = (const float*)d_in[16];
  const float* gb1  = (const float*)d_in[17];
  const float* gw2  = (const float*)d_in[18];
  const float* gb2  = (const float*)d_in[19];
  const float* wq = (const float*)d_in[20]; const float* bq = (const float*)d_in[21];
  const float* wk = (const float*)d_in[22]; const float* bk = (const float*)d_in[23];
  const float* wv = (const float*)d_in[24]; const float* bv = (const float*)d_in[25];
  const float* wm = (const float*)d_in[26]; const float* bm = (const float*)d_in[27];
  const float* mw1 = (const float*)d_in[28]; const float* mb1 = (const float*)d_in[29];
  const float* mw2 = (const float*)d_in[30]; const float* mb2 = (const float*)d_in[31];

  float* ws = (float*)d_ws;
  size_t off = 0;
  auto alloc = [&](size_t nel) { size_t r = off; off += (nel + 63) & ~(size_t)63; return r; };
  float* DW_A1 = ws + alloc(512*128);
  float* W_A1R = ws + alloc(128*384);
  float* DW_A2 = ws + alloc(512*128);
  float* W_A2R = ws + alloc(128*384);
  float* W_G2R = ws + alloc(128*384);
  float* DW_C1 = ws + alloc(256*128);
  float* DW_C2 = ws + alloc(512*128);
  float* W_KV  = ws + alloc(256*128);
  float* B_KV  = ws + alloc(256);
  float* SA   = ws + alloc((size_t)R2*128);
  float* XF0  = ws + alloc((size_t)4096*128);
  float* XF1  = ws + alloc((size_t)4096*128);
  int*   IDX  = (int*)(ws + alloc((size_t)R2*9));
  float* COSV = ws + alloc((size_t)R2*9);
  float* FT   = ws + alloc((size_t)R2*128);
  float* BIG  = ws + alloc((size_t)R2*512);
  float* ABUF = ws + alloc((size_t)R2*384);
  float* X1B  = ws + alloc((size_t)R2*128);
  float* FANG = ws + alloc((size_t)R2*128);
  float* X2B  = ws + alloc((size_t)R2*128);
  float* X3A  = ws + alloc((size_t)R2*128);
  float* X1O  = ws + alloc((size_t)R2*128);
  float* AB2  = ws + alloc((size_t)R2*256);
  float* X3O  = ws + alloc((size_t)R2*128);
  double* PART = (double*)(ws + alloc((size_t)2048*256*2*2));   // 1M doubles (8 MB)
  float*  PARTF = (float*)PART;                                  // aliased f32 partials
  float* STATS = ws + alloc(8*2048);
  float* MLB  = ws + alloc((size_t)SPLITK*8*NPTS*2);            // attn m/l partials
  float* ST_T   = STATS;
  float* ST_X1B = STATS + 2048;
  float* ST_FANG= STATS + 4096;
  float* ST_X2B = STATS + 6144;
  float* ST_X3A = STATS + 8192;
  float* ST_X1O = STATS + 10240;
  float* ST_AB  = STATS + 12288;
  float* ST_X3O = STATS + 14336;
  float* OP  = BIG;    // attn O partials: SPLITK*8*2048*32 = R2*512 floats exactly

  auto g64 = [&](const float* p0,int w0,const float* st0,int a0,int x0,
                 const float* p1,int w1,const float* st1,int a1,int x1,
                 const float* p2,int w2,const float* st2,int a2,int x2,
                 const float* addp,const float* addst,
                 const float* W,const float* bias,const float* resid,
                 float* Y,int R,int Cin,int O,int pack,float* Y2,float* part) {
    gemm_m<64><<<dim3(R/64, O/64), 256, 0, stream>>>(p0,w0,st0,a0,x0, p1,w1,st1,a1,x1,
        p2,w2,st2,a2,x2, addp,addst, W,bias,resid, Y,Cin,O,pack,Y2,part);
  };
  auto g32 = [&](const float* p0,int w0,const float* st0,int a0,int x0,
                 const float* p1,int w1,const float* st1,int a1,int x1,
                 const float* p2,int w2,const float* st2,int a2,int x2,
                 const float* addp,const float* addst,
                 const float* W,const float* bias,const float* resid,
                 float* Y,int R,int Cin,int O,int pack,float* Y2,float* part) {
    gemm_m<32><<<dim3(R/32, O/64), 256, 0, stream>>>(p0,w0,st0,a0,x0, p1,w1,st1,a1,x1,
        p2,w2,st2,a2,x2, addp,addst, W,bias,resid, Y,Cin,O,pack,Y2,part);
  };
  auto statsF = [&](float* stat, int O, int NB, int nblk, int count) {
    gm_final_f<<<(NB*O + 7)/8, 256, 0, stream>>>(PARTF, stat, O, NB, nblk, count);
  };
  auto statsD = [&](float* stat, int O, int NB, int nblk, int count) {
    gm_final<<<(NB*O + 7)/8, 256, 0, stream>>>(PART, stat, O, NB, nblk, count);
  };
  auto gathermax = [&](const float* G, float* mx, int Cc, float* stat) {
    gather_max_partial<<<R2/4, 256, 0, stream>>>(G, IDX, mx, PART, Cc);
    statsD(stat, Cc, 4, 512, 2048*9);
  };

  prep_weights<<<256, 256, 0, stream>>>(conv1w, conv2w, a1w1, a1w2, a2w1, a2w2, gw2,
                                        wk, bk, wv, bv,
                                        DW_A1, W_A1R, DW_A2, W_A2R, W_G2R, DW_C1, DW_C2,
                                        W_KV, B_KV);

  // ===== merged branch section (both descs, R2 = 8192 rows, 4 instances) =====
  transpose2<<<dim3(2048/32, 128/32, 4), dim3(32, 8), 0, stream>>>(desc0, desc1, FT, 128, 2048);
  knn2_kernel<<<2048, 256, 0, stream>>>(coords0, coords1, IDX, COSV);
  // annu1
  g64(FT,128,nullptr,0,0, nullptr,0,nullptr,0,0, nullptr,0,nullptr,0,0, nullptr,nullptr,
      DW_A1, nullptr, nullptr, BIG, R2, 128, 512, 0, nullptr, nullptr);
  combine_annu<<<R2/4, 256, 0, stream>>>(BIG, IDX, a1b1, ABUF, PART);
  statsD(ST_T, 128, 4, 512, 2048*3);
  g32(ABUF,384,ST_T,1,128, nullptr,0,nullptr,0,0, nullptr,0,nullptr,0,0, nullptr,nullptr,
      W_A1R, a1b2, nullptr, X1B, R2, 384, 128, 0, nullptr, PARTF);
  statsF(ST_X1B, 128, 4, 64, 2048);
  // f_ang (idx1 == idx2)
  cos_conv<<<R2/16, 256, 0, stream>>>(COSV, gw1, gb1, ABUF, PART);
  statsD(ST_T, 128, 4, 128, 2048*3);
  g32(ABUF,384,ST_T,1,128, nullptr,0,nullptr,0,0, nullptr,0,nullptr,0,0, nullptr,nullptr,
      W_G2R, gb2, nullptr, FANG, R2, 384, 128, 0, nullptr, PARTF);
  statsF(ST_FANG, 128, 4, 64, 2048);
  // annu2 (X1B raw, normed in staging)
  g64(X1B,128,ST_X1B,1,128, nullptr,0,nullptr,0,0, nullptr,0,nullptr,0,0, nullptr,nullptr,
      DW_A2, nullptr, nullptr, BIG, R2, 128, 512, 0, nullptr, nullptr);
  combine_annu<<<R2/4, 256, 0, stream>>>(BIG, IDX, a2b1, ABUF, PART);
  statsD(ST_T, 128, 4, 512, 2048*3);
  g32(ABUF,384,ST_T,1,128, nullptr,0,nullptr,0,0, nullptr,0,nullptr,0,0, nullptr,nullptr,
      W_A2R, a2b2, nullptr, X2B, R2, 384, 128, 0, nullptr, PARTF);
  statsF(ST_X2B, 128, 4, 64, 2048);
  // x3 = conv3 @ [x0 | n(x1)+n(fang) | n(x2)+n(fang)]
  g32(FT,128,nullptr,0,0, X1B,128,ST_X1B,1,128, X2B,128,ST_X2B,1,128, FANG,ST_FANG,
      conv3w, nullptr, nullptr, X3A, R2, 384, 128, 0, nullptr, PARTF);
  statsF(ST_X3A, 128, 4, 64, 2048);
  // x1o
  g64(FT,128,nullptr,0,0, nullptr,0,nullptr,0,0, nullptr,0,nullptr,0,0, nullptr,nullptr,
      DW_C1, nullptr, nullptr, BIG, R2, 128, 256, 0, nullptr, nullptr);
  gathermax(BIG, X1O, 128, ST_X1O);
  // x2o (X1O = raw max, normed lrelu in staging)
  g64(X1O,128,ST_X1O,2,128, nullptr,0,nullptr,0,0, nullptr,0,nullptr,0,0, nullptr,nullptr,
      DW_C2, nullptr, nullptr, BIG, R2, 128, 512, 0, nullptr, nullptr);
  gathermax(BIG, AB2, 256, ST_AB);
  // x3o = conv3o @ [x0 | n(x1o) | n(x2o)]
  g32(FT,128,nullptr,0,0, X1O,128,ST_X1O,2,128, AB2,256,ST_AB,2,256, nullptr,nullptr,
      conv3ow, nullptr, nullptr, X3O, R2, 512, 128, 0, nullptr, PARTF);
  statsF(ST_X3O, 128, 4, 64, 2048);
  norm_add2<<<(R2*128 + 255)/256, 256, 0, stream>>>(X3O, SA, ST_X3O, X3A, ST_X3A, R2*128);

  // ===== cross-attention props (rows 4096 each) =====
  float* SA0 = SA;
  float* SA1 = SA + (size_t)4096*128;
  auto prop = [&](const float* xin, const float* src, float* dst) {
    g32(xin,128,nullptr,0,0, nullptr,0,nullptr,0,0, nullptr,0,nullptr,0,0, nullptr,nullptr,
        wq, bq, nullptr, X1B, 4096, 128, 128, 1, nullptr, nullptr);                  // packed Q
    g32(src,128,nullptr,0,0, nullptr,0,nullptr,0,0, nullptr,0,nullptr,0,0, nullptr,nullptr,
        W_KV, B_KV, nullptr, X2B, 4096, 128, 256, 2, X3A, nullptr);                  // packed K + V
    attn_part<<<dim3(2048/64, SPLITK, 8), 256, 0, stream>>>(X1B, X2B, X3A, OP, MLB);
    attn_merge<<<(8*2048*16 + 255)/256, 256, 0, stream>>>(OP, MLB, FANG);
    g32(FANG,128,nullptr,0,0, nullptr,0,nullptr,0,0, nullptr,0,nullptr,0,0, nullptr,nullptr,
        wm, bm, nullptr, X1O, 4096, 128, 128, 0, nullptr, nullptr);
    g32(xin,128,nullptr,0,0, X1O,128,nullptr,0,0, nullptr,0,nullptr,0,0, nullptr,nullptr,
        mw1, mb1, nullptr, ABUF, 4096, 256, 256, 0, nullptr, PARTF);
    statsF(ST_T, 256, 2, 64, 2048);
    g32(ABUF,256,ST_T,1,256, nullptr,0,nullptr,0,0, nullptr,0,nullptr,0,0, nullptr,nullptr,
        mw2, mb2, xin, dst, 4096, 256, 128, 0, nullptr, nullptr);
  };

  prop(SA0, SA1, XF0);
  prop(SA1, XF0, XF1);

  transpose_k<<<dim3(128/32, 2048/32, 2), dim3(32, 8), 0, stream>>>(XF0, (float*)d_out, 2048, 128);
  transpose_k<<<dim3(128/32, 2048/32, 2), dim3(32, 8), 0, stream>>>(XF1, (float*)d_out + (size_t)4096*128, 2048, 128);
}